// Round 7
// baseline (326.347 us; speedup 1.0000x reference)
//
#include <hip/hip_runtime.h>
#include <hip/hip_bf16.h>
#include <math.h>

// ---------------------------------------------------------------------------
// LBANP encoder layer on MI355X (gfx950).
// Round 7: kv256p v2 — faithful m201-style phase discipline: per-phase
// {ds_reads; [stage whole next tile @p0]; barrier; lgkmcnt(0)+sched_barrier;
// setprio(1); 16 MFMA; setprio(0); barrier}; vmcnt(0) only at tile end
// (loads are 4 phases old by then). B-frags held in registers per K-tile.
// ---------------------------------------------------------------------------

typedef __attribute__((ext_vector_type(8))) short bf16x8;   // 8 x bf16 (4 VGPRs)
typedef __attribute__((ext_vector_type(4))) float f32x4;

#define DEVI __device__ __forceinline__

DEVI void load_lds16(const void* g, void* l) {
  __builtin_amdgcn_global_load_lds(
      (const __attribute__((address_space(1))) void*)g,
      (__attribute__((address_space(3))) void*)l, 16, 0, 0);
}

DEVI short bfbits(float x) {
  __hip_bfloat16 h = __float2bfloat16(x);
  return *reinterpret_cast<short*>(&h);
}

// ---------------------------------------------------------------------------
// GEMM: C[M,N] = A[M,K](bf16) * Bt[N,K](bf16)^T  (+ bias [+ residual])
// EPI 0: write bf16, no bias.  EPI 1: f32 = acc + bias.  EPI 2: f32 = acc+bias+res.
// 128x128 tile, 2-phase dbuf, slot-XOR swizzle, XCD swizzle.
// ---------------------------------------------------------------------------
template <int EPI>
__global__ __launch_bounds__(256) void gemm_bt(
    const __hip_bfloat16* __restrict__ A, const __hip_bfloat16* __restrict__ Bt,
    float* __restrict__ Cf, __hip_bfloat16* __restrict__ Cb,
    const float* __restrict__ bias, const float* __restrict__ res,
    int M, int N, int K) {
  const int nwg = gridDim.x * gridDim.y;
  const int lid = blockIdx.y * gridDim.x + blockIdx.x;
  const int work = (lid & 7) * (nwg >> 3) + (lid >> 3);
  const int n0 = (work % gridDim.x) * 128;
  const int m0 = (work / gridDim.x) * 128;

  const int t = threadIdx.x;
  const int w = t >> 6, l = t & 63;
  const int lr = l & 15, lk = l >> 4;
  const int wm = (w >> 1) * 64, wn = (w & 1) * 64;
  __shared__ __hip_bfloat16 Al[2][128 * 32];
  __shared__ __hip_bfloat16 Bl[2][128 * 32];

  f32x4 acc[4][4];
  const f32x4 z = {0.f, 0.f, 0.f, 0.f};
#pragma unroll
  for (int i = 0; i < 4; ++i)
#pragma unroll
    for (int j = 0; j < 4; ++j) acc[i][j] = z;

  const int srow = w * 16 + (l >> 2);
  const int scol = ((l & 3) ^ ((l >> 3) & 3)) * 8;
  const __hip_bfloat16* Ag = A + (size_t)(m0 + srow) * K + scol;
  const __hip_bfloat16* Bg = Bt + (size_t)(n0 + srow) * K + scol;

#define STAGE(buf, k0)                                                   \
  {                                                                      \
    load_lds16(Ag + (k0), (char*)Al[buf] + w * 1024);                    \
    load_lds16(Ag + (size_t)64 * K + (k0), (char*)Al[buf] + 4096 + w * 1024); \
    load_lds16(Bg + (k0), (char*)Bl[buf] + w * 1024);                    \
    load_lds16(Bg + (size_t)64 * K + (k0), (char*)Bl[buf] + 4096 + w * 1024); \
  }

  STAGE(0, 0);
  __syncthreads();
  int cur = 0;
  const int rs = (lk ^ ((lr >> 1) & 3)) * 16;
  for (int k0 = 0; k0 < K; k0 += 32) {
    if (k0 + 32 < K) STAGE(cur ^ 1, k0 + 32);
    bf16x8 af[4], bfr[4];
#pragma unroll
    for (int i = 0; i < 4; ++i)
      af[i] = *(const bf16x8*)((const char*)Al[cur] + ((wm + i * 16 + lr) * 64 + rs));
#pragma unroll
    for (int j = 0; j < 4; ++j)
      bfr[j] = *(const bf16x8*)((const char*)Bl[cur] + ((wn + j * 16 + lr) * 64 + rs));
#pragma unroll
    for (int i = 0; i < 4; ++i)
#pragma unroll
      for (int j = 0; j < 4; ++j)
        acc[i][j] = __builtin_amdgcn_mfma_f32_16x16x32_bf16(af[i], bfr[j], acc[i][j], 0, 0, 0);
    __syncthreads();
    cur ^= 1;
  }
#undef STAGE

#pragma unroll
  for (int i = 0; i < 4; ++i) {
    const int row = m0 + wm + i * 16 + lk * 4;
#pragma unroll
    for (int j = 0; j < 4; ++j) {
      const int col = n0 + wn + j * 16 + lr;
#pragma unroll
      for (int r = 0; r < 4; ++r) {
        float v = acc[i][j][r];
        const size_t idx = (size_t)(row + r) * N + col;
        if (EPI == 0) {
          Cb[idx] = __float2bfloat16(v);
        } else {
          v += bias[col];
          if (EPI == 2) v += res[idx];
          Cf[idx] = v;
        }
      }
    }
  }
}

// ---------------------------------------------------------------------------
// kv256p v2: KV projection, 256x256 tile, N=1024, K=512 fixed.
// cols 0..511 -> Kb[M,512]; cols 512..1023 -> Vt (transposed, 8B packs).
// 8 waves (2Mx4N), per-wave C = 128x64. LDS: 2 bufs x (A[256][64]+B[256][64])
// = 128 KiB, slot-XOR swizzled (slot ^= row&7). Phase discipline per m201.
// ---------------------------------------------------------------------------
__global__ __launch_bounds__(512) void kv256p_kernel(
    const __hip_bfloat16* __restrict__ A, const __hip_bfloat16* __restrict__ Bt,
    __hip_bfloat16* __restrict__ Kb, __hip_bfloat16* __restrict__ Vt,
    int rpb_shift) {
  const int nwg = gridDim.x;
  const int lid = blockIdx.x;
  const int work = (lid & 7) * (nwg >> 3) + (lid >> 3);   // nwg % 8 == 0
  const int m0 = (work >> 2) * 256;
  const int n0 = (work & 3) * 256;
  const int t = threadIdx.x;
  const int w = t >> 6, l = t & 63;
  const int lr = l & 15, lk = l >> 4;
  const int wr = w >> 2, wc = w & 3;          // 2 (M) x 4 (N) wave grid
  __shared__ char lds[131072];                // [d][A|B][256 rows][128 B]

  f32x4 acc[8][4];
  const f32x4 z = {0.f, 0.f, 0.f, 0.f};
#pragma unroll
  for (int i = 0; i < 8; ++i)
#pragma unroll
    for (int j = 0; j < 4; ++j) acc[i][j] = z;

  // staging: lane covers row +(l>>3), slot l&7; source slot pre-swizzled
  const int srow8 = l >> 3;
  const int sc8 = ((l & 7) ^ srow8) * 8;

  // stage the ENTIRE K-tile kt (A 256 rows + B 256 rows) into buf d_:
  // 8 global_load_lds per thread.
#define STAGE_TILE(d_, kt_)                                                   \
  {                                                                           \
    char* ab_ = lds + (d_) * 65536;                                           \
    _Pragma("unroll")                                                         \
    for (int c_ = 0; c_ < 4; ++c_) {                                          \
      const int rb_ = c_ * 64 + w * 8;                                        \
      load_lds16(A + (size_t)(m0 + rb_ + srow8) * 512 + (kt_) * 64 + sc8,     \
                 ab_ + rb_ * 128);                                            \
      load_lds16(Bt + (size_t)(n0 + rb_ + srow8) * 512 + (kt_) * 64 + sc8,    \
                 ab_ + 32768 + rb_ * 128);                                    \
    }                                                                         \
  }

  STAGE_TILE(0, 0);
  asm volatile("s_waitcnt vmcnt(0)" ::: "memory");
  __syncthreads();                            // tile 0 resident

  for (int tt = 0; tt < 8; ++tt) {            // K = 512 = 8 x BK=64
    const int d = tt & 1;
    const char* Ab = lds + d * 65536;
    const char* Bb = Ab + 32768;
    bf16x8 bfr[4][2];

    // ---- phase 0: 12 ds_reads (8 B + 4 A) + full next-tile stage ----
#pragma unroll
    for (int j = 0; j < 4; ++j) {
      const int br = wc * 64 + j * 16 + lr;
#pragma unroll
      for (int ks = 0; ks < 2; ++ks)
        bfr[j][ks] = *(const bf16x8*)(Bb + br * 128 + (((ks * 4 + lk) ^ (br & 7)) * 16));
    }
    bf16x8 a0[2][2];
#pragma unroll
    for (int ii = 0; ii < 2; ++ii) {
      const int ar = wr * 128 + ii * 16 + lr;
#pragma unroll
      for (int ks = 0; ks < 2; ++ks)
        a0[ii][ks] = *(const bf16x8*)(Ab + ar * 128 + (((ks * 4 + lk) ^ (ar & 7)) * 16));
    }
    if (tt < 7) STAGE_TILE(d ^ 1, tt + 1);
    asm volatile("s_waitcnt lgkmcnt(8)" ::: "memory");
    __builtin_amdgcn_s_barrier();
    asm volatile("s_waitcnt lgkmcnt(0)" ::: "memory");
    __builtin_amdgcn_sched_barrier(0);
    __builtin_amdgcn_s_setprio(1);
#pragma unroll
    for (int ii = 0; ii < 2; ++ii)
#pragma unroll
      for (int j = 0; j < 4; ++j) {
        acc[ii][j] = __builtin_amdgcn_mfma_f32_16x16x32_bf16(a0[ii][0], bfr[j][0], acc[ii][j], 0, 0, 0);
        acc[ii][j] = __builtin_amdgcn_mfma_f32_16x16x32_bf16(a0[ii][1], bfr[j][1], acc[ii][j], 0, 0, 0);
      }
    __builtin_amdgcn_s_setprio(0);
    __builtin_amdgcn_s_barrier();

    // ---- phases 1..3: 4 A ds_reads + 16 MFMA each ----
#pragma unroll
    for (int p = 1; p < 4; ++p) {
      bf16x8 af[2][2];
#pragma unroll
      for (int ii = 0; ii < 2; ++ii) {
        const int ar = wr * 128 + (p * 2 + ii) * 16 + lr;
#pragma unroll
        for (int ks = 0; ks < 2; ++ks)
          af[ii][ks] = *(const bf16x8*)(Ab + ar * 128 + (((ks * 4 + lk) ^ (ar & 7)) * 16));
      }
      __builtin_amdgcn_s_barrier();
      asm volatile("s_waitcnt lgkmcnt(0)" ::: "memory");
      __builtin_amdgcn_sched_barrier(0);
      __builtin_amdgcn_s_setprio(1);
#pragma unroll
      for (int ii = 0; ii < 2; ++ii)
#pragma unroll
        for (int j = 0; j < 4; ++j) {
          acc[p * 2 + ii][j] = __builtin_amdgcn_mfma_f32_16x16x32_bf16(
              af[ii][0], bfr[j][0], acc[p * 2 + ii][j], 0, 0, 0);
          acc[p * 2 + ii][j] = __builtin_amdgcn_mfma_f32_16x16x32_bf16(
              af[ii][1], bfr[j][1], acc[p * 2 + ii][j], 0, 0, 0);
        }
      __builtin_amdgcn_s_setprio(0);
      if (p == 3 && tt < 7)
        asm volatile("s_waitcnt vmcnt(0)" ::: "memory");  // next tile's loads are ~4 phases old
      __builtin_amdgcn_s_barrier();
    }
  }
#undef STAGE_TILE

  // epilogue: C/D layout col=lr, row=lk*4+r (within 16x16 frag)
  if (n0 < 512) {
#pragma unroll
    for (int i = 0; i < 8; ++i) {
      const int row0 = m0 + wr * 128 + i * 16 + lk * 4;
#pragma unroll
      for (int j = 0; j < 4; ++j) {
        const int col = n0 + wc * 64 + j * 16 + lr;
#pragma unroll
        for (int r = 0; r < 4; ++r)
          Kb[(size_t)(row0 + r) * 512 + col] = __float2bfloat16(acc[i][j][r]);
      }
    }
  } else {
    const int rpb = 1 << rpb_shift;
#pragma unroll
    for (int i = 0; i < 8; ++i) {
      const int row0 = m0 + wr * 128 + i * 16 + lk * 4;
      const int b = row0 >> rpb_shift;
      const int key0 = row0 & (rpb - 1);
#pragma unroll
      for (int j = 0; j < 4; ++j) {
        const int c = n0 - 512 + wc * 64 + j * 16 + lr;
        const int hh = c >> 6, dh = c & 63;
        short4 pk;
        pk.x = bfbits(acc[i][j][0]);
        pk.y = bfbits(acc[i][j][1]);
        pk.z = bfbits(acc[i][j][2]);
        pk.w = bfbits(acc[i][j][3]);
        *(short4*)&Vt[((size_t)((b * 8 + hh) * 64 + dh) << rpb_shift) + key0] = pk;
      }
    }
  }
}

// ---------------------------------------------------------------------------
// V transpose (self-attn only): KV[b*rows+key][512+h*64+dh] -> Vt[(b*8+h)*64+dh][key]
// ---------------------------------------------------------------------------
__global__ __launch_bounds__(256) void vt_kernel(
    const __hip_bfloat16* __restrict__ KV, __hip_bfloat16* __restrict__ Vt,
    int rows_per_b) {
  __shared__ __hip_bfloat16 tl[64][72];
  const int k0 = blockIdx.x * 64, h = blockIdx.y, b = blockIdx.z;
  const int t = threadIdx.x;
#pragma unroll
  for (int p = 0; p < 2; ++p) {
    const int idx = p * 256 + t;
    const int row = idx >> 3, c8 = idx & 7;
    bf16x8 v = *(const bf16x8*)&KV[(size_t)(b * rows_per_b + k0 + row) * 1024 +
                                   512 + h * 64 + c8 * 8];
    const __hip_bfloat16* ve = (const __hip_bfloat16*)&v;
#pragma unroll
    for (int j = 0; j < 8; ++j) tl[c8 * 8 + j][row] = ve[j];
  }
  __syncthreads();
  const size_t vtbase = (size_t)(b * 8 + h) * 64;
#pragma unroll
  for (int p = 0; p < 2; ++p) {
    const int idx = p * 256 + t;
    const int dh = idx >> 3, c8 = idx & 7;
    bf16x8 v = *(const bf16x8*)&tl[dh][c8 * 8];
    *(bf16x8*)&Vt[(vtbase + dh) * rows_per_b + k0 + c8 * 8] = v;
  }
}

// ---------------------------------------------------------------------------
// Key-split flash attention, static-max softmax (data-safe: |s|<~4 << 88).
// Kb row stride = kstride (512 cross / 1024 self-interleaved).
// ---------------------------------------------------------------------------
__global__ __launch_bounds__(256) void attn_split_kernel(
    const __hip_bfloat16* __restrict__ Q, const __hip_bfloat16* __restrict__ Kb,
    const __hip_bfloat16* __restrict__ Vt,
    float* __restrict__ Opart, float* __restrict__ Lv,
    int chunk, int rows_per_b, int kstride, int S) {
  const float SC2 = 0.18033688f;   // 0.125 * log2(e)
  const int h = blockIdx.x, b = blockIdx.y, s = blockIdx.z;
  const int t = threadIdx.x;
  const int w = t >> 6, l = t & 63;
  const int lr = l & 15, lk = l >> 4;
  __shared__ __hip_bfloat16 Kl[64 * 64];
  __shared__ __hip_bfloat16 Vl[64 * 64];
  __shared__ __hip_bfloat16 Pl[4][32 * 64];

  bf16x8 qf[2][2];
#pragma unroll
  for (int mf = 0; mf < 2; ++mf)
#pragma unroll
    for (int kf = 0; kf < 2; ++kf)
      qf[mf][kf] = *(const bf16x8*)&Q[(size_t)(b * 128 + w * 32 + mf * 16 + lr) * 512 +
                                      h * 64 + kf * 32 + lk * 8];

  f32x4 o[2][4];
  const f32x4 z = {0.f, 0.f, 0.f, 0.f};
#pragma unroll
  for (int mf = 0; mf < 2; ++mf)
#pragma unroll
    for (int nf = 0; nf < 4; ++nf) o[mf][nf] = z;
  float lsum[2][4];
#pragma unroll
  for (int mf = 0; mf < 2; ++mf)
#pragma unroll
    for (int r = 0; r < 4; ++r) lsum[mf][r] = 0.f;

  const __hip_bfloat16* kvb = Kb + (size_t)b * rows_per_b * kstride;
  const __hip_bfloat16* vtb = Vt + (size_t)(b * 8 + h) * 64 * rows_per_b;
  char* pw = (char*)Pl[w];
  const int srow = l >> 3;
  const int sslot = (l & 7) ^ srow;
  const int jend = s * chunk + chunk;

  for (int j0 = s * chunk; j0 < jend; j0 += 64) {
    __syncthreads();
#pragma unroll
    for (int p = 0; p < 2; ++p) {
      const int row = p * 32 + w * 8 + srow;
      load_lds16(&kvb[(size_t)(j0 + row) * kstride + h * 64 + sslot * 8],
                 (char*)Kl + p * 4096 + w * 1024);
      load_lds16(&vtb[(size_t)row * rows_per_b + j0 + sslot * 8],
                 (char*)Vl + p * 4096 + w * 1024);
    }
    __syncthreads();

    f32x4 sc[2][4];
#pragma unroll
    for (int mf = 0; mf < 2; ++mf)
#pragma unroll
      for (int nf = 0; nf < 4; ++nf) sc[mf][nf] = z;
    __builtin_amdgcn_s_setprio(1);
#pragma unroll
    for (int kf = 0; kf < 2; ++kf) {
      bf16x8 kb[4];
#pragma unroll
      for (int nf = 0; nf < 4; ++nf) {
        const int key = nf * 16 + lr;
        kb[nf] = *(const bf16x8*)((char*)Kl +
                  (key * 128 + (((kf * 4 + lk) ^ (key & 7)) * 16)));
      }
#pragma unroll
      for (int mf = 0; mf < 2; ++mf)
#pragma unroll
        for (int nf = 0; nf < 4; ++nf)
          sc[mf][nf] = __builtin_amdgcn_mfma_f32_16x16x32_bf16(qf[mf][kf], kb[nf], sc[mf][nf], 0, 0, 0);
    }
    __builtin_amdgcn_s_setprio(0);

#pragma unroll
    for (int mf = 0; mf < 2; ++mf)
#pragma unroll
      for (int nf = 0; nf < 4; ++nf)
#pragma unroll
        for (int r = 0; r < 4; ++r) {
          const float p = exp2f(sc[mf][nf][r] * SC2);
          sc[mf][nf][r] = p;
          lsum[mf][r] += p;
        }

#pragma unroll
    for (int mf = 0; mf < 2; ++mf)
#pragma unroll
      for (int r = 0; r < 4; ++r) {
        const int prow = mf * 16 + lk * 4 + r;
#pragma unroll
        for (int nf = 0; nf < 4; ++nf) {
          const int pcol = nf * 16 + lr;
          *(__hip_bfloat16*)(pw + ((prow * 128 + pcol * 2) ^ ((prow & 7) << 4))) =
              __float2bfloat16(sc[mf][nf][r]);
        }
      }

    __builtin_amdgcn_s_setprio(1);
#pragma unroll
    for (int kf = 0; kf < 2; ++kf) {
      bf16x8 pa[2], vb[4];
#pragma unroll
      for (int mf = 0; mf < 2; ++mf) {
        const int prow = mf * 16 + lr;
        pa[mf] = *(const bf16x8*)(pw + ((prow * 128 + (kf * 4 + lk) * 16) ^ ((prow & 7) << 4)));
      }
#pragma unroll
      for (int nf = 0; nf < 4; ++nf) {
        const int dh = nf * 16 + lr;
        vb[nf] = *(const bf16x8*)((char*)Vl +
                  (dh * 128 + (((kf * 4 + lk) ^ (dh & 7)) * 16)));
      }
#pragma unroll
      for (int mf = 0; mf < 2; ++mf)
#pragma unroll
        for (int nf = 0; nf < 4; ++nf)
          o[mf][nf] = __builtin_amdgcn_mfma_f32_16x16x32_bf16(pa[mf], vb[nf], o[mf][nf], 0, 0, 0);
    }
    __builtin_amdgcn_s_setprio(0);
  }

  const int part = (b * 8 + h) * S + s;
  float* op = Opart + (size_t)part * 8192;
#pragma unroll
  for (int mf = 0; mf < 2; ++mf)
#pragma unroll
    for (int r = 0; r < 4; ++r) {
      float ls = lsum[mf][r];
      ls += __shfl_xor(ls, 1);
      ls += __shfl_xor(ls, 2);
      ls += __shfl_xor(ls, 4);
      ls += __shfl_xor(ls, 8);
      const int row = w * 32 + mf * 16 + lk * 4 + r;
#pragma unroll
      for (int nf = 0; nf < 4; ++nf)
        op[(size_t)row * 64 + nf * 16 + lr] = o[mf][nf][r];
      if (lr == 0) Lv[(size_t)part * 128 + row] = ls;
    }
}

__global__ __launch_bounds__(256) void attn_combine_kernel(
    const float* __restrict__ Opart, const float* __restrict__ Lv,
    __hip_bfloat16* __restrict__ O, int S) {
  const int row = blockIdx.x;
  const int b = row >> 7, i = row & 127;
  for (int c = threadIdx.x; c < 512; c += 256) {
    const int h = c >> 6, dh = c & 63;
    const int pbase = (b * 8 + h) * S;
    float L = 0.f, val = 0.f;
    for (int s = 0; s < S; ++s) {
      L += Lv[(size_t)(pbase + s) * 128 + i];
      val += Opart[((size_t)(pbase + s) * 128 + i) * 64 + dh];
    }
    O[(size_t)row * 512 + c] = __float2bfloat16(val / L);
  }
}

// ---------------------------------------------------------------------------
__global__ __launch_bounds__(256) void ln_kernel(
    const float* __restrict__ x, const float* __restrict__ w,
    const float* __restrict__ bb, __hip_bfloat16* __restrict__ y) {
  const int row = blockIdx.x;
  const int t = threadIdx.x;
  const float2 v = *(const float2*)&x[(size_t)row * 512 + t * 2];
  float s = v.x + v.y;
  float sq = v.x * v.x + v.y * v.y;
#pragma unroll
  for (int d = 1; d < 64; d <<= 1) {
    s += __shfl_xor(s, d);
    sq += __shfl_xor(sq, d);
  }
  __shared__ float ss[4], ssq[4];
  if ((t & 63) == 0) { ss[t >> 6] = s; ssq[t >> 6] = sq; }
  __syncthreads();
  s = ss[0] + ss[1] + ss[2] + ss[3];
  sq = ssq[0] + ssq[1] + ssq[2] + ssq[3];
  const float mean = s * (1.f / 512.f);
  const float var = sq * (1.f / 512.f) - mean * mean;
  const float rstd = rsqrtf(var + 1e-5f);
  const float2 wv = *(const float2*)&w[t * 2];
  const float2 bv = *(const float2*)&bb[t * 2];
  y[(size_t)row * 512 + t * 2] = __float2bfloat16((v.x - mean) * rstd * wv.x + bv.x);
  y[(size_t)row * 512 + t * 2 + 1] = __float2bfloat16((v.y - mean) * rstd * wv.y + bv.y);
}

// ---------------------------------------------------------------------------
struct WcvtDesc { const float* src[10]; __hip_bfloat16* dst[10]; };

__global__ __launch_bounds__(256) void wcvt_all_kernel(WcvtDesc d) {
  int tile = blockIdx.x;
  const int set = tile >> 12;
  tile &= 4095;
  int wi, K, N, base;
  if (tile < 256)       { wi = 0; K = 512;  N = 512;  base = 0; }
  else if (tile < 768)  { wi = 1; K = 512;  N = 1024; base = 256; }
  else if (tile < 1024) { wi = 2; K = 512;  N = 512;  base = 768; }
  else if (tile < 3072) { wi = 3; K = 512;  N = 4096; base = 1024; }
  else                  { wi = 4; K = 2048; N = 512;  base = 3072; }
  wi += set * 5;
  const int rel = tile - base;
  const int ntx = N >> 5;
  const int n0 = (rel % ntx) * 32, k0 = (rel / ntx) * 32;
  const float* W = d.src[wi];
  __hip_bfloat16* Wt = d.dst[wi];
  __shared__ float tl[32][33];
  const int tx = threadIdx.x & 31, ty = threadIdx.x >> 5;
#pragma unroll
  for (int j = 0; j < 4; ++j)
    tl[ty + j * 8][tx] = W[(size_t)(k0 + ty + j * 8) * N + n0 + tx];
  __syncthreads();
#pragma unroll
  for (int j = 0; j < 4; ++j)
    Wt[(size_t)(n0 + ty + j * 8) * K + k0 + tx] = __float2bfloat16(tl[tx][ty + j * 8]);
}

// ---------------------------------------------------------------------------
__global__ __launch_bounds__(256) void geglu_kernel(
    const float* __restrict__ hh, __hip_bfloat16* __restrict__ out) {
  const int i = blockIdx.x * 256 + threadIdx.x;
  const int row = i >> 11, col = i & 2047;
  const float a = hh[(size_t)row * 4096 + col];
  const float g = hh[(size_t)row * 4096 + 2048 + col];
  const float ge = 0.5f * g * (1.f + erff(g * 0.70710678118f));
  out[i] = __float2bfloat16(a * ge);
}

// ---------------------------------------------------------------------------
extern "C" void kernel_launch(void* const* d_in, const int* in_sizes, int n_in,
                              void* d_out, int out_size, void* d_ws, size_t ws_size,
                              hipStream_t stream) {
  (void)in_sizes; (void)n_in; (void)out_size; (void)ws_size;
  const float* context = (const float*)d_in[0];
  const float* latents = (const float*)d_in[1];
  const float* ca_ln_w = (const float*)d_in[2];
  const float* ca_ln_b = (const float*)d_in[3];
  const float* ca_lnc_w = (const float*)d_in[4];
  const float* ca_lnc_b = (const float*)d_in[5];
  const float* ca_wq = (const float*)d_in[6];
  const float* ca_wkv = (const float*)d_in[7];
  const float* ca_wo = (const float*)d_in[8];
  const float* ca_bo = (const float*)d_in[9];
  const float* cf_ln_w = (const float*)d_in[10];
  const float* cf_ln_b = (const float*)d_in[11];
  const float* cf_w1 = (const float*)d_in[12];
  const float* cf_b1 = (const float*)d_in[13];
  const float* cf_w2 = (const float*)d_in[14];
  const float* cf_b2 = (const float*)d_in[15];
  const float* sa_ln_w = (const float*)d_in[16];
  const float* sa_ln_b = (const float*)d_in[17];
  const float* sa_wq = (const float*)d_in[18];
  const float* sa_wkv = (const float*)d_in[19];
  const float* sa_wo = (const float*)d_in[20];
  const float* sa_bo = (const float*)d_in[21];
  const float* lf_ln_w = (const float*)d_in[22];
  const float* lf_ln_b = (const float*)d_in[23];
  const float* lf_w1 = (const float*)d_in[24];
  const float* lf_b1 = (const float*)d_in[25];
  const float* lf_w2 = (const float*)d_in[26];
  const float* lf_b2 = (const float*)d_in[27];

  typedef __hip_bfloat16 bf;
  char* ws = (char*)d_ws;
  size_t off = 0;
  auto alloc = [&](size_t bytes) -> void* {
    void* p = ws + off;
    off += (bytes + 255) & ~(size_t)255;
    return p;
  };
  bf* wq1t = (bf*)alloc((size_t)512 * 512 * 2);
  bf* wkv1t = (bf*)alloc((size_t)1024 * 512 * 2);
  bf* wo1t = (bf*)alloc((size_t)512 * 512 * 2);
  bf* w1ct = (bf*)alloc((size_t)4096 * 512 * 2);
  bf* w2ct = (bf*)alloc((size_t)512 * 2048 * 2);
  bf* wq2t = (bf*)alloc((size_t)512 * 512 * 2);
  bf* wkv2t = (bf*)alloc((size_t)1024 * 512 * 2);
  bf* wo2t = (bf*)alloc((size_t)512 * 512 * 2);
  bf* w1lt = (bf*)alloc((size_t)4096 * 512 * 2);
  bf* w2lt = (bf*)alloc((size_t)512 * 2048 * 2);
  bf* cn = (bf*)alloc((size_t)32768 * 512 * 2);     // 33.5 MB; multi-reused
  bf* kbuf = (bf*)alloc((size_t)32768 * 512 * 2);   // cross K [row][512]
  bf* vt = (bf*)alloc((size_t)64 * 64 * 4096 * 2);  // cross V^T
  bf* kv2b = (bf*)alloc((size_t)1024 * 1024 * 2);   // self KV interleaved
  bf* vt2 = (bf*)alloc((size_t)64 * 64 * 128 * 2);  // self V^T
  float* lv = (float*)alloc((size_t)1024 * 128 * 4);
  bf* xnb = (bf*)alloc((size_t)1024 * 512 * 2);
  bf* qb = (bf*)alloc((size_t)1024 * 512 * 2);
  bf* aob = (bf*)alloc((size_t)1024 * 512 * 2);
  bf* q2b = (bf*)alloc((size_t)1024 * 512 * 2);
  bf* ao2b = (bf*)alloc((size_t)1024 * 512 * 2);
  float* x1 = (float*)alloc((size_t)1024 * 512 * 4);
  float* x2 = (float*)alloc((size_t)1024 * 512 * 4);
  float* x3 = (float*)alloc((size_t)1024 * 512 * 4);
  bf* x2n = (bf*)alloc((size_t)1024 * 512 * 2);
  bf* x3n = (bf*)alloc((size_t)1024 * 512 * 2);
  float* opart = (float*)cn;                       // attn partials (<=33.5 MB)
  float* hb = (float*)cn;                          // FFN hidden (16.8 MB)
  bf* agb = (bf*)((char*)cn + 17 * 1024 * 1024);   // GEGLU out (4.2 MB)

  WcvtDesc wd;
  wd.src[0] = ca_wq;  wd.dst[0] = wq1t;
  wd.src[1] = ca_wkv; wd.dst[1] = wkv1t;
  wd.src[2] = ca_wo;  wd.dst[2] = wo1t;
  wd.src[3] = cf_w1;  wd.dst[3] = w1ct;
  wd.src[4] = cf_w2;  wd.dst[4] = w2ct;
  wd.src[5] = sa_wq;  wd.dst[5] = wq2t;
  wd.src[6] = sa_wkv; wd.dst[6] = wkv2t;
  wd.src[7] = sa_wo;  wd.dst[7] = wo2t;
  wd.src[8] = lf_w1;  wd.dst[8] = w1lt;
  wd.src[9] = lf_w2;  wd.dst[9] = w2lt;
  wcvt_all_kernel<<<8192, 256, 0, stream>>>(wd);

  // --- sublayer 1: cross attention ---
  ln_kernel<<<1024, 256, 0, stream>>>(latents, ca_ln_w, ca_ln_b, xnb);
  ln_kernel<<<32768, 256, 0, stream>>>(context, ca_lnc_w, ca_lnc_b, cn);
  gemm_bt<0><<<dim3(4, 8), 256, 0, stream>>>(xnb, wq1t, nullptr, qb, nullptr, nullptr, 1024, 512, 512);
  kv256p_kernel<<<512, 512, 0, stream>>>(cn, wkv1t, kbuf, vt, 12);
  attn_split_kernel<<<dim3(8, 8, 16), 256, 0, stream>>>(qb, kbuf, vt, opart, lv, 256, 4096, 512, 16);
  attn_combine_kernel<<<1024, 256, 0, stream>>>(opart, lv, aob, 16);
  gemm_bt<2><<<dim3(4, 8), 256, 0, stream>>>(aob, wo1t, x1, nullptr, ca_bo, latents, 1024, 512, 512);

  // --- sublayer 2: cross FFN (GEGLU) ---
  ln_kernel<<<1024, 256, 0, stream>>>(x1, cf_ln_w, cf_ln_b, xnb);
  gemm_bt<1><<<dim3(32, 8), 256, 0, stream>>>(xnb, w1ct, hb, nullptr, cf_b1, nullptr, 1024, 4096, 512);
  geglu_kernel<<<8192, 256, 0, stream>>>(hb, agb);
  gemm_bt<2><<<dim3(4, 8), 256, 0, stream>>>(agb, w2ct, x2, nullptr, cf_b2, x1, 1024, 512, 2048);

  // --- sublayer 3: latent self-attention (S=1, 128 keys) ---
  ln_kernel<<<1024, 256, 0, stream>>>(x2, sa_ln_w, sa_ln_b, x2n);
  gemm_bt<0><<<dim3(4, 8), 256, 0, stream>>>(x2n, wq2t, nullptr, q2b, nullptr, nullptr, 1024, 512, 512);
  gemm_bt<0><<<dim3(8, 8), 256, 0, stream>>>(x2n, wkv2t, nullptr, kv2b, nullptr, nullptr, 1024, 1024, 512);
  vt_kernel<<<dim3(2, 8, 8), 256, 0, stream>>>(kv2b, vt2, 128);
  attn_split_kernel<<<dim3(8, 8, 1), 256, 0, stream>>>(q2b, kv2b, vt2, opart, lv, 128, 128, 1024, 1);
  attn_combine_kernel<<<1024, 256, 0, stream>>>(opart, lv, ao2b, 1);
  gemm_bt<2><<<dim3(4, 8), 256, 0, stream>>>(ao2b, wo2t, x3, nullptr, sa_bo, x2, 1024, 512, 512);

  // --- sublayer 4: latent FFN (GEGLU) ---
  ln_kernel<<<1024, 256, 0, stream>>>(x3, lf_ln_w, lf_ln_b, x3n);
  gemm_bt<1><<<dim3(32, 8), 256, 0, stream>>>(x3n, w1lt, hb, nullptr, lf_b1, nullptr, 1024, 4096, 512);
  geglu_kernel<<<8192, 256, 0, stream>>>(hb, agb);
  gemm_bt<2><<<dim3(4, 8), 256, 0, stream>>>(agb, w2lt, (float*)d_out, nullptr, lf_b2, x3, 1024, 512, 2048);
}

// Round 8
// 284.728 us; speedup vs baseline: 1.1462x; 1.1462x over previous
//
#include <hip/hip_runtime.h>
#include <hip/hip_bf16.h>
#include <math.h>

// ---------------------------------------------------------------------------
// LBANP encoder layer on MI355X (gfx950).
// Round 8: revert KV projection to proven 128^2 2-phase structure with fused
// V-transpose epilogue (kv128); self-attn direct-write (no combine); merged
// leading LNs; split-K for the K=2048 FFN-down GEMMs.
// ---------------------------------------------------------------------------

typedef __attribute__((ext_vector_type(8))) short bf16x8;   // 8 x bf16 (4 VGPRs)
typedef __attribute__((ext_vector_type(4))) float f32x4;

#define DEVI __device__ __forceinline__

DEVI void load_lds16(const void* g, void* l) {
  __builtin_amdgcn_global_load_lds(
      (const __attribute__((address_space(1))) void*)g,
      (__attribute__((address_space(3))) void*)l, 16, 0, 0);
}

DEVI short bfbits(float x) {
  __hip_bfloat16 h = __float2bfloat16(x);
  return *reinterpret_cast<short*>(&h);
}

// ---------------------------------------------------------------------------
// GEMM: C[M,N] = A[M,K](bf16) * Bt[N,K](bf16)^T  (+ bias [+ residual])
// EPI 0: write bf16, no bias.  EPI 1: f32 = acc + bias.  EPI 2: f32 = acc+bias+res.
// 128x128 tile, 2-phase dbuf, slot-XOR swizzle, XCD swizzle.
// ---------------------------------------------------------------------------
template <int EPI>
__global__ __launch_bounds__(256) void gemm_bt(
    const __hip_bfloat16* __restrict__ A, const __hip_bfloat16* __restrict__ Bt,
    float* __restrict__ Cf, __hip_bfloat16* __restrict__ Cb,
    const float* __restrict__ bias, const float* __restrict__ res,
    int M, int N, int K) {
  const int nwg = gridDim.x * gridDim.y;
  const int lid = blockIdx.y * gridDim.x + blockIdx.x;
  const int work = (lid & 7) * (nwg >> 3) + (lid >> 3);
  const int n0 = (work % gridDim.x) * 128;
  const int m0 = (work / gridDim.x) * 128;

  const int t = threadIdx.x;
  const int w = t >> 6, l = t & 63;
  const int lr = l & 15, lk = l >> 4;
  const int wm = (w >> 1) * 64, wn = (w & 1) * 64;
  __shared__ __hip_bfloat16 Al[2][128 * 32];
  __shared__ __hip_bfloat16 Bl[2][128 * 32];

  f32x4 acc[4][4];
  const f32x4 z = {0.f, 0.f, 0.f, 0.f};
#pragma unroll
  for (int i = 0; i < 4; ++i)
#pragma unroll
    for (int j = 0; j < 4; ++j) acc[i][j] = z;

  const int srow = w * 16 + (l >> 2);
  const int scol = ((l & 3) ^ ((l >> 3) & 3)) * 8;
  const __hip_bfloat16* Ag = A + (size_t)(m0 + srow) * K + scol;
  const __hip_bfloat16* Bg = Bt + (size_t)(n0 + srow) * K + scol;

#define STAGE(buf, k0)                                                   \
  {                                                                      \
    load_lds16(Ag + (k0), (char*)Al[buf] + w * 1024);                    \
    load_lds16(Ag + (size_t)64 * K + (k0), (char*)Al[buf] + 4096 + w * 1024); \
    load_lds16(Bg + (k0), (char*)Bl[buf] + w * 1024);                    \
    load_lds16(Bg + (size_t)64 * K + (k0), (char*)Bl[buf] + 4096 + w * 1024); \
  }

  STAGE(0, 0);
  __syncthreads();
  int cur = 0;
  const int rs = (lk ^ ((lr >> 1) & 3)) * 16;
  for (int k0 = 0; k0 < K; k0 += 32) {
    if (k0 + 32 < K) STAGE(cur ^ 1, k0 + 32);
    bf16x8 af[4], bfr[4];
#pragma unroll
    for (int i = 0; i < 4; ++i)
      af[i] = *(const bf16x8*)((const char*)Al[cur] + ((wm + i * 16 + lr) * 64 + rs));
#pragma unroll
    for (int j = 0; j < 4; ++j)
      bfr[j] = *(const bf16x8*)((const char*)Bl[cur] + ((wn + j * 16 + lr) * 64 + rs));
#pragma unroll
    for (int i = 0; i < 4; ++i)
#pragma unroll
      for (int j = 0; j < 4; ++j)
        acc[i][j] = __builtin_amdgcn_mfma_f32_16x16x32_bf16(af[i], bfr[j], acc[i][j], 0, 0, 0);
    __syncthreads();
    cur ^= 1;
  }
#undef STAGE

#pragma unroll
  for (int i = 0; i < 4; ++i) {
    const int row = m0 + wm + i * 16 + lk * 4;
#pragma unroll
    for (int j = 0; j < 4; ++j) {
      const int col = n0 + wn + j * 16 + lr;
#pragma unroll
      for (int r = 0; r < 4; ++r) {
        float v = acc[i][j][r];
        const size_t idx = (size_t)(row + r) * N + col;
        if (EPI == 0) {
          Cb[idx] = __float2bfloat16(v);
        } else {
          v += bias[col];
          if (EPI == 2) v += res[idx];
          Cf[idx] = v;
        }
      }
    }
  }
}

// ---------------------------------------------------------------------------
// Split-K GEMM: P[sk][M*N] += A[M, kseg] * Bt^T (kseg = K/gridDim.z).
// Same 128x128 2-phase structure; partial f32 output, no bias.
// ---------------------------------------------------------------------------
__global__ __launch_bounds__(256) void gemm_sk(
    const __hip_bfloat16* __restrict__ A, const __hip_bfloat16* __restrict__ Bt,
    float* __restrict__ P, int M, int N, int K) {
  const int nwg = gridDim.x * gridDim.y;
  const int lid = blockIdx.y * gridDim.x + blockIdx.x;
  const int work = (lid & 7) * (nwg >> 3) + (lid >> 3);
  const int n0 = (work % gridDim.x) * 128;
  const int m0 = (work / gridDim.x) * 128;
  const int KS = K / gridDim.z;
  const int kbeg = blockIdx.z * KS;

  const int t = threadIdx.x;
  const int w = t >> 6, l = t & 63;
  const int lr = l & 15, lk = l >> 4;
  const int wm = (w >> 1) * 64, wn = (w & 1) * 64;
  __shared__ __hip_bfloat16 Al[2][128 * 32];
  __shared__ __hip_bfloat16 Bl[2][128 * 32];

  f32x4 acc[4][4];
  const f32x4 z = {0.f, 0.f, 0.f, 0.f};
#pragma unroll
  for (int i = 0; i < 4; ++i)
#pragma unroll
    for (int j = 0; j < 4; ++j) acc[i][j] = z;

  const int srow = w * 16 + (l >> 2);
  const int scol = ((l & 3) ^ ((l >> 3) & 3)) * 8;
  const __hip_bfloat16* Ag = A + (size_t)(m0 + srow) * K + kbeg + scol;
  const __hip_bfloat16* Bg = Bt + (size_t)(n0 + srow) * K + kbeg + scol;

#define STAGE(buf, k0)                                                   \
  {                                                                      \
    load_lds16(Ag + (k0), (char*)Al[buf] + w * 1024);                    \
    load_lds16(Ag + (size_t)64 * K + (k0), (char*)Al[buf] + 4096 + w * 1024); \
    load_lds16(Bg + (k0), (char*)Bl[buf] + w * 1024);                    \
    load_lds16(Bg + (size_t)64 * K + (k0), (char*)Bl[buf] + 4096 + w * 1024); \
  }

  STAGE(0, 0);
  __syncthreads();
  int cur = 0;
  const int rs = (lk ^ ((lr >> 1) & 3)) * 16;
  for (int k0 = 0; k0 < KS; k0 += 32) {
    if (k0 + 32 < KS) STAGE(cur ^ 1, k0 + 32);
    bf16x8 af[4], bfr[4];
#pragma unroll
    for (int i = 0; i < 4; ++i)
      af[i] = *(const bf16x8*)((const char*)Al[cur] + ((wm + i * 16 + lr) * 64 + rs));
#pragma unroll
    for (int j = 0; j < 4; ++j)
      bfr[j] = *(const bf16x8*)((const char*)Bl[cur] + ((wn + j * 16 + lr) * 64 + rs));
#pragma unroll
    for (int i = 0; i < 4; ++i)
#pragma unroll
      for (int j = 0; j < 4; ++j)
        acc[i][j] = __builtin_amdgcn_mfma_f32_16x16x32_bf16(af[i], bfr[j], acc[i][j], 0, 0, 0);
    __syncthreads();
    cur ^= 1;
  }
#undef STAGE

  float* Pz = P + (size_t)blockIdx.z * M * N;
#pragma unroll
  for (int i = 0; i < 4; ++i) {
    const int row = m0 + wm + i * 16 + lk * 4;
#pragma unroll
    for (int j = 0; j < 4; ++j) {
      const int col = n0 + wn + j * 16 + lr;
#pragma unroll
      for (int r = 0; r < 4; ++r)
        Pz[(size_t)(row + r) * N + col] = acc[i][j][r];
    }
  }
}

// reduce split-K partials: out = sum_sk P + bias + res   (N=512 fixed)
__global__ __launch_bounds__(256) void reduce_sk(
    const float* __restrict__ P, const float* __restrict__ bias,
    const float* __restrict__ res, float* __restrict__ out, int SK) {
  const int i = blockIdx.x * 256 + threadIdx.x;   // M*N = 524288
  float v = bias[i & 511] + res[i];
  for (int s = 0; s < SK; ++s) v += P[(size_t)s * 524288 + i];
  out[i] = v;
}

// ---------------------------------------------------------------------------
// kv128: KV projection, 128x128 2-phase structure (proven 56.7us @32768x1024),
// V half written TRANSPOSED: Vt[((b*8+h)*64+dh) << rpb_shift | key].
// grid = (8, M/128). K = 512 fixed.
// ---------------------------------------------------------------------------
__global__ __launch_bounds__(256) void kv128_kernel(
    const __hip_bfloat16* __restrict__ A, const __hip_bfloat16* __restrict__ Bt,
    __hip_bfloat16* __restrict__ Kb, __hip_bfloat16* __restrict__ Vt,
    int M, int rpb_shift) {
  const int nwg = gridDim.x * gridDim.y;
  const int lid = blockIdx.y * gridDim.x + blockIdx.x;
  const int work = (lid & 7) * (nwg >> 3) + (lid >> 3);
  const int n0 = (work & 7) * 128;
  const int m0 = (work >> 3) * 128;
  const int K = 512;

  const int t = threadIdx.x;
  const int w = t >> 6, l = t & 63;
  const int lr = l & 15, lk = l >> 4;
  const int wm = (w >> 1) * 64, wn = (w & 1) * 64;
  __shared__ __hip_bfloat16 Al[2][128 * 32];
  __shared__ __hip_bfloat16 Bl[2][128 * 32];

  f32x4 acc[4][4];
  const f32x4 z = {0.f, 0.f, 0.f, 0.f};
#pragma unroll
  for (int i = 0; i < 4; ++i)
#pragma unroll
    for (int j = 0; j < 4; ++j) acc[i][j] = z;

  const int srow = w * 16 + (l >> 2);
  const int scol = ((l & 3) ^ ((l >> 3) & 3)) * 8;
  const __hip_bfloat16* Ag = A + (size_t)(m0 + srow) * K + scol;
  const __hip_bfloat16* Bg = Bt + (size_t)(n0 + srow) * K + scol;

#define STAGE(buf, k0)                                                   \
  {                                                                      \
    load_lds16(Ag + (k0), (char*)Al[buf] + w * 1024);                    \
    load_lds16(Ag + (size_t)64 * K + (k0), (char*)Al[buf] + 4096 + w * 1024); \
    load_lds16(Bg + (k0), (char*)Bl[buf] + w * 1024);                    \
    load_lds16(Bg + (size_t)64 * K + (k0), (char*)Bl[buf] + 4096 + w * 1024); \
  }

  STAGE(0, 0);
  __syncthreads();
  int cur = 0;
  const int rs = (lk ^ ((lr >> 1) & 3)) * 16;
  for (int k0 = 0; k0 < K; k0 += 32) {
    if (k0 + 32 < K) STAGE(cur ^ 1, k0 + 32);
    bf16x8 af[4], bfr[4];
#pragma unroll
    for (int i = 0; i < 4; ++i)
      af[i] = *(const bf16x8*)((const char*)Al[cur] + ((wm + i * 16 + lr) * 64 + rs));
#pragma unroll
    for (int j = 0; j < 4; ++j)
      bfr[j] = *(const bf16x8*)((const char*)Bl[cur] + ((wn + j * 16 + lr) * 64 + rs));
#pragma unroll
    for (int i = 0; i < 4; ++i)
#pragma unroll
      for (int j = 0; j < 4; ++j)
        acc[i][j] = __builtin_amdgcn_mfma_f32_16x16x32_bf16(af[i], bfr[j], acc[i][j], 0, 0, 0);
    __syncthreads();
    cur ^= 1;
  }
#undef STAGE

  if (n0 < 512) {
    // K half -> Kb[row][col], stride 512
#pragma unroll
    for (int i = 0; i < 4; ++i) {
      const int row = m0 + wm + i * 16 + lk * 4;
#pragma unroll
      for (int j = 0; j < 4; ++j) {
        const int col = n0 + wn + j * 16 + lr;
#pragma unroll
        for (int r = 0; r < 4; ++r)
          Kb[(size_t)(row + r) * 512 + col] = __float2bfloat16(acc[i][j][r]);
      }
    }
  } else {
    // V half -> Vt transposed, 4 keys packed per 8B store
    const int rpb = 1 << rpb_shift;
#pragma unroll
    for (int i = 0; i < 4; ++i) {
      const int row0 = m0 + wm + i * 16 + lk * 4;
      const int b = row0 >> rpb_shift;
      const int key0 = row0 & (rpb - 1);
#pragma unroll
      for (int j = 0; j < 4; ++j) {
        const int c = n0 - 512 + wn + j * 16 + lr;
        const int hh = c >> 6, dh = c & 63;
        short4 pk;
        pk.x = bfbits(acc[i][j][0]);
        pk.y = bfbits(acc[i][j][1]);
        pk.z = bfbits(acc[i][j][2]);
        pk.w = bfbits(acc[i][j][3]);
        *(short4*)&Vt[((size_t)((b * 8 + hh) * 64 + dh) << rpb_shift) + key0] = pk;
      }
    }
  }
}

// ---------------------------------------------------------------------------
// Key-split flash attention, static-max softmax (data-safe: |s|<~4 << 88).
// Kb [b*rows+key][512], Vt [(b*8+h)*64+dh][rows].
// If Od != nullptr (S==1): write normalized bf16 directly, skip partials.
// ---------------------------------------------------------------------------
__global__ __launch_bounds__(256) void attn_split_kernel(
    const __hip_bfloat16* __restrict__ Q, const __hip_bfloat16* __restrict__ Kb,
    const __hip_bfloat16* __restrict__ Vt,
    float* __restrict__ Opart, float* __restrict__ Lv,
    __hip_bfloat16* __restrict__ Od,
    int chunk, int rows_per_b, int S) {
  const float SC2 = 0.18033688f;   // 0.125 * log2(e)
  const int h = blockIdx.x, b = blockIdx.y, s = blockIdx.z;
  const int t = threadIdx.x;
  const int w = t >> 6, l = t & 63;
  const int lr = l & 15, lk = l >> 4;
  __shared__ __hip_bfloat16 Kl[64 * 64];
  __shared__ __hip_bfloat16 Vl[64 * 64];
  __shared__ __hip_bfloat16 Pl[4][32 * 64];

  bf16x8 qf[2][2];
#pragma unroll
  for (int mf = 0; mf < 2; ++mf)
#pragma unroll
    for (int kf = 0; kf < 2; ++kf)
      qf[mf][kf] = *(const bf16x8*)&Q[(size_t)(b * 128 + w * 32 + mf * 16 + lr) * 512 +
                                      h * 64 + kf * 32 + lk * 8];

  f32x4 o[2][4];
  const f32x4 z = {0.f, 0.f, 0.f, 0.f};
#pragma unroll
  for (int mf = 0; mf < 2; ++mf)
#pragma unroll
    for (int nf = 0; nf < 4; ++nf) o[mf][nf] = z;
  float lsum[2][4];
#pragma unroll
  for (int mf = 0; mf < 2; ++mf)
#pragma unroll
    for (int r = 0; r < 4; ++r) lsum[mf][r] = 0.f;

  const __hip_bfloat16* kvb = Kb + (size_t)b * rows_per_b * 512;
  const __hip_bfloat16* vtb = Vt + (size_t)(b * 8 + h) * 64 * rows_per_b;
  char* pw = (char*)Pl[w];
  const int srow = l >> 3;
  const int sslot = (l & 7) ^ srow;
  const int jend = s * chunk + chunk;

  for (int j0 = s * chunk; j0 < jend; j0 += 64) {
    __syncthreads();
#pragma unroll
    for (int p = 0; p < 2; ++p) {
      const int row = p * 32 + w * 8 + srow;
      load_lds16(&kvb[(size_t)(j0 + row) * 512 + h * 64 + sslot * 8],
                 (char*)Kl + p * 4096 + w * 1024);
      load_lds16(&vtb[(size_t)row * rows_per_b + j0 + sslot * 8],
                 (char*)Vl + p * 4096 + w * 1024);
    }
    __syncthreads();

    f32x4 sc[2][4];
#pragma unroll
    for (int mf = 0; mf < 2; ++mf)
#pragma unroll
      for (int nf = 0; nf < 4; ++nf) sc[mf][nf] = z;
    __builtin_amdgcn_s_setprio(1);
#pragma unroll
    for (int kf = 0; kf < 2; ++kf) {
      bf16x8 kb[4];
#pragma unroll
      for (int nf = 0; nf < 4; ++nf) {
        const int key = nf * 16 + lr;
        kb[nf] = *(const bf16x8*)((char*)Kl +
                  (key * 128 + (((kf * 4 + lk) ^ (key & 7)) * 16)));
      }
#pragma unroll
      for (int mf = 0; mf < 2; ++mf)
#pragma unroll
        for (int nf = 0; nf < 4; ++nf)
          sc[mf][nf] = __builtin_amdgcn_mfma_f32_16x16x32_bf16(qf[mf][kf], kb[nf], sc[mf][nf], 0, 0, 0);
    }
    __builtin_amdgcn_s_setprio(0);

#pragma unroll
    for (int mf = 0; mf < 2; ++mf)
#pragma unroll
      for (int nf = 0; nf < 4; ++nf)
#pragma unroll
        for (int r = 0; r < 4; ++r) {
          const float p = exp2f(sc[mf][nf][r] * SC2);
          sc[mf][nf][r] = p;
          lsum[mf][r] += p;
        }

#pragma unroll
    for (int mf = 0; mf < 2; ++mf)
#pragma unroll
      for (int r = 0; r < 4; ++r) {
        const int prow = mf * 16 + lk * 4 + r;
#pragma unroll
        for (int nf = 0; nf < 4; ++nf) {
          const int pcol = nf * 16 + lr;
          *(__hip_bfloat16*)(pw + ((prow * 128 + pcol * 2) ^ ((prow & 7) << 4))) =
              __float2bfloat16(sc[mf][nf][r]);
        }
      }

    __builtin_amdgcn_s_setprio(1);
#pragma unroll
    for (int kf = 0; kf < 2; ++kf) {
      bf16x8 pa[2], vb[4];
#pragma unroll
      for (int mf = 0; mf < 2; ++mf) {
        const int prow = mf * 16 + lr;
        pa[mf] = *(const bf16x8*)(pw + ((prow * 128 + (kf * 4 + lk) * 16) ^ ((prow & 7) << 4)));
      }
#pragma unroll
      for (int nf = 0; nf < 4; ++nf) {
        const int dh = nf * 16 + lr;
        vb[nf] = *(const bf16x8*)((char*)Vl +
                  (dh * 128 + (((kf * 4 + lk) ^ (dh & 7)) * 16)));
      }
#pragma unroll
      for (int mf = 0; mf < 2; ++mf)
#pragma unroll
        for (int nf = 0; nf < 4; ++nf)
          o[mf][nf] = __builtin_amdgcn_mfma_f32_16x16x32_bf16(pa[mf], vb[nf], o[mf][nf], 0, 0, 0);
    }
    __builtin_amdgcn_s_setprio(0);
  }

  const int part = (b * 8 + h) * S + s;
  float* op = Opart + (size_t)part * 8192;
#pragma unroll
  for (int mf = 0; mf < 2; ++mf)
#pragma unroll
    for (int r = 0; r < 4; ++r) {
      float ls = lsum[mf][r];
      ls += __shfl_xor(ls, 1);
      ls += __shfl_xor(ls, 2);
      ls += __shfl_xor(ls, 4);
      ls += __shfl_xor(ls, 8);
      const int row = w * 32 + mf * 16 + lk * 4 + r;
      if (Od) {
        const float inv = 1.f / ls;
#pragma unroll
        for (int nf = 0; nf < 4; ++nf)
          Od[(size_t)(b * 128 + row) * 512 + h * 64 + nf * 16 + lr] =
              __float2bfloat16(o[mf][nf][r] * inv);
      } else {
#pragma unroll
        for (int nf = 0; nf < 4; ++nf)
          op[(size_t)row * 64 + nf * 16 + lr] = o[mf][nf][r];
        if (lr == 0) Lv[(size_t)part * 128 + row] = ls;
      }
    }
}

__global__ __launch_bounds__(256) void attn_combine_kernel(
    const float* __restrict__ Opart, const float* __restrict__ Lv,
    __hip_bfloat16* __restrict__ O, int S) {
  const int row = blockIdx.x;
  const int b = row >> 7, i = row & 127;
  for (int c = threadIdx.x; c < 512; c += 256) {
    const int h = c >> 6, dh = c & 63;
    const int pbase = (b * 8 + h) * S;
    float L = 0.f, val = 0.f;
    for (int s = 0; s < S; ++s) {
      L += Lv[(size_t)(pbase + s) * 128 + i];
      val += Opart[((size_t)(pbase + s) * 128 + i) * 64 + dh];
    }
    O[(size_t)row * 512 + c] = __float2bfloat16(val / L);
  }
}

// ---------------------------------------------------------------------------
// LayerNorm: fp32 [R,512] -> bf16, one block (256 thr) per row
// ---------------------------------------------------------------------------
DEVI void ln_row(const float* __restrict__ x, const float* __restrict__ w,
                 const float* __restrict__ bb, __hip_bfloat16* __restrict__ y,
                 int row, int t) {
  const float2 v = *(const float2*)&x[(size_t)row * 512 + t * 2];
  float s = v.x + v.y;
  float sq = v.x * v.x + v.y * v.y;
#pragma unroll
  for (int d = 1; d < 64; d <<= 1) {
    s += __shfl_xor(s, d);
    sq += __shfl_xor(sq, d);
  }
  __shared__ float ss[4], ssq[4];
  if ((t & 63) == 0) { ss[t >> 6] = s; ssq[t >> 6] = sq; }
  __syncthreads();
  s = ss[0] + ss[1] + ss[2] + ss[3];
  sq = ssq[0] + ssq[1] + ssq[2] + ssq[3];
  const float mean = s * (1.f / 512.f);
  const float var = sq * (1.f / 512.f) - mean * mean;
  const float rstd = rsqrtf(var + 1e-5f);
  const float2 wv = *(const float2*)&w[t * 2];
  const float2 bv = *(const float2*)&bb[t * 2];
  y[(size_t)row * 512 + t * 2] = __float2bfloat16((v.x - mean) * rstd * wv.x + bv.x);
  y[(size_t)row * 512 + t * 2 + 1] = __float2bfloat16((v.y - mean) * rstd * wv.y + bv.y);
}

__global__ __launch_bounds__(256) void ln_kernel(
    const float* __restrict__ x, const float* __restrict__ w,
    const float* __restrict__ bb, __hip_bfloat16* __restrict__ y) {
  ln_row(x, w, bb, y, blockIdx.x, threadIdx.x);
}

// merged leading LNs: rows 0..1023 = latents -> xnb; 1024.. = context -> cn
__global__ __launch_bounds__(256) void ln2_kernel(
    const float* __restrict__ lat, const float* __restrict__ lw, const float* __restrict__ lb,
    __hip_bfloat16* __restrict__ xout,
    const float* __restrict__ ctx, const float* __restrict__ cw, const float* __restrict__ cb,
    __hip_bfloat16* __restrict__ cout) {
  const int row = blockIdx.x;
  if (row < 1024)
    ln_row(lat, lw, lb, xout, row, threadIdx.x);
  else
    ln_row(ctx, cw, cb, cout, row - 1024, threadIdx.x);
}

// ---------------------------------------------------------------------------
struct WcvtDesc { const float* src[10]; __hip_bfloat16* dst[10]; };

__global__ __launch_bounds__(256) void wcvt_all_kernel(WcvtDesc d) {
  int tile = blockIdx.x;
  const int set = tile >> 12;
  tile &= 4095;
  int wi, K, N, base;
  if (tile < 256)       { wi = 0; K = 512;  N = 512;  base = 0; }
  else if (tile < 768)  { wi = 1; K = 512;  N = 1024; base = 256; }
  else if (tile < 1024) { wi = 2; K = 512;  N = 512;  base = 768; }
  else if (tile < 3072) { wi = 3; K = 512;  N = 4096; base = 1024; }
  else                  { wi = 4; K = 2048; N = 512;  base = 3072; }
  wi += set * 5;
  const int rel = tile - base;
  const int ntx = N >> 5;
  const int n0 = (rel % ntx) * 32, k0 = (rel / ntx) * 32;
  const float* W = d.src[wi];
  __hip_bfloat16* Wt = d.dst[wi];
  __shared__ float tl[32][33];
  const int tx = threadIdx.x & 31, ty = threadIdx.x >> 5;
#pragma unroll
  for (int j = 0; j < 4; ++j)
    tl[ty + j * 8][tx] = W[(size_t)(k0 + ty + j * 8) * N + n0 + tx];
  __syncthreads();
#pragma unroll
  for (int j = 0; j < 4; ++j)
    Wt[(size_t)(n0 + ty + j * 8) * K + k0 + tx] = __float2bfloat16(tl[tx][ty + j * 8]);
}

// ---------------------------------------------------------------------------
__global__ __launch_bounds__(256) void geglu_kernel(
    const float* __restrict__ hh, __hip_bfloat16* __restrict__ out) {
  const int i = blockIdx.x * 256 + threadIdx.x;
  const int row = i >> 11, col = i & 2047;
  const float a = hh[(size_t)row * 4096 + col];
  const float g = hh[(size_t)row * 4096 + 2048 + col];
  const float ge = 0.5f * g * (1.f + erff(g * 0.70710678118f));
  out[i] = __float2bfloat16(a * ge);
}

// ---------------------------------------------------------------------------
extern "C" void kernel_launch(void* const* d_in, const int* in_sizes, int n_in,
                              void* d_out, int out_size, void* d_ws, size_t ws_size,
                              hipStream_t stream) {
  (void)in_sizes; (void)n_in; (void)out_size; (void)ws_size;
  const float* context = (const float*)d_in[0];
  const float* latents = (const float*)d_in[1];
  const float* ca_ln_w = (const float*)d_in[2];
  const float* ca_ln_b = (const float*)d_in[3];
  const float* ca_lnc_w = (const float*)d_in[4];
  const float* ca_lnc_b = (const float*)d_in[5];
  const float* ca_wq = (const float*)d_in[6];
  const float* ca_wkv = (const float*)d_in[7];
  const float* ca_wo = (const float*)d_in[8];
  const float* ca_bo = (const float*)d_in[9];
  const float* cf_ln_w = (const float*)d_in[10];
  const float* cf_ln_b = (const float*)d_in[11];
  const float* cf_w1 = (const float*)d_in[12];
  const float* cf_b1 = (const float*)d_in[13];
  const float* cf_w2 = (const float*)d_in[14];
  const float* cf_b2 = (const float*)d_in[15];
  const float* sa_ln_w = (const float*)d_in[16];
  const float* sa_ln_b = (const float*)d_in[17];
  const float* sa_wq = (const float*)d_in[18];
  const float* sa_wkv = (const float*)d_in[19];
  const float* sa_wo = (const float*)d_in[20];
  const float* sa_bo = (const float*)d_in[21];
  const float* lf_ln_w = (const float*)d_in[22];
  const float* lf_ln_b = (const float*)d_in[23];
  const float* lf_w1 = (const float*)d_in[24];
  const float* lf_b1 = (const float*)d_in[25];
  const float* lf_w2 = (const float*)d_in[26];
  const float* lf_b2 = (const float*)d_in[27];

  typedef __hip_bfloat16 bf;
  char* ws = (char*)d_ws;
  size_t off = 0;
  auto alloc = [&](size_t bytes) -> void* {
    void* p = ws + off;
    off += (bytes + 255) & ~(size_t)255;
    return p;
  };
  bf* wq1t = (bf*)alloc((size_t)512 * 512 * 2);
  bf* wkv1t = (bf*)alloc((size_t)1024 * 512 * 2);
  bf* wo1t = (bf*)alloc((size_t)512 * 512 * 2);
  bf* w1ct = (bf*)alloc((size_t)4096 * 512 * 2);
  bf* w2ct = (bf*)alloc((size_t)512 * 2048 * 2);
  bf* wq2t = (bf*)alloc((size_t)512 * 512 * 2);
  bf* wkv2t = (bf*)alloc((size_t)1024 * 512 * 2);
  bf* wo2t = (bf*)alloc((size_t)512 * 512 * 2);
  bf* w1lt = (bf*)alloc((size_t)4096 * 512 * 2);
  bf* w2lt = (bf*)alloc((size_t)512 * 2048 * 2);
  bf* cn = (bf*)alloc((size_t)32768 * 512 * 2);     // 33.5 MB; multi-reused
  bf* kbuf = (bf*)alloc((size_t)32768 * 512 * 2);   // cross K [row][512]
  bf* vt = (bf*)alloc((size_t)64 * 64 * 4096 * 2);  // cross V^T
  bf* kb2 = (bf*)alloc((size_t)1024 * 512 * 2);     // self K [row][512]
  bf* vt2 = (bf*)alloc((size_t)64 * 64 * 128 * 2);  // self V^T
  float* lv = (float*)alloc((size_t)1024 * 128 * 4);
  bf* xnb = (bf*)alloc((size_t)1024 * 512 * 2);
  bf* qb = (bf*)alloc((size_t)1024 * 512 * 2);
  bf* aob = (bf*)alloc((size_t)1024 * 512 * 2);
  bf* q2b = (bf*)alloc((size_t)1024 * 512 * 2);
  bf* ao2b = (bf*)alloc((size_t)1024 * 512 * 2);
  float* x1 = (float*)alloc((size_t)1024 * 512 * 4);
  float* x2 = (float*)alloc((size_t)1024 * 512 * 4);
  float* x3 = (float*)alloc((size_t)1024 * 512 * 4);
  bf* x2n = (bf*)alloc((size_t)1024 * 512 * 2);
  bf* x3n = (bf*)alloc((size_t)1024 * 512 * 2);
  float* opart = (float*)cn;                       // attn partials (<=33.5 MB)
  float* hb = (float*)cn;                          // FFN hidden (16.8 MB)
  float* skp = (float*)cn;                         // split-K partials (8 MB)
  bf* agb = (bf*)((char*)cn + 17 * 1024 * 1024);   // GEGLU out (4.2 MB)

  WcvtDesc wd;
  wd.src[0] = ca_wq;  wd.dst[0] = wq1t;
  wd.src[1] = ca_wkv; wd.dst[1] = wkv1t;
  wd.src[2] = ca_wo;  wd.dst[2] = wo1t;
  wd.src[3] = cf_w1;  wd.dst[3] = w1ct;
  wd.src[4] = cf_w2;  wd.dst[4] = w2ct;
  wd.src[5] = sa_wq;  wd.dst[5] = wq2t;
  wd.src[6] = sa_wkv; wd.dst[6] = wkv2t;
  wd.src[7] = sa_wo;  wd.dst[7] = wo2t;
  wd.src[8] = lf_w1;  wd.dst[8] = w1lt;
  wd.src[9] = lf_w2;  wd.dst[9] = w2lt;
  wcvt_all_kernel<<<8192, 256, 0, stream>>>(wd);

  // --- sublayer 1: cross attention ---
  ln2_kernel<<<33792, 256, 0, stream>>>(latents, ca_ln_w, ca_ln_b, xnb,
                                        context, ca_lnc_w, ca_lnc_b, cn);
  gemm_bt<0><<<dim3(4, 8), 256, 0, stream>>>(xnb, wq1t, nullptr, qb, nullptr, nullptr, 1024, 512, 512);
  kv128_kernel<<<dim3(8, 256), 256, 0, stream>>>(cn, wkv1t, kbuf, vt, 32768, 12);
  attn_split_kernel<<<dim3(8, 8, 16), 256, 0, stream>>>(qb, kbuf, vt, opart, lv, nullptr, 256, 4096, 16);
  attn_combine_kernel<<<1024, 256, 0, stream>>>(opart, lv, aob, 16);
  gemm_bt<2><<<dim3(4, 8), 256, 0, stream>>>(aob, wo1t, x1, nullptr, ca_bo, latents, 1024, 512, 512);

  // --- sublayer 2: cross FFN (GEGLU), split-K down-proj ---
  ln_kernel<<<1024, 256, 0, stream>>>(x1, cf_ln_w, cf_ln_b, xnb);
  gemm_bt<1><<<dim3(32, 8), 256, 0, stream>>>(xnb, w1ct, hb, nullptr, cf_b1, nullptr, 1024, 4096, 512);
  geglu_kernel<<<8192, 256, 0, stream>>>(hb, agb);
  gemm_sk<<<dim3(4, 8, 4), 256, 0, stream>>>(agb, w2ct, skp, 1024, 512, 2048);
  reduce_sk<<<2048, 256, 0, stream>>>(skp, cf_b2, x1, x2, 4);

  // --- sublayer 3: latent self-attention (S=1, 128 keys, direct write) ---
  ln_kernel<<<1024, 256, 0, stream>>>(x2, sa_ln_w, sa_ln_b, x2n);
  gemm_bt<0><<<dim3(4, 8), 256, 0, stream>>>(x2n, wq2t, nullptr, q2b, nullptr, nullptr, 1024, 512, 512);
  kv128_kernel<<<dim3(8, 8), 256, 0, stream>>>(x2n, wkv2t, kb2, vt2, 1024, 7);
  attn_split_kernel<<<dim3(8, 8, 1), 256, 0, stream>>>(q2b, kb2, vt2, nullptr, nullptr, ao2b, 128, 128, 1);
  gemm_bt<2><<<dim3(4, 8), 256, 0, stream>>>(ao2b, wo2t, x3, nullptr, sa_bo, x2, 1024, 512, 512);

  // --- sublayer 4: latent FFN (GEGLU), split-K down-proj ---
  ln_kernel<<<1024, 256, 0, stream>>>(x3, lf_ln_w, lf_ln_b, x3n);
  gemm_bt<1><<<dim3(32, 8), 256, 0, stream>>>(x3n, w1lt, hb, nullptr, lf_b1, nullptr, 1024, 4096, 512);
  geglu_kernel<<<8192, 256, 0, stream>>>(hb, agb);
  gemm_sk<<<dim3(4, 8, 4), 256, 0, stream>>>(agb, w2lt, skp, 1024, 512, 2048);
  reduce_sk<<<2048, 256, 0, stream>>>(skp, lf_b2, x3, (float*)d_out, 4);
}

// Round 9
// 259.448 us; speedup vs baseline: 1.2578x; 1.0974x over previous
//
#include <hip/hip_runtime.h>
#include <hip/hip_bf16.h>
#include <math.h>

// ---------------------------------------------------------------------------
// LBANP encoder layer on MI355X (gfx950).
// Round 9: GEGLU fused into up-proj epilogue via column-permuted w1
// (a/g pairs land in same lane); reduce_sk+LN fusion; merged self QKV proj.
// ---------------------------------------------------------------------------

typedef __attribute__((ext_vector_type(8))) short bf16x8;   // 8 x bf16 (4 VGPRs)
typedef __attribute__((ext_vector_type(4))) float f32x4;

#define DEVI __device__ __forceinline__

DEVI void load_lds16(const void* g, void* l) {
  __builtin_amdgcn_global_load_lds(
      (const __attribute__((address_space(1))) void*)g,
      (__attribute__((address_space(3))) void*)l, 16, 0, 0);
}

DEVI short bfbits(float x) {
  __hip_bfloat16 h = __float2bfloat16(x);
  return *reinterpret_cast<short*>(&h);
}

// ---------------------------------------------------------------------------
// GEMM: C[M,N] = A[M,K](bf16) * Bt[N,K](bf16)^T
// EPI 0: bf16, no bias. EPI 1: f32 = acc+bias. EPI 2: f32 = acc+bias+res.
// EPI 3: GEGLU epilogue on permuted-w1 output: per 64-col group, cols 0-31 = a,
//        32-63 = matching g; writes bf16 [M, N/2] = (a+b1[n])*gelu(g+b1[2048+n]).
// 128x128 tile, 2-phase dbuf, slot-XOR swizzle, XCD swizzle.
// ---------------------------------------------------------------------------
template <int EPI>
__global__ __launch_bounds__(256) void gemm_bt(
    const __hip_bfloat16* __restrict__ A, const __hip_bfloat16* __restrict__ Bt,
    float* __restrict__ Cf, __hip_bfloat16* __restrict__ Cb,
    const float* __restrict__ bias, const float* __restrict__ res,
    int M, int N, int K) {
  const int nwg = gridDim.x * gridDim.y;
  const int lid = blockIdx.y * gridDim.x + blockIdx.x;
  const int work = (lid & 7) * (nwg >> 3) + (lid >> 3);
  const int n0 = (work % gridDim.x) * 128;
  const int m0 = (work / gridDim.x) * 128;

  const int t = threadIdx.x;
  const int w = t >> 6, l = t & 63;
  const int lr = l & 15, lk = l >> 4;
  const int wm = (w >> 1) * 64, wn = (w & 1) * 64;
  __shared__ __hip_bfloat16 Al[2][128 * 32];
  __shared__ __hip_bfloat16 Bl[2][128 * 32];

  f32x4 acc[4][4];
  const f32x4 z = {0.f, 0.f, 0.f, 0.f};
#pragma unroll
  for (int i = 0; i < 4; ++i)
#pragma unroll
    for (int j = 0; j < 4; ++j) acc[i][j] = z;

  const int srow = w * 16 + (l >> 2);
  const int scol = ((l & 3) ^ ((l >> 3) & 3)) * 8;
  const __hip_bfloat16* Ag = A + (size_t)(m0 + srow) * K + scol;
  const __hip_bfloat16* Bg = Bt + (size_t)(n0 + srow) * K + scol;

#define STAGE(buf, k0)                                                   \
  {                                                                      \
    load_lds16(Ag + (k0), (char*)Al[buf] + w * 1024);                    \
    load_lds16(Ag + (size_t)64 * K + (k0), (char*)Al[buf] + 4096 + w * 1024); \
    load_lds16(Bg + (k0), (char*)Bl[buf] + w * 1024);                    \
    load_lds16(Bg + (size_t)64 * K + (k0), (char*)Bl[buf] + 4096 + w * 1024); \
  }

  STAGE(0, 0);
  __syncthreads();
  int cur = 0;
  const int rs = (lk ^ ((lr >> 1) & 3)) * 16;
  for (int k0 = 0; k0 < K; k0 += 32) {
    if (k0 + 32 < K) STAGE(cur ^ 1, k0 + 32);
    bf16x8 af[4], bfr[4];
#pragma unroll
    for (int i = 0; i < 4; ++i)
      af[i] = *(const bf16x8*)((const char*)Al[cur] + ((wm + i * 16 + lr) * 64 + rs));
#pragma unroll
    for (int j = 0; j < 4; ++j)
      bfr[j] = *(const bf16x8*)((const char*)Bl[cur] + ((wn + j * 16 + lr) * 64 + rs));
#pragma unroll
    for (int i = 0; i < 4; ++i)
#pragma unroll
      for (int j = 0; j < 4; ++j)
        acc[i][j] = __builtin_amdgcn_mfma_f32_16x16x32_bf16(af[i], bfr[j], acc[i][j], 0, 0, 0);
    __syncthreads();
    cur ^= 1;
  }
#undef STAGE

  if (EPI == 3) {
    const int nb = (n0 + wn) >> 1;   // output col base (N/2 space)
    float ba[2], bg[2];
#pragma unroll
    for (int jj = 0; jj < 2; ++jj) {
      ba[jj] = bias[nb + jj * 16 + lr];
      bg[jj] = bias[2048 + nb + jj * 16 + lr];
    }
#pragma unroll
    for (int i = 0; i < 4; ++i) {
      const int row = m0 + wm + i * 16 + lk * 4;
#pragma unroll
      for (int jj = 0; jj < 2; ++jj) {
        const int col = nb + jj * 16 + lr;
#pragma unroll
        for (int r = 0; r < 4; ++r) {
          const float a = acc[i][jj][r] + ba[jj];
          const float g = acc[i][jj + 2][r] + bg[jj];
          const float ge = 0.5f * g * (1.f + erff(g * 0.70710678118f));
          Cb[(size_t)(row + r) * 2048 + col] = __float2bfloat16(a * ge);
        }
      }
    }
  } else {
#pragma unroll
    for (int i = 0; i < 4; ++i) {
      const int row = m0 + wm + i * 16 + lk * 4;
#pragma unroll
      for (int j = 0; j < 4; ++j) {
        const int col = n0 + wn + j * 16 + lr;
#pragma unroll
        for (int r = 0; r < 4; ++r) {
          float v = acc[i][j][r];
          const size_t idx = (size_t)(row + r) * N + col;
          if (EPI == 0) {
            Cb[idx] = __float2bfloat16(v);
          } else {
            v += bias[col];
            if (EPI == 2) v += res[idx];
            Cf[idx] = v;
          }
        }
      }
    }
  }
}

// ---------------------------------------------------------------------------
// Split-K GEMM: P[sk][M*N] = A[M, kseg] * Bt^T partials (f32).
// ---------------------------------------------------------------------------
__global__ __launch_bounds__(256) void gemm_sk(
    const __hip_bfloat16* __restrict__ A, const __hip_bfloat16* __restrict__ Bt,
    float* __restrict__ P, int M, int N, int K) {
  const int nwg = gridDim.x * gridDim.y;
  const int lid = blockIdx.y * gridDim.x + blockIdx.x;
  const int work = (lid & 7) * (nwg >> 3) + (lid >> 3);
  const int n0 = (work % gridDim.x) * 128;
  const int m0 = (work / gridDim.x) * 128;
  const int KS = K / gridDim.z;
  const int kbeg = blockIdx.z * KS;

  const int t = threadIdx.x;
  const int w = t >> 6, l = t & 63;
  const int lr = l & 15, lk = l >> 4;
  const int wm = (w >> 1) * 64, wn = (w & 1) * 64;
  __shared__ __hip_bfloat16 Al[2][128 * 32];
  __shared__ __hip_bfloat16 Bl[2][128 * 32];

  f32x4 acc[4][4];
  const f32x4 z = {0.f, 0.f, 0.f, 0.f};
#pragma unroll
  for (int i = 0; i < 4; ++i)
#pragma unroll
    for (int j = 0; j < 4; ++j) acc[i][j] = z;

  const int srow = w * 16 + (l >> 2);
  const int scol = ((l & 3) ^ ((l >> 3) & 3)) * 8;
  const __hip_bfloat16* Ag = A + (size_t)(m0 + srow) * K + kbeg + scol;
  const __hip_bfloat16* Bg = Bt + (size_t)(n0 + srow) * K + kbeg + scol;

#define STAGE(buf, k0)                                                   \
  {                                                                      \
    load_lds16(Ag + (k0), (char*)Al[buf] + w * 1024);                    \
    load_lds16(Ag + (size_t)64 * K + (k0), (char*)Al[buf] + 4096 + w * 1024); \
    load_lds16(Bg + (k0), (char*)Bl[buf] + w * 1024);                    \
    load_lds16(Bg + (size_t)64 * K + (k0), (char*)Bl[buf] + 4096 + w * 1024); \
  }

  STAGE(0, 0);
  __syncthreads();
  int cur = 0;
  const int rs = (lk ^ ((lr >> 1) & 3)) * 16;
  for (int k0 = 0; k0 < KS; k0 += 32) {
    if (k0 + 32 < KS) STAGE(cur ^ 1, k0 + 32);
    bf16x8 af[4], bfr[4];
#pragma unroll
    for (int i = 0; i < 4; ++i)
      af[i] = *(const bf16x8*)((const char*)Al[cur] + ((wm + i * 16 + lr) * 64 + rs));
#pragma unroll
    for (int j = 0; j < 4; ++j)
      bfr[j] = *(const bf16x8*)((const char*)Bl[cur] + ((wn + j * 16 + lr) * 64 + rs));
#pragma unroll
    for (int i = 0; i < 4; ++i)
#pragma unroll
      for (int j = 0; j < 4; ++j)
        acc[i][j] = __builtin_amdgcn_mfma_f32_16x16x32_bf16(af[i], bfr[j], acc[i][j], 0, 0, 0);
    __syncthreads();
    cur ^= 1;
  }
#undef STAGE

  float* Pz = P + (size_t)blockIdx.z * M * N;
#pragma unroll
  for (int i = 0; i < 4; ++i) {
    const int row = m0 + wm + i * 16 + lk * 4;
#pragma unroll
    for (int j = 0; j < 4; ++j) {
      const int col = n0 + wn + j * 16 + lr;
#pragma unroll
      for (int r = 0; r < 4; ++r)
        Pz[(size_t)(row + r) * N + col] = acc[i][j][r];
    }
  }
}

// reduce split-K partials: out = sum_sk P + bias + res   (N=512)
__global__ __launch_bounds__(256) void reduce_sk(
    const float* __restrict__ P, const float* __restrict__ bias,
    const float* __restrict__ res, float* __restrict__ out, int SK) {
  const int i = blockIdx.x * 256 + threadIdx.x;
  float v = bias[i & 511] + res[i];
  for (int s = 0; s < SK; ++s) v += P[(size_t)s * 524288 + i];
  out[i] = v;
}

// reduce split-K + LayerNorm fused: one block per row; emits f32 x and bf16 LN(x)
__global__ __launch_bounds__(256) void reduce_ln_sk(
    const float* __restrict__ P, const float* __restrict__ bias,
    const float* __restrict__ res, float* __restrict__ xout,
    const float* __restrict__ w, const float* __restrict__ b,
    __hip_bfloat16* __restrict__ y, int SK) {
  const int row = blockIdx.x, t = threadIdx.x;
  const int c = t * 2;
  const size_t base = (size_t)row * 512 + c;
  float2 v = *(const float2*)&res[base];
  v.x += bias[c];
  v.y += bias[c + 1];
  for (int s = 0; s < SK; ++s) {
    const float2 p = *(const float2*)&P[(size_t)s * 524288 + base];
    v.x += p.x;
    v.y += p.y;
  }
  *(float2*)&xout[base] = v;
  float s1 = v.x + v.y, s2 = v.x * v.x + v.y * v.y;
#pragma unroll
  for (int d = 1; d < 64; d <<= 1) {
    s1 += __shfl_xor(s1, d);
    s2 += __shfl_xor(s2, d);
  }
  __shared__ float ss[4], ssq[4];
  if ((t & 63) == 0) { ss[t >> 6] = s1; ssq[t >> 6] = s2; }
  __syncthreads();
  s1 = ss[0] + ss[1] + ss[2] + ss[3];
  s2 = ssq[0] + ssq[1] + ssq[2] + ssq[3];
  const float mean = s1 * (1.f / 512.f);
  const float var = s2 * (1.f / 512.f) - mean * mean;
  const float rstd = rsqrtf(var + 1e-5f);
  y[base] = __float2bfloat16((v.x - mean) * rstd * w[c] + b[c]);
  y[base + 1] = __float2bfloat16((v.y - mean) * rstd * w[c + 1] + b[c + 1]);
}

// ---------------------------------------------------------------------------
// proj: C = A[M,512] * Bt^T with 3-way epilogue by column:
//   col <  qcols           -> Qb[row*512+col]           (plain bf16)
//   col <  qcols+512       -> Kb[row*512+col-qcols]     (plain bf16)
//   else                   -> Vt transposed (c = col-qcols-512), 4-key packs
// 128x128 2-phase structure. grid = ((qcols+1024)/128, M/128). K=512 fixed.
// ---------------------------------------------------------------------------
__global__ __launch_bounds__(256) void proj_kernel(
    const __hip_bfloat16* __restrict__ A, const __hip_bfloat16* __restrict__ Bt,
    __hip_bfloat16* __restrict__ Qb, __hip_bfloat16* __restrict__ Kb,
    __hip_bfloat16* __restrict__ Vt, int qcols, int rpb_shift) {
  const int nwg = gridDim.x * gridDim.y;
  const int lid = blockIdx.y * gridDim.x + blockIdx.x;
  const int work = (lid & 7) * (nwg >> 3) + (lid >> 3);
  const int n0 = (work % gridDim.x) * 128;
  const int m0 = (work / gridDim.x) * 128;
  const int K = 512;

  const int t = threadIdx.x;
  const int w = t >> 6, l = t & 63;
  const int lr = l & 15, lk = l >> 4;
  const int wm = (w >> 1) * 64, wn = (w & 1) * 64;
  __shared__ __hip_bfloat16 Al[2][128 * 32];
  __shared__ __hip_bfloat16 Bl[2][128 * 32];

  f32x4 acc[4][4];
  const f32x4 z = {0.f, 0.f, 0.f, 0.f};
#pragma unroll
  for (int i = 0; i < 4; ++i)
#pragma unroll
    for (int j = 0; j < 4; ++j) acc[i][j] = z;

  const int srow = w * 16 + (l >> 2);
  const int scol = ((l & 3) ^ ((l >> 3) & 3)) * 8;
  const __hip_bfloat16* Ag = A + (size_t)(m0 + srow) * K + scol;
  const __hip_bfloat16* Bg = Bt + (size_t)(n0 + srow) * K + scol;

#define STAGE(buf, k0)                                                   \
  {                                                                      \
    load_lds16(Ag + (k0), (char*)Al[buf] + w * 1024);                    \
    load_lds16(Ag + (size_t)64 * K + (k0), (char*)Al[buf] + 4096 + w * 1024); \
    load_lds16(Bg + (k0), (char*)Bl[buf] + w * 1024);                    \
    load_lds16(Bg + (size_t)64 * K + (k0), (char*)Bl[buf] + 4096 + w * 1024); \
  }

  STAGE(0, 0);
  __syncthreads();
  int cur = 0;
  const int rs = (lk ^ ((lr >> 1) & 3)) * 16;
  for (int k0 = 0; k0 < K; k0 += 32) {
    if (k0 + 32 < K) STAGE(cur ^ 1, k0 + 32);
    bf16x8 af[4], bfr[4];
#pragma unroll
    for (int i = 0; i < 4; ++i)
      af[i] = *(const bf16x8*)((const char*)Al[cur] + ((wm + i * 16 + lr) * 64 + rs));
#pragma unroll
    for (int j = 0; j < 4; ++j)
      bfr[j] = *(const bf16x8*)((const char*)Bl[cur] + ((wn + j * 16 + lr) * 64 + rs));
#pragma unroll
    for (int i = 0; i < 4; ++i)
#pragma unroll
      for (int j = 0; j < 4; ++j)
        acc[i][j] = __builtin_amdgcn_mfma_f32_16x16x32_bf16(af[i], bfr[j], acc[i][j], 0, 0, 0);
    __syncthreads();
    cur ^= 1;
  }
#undef STAGE

  if (n0 < qcols) {
    // Q half
#pragma unroll
    for (int i = 0; i < 4; ++i) {
      const int row = m0 + wm + i * 16 + lk * 4;
#pragma unroll
      for (int j = 0; j < 4; ++j) {
        const int col = n0 + wn + j * 16 + lr;
#pragma unroll
        for (int r = 0; r < 4; ++r)
          Qb[(size_t)(row + r) * 512 + col] = __float2bfloat16(acc[i][j][r]);
      }
    }
  } else if (n0 < qcols + 512) {
    // K half
#pragma unroll
    for (int i = 0; i < 4; ++i) {
      const int row = m0 + wm + i * 16 + lk * 4;
#pragma unroll
      for (int j = 0; j < 4; ++j) {
        const int col = n0 + wn + j * 16 + lr - qcols;
#pragma unroll
        for (int r = 0; r < 4; ++r)
          Kb[(size_t)(row + r) * 512 + col] = __float2bfloat16(acc[i][j][r]);
      }
    }
  } else {
    // V half, transposed
    const int rpb = 1 << rpb_shift;
#pragma unroll
    for (int i = 0; i < 4; ++i) {
      const int row0 = m0 + wm + i * 16 + lk * 4;
      const int b = row0 >> rpb_shift;
      const int key0 = row0 & (rpb - 1);
#pragma unroll
      for (int j = 0; j < 4; ++j) {
        const int c = n0 + wn + j * 16 + lr - qcols - 512;
        const int hh = c >> 6, dh = c & 63;
        short4 pk;
        pk.x = bfbits(acc[i][j][0]);
        pk.y = bfbits(acc[i][j][1]);
        pk.z = bfbits(acc[i][j][2]);
        pk.w = bfbits(acc[i][j][3]);
        *(short4*)&Vt[((size_t)((b * 8 + hh) * 64 + dh) << rpb_shift) + key0] = pk;
      }
    }
  }
}

// ---------------------------------------------------------------------------
// Key-split flash attention, static-max softmax (data-safe: |s|<~4 << 88).
// If Od != nullptr (S==1): write normalized bf16 directly, skip partials.
// ---------------------------------------------------------------------------
__global__ __launch_bounds__(256) void attn_split_kernel(
    const __hip_bfloat16* __restrict__ Q, const __hip_bfloat16* __restrict__ Kb,
    const __hip_bfloat16* __restrict__ Vt,
    float* __restrict__ Opart, float* __restrict__ Lv,
    __hip_bfloat16* __restrict__ Od,
    int chunk, int rows_per_b, int S) {
  const float SC2 = 0.18033688f;   // 0.125 * log2(e)
  const int h = blockIdx.x, b = blockIdx.y, s = blockIdx.z;
  const int t = threadIdx.x;
  const int w = t >> 6, l = t & 63;
  const int lr = l & 15, lk = l >> 4;
  __shared__ __hip_bfloat16 Kl[64 * 64];
  __shared__ __hip_bfloat16 Vl[64 * 64];
  __shared__ __hip_bfloat16 Pl[4][32 * 64];

  bf16x8 qf[2][2];
#pragma unroll
  for (int mf = 0; mf < 2; ++mf)
#pragma unroll
    for (int kf = 0; kf < 2; ++kf)
      qf[mf][kf] = *(const bf16x8*)&Q[(size_t)(b * 128 + w * 32 + mf * 16 + lr) * 512 +
                                      h * 64 + kf * 32 + lk * 8];

  f32x4 o[2][4];
  const f32x4 z = {0.f, 0.f, 0.f, 0.f};
#pragma unroll
  for (int mf = 0; mf < 2; ++mf)
#pragma unroll
    for (int nf = 0; nf < 4; ++nf) o[mf][nf] = z;
  float lsum[2][4];
#pragma unroll
  for (int mf = 0; mf < 2; ++mf)
#pragma unroll
    for (int r = 0; r < 4; ++r) lsum[mf][r] = 0.f;

  const __hip_bfloat16* kvb = Kb + (size_t)b * rows_per_b * 512;
  const __hip_bfloat16* vtb = Vt + (size_t)(b * 8 + h) * 64 * rows_per_b;
  char* pw = (char*)Pl[w];
  const int srow = l >> 3;
  const int sslot = (l & 7) ^ srow;
  const int jend = s * chunk + chunk;

  for (int j0 = s * chunk; j0 < jend; j0 += 64) {
    __syncthreads();
#pragma unroll
    for (int p = 0; p < 2; ++p) {
      const int row = p * 32 + w * 8 + srow;
      load_lds16(&kvb[(size_t)(j0 + row) * 512 + h * 64 + sslot * 8],
                 (char*)Kl + p * 4096 + w * 1024);
      load_lds16(&vtb[(size_t)row * rows_per_b + j0 + sslot * 8],
                 (char*)Vl + p * 4096 + w * 1024);
    }
    __syncthreads();

    f32x4 sc[2][4];
#pragma unroll
    for (int mf = 0; mf < 2; ++mf)
#pragma unroll
      for (int nf = 0; nf < 4; ++nf) sc[mf][nf] = z;
    __builtin_amdgcn_s_setprio(1);
#pragma unroll
    for (int kf = 0; kf < 2; ++kf) {
      bf16x8 kb[4];
#pragma unroll
      for (int nf = 0; nf < 4; ++nf) {
        const int key = nf * 16 + lr;
        kb[nf] = *(const bf16x8*)((char*)Kl +
                  (key * 128 + (((kf * 4 + lk) ^ (key & 7)) * 16)));
      }
#pragma unroll
      for (int mf = 0; mf < 2; ++mf)
#pragma unroll
        for (int nf = 0; nf < 4; ++nf)
          sc[mf][nf] = __builtin_amdgcn_mfma_f32_16x16x32_bf16(qf[mf][kf], kb[nf], sc[mf][nf], 0, 0, 0);
    }
    __builtin_amdgcn_s_setprio(0);

#pragma unroll
    for (int mf = 0; mf < 2; ++mf)
#pragma unroll
      for (int nf = 0; nf < 4; ++nf)
#pragma unroll
        for (int r = 0; r < 4; ++r) {
          const float p = exp2f(sc[mf][nf][r] * SC2);
          sc[mf][nf][r] = p;
          lsum[mf][r] += p;
        }

#pragma unroll
    for (int mf = 0; mf < 2; ++mf)
#pragma unroll
      for (int r = 0; r < 4; ++r) {
        const int prow = mf * 16 + lk * 4 + r;
#pragma unroll
        for (int nf = 0; nf < 4; ++nf) {
          const int pcol = nf * 16 + lr;
          *(__hip_bfloat16*)(pw + ((prow * 128 + pcol * 2) ^ ((prow & 7) << 4))) =
              __float2bfloat16(sc[mf][nf][r]);
        }
      }

    __builtin_amdgcn_s_setprio(1);
#pragma unroll
    for (int kf = 0; kf < 2; ++kf) {
      bf16x8 pa[2], vb[4];
#pragma unroll
      for (int mf = 0; mf < 2; ++mf) {
        const int prow = mf * 16 + lr;
        pa[mf] = *(const bf16x8*)(pw + ((prow * 128 + (kf * 4 + lk) * 16) ^ ((prow & 7) << 4)));
      }
#pragma unroll
      for (int nf = 0; nf < 4; ++nf) {
        const int dh = nf * 16 + lr;
        vb[nf] = *(const bf16x8*)((char*)Vl +
                  (dh * 128 + (((kf * 4 + lk) ^ (dh & 7)) * 16)));
      }
#pragma unroll
      for (int mf = 0; mf < 2; ++mf)
#pragma unroll
        for (int nf = 0; nf < 4; ++nf)
          o[mf][nf] = __builtin_amdgcn_mfma_f32_16x16x32_bf16(pa[mf], vb[nf], o[mf][nf], 0, 0, 0);
    }
    __builtin_amdgcn_s_setprio(0);
  }

  const int part = (b * 8 + h) * S + s;
  float* op = Opart + (size_t)part * 8192;
#pragma unroll
  for (int mf = 0; mf < 2; ++mf)
#pragma unroll
    for (int r = 0; r < 4; ++r) {
      float ls = lsum[mf][r];
      ls += __shfl_xor(ls, 1);
      ls += __shfl_xor(ls, 2);
      ls += __shfl_xor(ls, 4);
      ls += __shfl_xor(ls, 8);
      const int row = w * 32 + mf * 16 + lk * 4 + r;
      if (Od) {
        const float inv = 1.f / ls;
#pragma unroll
        for (int nf = 0; nf < 4; ++nf)
          Od[(size_t)(b * 128 + row) * 512 + h * 64 + nf * 16 + lr] =
              __float2bfloat16(o[mf][nf][r] * inv);
      } else {
#pragma unroll
        for (int nf = 0; nf < 4; ++nf)
          op[(size_t)row * 64 + nf * 16 + lr] = o[mf][nf][r];
        if (lr == 0) Lv[(size_t)part * 128 + row] = ls;
      }
    }
}

__global__ __launch_bounds__(256) void attn_combine_kernel(
    const float* __restrict__ Opart, const float* __restrict__ Lv,
    __hip_bfloat16* __restrict__ O, int S) {
  const int row = blockIdx.x;
  const int b = row >> 7, i = row & 127;
  for (int c = threadIdx.x; c < 512; c += 256) {
    const int h = c >> 6, dh = c & 63;
    const int pbase = (b * 8 + h) * S;
    float L = 0.f, val = 0.f;
    for (int s = 0; s < S; ++s) {
      L += Lv[(size_t)(pbase + s) * 128 + i];
      val += Opart[((size_t)(pbase + s) * 128 + i) * 64 + dh];
    }
    O[(size_t)row * 512 + c] = __float2bfloat16(val / L);
  }
}

// ---------------------------------------------------------------------------
// LayerNorm: fp32 [R,512] -> bf16, one block (256 thr) per row
// ---------------------------------------------------------------------------
DEVI void ln_row(const float* __restrict__ x, const float* __restrict__ w,
                 const float* __restrict__ bb, __hip_bfloat16* __restrict__ y,
                 int row, int t) {
  const float2 v = *(const float2*)&x[(size_t)row * 512 + t * 2];
  float s = v.x + v.y;
  float sq = v.x * v.x + v.y * v.y;
#pragma unroll
  for (int d = 1; d < 64; d <<= 1) {
    s += __shfl_xor(s, d);
    sq += __shfl_xor(sq, d);
  }
  __shared__ float ss[4], ssq[4];
  if ((t & 63) == 0) { ss[t >> 6] = s; ssq[t >> 6] = sq; }
  __syncthreads();
  s = ss[0] + ss[1] + ss[2] + ss[3];
  sq = ssq[0] + ssq[1] + ssq[2] + ssq[3];
  const float mean = s * (1.f / 512.f);
  const float var = sq * (1.f / 512.f) - mean * mean;
  const float rstd = rsqrtf(var + 1e-5f);
  const float2 wv = *(const float2*)&w[t * 2];
  const float2 bv = *(const float2*)&bb[t * 2];
  y[(size_t)row * 512 + t * 2] = __float2bfloat16((v.x - mean) * rstd * wv.x + bv.x);
  y[(size_t)row * 512 + t * 2 + 1] = __float2bfloat16((v.y - mean) * rstd * wv.y + bv.y);
}

__global__ __launch_bounds__(256) void ln_kernel(
    const float* __restrict__ x, const float* __restrict__ w,
    const float* __restrict__ bb, __hip_bfloat16* __restrict__ y) {
  ln_row(x, w, bb, y, blockIdx.x, threadIdx.x);
}

__global__ __launch_bounds__(256) void ln2_kernel(
    const float* __restrict__ lat, const float* __restrict__ lw, const float* __restrict__ lb,
    __hip_bfloat16* __restrict__ xout,
    const float* __restrict__ ctx, const float* __restrict__ cw, const float* __restrict__ cb,
    __hip_bfloat16* __restrict__ cout) {
  const int row = blockIdx.x;
  if (row < 1024)
    ln_row(lat, lw, lb, xout, row, threadIdx.x);
  else
    ln_row(ctx, cw, cb, cout, row - 1024, threadIdx.x);
}

// ---------------------------------------------------------------------------
// Fused weight convert+transpose. For the two w1 weights (wi 3/8) the column
// space is PERMUTED for the GEGLU epilogue: permuted 64-group g: cols
// [g*64, g*64+32) <- a-cols [g*32, g*32+32); [g*64+32, g*64+64) <- g-cols
// [2048+g*32, ...). Tiles are 32 wide, so per tile it's a remapped source base.
// ---------------------------------------------------------------------------
struct WcvtDesc { const float* src[10]; __hip_bfloat16* dst[10]; };

__global__ __launch_bounds__(256) void wcvt_all_kernel(WcvtDesc d) {
  int tile = blockIdx.x;
  const int set = tile >> 12;
  tile &= 4095;
  int wi, K, N, base;
  if (tile < 256)       { wi = 0; K = 512;  N = 512;  base = 0; }
  else if (tile < 768)  { wi = 1; K = 512;  N = 1024; base = 256; }
  else if (tile < 1024) { wi = 2; K = 512;  N = 512;  base = 768; }
  else if (tile < 3072) { wi = 3; K = 512;  N = 4096; base = 1024; }
  else                  { wi = 4; K = 2048; N = 512;  base = 3072; }
  const bool permute = (wi == 3);
  wi += set * 5;
  const int rel = tile - base;
  const int ntx = N >> 5;
  const int n0 = (rel % ntx) * 32, k0 = (rel / ntx) * 32;
  // permuted source column base for w1 tiles
  const int sn0 = permute ? (((n0 >> 6) << 5) + ((n0 & 32) ? 2048 : 0)) : n0;
  const float* W = d.src[wi];
  __hip_bfloat16* Wt = d.dst[wi];
  __shared__ float tl[32][33];
  const int tx = threadIdx.x & 31, ty = threadIdx.x >> 5;
#pragma unroll
  for (int j = 0; j < 4; ++j)
    tl[ty + j * 8][tx] = W[(size_t)(k0 + ty + j * 8) * N + sn0 + tx];
  __syncthreads();
#pragma unroll
  for (int j = 0; j < 4; ++j)
    Wt[(size_t)(n0 + ty + j * 8) * K + k0 + tx] = __float2bfloat16(tl[tx][ty + j * 8]);
}

// ---------------------------------------------------------------------------
extern "C" void kernel_launch(void* const* d_in, const int* in_sizes, int n_in,
                              void* d_out, int out_size, void* d_ws, size_t ws_size,
                              hipStream_t stream) {
  (void)in_sizes; (void)n_in; (void)out_size; (void)ws_size;
  const float* context = (const float*)d_in[0];
  const float* latents = (const float*)d_in[1];
  const float* ca_ln_w = (const float*)d_in[2];
  const float* ca_ln_b = (const float*)d_in[3];
  const float* ca_lnc_w = (const float*)d_in[4];
  const float* ca_lnc_b = (const float*)d_in[5];
  const float* ca_wq = (const float*)d_in[6];
  const float* ca_wkv = (const float*)d_in[7];
  const float* ca_wo = (const float*)d_in[8];
  const float* ca_bo = (const float*)d_in[9];
  const float* cf_ln_w = (const float*)d_in[10];
  const float* cf_ln_b = (const float*)d_in[11];
  const float* cf_w1 = (const float*)d_in[12];
  const float* cf_b1 = (const float*)d_in[13];
  const float* cf_w2 = (const float*)d_in[14];
  const float* cf_b2 = (const float*)d_in[15];
  const float* sa_ln_w = (const float*)d_in[16];
  const float* sa_ln_b = (const float*)d_in[17];
  const float* sa_wq = (const float*)d_in[18];
  const float* sa_wkv = (const float*)d_in[19];
  const float* sa_wo = (const float*)d_in[20];
  const float* sa_bo = (const float*)d_in[21];
  const float* lf_ln_w = (const float*)d_in[22];
  const float* lf_ln_b = (const float*)d_in[23];
  const float* lf_w1 = (const float*)d_in[24];
  const float* lf_b1 = (const float*)d_in[25];
  const float* lf_w2 = (const float*)d_in[26];
  const float* lf_b2 = (const float*)d_in[27];

  typedef __hip_bfloat16 bf;
  char* ws = (char*)d_ws;
  size_t off = 0;
  auto alloc = [&](size_t bytes) -> void* {
    void* p = ws + off;
    off += (bytes + 255) & ~(size_t)255;
    return p;
  };
  bf* wq1t = (bf*)alloc((size_t)512 * 512 * 2);
  bf* wkv1t = (bf*)alloc((size_t)1024 * 512 * 2);
  bf* wo1t = (bf*)alloc((size_t)512 * 512 * 2);
  bf* w1ct = (bf*)alloc((size_t)4096 * 512 * 2);
  bf* w2ct = (bf*)alloc((size_t)512 * 2048 * 2);
  bf* wq2t = (bf*)alloc((size_t)512 * 512 * 2);    // contiguous with wkv2t:
  bf* wkv2t = (bf*)alloc((size_t)1024 * 512 * 2);  // combined 1536-row Bt
  bf* wo2t = (bf*)alloc((size_t)512 * 512 * 2);
  bf* w1lt = (bf*)alloc((size_t)4096 * 512 * 2);
  bf* w2lt = (bf*)alloc((size_t)512 * 2048 * 2);
  bf* cn = (bf*)alloc((size_t)32768 * 512 * 2);     // 33.5 MB; multi-reused
  bf* kbuf = (bf*)alloc((size_t)32768 * 512 * 2);   // cross K [row][512]
  bf* vt = (bf*)alloc((size_t)64 * 64 * 4096 * 2);  // cross V^T
  bf* kb2 = (bf*)alloc((size_t)1024 * 512 * 2);     // self K [row][512]
  bf* vt2 = (bf*)alloc((size_t)64 * 64 * 128 * 2);  // self V^T
  float* lv = (float*)alloc((size_t)1024 * 128 * 4);
  bf* xnb = (bf*)alloc((size_t)1024 * 512 * 2);
  bf* qb = (bf*)alloc((size_t)1024 * 512 * 2);
  bf* aob = (bf*)alloc((size_t)1024 * 512 * 2);
  bf* q2b = (bf*)alloc((size_t)1024 * 512 * 2);
  bf* ao2b = (bf*)alloc((size_t)1024 * 512 * 2);
  float* x1 = (float*)alloc((size_t)1024 * 512 * 4);
  float* x2 = (float*)alloc((size_t)1024 * 512 * 4);
  float* x3 = (float*)alloc((size_t)1024 * 512 * 4);
  bf* x2n = (bf*)alloc((size_t)1024 * 512 * 2);
  bf* x3n = (bf*)alloc((size_t)1024 * 512 * 2);
  float* opart = (float*)cn;                       // attn partials (<=33.5 MB)
  float* skp = (float*)cn;                         // split-K partials (8 MB)
  bf* agb = (bf*)((char*)cn + 17 * 1024 * 1024);   // GEGLU out (4.2 MB)

  WcvtDesc wd;
  wd.src[0] = ca_wq;  wd.dst[0] = wq1t;
  wd.src[1] = ca_wkv; wd.dst[1] = wkv1t;
  wd.src[2] = ca_wo;  wd.dst[2] = wo1t;
  wd.src[3] = cf_w1;  wd.dst[3] = w1ct;
  wd.src[4] = cf_w2;  wd.dst[4] = w2ct;
  wd.src[5] = sa_wq;  wd.dst[5] = wq2t;
  wd.src[6] = sa_wkv; wd.dst[6] = wkv2t;
  wd.src[7] = sa_wo;  wd.dst[7] = wo2t;
  wd.src[8] = lf_w1;  wd.dst[8] = w1lt;
  wd.src[9] = lf_w2;  wd.dst[9] = w2lt;
  wcvt_all_kernel<<<8192, 256, 0, stream>>>(wd);

  // --- sublayer 1: cross attention ---
  ln2_kernel<<<33792, 256, 0, stream>>>(latents, ca_ln_w, ca_ln_b, xnb,
                                        context, ca_lnc_w, ca_lnc_b, cn);
  gemm_bt<0><<<dim3(4, 8), 256, 0, stream>>>(xnb, wq1t, nullptr, qb, nullptr, nullptr, 1024, 512, 512);
  proj_kernel<<<dim3(8, 256), 256, 0, stream>>>(cn, wkv1t, nullptr, kbuf, vt, 0, 12);
  attn_split_kernel<<<dim3(8, 8, 16), 256, 0, stream>>>(qb, kbuf, vt, opart, lv, nullptr, 256, 4096, 16);
  attn_combine_kernel<<<1024, 256, 0, stream>>>(opart, lv, aob, 16);
  gemm_bt<2><<<dim3(4, 8), 256, 0, stream>>>(aob, wo1t, x1, nullptr, ca_bo, latents, 1024, 512, 512);

  // --- sublayer 2: cross FFN (GEGLU fused into up-proj), split-K down-proj ---
  ln_kernel<<<1024, 256, 0, stream>>>(x1, cf_ln_w, cf_ln_b, xnb);
  gemm_bt<3><<<dim3(32, 8), 256, 0, stream>>>(xnb, w1ct, nullptr, agb, cf_b1, nullptr, 1024, 4096, 512);
  gemm_sk<<<dim3(4, 8, 4), 256, 0, stream>>>(agb, w2ct, skp, 1024, 512, 2048);
  reduce_ln_sk<<<1024, 256, 0, stream>>>(skp, cf_b2, x1, x2, sa_ln_w, sa_ln_b, x2n, 4);

  // --- sublayer 3: latent self-attention (merged QKV, direct write) ---
  proj_kernel<<<dim3(12, 8), 256, 0, stream>>>(x2n, wq2t, q2b, kb2, vt2, 512, 7);
  attn_split_kernel<<<dim3(8, 8, 1), 256, 0, stream>>>(q2b, kb2, vt2, nullptr, nullptr, ao2b, 128, 128, 1);
  gemm_bt<2><<<dim3(4, 8), 256, 0, stream>>>(ao2b, wo2t, x3, nullptr, sa_bo, x2, 1024, 512, 512);

  // --- sublayer 4: latent FFN (GEGLU fused), split-K down-proj ---
  ln_kernel<<<1024, 256, 0, stream>>>(x3, lf_ln_w, lf_ln_b, x3n);
  gemm_bt<3><<<dim3(32, 8), 256, 0, stream>>>(x3n, w1lt, nullptr, agb, lf_b1, nullptr, 1024, 4096, 512);
  gemm_sk<<<dim3(4, 8, 4), 256, 0, stream>>>(agb, w2lt, skp, 1024, 512, 2048);
  reduce_sk<<<2048, 256, 0, stream>>>(skp, lf_b2, x3, (float*)d_out, 4);
}

// Round 10
// 257.477 us; speedup vs baseline: 1.2675x; 1.0077x over previous
//
#include <hip/hip_runtime.h>
#include <hip/hip_bf16.h>
#include <math.h>

// ---------------------------------------------------------------------------
// LBANP encoder layer on MI355X (gfx950).
// Round 10: __launch_bounds__(256, 4) on the GEMM family (gemm_bt, gemm_sk,
// proj_kernel) — caps unified VGPR+AGPR at 128/wave so 4 blocks/CU become
// resident (was 2-3, register-capped at ~144 regs), hiding the per-K-step
// global_load_lds drain stall. Attention kernels unchanged (would spill).
// ---------------------------------------------------------------------------

typedef __attribute__((ext_vector_type(8))) short bf16x8;   // 8 x bf16 (4 VGPRs)
typedef __attribute__((ext_vector_type(4))) float f32x4;

#define DEVI __device__ __forceinline__

DEVI void load_lds16(const void* g, void* l) {
  __builtin_amdgcn_global_load_lds(
      (const __attribute__((address_space(1))) void*)g,
      (__attribute__((address_space(3))) void*)l, 16, 0, 0);
}

DEVI short bfbits(float x) {
  __hip_bfloat16 h = __float2bfloat16(x);
  return *reinterpret_cast<short*>(&h);
}

// ---------------------------------------------------------------------------
// GEMM: C[M,N] = A[M,K](bf16) * Bt[N,K](bf16)^T
// EPI 0: bf16, no bias. EPI 1: f32 = acc+bias. EPI 2: f32 = acc+bias+res.
// EPI 3: GEGLU epilogue on permuted-w1 output: per 64-col group, cols 0-31 = a,
//        32-63 = matching g; writes bf16 [M, N/2] = (a+b1[n])*gelu(g+b1[2048+n]).
// 128x128 tile, 2-phase dbuf, slot-XOR swizzle, XCD swizzle.
// ---------------------------------------------------------------------------
template <int EPI>
__global__ __launch_bounds__(256, 4) void gemm_bt(
    const __hip_bfloat16* __restrict__ A, const __hip_bfloat16* __restrict__ Bt,
    float* __restrict__ Cf, __hip_bfloat16* __restrict__ Cb,
    const float* __restrict__ bias, const float* __restrict__ res,
    int M, int N, int K) {
  const int nwg = gridDim.x * gridDim.y;
  const int lid = blockIdx.y * gridDim.x + blockIdx.x;
  const int work = (lid & 7) * (nwg >> 3) + (lid >> 3);
  const int n0 = (work % gridDim.x) * 128;
  const int m0 = (work / gridDim.x) * 128;

  const int t = threadIdx.x;
  const int w = t >> 6, l = t & 63;
  const int lr = l & 15, lk = l >> 4;
  const int wm = (w >> 1) * 64, wn = (w & 1) * 64;
  __shared__ __hip_bfloat16 Al[2][128 * 32];
  __shared__ __hip_bfloat16 Bl[2][128 * 32];

  f32x4 acc[4][4];
  const f32x4 z = {0.f, 0.f, 0.f, 0.f};
#pragma unroll
  for (int i = 0; i < 4; ++i)
#pragma unroll
    for (int j = 0; j < 4; ++j) acc[i][j] = z;

  const int srow = w * 16 + (l >> 2);
  const int scol = ((l & 3) ^ ((l >> 3) & 3)) * 8;
  const __hip_bfloat16* Ag = A + (size_t)(m0 + srow) * K + scol;
  const __hip_bfloat16* Bg = Bt + (size_t)(n0 + srow) * K + scol;

#define STAGE(buf, k0)                                                   \
  {                                                                      \
    load_lds16(Ag + (k0), (char*)Al[buf] + w * 1024);                    \
    load_lds16(Ag + (size_t)64 * K + (k0), (char*)Al[buf] + 4096 + w * 1024); \
    load_lds16(Bg + (k0), (char*)Bl[buf] + w * 1024);                    \
    load_lds16(Bg + (size_t)64 * K + (k0), (char*)Bl[buf] + 4096 + w * 1024); \
  }

  STAGE(0, 0);
  __syncthreads();
  int cur = 0;
  const int rs = (lk ^ ((lr >> 1) & 3)) * 16;
  for (int k0 = 0; k0 < K; k0 += 32) {
    if (k0 + 32 < K) STAGE(cur ^ 1, k0 + 32);
    bf16x8 af[4], bfr[4];
#pragma unroll
    for (int i = 0; i < 4; ++i)
      af[i] = *(const bf16x8*)((const char*)Al[cur] + ((wm + i * 16 + lr) * 64 + rs));
#pragma unroll
    for (int j = 0; j < 4; ++j)
      bfr[j] = *(const bf16x8*)((const char*)Bl[cur] + ((wn + j * 16 + lr) * 64 + rs));
#pragma unroll
    for (int i = 0; i < 4; ++i)
#pragma unroll
      for (int j = 0; j < 4; ++j)
        acc[i][j] = __builtin_amdgcn_mfma_f32_16x16x32_bf16(af[i], bfr[j], acc[i][j], 0, 0, 0);
    __syncthreads();
    cur ^= 1;
  }
#undef STAGE

  if (EPI == 3) {
    const int nb = (n0 + wn) >> 1;   // output col base (N/2 space)
    float ba[2], bg[2];
#pragma unroll
    for (int jj = 0; jj < 2; ++jj) {
      ba[jj] = bias[nb + jj * 16 + lr];
      bg[jj] = bias[2048 + nb + jj * 16 + lr];
    }
#pragma unroll
    for (int i = 0; i < 4; ++i) {
      const int row = m0 + wm + i * 16 + lk * 4;
#pragma unroll
      for (int jj = 0; jj < 2; ++jj) {
        const int col = nb + jj * 16 + lr;
#pragma unroll
        for (int r = 0; r < 4; ++r) {
          const float a = acc[i][jj][r] + ba[jj];
          const float g = acc[i][jj + 2][r] + bg[jj];
          const float ge = 0.5f * g * (1.f + erff(g * 0.70710678118f));
          Cb[(size_t)(row + r) * 2048 + col] = __float2bfloat16(a * ge);
        }
      }
    }
  } else {
#pragma unroll
    for (int i = 0; i < 4; ++i) {
      const int row = m0 + wm + i * 16 + lk * 4;
#pragma unroll
      for (int j = 0; j < 4; ++j) {
        const int col = n0 + wn + j * 16 + lr;
#pragma unroll
        for (int r = 0; r < 4; ++r) {
          float v = acc[i][j][r];
          const size_t idx = (size_t)(row + r) * N + col;
          if (EPI == 0) {
            Cb[idx] = __float2bfloat16(v);
          } else {
            v += bias[col];
            if (EPI == 2) v += res[idx];
            Cf[idx] = v;
          }
        }
      }
    }
  }
}

// ---------------------------------------------------------------------------
// Split-K GEMM: P[sk][M*N] = A[M, kseg] * Bt^T partials (f32).
// ---------------------------------------------------------------------------
__global__ __launch_bounds__(256, 4) void gemm_sk(
    const __hip_bfloat16* __restrict__ A, const __hip_bfloat16* __restrict__ Bt,
    float* __restrict__ P, int M, int N, int K) {
  const int nwg = gridDim.x * gridDim.y;
  const int lid = blockIdx.y * gridDim.x + blockIdx.x;
  const int work = (lid & 7) * (nwg >> 3) + (lid >> 3);
  const int n0 = (work % gridDim.x) * 128;
  const int m0 = (work / gridDim.x) * 128;
  const int KS = K / gridDim.z;
  const int kbeg = blockIdx.z * KS;

  const int t = threadIdx.x;
  const int w = t >> 6, l = t & 63;
  const int lr = l & 15, lk = l >> 4;
  const int wm = (w >> 1) * 64, wn = (w & 1) * 64;
  __shared__ __hip_bfloat16 Al[2][128 * 32];
  __shared__ __hip_bfloat16 Bl[2][128 * 32];

  f32x4 acc[4][4];
  const f32x4 z = {0.f, 0.f, 0.f, 0.f};
#pragma unroll
  for (int i = 0; i < 4; ++i)
#pragma unroll
    for (int j = 0; j < 4; ++j) acc[i][j] = z;

  const int srow = w * 16 + (l >> 2);
  const int scol = ((l & 3) ^ ((l >> 3) & 3)) * 8;
  const __hip_bfloat16* Ag = A + (size_t)(m0 + srow) * K + kbeg + scol;
  const __hip_bfloat16* Bg = Bt + (size_t)(n0 + srow) * K + kbeg + scol;

#define STAGE(buf, k0)                                                   \
  {                                                                      \
    load_lds16(Ag + (k0), (char*)Al[buf] + w * 1024);                    \
    load_lds16(Ag + (size_t)64 * K + (k0), (char*)Al[buf] + 4096 + w * 1024); \
    load_lds16(Bg + (k0), (char*)Bl[buf] + w * 1024);                    \
    load_lds16(Bg + (size_t)64 * K + (k0), (char*)Bl[buf] + 4096 + w * 1024); \
  }

  STAGE(0, 0);
  __syncthreads();
  int cur = 0;
  const int rs = (lk ^ ((lr >> 1) & 3)) * 16;
  for (int k0 = 0; k0 < KS; k0 += 32) {
    if (k0 + 32 < KS) STAGE(cur ^ 1, k0 + 32);
    bf16x8 af[4], bfr[4];
#pragma unroll
    for (int i = 0; i < 4; ++i)
      af[i] = *(const bf16x8*)((const char*)Al[cur] + ((wm + i * 16 + lr) * 64 + rs));
#pragma unroll
    for (int j = 0; j < 4; ++j)
      bfr[j] = *(const bf16x8*)((const char*)Bl[cur] + ((wn + j * 16 + lr) * 64 + rs));
#pragma unroll
    for (int i = 0; i < 4; ++i)
#pragma unroll
      for (int j = 0; j < 4; ++j)
        acc[i][j] = __builtin_amdgcn_mfma_f32_16x16x32_bf16(af[i], bfr[j], acc[i][j], 0, 0, 0);
    __syncthreads();
    cur ^= 1;
  }
#undef STAGE

  float* Pz = P + (size_t)blockIdx.z * M * N;
#pragma unroll
  for (int i = 0; i < 4; ++i) {
    const int row = m0 + wm + i * 16 + lk * 4;
#pragma unroll
    for (int j = 0; j < 4; ++j) {
      const int col = n0 + wn + j * 16 + lr;
#pragma unroll
      for (int r = 0; r < 4; ++r)
        Pz[(size_t)(row + r) * N + col] = acc[i][j][r];
    }
  }
}

// reduce split-K partials: out = sum_sk P + bias + res   (N=512)
__global__ __launch_bounds__(256) void reduce_sk(
    const float* __restrict__ P, const float* __restrict__ bias,
    const float* __restrict__ res, float* __restrict__ out, int SK) {
  const int i = blockIdx.x * 256 + threadIdx.x;
  float v = bias[i & 511] + res[i];
  for (int s = 0; s < SK; ++s) v += P[(size_t)s * 524288 + i];
  out[i] = v;
}

// reduce split-K + LayerNorm fused: one block per row; emits f32 x and bf16 LN(x)
__global__ __launch_bounds__(256) void reduce_ln_sk(
    const float* __restrict__ P, const float* __restrict__ bias,
    const float* __restrict__ res, float* __restrict__ xout,
    const float* __restrict__ w, const float* __restrict__ b,
    __hip_bfloat16* __restrict__ y, int SK) {
  const int row = blockIdx.x, t = threadIdx.x;
  const int c = t * 2;
  const size_t base = (size_t)row * 512 + c;
  float2 v = *(const float2*)&res[base];
  v.x += bias[c];
  v.y += bias[c + 1];
  for (int s = 0; s < SK; ++s) {
    const float2 p = *(const float2*)&P[(size_t)s * 524288 + base];
    v.x += p.x;
    v.y += p.y;
  }
  *(float2*)&xout[base] = v;
  float s1 = v.x + v.y, s2 = v.x * v.x + v.y * v.y;
#pragma unroll
  for (int d = 1; d < 64; d <<= 1) {
    s1 += __shfl_xor(s1, d);
    s2 += __shfl_xor(s2, d);
  }
  __shared__ float ss[4], ssq[4];
  if ((t & 63) == 0) { ss[t >> 6] = s1; ssq[t >> 6] = s2; }
  __syncthreads();
  s1 = ss[0] + ss[1] + ss[2] + ss[3];
  s2 = ssq[0] + ssq[1] + ssq[2] + ssq[3];
  const float mean = s1 * (1.f / 512.f);
  const float var = s2 * (1.f / 512.f) - mean * mean;
  const float rstd = rsqrtf(var + 1e-5f);
  y[base] = __float2bfloat16((v.x - mean) * rstd * w[c] + b[c]);
  y[base + 1] = __float2bfloat16((v.y - mean) * rstd * w[c + 1] + b[c + 1]);
}

// ---------------------------------------------------------------------------
// proj: C = A[M,512] * Bt^T with 3-way epilogue by column:
//   col <  qcols           -> Qb[row*512+col]           (plain bf16)
//   col <  qcols+512       -> Kb[row*512+col-qcols]     (plain bf16)
//   else                   -> Vt transposed (c = col-qcols-512), 4-key packs
// 128x128 2-phase structure. grid = ((qcols+1024)/128, M/128). K=512 fixed.
// ---------------------------------------------------------------------------
__global__ __launch_bounds__(256, 4) void proj_kernel(
    const __hip_bfloat16* __restrict__ A, const __hip_bfloat16* __restrict__ Bt,
    __hip_bfloat16* __restrict__ Qb, __hip_bfloat16* __restrict__ Kb,
    __hip_bfloat16* __restrict__ Vt, int qcols, int rpb_shift) {
  const int nwg = gridDim.x * gridDim.y;
  const int lid = blockIdx.y * gridDim.x + blockIdx.x;
  const int work = (lid & 7) * (nwg >> 3) + (lid >> 3);
  const int n0 = (work % gridDim.x) * 128;
  const int m0 = (work / gridDim.x) * 128;
  const int K = 512;

  const int t = threadIdx.x;
  const int w = t >> 6, l = t & 63;
  const int lr = l & 15, lk = l >> 4;
  const int wm = (w >> 1) * 64, wn = (w & 1) * 64;
  __shared__ __hip_bfloat16 Al[2][128 * 32];
  __shared__ __hip_bfloat16 Bl[2][128 * 32];

  f32x4 acc[4][4];
  const f32x4 z = {0.f, 0.f, 0.f, 0.f};
#pragma unroll
  for (int i = 0; i < 4; ++i)
#pragma unroll
    for (int j = 0; j < 4; ++j) acc[i][j] = z;

  const int srow = w * 16 + (l >> 2);
  const int scol = ((l & 3) ^ ((l >> 3) & 3)) * 8;
  const __hip_bfloat16* Ag = A + (size_t)(m0 + srow) * K + scol;
  const __hip_bfloat16* Bg = Bt + (size_t)(n0 + srow) * K + scol;

#define STAGE(buf, k0)                                                   \
  {                                                                      \
    load_lds16(Ag + (k0), (char*)Al[buf] + w * 1024);                    \
    load_lds16(Ag + (size_t)64 * K + (k0), (char*)Al[buf] + 4096 + w * 1024); \
    load_lds16(Bg + (k0), (char*)Bl[buf] + w * 1024);                    \
    load_lds16(Bg + (size_t)64 * K + (k0), (char*)Bl[buf] + 4096 + w * 1024); \
  }

  STAGE(0, 0);
  __syncthreads();
  int cur = 0;
  const int rs = (lk ^ ((lr >> 1) & 3)) * 16;
  for (int k0 = 0; k0 < K; k0 += 32) {
    if (k0 + 32 < K) STAGE(cur ^ 1, k0 + 32);
    bf16x8 af[4], bfr[4];
#pragma unroll
    for (int i = 0; i < 4; ++i)
      af[i] = *(const bf16x8*)((const char*)Al[cur] + ((wm + i * 16 + lr) * 64 + rs));
#pragma unroll
    for (int j = 0; j < 4; ++j)
      bfr[j] = *(const bf16x8*)((const char*)Bl[cur] + ((wn + j * 16 + lr) * 64 + rs));
#pragma unroll
    for (int i = 0; i < 4; ++i)
#pragma unroll
      for (int j = 0; j < 4; ++j)
        acc[i][j] = __builtin_amdgcn_mfma_f32_16x16x32_bf16(af[i], bfr[j], acc[i][j], 0, 0, 0);
    __syncthreads();
    cur ^= 1;
  }
#undef STAGE

  if (n0 < qcols) {
    // Q half
#pragma unroll
    for (int i = 0; i < 4; ++i) {
      const int row = m0 + wm + i * 16 + lk * 4;
#pragma unroll
      for (int j = 0; j < 4; ++j) {
        const int col = n0 + wn + j * 16 + lr;
#pragma unroll
        for (int r = 0; r < 4; ++r)
          Qb[(size_t)(row + r) * 512 + col] = __float2bfloat16(acc[i][j][r]);
      }
    }
  } else if (n0 < qcols + 512) {
    // K half
#pragma unroll
    for (int i = 0; i < 4; ++i) {
      const int row = m0 + wm + i * 16 + lk * 4;
#pragma unroll
      for (int j = 0; j < 4; ++j) {
        const int col = n0 + wn + j * 16 + lr - qcols;
#pragma unroll
        for (int r = 0; r < 4; ++r)
          Kb[(size_t)(row + r) * 512 + col] = __float2bfloat16(acc[i][j][r]);
      }
    }
  } else {
    // V half, transposed
    const int rpb = 1 << rpb_shift;
#pragma unroll
    for (int i = 0; i < 4; ++i) {
      const int row0 = m0 + wm + i * 16 + lk * 4;
      const int b = row0 >> rpb_shift;
      const int key0 = row0 & (rpb - 1);
#pragma unroll
      for (int j = 0; j < 4; ++j) {
        const int c = n0 + wn + j * 16 + lr - qcols - 512;
        const int hh = c >> 6, dh = c & 63;
        short4 pk;
        pk.x = bfbits(acc[i][j][0]);
        pk.y = bfbits(acc[i][j][1]);
        pk.z = bfbits(acc[i][j][2]);
        pk.w = bfbits(acc[i][j][3]);
        *(short4*)&Vt[((size_t)((b * 8 + hh) * 64 + dh) << rpb_shift) + key0] = pk;
      }
    }
  }
}

// ---------------------------------------------------------------------------
// Key-split flash attention, static-max softmax (data-safe: |s|<~4 << 88).
// If Od != nullptr (S==1): write normalized bf16 directly, skip partials.
// ---------------------------------------------------------------------------
__global__ __launch_bounds__(256) void attn_split_kernel(
    const __hip_bfloat16* __restrict__ Q, const __hip_bfloat16* __restrict__ Kb,
    const __hip_bfloat16* __restrict__ Vt,
    float* __restrict__ Opart, float* __restrict__ Lv,
    __hip_bfloat16* __restrict__ Od,
    int chunk, int rows_per_b, int S) {
  const float SC2 = 0.18033688f;   // 0.125 * log2(e)
  const int h = blockIdx.x, b = blockIdx.y, s = blockIdx.z;
  const int t = threadIdx.x;
  const int w = t >> 6, l = t & 63;
  const int lr = l & 15, lk = l >> 4;
  __shared__ __hip_bfloat16 Kl[64 * 64];
  __shared__ __hip_bfloat16 Vl[64 * 64];
  __shared__ __hip_bfloat16 Pl[4][32 * 64];

  bf16x8 qf[2][2];
#pragma unroll
  for (int mf = 0; mf < 2; ++mf)
#pragma unroll
    for (int kf = 0; kf < 2; ++kf)
      qf[mf][kf] = *(const bf16x8*)&Q[(size_t)(b * 128 + w * 32 + mf * 16 + lr) * 512 +
                                      h * 64 + kf * 32 + lk * 8];

  f32x4 o[2][4];
  const f32x4 z = {0.f, 0.f, 0.f, 0.f};
#pragma unroll
  for (int mf = 0; mf < 2; ++mf)
#pragma unroll
    for (int nf = 0; nf < 4; ++nf) o[mf][nf] = z;
  float lsum[2][4];
#pragma unroll
  for (int mf = 0; mf < 2; ++mf)
#pragma unroll
    for (int r = 0; r < 4; ++r) lsum[mf][r] = 0.f;

  const __hip_bfloat16* kvb = Kb + (size_t)b * rows_per_b * 512;
  const __hip_bfloat16* vtb = Vt + (size_t)(b * 8 + h) * 64 * rows_per_b;
  char* pw = (char*)Pl[w];
  const int srow = l >> 3;
  const int sslot = (l & 7) ^ srow;
  const int jend = s * chunk + chunk;

  for (int j0 = s * chunk; j0 < jend; j0 += 64) {
    __syncthreads();
#pragma unroll
    for (int p = 0; p < 2; ++p) {
      const int row = p * 32 + w * 8 + srow;
      load_lds16(&kvb[(size_t)(j0 + row) * 512 + h * 64 + sslot * 8],
                 (char*)Kl + p * 4096 + w * 1024);
      load_lds16(&vtb[(size_t)row * rows_per_b + j0 + sslot * 8],
                 (char*)Vl + p * 4096 + w * 1024);
    }
    __syncthreads();

    f32x4 sc[2][4];
#pragma unroll
    for (int mf = 0; mf < 2; ++mf)
#pragma unroll
      for (int nf = 0; nf < 4; ++nf) sc[mf][nf] = z;
    __builtin_amdgcn_s_setprio(1);
#pragma unroll
    for (int kf = 0; kf < 2; ++kf) {
      bf16x8 kb[4];
#pragma unroll
      for (int nf = 0; nf < 4; ++nf) {
        const int key = nf * 16 + lr;
        kb[nf] = *(const bf16x8*)((char*)Kl +
                  (key * 128 + (((kf * 4 + lk) ^ (key & 7)) * 16)));
      }
#pragma unroll
      for (int mf = 0; mf < 2; ++mf)
#pragma unroll
        for (int nf = 0; nf < 4; ++nf)
          sc[mf][nf] = __builtin_amdgcn_mfma_f32_16x16x32_bf16(qf[mf][kf], kb[nf], sc[mf][nf], 0, 0, 0);
    }
    __builtin_amdgcn_s_setprio(0);

#pragma unroll
    for (int mf = 0; mf < 2; ++mf)
#pragma unroll
      for (int nf = 0; nf < 4; ++nf)
#pragma unroll
        for (int r = 0; r < 4; ++r) {
          const float p = exp2f(sc[mf][nf][r] * SC2);
          sc[mf][nf][r] = p;
          lsum[mf][r] += p;
        }

#pragma unroll
    for (int mf = 0; mf < 2; ++mf)
#pragma unroll
      for (int r = 0; r < 4; ++r) {
        const int prow = mf * 16 + lk * 4 + r;
#pragma unroll
        for (int nf = 0; nf < 4; ++nf) {
          const int pcol = nf * 16 + lr;
          *(__hip_bfloat16*)(pw + ((prow * 128 + pcol * 2) ^ ((prow & 7) << 4))) =
              __float2bfloat16(sc[mf][nf][r]);
        }
      }

    __builtin_amdgcn_s_setprio(1);
#pragma unroll
    for (int kf = 0; kf < 2; ++kf) {
      bf16x8 pa[2], vb[4];
#pragma unroll
      for (int mf = 0; mf < 2; ++mf) {
        const int prow = mf * 16 + lr;
        pa[mf] = *(const bf16x8*)(pw + ((prow * 128 + (kf * 4 + lk) * 16) ^ ((prow & 7) << 4)));
      }
#pragma unroll
      for (int nf = 0; nf < 4; ++nf) {
        const int dh = nf * 16 + lr;
        vb[nf] = *(const bf16x8*)((char*)Vl +
                  (dh * 128 + (((kf * 4 + lk) ^ (dh & 7)) * 16)));
      }
#pragma unroll
      for (int mf = 0; mf < 2; ++mf)
#pragma unroll
        for (int nf = 0; nf < 4; ++nf)
          o[mf][nf] = __builtin_amdgcn_mfma_f32_16x16x32_bf16(pa[mf], vb[nf], o[mf][nf], 0, 0, 0);
    }
    __builtin_amdgcn_s_setprio(0);
  }

  const int part = (b * 8 + h) * S + s;
  float* op = Opart + (size_t)part * 8192;
#pragma unroll
  for (int mf = 0; mf < 2; ++mf)
#pragma unroll
    for (int r = 0; r < 4; ++r) {
      float ls = lsum[mf][r];
      ls += __shfl_xor(ls, 1);
      ls += __shfl_xor(ls, 2);
      ls += __shfl_xor(ls, 4);
      ls += __shfl_xor(ls, 8);
      const int row = w * 32 + mf * 16 + lk * 4 + r;
      if (Od) {
        const float inv = 1.f / ls;
#pragma unroll
        for (int nf = 0; nf < 4; ++nf)
          Od[(size_t)(b * 128 + row) * 512 + h * 64 + nf * 16 + lr] =
              __float2bfloat16(o[mf][nf][r] * inv);
      } else {
#pragma unroll
        for (int nf = 0; nf < 4; ++nf)
          op[(size_t)row * 64 + nf * 16 + lr] = o[mf][nf][r];
        if (lr == 0) Lv[(size_t)part * 128 + row] = ls;
      }
    }
}

__global__ __launch_bounds__(256) void attn_combine_kernel(
    const float* __restrict__ Opart, const float* __restrict__ Lv,
    __hip_bfloat16* __restrict__ O, int S) {
  const int row = blockIdx.x;
  const int b = row >> 7, i = row & 127;
  for (int c = threadIdx.x; c < 512; c += 256) {
    const int h = c >> 6, dh = c & 63;
    const int pbase = (b * 8 + h) * S;
    float L = 0.f, val = 0.f;
    for (int s = 0; s < S; ++s) {
      L += Lv[(size_t)(pbase + s) * 128 + i];
      val += Opart[((size_t)(pbase + s) * 128 + i) * 64 + dh];
    }
    O[(size_t)row * 512 + c] = __float2bfloat16(val / L);
  }
}

// ---------------------------------------------------------------------------
// LayerNorm: fp32 [R,512] -> bf16, one block (256 thr) per row
// ---------------------------------------------------------------------------
DEVI void ln_row(const float* __restrict__ x, const float* __restrict__ w,
                 const float* __restrict__ bb, __hip_bfloat16* __restrict__ y,
                 int row, int t) {
  const float2 v = *(const float2*)&x[(size_t)row * 512 + t * 2];
  float s = v.x + v.y;
  float sq = v.x * v.x + v.y * v.y;
#pragma unroll
  for (int d = 1; d < 64; d <<= 1) {
    s += __shfl_xor(s, d);
    sq += __shfl_xor(sq, d);
  }
  __shared__ float ss[4], ssq[4];
  if ((t & 63) == 0) { ss[t >> 6] = s; ssq[t >> 6] = sq; }
  __syncthreads();
  s = ss[0] + ss[1] + ss[2] + ss[3];
  sq = ssq[0] + ssq[1] + ssq[2] + ssq[3];
  const float mean = s * (1.f / 512.f);
  const float var = sq * (1.f / 512.f) - mean * mean;
  const float rstd = rsqrtf(var + 1e-5f);
  const float2 wv = *(const float2*)&w[t * 2];
  const float2 bv = *(const float2*)&bb[t * 2];
  y[(size_t)row * 512 + t * 2] = __float2bfloat16((v.x - mean) * rstd * wv.x + bv.x);
  y[(size_t)row * 512 + t * 2 + 1] = __float2bfloat16((v.y - mean) * rstd * wv.y + bv.y);
}

__global__ __launch_bounds__(256) void ln_kernel(
    const float* __restrict__ x, const float* __restrict__ w,
    const float* __restrict__ bb, __hip_bfloat16* __restrict__ y) {
  ln_row(x, w, bb, y, blockIdx.x, threadIdx.x);
}

__global__ __launch_bounds__(256) void ln2_kernel(
    const float* __restrict__ lat, const float* __restrict__ lw, const float* __restrict__ lb,
    __hip_bfloat16* __restrict__ xout,
    const float* __restrict__ ctx, const float* __restrict__ cw, const float* __restrict__ cb,
    __hip_bfloat16* __restrict__ cout) {
  const int row = blockIdx.x;
  if (row < 1024)
    ln_row(lat, lw, lb, xout, row, threadIdx.x);
  else
    ln_row(ctx, cw, cb, cout, row - 1024, threadIdx.x);
}

// ---------------------------------------------------------------------------
// Fused weight convert+transpose. For the two w1 weights (wi 3/8) the column
// space is PERMUTED for the GEGLU epilogue.
// ---------------------------------------------------------------------------
struct WcvtDesc { const float* src[10]; __hip_bfloat16* dst[10]; };

__global__ __launch_bounds__(256) void wcvt_all_kernel(WcvtDesc d) {
  int tile = blockIdx.x;
  const int set = tile >> 12;
  tile &= 4095;
  int wi, K, N, base;
  if (tile < 256)       { wi = 0; K = 512;  N = 512;  base = 0; }
  else if (tile < 768)  { wi = 1; K = 512;  N = 1024; base = 256; }
  else if (tile < 1024) { wi = 2; K = 512;  N = 512;  base = 768; }
  else if (tile < 3072) { wi = 3; K = 512;  N = 4096; base = 1024; }
  else                  { wi = 4; K = 2048; N = 512;  base = 3072; }
  const bool permute = (wi == 3);
  wi += set * 5;
  const int rel = tile - base;
  const int ntx = N >> 5;
  const int n0 = (rel % ntx) * 32, k0 = (rel / ntx) * 32;
  const int sn0 = permute ? (((n0 >> 6) << 5) + ((n0 & 32) ? 2048 : 0)) : n0;
  const float* W = d.src[wi];
  __hip_bfloat16* Wt = d.dst[wi];
  __shared__ float tl[32][33];
  const int tx = threadIdx.x & 31, ty = threadIdx.x >> 5;
#pragma unroll
  for (int j = 0; j < 4; ++j)
    tl[ty + j * 8][tx] = W[(size_t)(k0 + ty + j * 8) * N + sn0 + tx];
  __syncthreads();
#pragma unroll
  for (int j = 0; j < 4; ++j)
    Wt[(size_t)(n0 + ty + j * 8) * K + k0 + tx] = __float2bfloat16(tl[tx][ty + j * 8]);
}

// ---------------------------------------------------------------------------
extern "C" void kernel_launch(void* const* d_in, const int* in_sizes, int n_in,
                              void* d_out, int out_size, void* d_ws, size_t ws_size,
                              hipStream_t stream) {
  (void)in_sizes; (void)n_in; (void)out_size; (void)ws_size;
  const float* context = (const float*)d_in[0];
  const float* latents = (const float*)d_in[1];
  const float* ca_ln_w = (const float*)d_in[2];
  const float* ca_ln_b = (const float*)d_in[3];
  const float* ca_lnc_w = (const float*)d_in[4];
  const float* ca_lnc_b = (const float*)d_in[5];
  const float* ca_wq = (const float*)d_in[6];
  const float* ca_wkv = (const float*)d_in[7];
  const float* ca_wo = (const float*)d_in[8];
  const float* ca_bo = (const float*)d_in[9];
  const float* cf_ln_w = (const float*)d_in[10];
  const float* cf_ln_b = (const float*)d_in[11];
  const float* cf_w1 = (const float*)d_in[12];
  const float* cf_b1 = (const float*)d_in[13];
  const float* cf_w2 = (const float*)d_in[14];
  const float* cf_b2 = (const float*)d_in[15];
  const float* sa_ln_w = (const float*)d_in[16];
  const float* sa_ln_b = (const float*)d_in[17];
  const float* sa_wq = (const float*)d_in[18];
  const float* sa_wkv = (const float*)d_in[19];
  const float* sa_wo = (const float*)d_in[20];
  const float* sa_bo = (const float*)d_in[21];
  const float* lf_ln_w = (const float*)d_in[22];
  const float* lf_ln_b = (const float*)d_in[23];
  const float* lf_w1 = (const float*)d_in[24];
  const float* lf_b1 = (const float*)d_in[25];
  const float* lf_w2 = (const float*)d_in[26];
  const float* lf_b2 = (const float*)d_in[27];

  typedef __hip_bfloat16 bf;
  char* ws = (char*)d_ws;
  size_t off = 0;
  auto alloc = [&](size_t bytes) -> void* {
    void* p = ws + off;
    off += (bytes + 255) & ~(size_t)255;
    return p;
  };
  bf* wq1t = (bf*)alloc((size_t)512 * 512 * 2);
  bf* wkv1t = (bf*)alloc((size_t)1024 * 512 * 2);
  bf* wo1t = (bf*)alloc((size_t)512 * 512 * 2);
  bf* w1ct = (bf*)alloc((size_t)4096 * 512 * 2);
  bf* w2ct = (bf*)alloc((size_t)512 * 2048 * 2);
  bf* wq2t = (bf*)alloc((size_t)512 * 512 * 2);    // contiguous with wkv2t
  bf* wkv2t = (bf*)alloc((size_t)1024 * 512 * 2);
  bf* wo2t = (bf*)alloc((size_t)512 * 512 * 2);
  bf* w1lt = (bf*)alloc((size_t)4096 * 512 * 2);
  bf* w2lt = (bf*)alloc((size_t)512 * 2048 * 2);
  bf* cn = (bf*)alloc((size_t)32768 * 512 * 2);     // 33.5 MB; multi-reused
  bf* kbuf = (bf*)alloc((size_t)32768 * 512 * 2);   // cross K [row][512]
  bf* vt = (bf*)alloc((size_t)64 * 64 * 4096 * 2);  // cross V^T
  bf* kb2 = (bf*)alloc((size_t)1024 * 512 * 2);     // self K [row][512]
  bf* vt2 = (bf*)alloc((size_t)64 * 64 * 128 * 2);  // self V^T
  float* lv = (float*)alloc((size_t)1024 * 128 * 4);
  bf* xnb = (bf*)alloc((size_t)1024 * 512 * 2);
  bf* qb = (bf*)alloc((size_t)1024 * 512 * 2);
  bf* aob = (bf*)alloc((size_t)1024 * 512 * 2);
  bf* q2b = (bf*)alloc((size_t)1024 * 512 * 2);
  bf* ao2b = (bf*)alloc((size_t)1024 * 512 * 2);
  float* x1 = (float*)alloc((size_t)1024 * 512 * 4);
  float* x2 = (float*)alloc((size_t)1024 * 512 * 4);
  float* x3 = (float*)alloc((size_t)1024 * 512 * 4);
  bf* x2n = (bf*)alloc((size_t)1024 * 512 * 2);
  bf* x3n = (bf*)alloc((size_t)1024 * 512 * 2);
  float* opart = (float*)cn;                       // attn partials (<=33.5 MB)
  float* skp = (float*)cn;                         // split-K partials (8 MB)
  bf* agb = (bf*)((char*)cn + 17 * 1024 * 1024);   // GEGLU out (4.2 MB)

  WcvtDesc wd;
  wd.src[0] = ca_wq;  wd.dst[0] = wq1t;
  wd.src[1] = ca_wkv; wd.dst[1] = wkv1t;
  wd.src[2] = ca_wo;  wd.dst[2] = wo1t;
  wd.src[3] = cf_w1;  wd.dst[3] = w1ct;
  wd.src[4] = cf_w2;  wd.dst[4] = w2ct;
  wd.src[5] = sa_wq;  wd.dst[5] = wq2t;
  wd.src[6] = sa_wkv; wd.dst[6] = wkv2t;
  wd.src[7] = sa_wo;  wd.dst[7] = wo2t;
  wd.src[8] = lf_w1;  wd.dst[8] = w1lt;
  wd.src[9] = lf_w2;  wd.dst[9] = w2lt;
  wcvt_all_kernel<<<8192, 256, 0, stream>>>(wd);

  // --- sublayer 1: cross attention ---
  ln2_kernel<<<33792, 256, 0, stream>>>(latents, ca_ln_w, ca_ln_b, xnb,
                                        context, ca_lnc_w, ca_lnc_b, cn);
  gemm_bt<0><<<dim3(4, 8), 256, 0, stream>>>(xnb, wq1t, nullptr, qb, nullptr, nullptr, 1024, 512, 512);
  proj_kernel<<<dim3(8, 256), 256, 0, stream>>>(cn, wkv1t, nullptr, kbuf, vt, 0, 12);
  attn_split_kernel<<<dim3(8, 8, 16), 256, 0, stream>>>(qb, kbuf, vt, opart, lv, nullptr, 256, 4096, 16);
  attn_combine_kernel<<<1024, 256, 0, stream>>>(opart, lv, aob, 16);
  gemm_bt<2><<<dim3(4, 8), 256, 0, stream>>>(aob, wo1t, x1, nullptr, ca_bo, latents, 1024, 512, 512);

  // --- sublayer 2: cross FFN (GEGLU fused into up-proj), split-K down-proj ---
  ln_kernel<<<1024, 256, 0, stream>>>(x1, cf_ln_w, cf_ln_b, xnb);
  gemm_bt<3><<<dim3(32, 8), 256, 0, stream>>>(xnb, w1ct, nullptr, agb, cf_b1, nullptr, 1024, 4096, 512);
  gemm_sk<<<dim3(4, 8, 4), 256, 0, stream>>>(agb, w2ct, skp, 1024, 512, 2048);
  reduce_ln_sk<<<1024, 256, 0, stream>>>(skp, cf_b2, x1, x2, sa_ln_w, sa_ln_b, x2n, 4);

  // --- sublayer 3: latent self-attention (merged QKV, direct write) ---
  proj_kernel<<<dim3(12, 8), 256, 0, stream>>>(x2n, wq2t, q2b, kb2, vt2, 512, 7);
  attn_split_kernel<<<dim3(8, 8, 1), 256, 0, stream>>>(q2b, kb2, vt2, nullptr, nullptr, ao2b, 128, 128, 1);
  gemm_bt<2><<<dim3(4, 8), 256, 0, stream>>>(ao2b, wo2t, x3, nullptr, sa_bo, x2, 1024, 512, 512);

  // --- sublayer 4: latent FFN (GEGLU fused), split-K down-proj ---
  ln_kernel<<<1024, 256, 0, stream>>>(x3, lf_ln_w, lf_ln_b, x3n);
  gemm_bt<3><<<dim3(32, 8), 256, 0, stream>>>(x3n, w1lt, nullptr, agb, lf_b1, nullptr, 1024, 4096, 512);
  gemm_sk<<<dim3(4, 8, 4), 256, 0, stream>>>(agb, w2lt, skp, 1024, 512, 2048);
  reduce_sk<<<2048, 256, 0, stream>>>(skp, lf_b2, x3, (float*)d_out, 4);
}

// Round 11
// 235.150 us; speedup vs baseline: 1.3878x; 1.0949x over previous
//
#include <hip/hip_runtime.h>
#include <hip/hip_bf16.h>
#include <math.h>

// ---------------------------------------------------------------------------
// LBANP encoder layer on MI355X (gfx950).
// Round 11: parallelism for the mid GEMMs — split-K (SK=4) for q/wo proj with
// LN-fused reduces, SK=8 for FFN-down, 64x128-tile gemm_geglu (512 blocks).
// ---------------------------------------------------------------------------

typedef __attribute__((ext_vector_type(8))) short bf16x8;   // 8 x bf16 (4 VGPRs)
typedef __attribute__((ext_vector_type(4))) float f32x4;

#define DEVI __device__ __forceinline__

DEVI void load_lds16(const void* g, void* l) {
  __builtin_amdgcn_global_load_lds(
      (const __attribute__((address_space(1))) void*)g,
      (__attribute__((address_space(3))) void*)l, 16, 0, 0);
}

DEVI short bfbits(float x) {
  __hip_bfloat16 h = __float2bfloat16(x);
  return *reinterpret_cast<short*>(&h);
}

// ---------------------------------------------------------------------------
// Split-K GEMM: P[z][M*N] = A[M, kseg] * Bt^T partials (f32).
// 128x128 tile, 2-phase dbuf, slot-XOR swizzle, XCD swizzle.
// ---------------------------------------------------------------------------
__global__ __launch_bounds__(256, 4) void gemm_sk(
    const __hip_bfloat16* __restrict__ A, const __hip_bfloat16* __restrict__ Bt,
    float* __restrict__ P, int M, int N, int K) {
  const int nwg = gridDim.x * gridDim.y;
  const int lid = blockIdx.y * gridDim.x + blockIdx.x;
  const int work = (lid & 7) * (nwg >> 3) + (lid >> 3);
  const int n0 = (work % gridDim.x) * 128;
  const int m0 = (work / gridDim.x) * 128;
  const int KS = K / gridDim.z;
  const int kbeg = blockIdx.z * KS;

  const int t = threadIdx.x;
  const int w = t >> 6, l = t & 63;
  const int lr = l & 15, lk = l >> 4;
  const int wm = (w >> 1) * 64, wn = (w & 1) * 64;
  __shared__ __hip_bfloat16 Al[2][128 * 32];
  __shared__ __hip_bfloat16 Bl[2][128 * 32];

  f32x4 acc[4][4];
  const f32x4 z = {0.f, 0.f, 0.f, 0.f};
#pragma unroll
  for (int i = 0; i < 4; ++i)
#pragma unroll
    for (int j = 0; j < 4; ++j) acc[i][j] = z;

  const int srow = w * 16 + (l >> 2);
  const int scol = ((l & 3) ^ ((l >> 3) & 3)) * 8;
  const __hip_bfloat16* Ag = A + (size_t)(m0 + srow) * K + kbeg + scol;
  const __hip_bfloat16* Bg = Bt + (size_t)(n0 + srow) * K + kbeg + scol;

#define STAGE(buf, k0)                                                   \
  {                                                                      \
    load_lds16(Ag + (k0), (char*)Al[buf] + w * 1024);                    \
    load_lds16(Ag + (size_t)64 * K + (k0), (char*)Al[buf] + 4096 + w * 1024); \
    load_lds16(Bg + (k0), (char*)Bl[buf] + w * 1024);                    \
    load_lds16(Bg + (size_t)64 * K + (k0), (char*)Bl[buf] + 4096 + w * 1024); \
  }

  STAGE(0, 0);
  __syncthreads();
  int cur = 0;
  const int rs = (lk ^ ((lr >> 1) & 3)) * 16;
  for (int k0 = 0; k0 < KS; k0 += 32) {
    if (k0 + 32 < KS) STAGE(cur ^ 1, k0 + 32);
    bf16x8 af[4], bfr[4];
#pragma unroll
    for (int i = 0; i < 4; ++i)
      af[i] = *(const bf16x8*)((const char*)Al[cur] + ((wm + i * 16 + lr) * 64 + rs));
#pragma unroll
    for (int j = 0; j < 4; ++j)
      bfr[j] = *(const bf16x8*)((const char*)Bl[cur] + ((wn + j * 16 + lr) * 64 + rs));
#pragma unroll
    for (int i = 0; i < 4; ++i)
#pragma unroll
      for (int j = 0; j < 4; ++j)
        acc[i][j] = __builtin_amdgcn_mfma_f32_16x16x32_bf16(af[i], bfr[j], acc[i][j], 0, 0, 0);
    __syncthreads();
    cur ^= 1;
  }
#undef STAGE

  float* Pz = P + (size_t)blockIdx.z * M * N;
#pragma unroll
  for (int i = 0; i < 4; ++i) {
    const int row = m0 + wm + i * 16 + lk * 4;
#pragma unroll
    for (int j = 0; j < 4; ++j) {
      const int col = n0 + wn + j * 16 + lr;
#pragma unroll
      for (int r = 0; r < 4; ++r)
        Pz[(size_t)(row + r) * N + col] = acc[i][j][r];
    }
  }
}

// reduce split-K partials: out = sum_sk P + bias + res   (M*N = 524288, N=512)
__global__ __launch_bounds__(256) void reduce_sk(
    const float* __restrict__ P, const float* __restrict__ bias,
    const float* __restrict__ res, float* __restrict__ out, int SK) {
  const int i = blockIdx.x * 256 + threadIdx.x;
  float v = bias[i & 511] + res[i];
  for (int s = 0; s < SK; ++s) v += P[(size_t)s * 524288 + i];
  out[i] = v;
}

// reduce split-K partials -> bf16 (no bias/res)
__global__ __launch_bounds__(256) void reduce_bf16_sk(
    const float* __restrict__ P, __hip_bfloat16* __restrict__ out, int SK) {
  const int i = blockIdx.x * 256 + threadIdx.x;
  float v = 0.f;
  for (int s = 0; s < SK; ++s) v += P[(size_t)s * 524288 + i];
  out[i] = __float2bfloat16(v);
}

// reduce split-K + LayerNorm fused: one block per row; emits f32 x and bf16 LN(x)
__global__ __launch_bounds__(256) void reduce_ln_sk(
    const float* __restrict__ P, const float* __restrict__ bias,
    const float* __restrict__ res, float* __restrict__ xout,
    const float* __restrict__ w, const float* __restrict__ b,
    __hip_bfloat16* __restrict__ y, int SK) {
  const int row = blockIdx.x, t = threadIdx.x;
  const int c = t * 2;
  const size_t base = (size_t)row * 512 + c;
  float2 v = *(const float2*)&res[base];
  v.x += bias[c];
  v.y += bias[c + 1];
  for (int s = 0; s < SK; ++s) {
    const float2 p = *(const float2*)&P[(size_t)s * 524288 + base];
    v.x += p.x;
    v.y += p.y;
  }
  *(float2*)&xout[base] = v;
  float s1 = v.x + v.y, s2 = v.x * v.x + v.y * v.y;
#pragma unroll
  for (int d = 1; d < 64; d <<= 1) {
    s1 += __shfl_xor(s1, d);
    s2 += __shfl_xor(s2, d);
  }
  __shared__ float ss[4], ssq[4];
  if ((t & 63) == 0) { ss[t >> 6] = s1; ssq[t >> 6] = s2; }
  __syncthreads();
  s1 = ss[0] + ss[1] + ss[2] + ss[3];
  s2 = ssq[0] + ssq[1] + ssq[2] + ssq[3];
  const float mean = s1 * (1.f / 512.f);
  const float var = s2 * (1.f / 512.f) - mean * mean;
  const float rstd = rsqrtf(var + 1e-5f);
  y[base] = __float2bfloat16((v.x - mean) * rstd * w[c] + b[c]);
  y[base + 1] = __float2bfloat16((v.y - mean) * rstd * w[c + 1] + b[c + 1]);
}

// ---------------------------------------------------------------------------
// gemm_geglu: 64x128-tile GEMM with fused GEGLU epilogue (permuted w1).
// A[1024,512] bf16, Bt = permuted w1t[4096,512], out agb[1024,2048] bf16.
// grid (32, 16) = 512 blocks (2/CU). 4 waves, wave grid 2Mx2N, 32x64/wave,
// acc[2][4]. LDS 24 KB. Per 64-col group: cols 0-31 = a, 32-63 = matching g.
// ---------------------------------------------------------------------------
__global__ __launch_bounds__(256, 4) void gemm_geglu(
    const __hip_bfloat16* __restrict__ A, const __hip_bfloat16* __restrict__ Bt,
    __hip_bfloat16* __restrict__ Cb, const float* __restrict__ bias) {
  const int K = 512;
  const int nwg = gridDim.x * gridDim.y;
  const int lid = blockIdx.y * gridDim.x + blockIdx.x;
  const int work = (lid & 7) * (nwg >> 3) + (lid >> 3);
  const int n0 = (work % gridDim.x) * 128;
  const int m0 = (work / gridDim.x) * 64;

  const int t = threadIdx.x;
  const int w = t >> 6, l = t & 63;
  const int lr = l & 15, lk = l >> 4;
  const int wm = (w >> 1) * 32, wn = (w & 1) * 64;
  __shared__ __hip_bfloat16 Al[2][64 * 32];
  __shared__ __hip_bfloat16 Bl[2][128 * 32];

  f32x4 acc[2][4];
  const f32x4 z = {0.f, 0.f, 0.f, 0.f};
#pragma unroll
  for (int i = 0; i < 2; ++i)
#pragma unroll
    for (int j = 0; j < 4; ++j) acc[i][j] = z;

  const int srow = w * 16 + (l >> 2);
  const int scol = ((l & 3) ^ ((l >> 3) & 3)) * 8;
  const __hip_bfloat16* Ag = A + (size_t)(m0 + srow) * K + scol;
  const __hip_bfloat16* Bg = Bt + (size_t)(n0 + srow) * K + scol;

#define STAGE(buf, k0)                                                   \
  {                                                                      \
    load_lds16(Ag + (k0), (char*)Al[buf] + w * 1024);                    \
    load_lds16(Bg + (k0), (char*)Bl[buf] + w * 1024);                    \
    load_lds16(Bg + (size_t)64 * K + (k0), (char*)Bl[buf] + 4096 + w * 1024); \
  }

  STAGE(0, 0);
  __syncthreads();
  int cur = 0;
  const int rs = (lk ^ ((lr >> 1) & 3)) * 16;
  for (int k0 = 0; k0 < K; k0 += 32) {
    if (k0 + 32 < K) STAGE(cur ^ 1, k0 + 32);
    bf16x8 af[2], bfr[4];
#pragma unroll
    for (int i = 0; i < 2; ++i)
      af[i] = *(const bf16x8*)((const char*)Al[cur] + ((wm + i * 16 + lr) * 64 + rs));
#pragma unroll
    for (int j = 0; j < 4; ++j)
      bfr[j] = *(const bf16x8*)((const char*)Bl[cur] + ((wn + j * 16 + lr) * 64 + rs));
#pragma unroll
    for (int i = 0; i < 2; ++i)
#pragma unroll
      for (int j = 0; j < 4; ++j)
        acc[i][j] = __builtin_amdgcn_mfma_f32_16x16x32_bf16(af[i], bfr[j], acc[i][j], 0, 0, 0);
    __syncthreads();
    cur ^= 1;
  }
#undef STAGE

  const int nb = (n0 + wn) >> 1;   // output col base (N/2 space)
  float ba[2], bg[2];
#pragma unroll
  for (int jj = 0; jj < 2; ++jj) {
    ba[jj] = bias[nb + jj * 16 + lr];
    bg[jj] = bias[2048 + nb + jj * 16 + lr];
  }
#pragma unroll
  for (int i = 0; i < 2; ++i) {
    const int row = m0 + wm + i * 16 + lk * 4;
#pragma unroll
    for (int jj = 0; jj < 2; ++jj) {
      const int col = nb + jj * 16 + lr;
#pragma unroll
      for (int r = 0; r < 4; ++r) {
        const float a = acc[i][jj][r] + ba[jj];
        const float g = acc[i][jj + 2][r] + bg[jj];
        const float ge = 0.5f * g * (1.f + erff(g * 0.70710678118f));
        Cb[(size_t)(row + r) * 2048 + col] = __float2bfloat16(a * ge);
      }
    }
  }
}

// ---------------------------------------------------------------------------
// proj: C = A[M,512] * Bt^T with 3-way epilogue by column:
//   col < qcols -> Qb ; col < qcols+512 -> Kb ; else Vt transposed (4-key packs)
// ---------------------------------------------------------------------------
__global__ __launch_bounds__(256, 4) void proj_kernel(
    const __hip_bfloat16* __restrict__ A, const __hip_bfloat16* __restrict__ Bt,
    __hip_bfloat16* __restrict__ Qb, __hip_bfloat16* __restrict__ Kb,
    __hip_bfloat16* __restrict__ Vt, int qcols, int rpb_shift) {
  const int nwg = gridDim.x * gridDim.y;
  const int lid = blockIdx.y * gridDim.x + blockIdx.x;
  const int work = (lid & 7) * (nwg >> 3) + (lid >> 3);
  const int n0 = (work % gridDim.x) * 128;
  const int m0 = (work / gridDim.x) * 128;
  const int K = 512;

  const int t = threadIdx.x;
  const int w = t >> 6, l = t & 63;
  const int lr = l & 15, lk = l >> 4;
  const int wm = (w >> 1) * 64, wn = (w & 1) * 64;
  __shared__ __hip_bfloat16 Al[2][128 * 32];
  __shared__ __hip_bfloat16 Bl[2][128 * 32];

  f32x4 acc[4][4];
  const f32x4 z = {0.f, 0.f, 0.f, 0.f};
#pragma unroll
  for (int i = 0; i < 4; ++i)
#pragma unroll
    for (int j = 0; j < 4; ++j) acc[i][j] = z;

  const int srow = w * 16 + (l >> 2);
  const int scol = ((l & 3) ^ ((l >> 3) & 3)) * 8;
  const __hip_bfloat16* Ag = A + (size_t)(m0 + srow) * K + scol;
  const __hip_bfloat16* Bg = Bt + (size_t)(n0 + srow) * K + scol;

#define STAGE(buf, k0)                                                   \
  {                                                                      \
    load_lds16(Ag + (k0), (char*)Al[buf] + w * 1024);                    \
    load_lds16(Ag + (size_t)64 * K + (k0), (char*)Al[buf] + 4096 + w * 1024); \
    load_lds16(Bg + (k0), (char*)Bl[buf] + w * 1024);                    \
    load_lds16(Bg + (size_t)64 * K + (k0), (char*)Bl[buf] + 4096 + w * 1024); \
  }

  STAGE(0, 0);
  __syncthreads();
  int cur = 0;
  const int rs = (lk ^ ((lr >> 1) & 3)) * 16;
  for (int k0 = 0; k0 < K; k0 += 32) {
    if (k0 + 32 < K) STAGE(cur ^ 1, k0 + 32);
    bf16x8 af[4], bfr[4];
#pragma unroll
    for (int i = 0; i < 4; ++i)
      af[i] = *(const bf16x8*)((const char*)Al[cur] + ((wm + i * 16 + lr) * 64 + rs));
#pragma unroll
    for (int j = 0; j < 4; ++j)
      bfr[j] = *(const bf16x8*)((const char*)Bl[cur] + ((wn + j * 16 + lr) * 64 + rs));
#pragma unroll
    for (int i = 0; i < 4; ++i)
#pragma unroll
      for (int j = 0; j < 4; ++j)
        acc[i][j] = __builtin_amdgcn_mfma_f32_16x16x32_bf16(af[i], bfr[j], acc[i][j], 0, 0, 0);
    __syncthreads();
    cur ^= 1;
  }
#undef STAGE

  if (n0 < qcols) {
#pragma unroll
    for (int i = 0; i < 4; ++i) {
      const int row = m0 + wm + i * 16 + lk * 4;
#pragma unroll
      for (int j = 0; j < 4; ++j) {
        const int col = n0 + wn + j * 16 + lr;
#pragma unroll
        for (int r = 0; r < 4; ++r)
          Qb[(size_t)(row + r) * 512 + col] = __float2bfloat16(acc[i][j][r]);
      }
    }
  } else if (n0 < qcols + 512) {
#pragma unroll
    for (int i = 0; i < 4; ++i) {
      const int row = m0 + wm + i * 16 + lk * 4;
#pragma unroll
      for (int j = 0; j < 4; ++j) {
        const int col = n0 + wn + j * 16 + lr - qcols;
#pragma unroll
        for (int r = 0; r < 4; ++r)
          Kb[(size_t)(row + r) * 512 + col] = __float2bfloat16(acc[i][j][r]);
      }
    }
  } else {
    const int rpb = 1 << rpb_shift;
#pragma unroll
    for (int i = 0; i < 4; ++i) {
      const int row0 = m0 + wm + i * 16 + lk * 4;
      const int b = row0 >> rpb_shift;
      const int key0 = row0 & (rpb - 1);
#pragma unroll
      for (int j = 0; j < 4; ++j) {
        const int c = n0 + wn + j * 16 + lr - qcols - 512;
        const int hh = c >> 6, dh = c & 63;
        short4 pk;
        pk.x = bfbits(acc[i][j][0]);
        pk.y = bfbits(acc[i][j][1]);
        pk.z = bfbits(acc[i][j][2]);
        pk.w = bfbits(acc[i][j][3]);
        *(short4*)&Vt[((size_t)((b * 8 + hh) * 64 + dh) << rpb_shift) + key0] = pk;
      }
    }
  }
}

// ---------------------------------------------------------------------------
// Key-split flash attention, static-max softmax (data-safe: |s|<~4 << 88).
// If Od != nullptr (S==1): write normalized bf16 directly, skip partials.
// ---------------------------------------------------------------------------
__global__ __launch_bounds__(256) void attn_split_kernel(
    const __hip_bfloat16* __restrict__ Q, const __hip_bfloat16* __restrict__ Kb,
    const __hip_bfloat16* __restrict__ Vt,
    float* __restrict__ Opart, float* __restrict__ Lv,
    __hip_bfloat16* __restrict__ Od,
    int chunk, int rows_per_b, int S) {
  const float SC2 = 0.18033688f;   // 0.125 * log2(e)
  const int h = blockIdx.x, b = blockIdx.y, s = blockIdx.z;
  const int t = threadIdx.x;
  const int w = t >> 6, l = t & 63;
  const int lr = l & 15, lk = l >> 4;
  __shared__ __hip_bfloat16 Kl[64 * 64];
  __shared__ __hip_bfloat16 Vl[64 * 64];
  __shared__ __hip_bfloat16 Pl[4][32 * 64];

  bf16x8 qf[2][2];
#pragma unroll
  for (int mf = 0; mf < 2; ++mf)
#pragma unroll
    for (int kf = 0; kf < 2; ++kf)
      qf[mf][kf] = *(const bf16x8*)&Q[(size_t)(b * 128 + w * 32 + mf * 16 + lr) * 512 +
                                      h * 64 + kf * 32 + lk * 8];

  f32x4 o[2][4];
  const f32x4 z = {0.f, 0.f, 0.f, 0.f};
#pragma unroll
  for (int mf = 0; mf < 2; ++mf)
#pragma unroll
    for (int nf = 0; nf < 4; ++nf) o[mf][nf] = z;
  float lsum[2][4];
#pragma unroll
  for (int mf = 0; mf < 2; ++mf)
#pragma unroll
    for (int r = 0; r < 4; ++r) lsum[mf][r] = 0.f;

  const __hip_bfloat16* kvb = Kb + (size_t)b * rows_per_b * 512;
  const __hip_bfloat16* vtb = Vt + (size_t)(b * 8 + h) * 64 * rows_per_b;
  char* pw = (char*)Pl[w];
  const int srow = l >> 3;
  const int sslot = (l & 7) ^ srow;
  const int jend = s * chunk + chunk;

  for (int j0 = s * chunk; j0 < jend; j0 += 64) {
    __syncthreads();
#pragma unroll
    for (int p = 0; p < 2; ++p) {
      const int row = p * 32 + w * 8 + srow;
      load_lds16(&kvb[(size_t)(j0 + row) * 512 + h * 64 + sslot * 8],
                 (char*)Kl + p * 4096 + w * 1024);
      load_lds16(&vtb[(size_t)row * rows_per_b + j0 + sslot * 8],
                 (char*)Vl + p * 4096 + w * 1024);
    }
    __syncthreads();

    f32x4 sc[2][4];
#pragma unroll
    for (int mf = 0; mf < 2; ++mf)
#pragma unroll
      for (int nf = 0; nf < 4; ++nf) sc[mf][nf] = z;
    __builtin_amdgcn_s_setprio(1);
#pragma unroll
    for (int kf = 0; kf < 2; ++kf) {
      bf16x8 kb[4];
#pragma unroll
      for (int nf = 0; nf < 4; ++nf) {
        const int key = nf * 16 + lr;
        kb[nf] = *(const bf16x8*)((char*)Kl +
                  (key * 128 + (((kf * 4 + lk) ^ (key & 7)) * 16)));
      }
#pragma unroll
      for (int mf = 0; mf < 2; ++mf)
#pragma unroll
        for (int nf = 0; nf < 4; ++nf)
          sc[mf][nf] = __builtin_amdgcn_mfma_f32_16x16x32_bf16(qf[mf][kf], kb[nf], sc[mf][nf], 0, 0, 0);
    }
    __builtin_amdgcn_s_setprio(0);

#pragma unroll
    for (int mf = 0; mf < 2; ++mf)
#pragma unroll
      for (int nf = 0; nf < 4; ++nf)
#pragma unroll
        for (int r = 0; r < 4; ++r) {
          const float p = exp2f(sc[mf][nf][r] * SC2);
          sc[mf][nf][r] = p;
          lsum[mf][r] += p;
        }

#pragma unroll
    for (int mf = 0; mf < 2; ++mf)
#pragma unroll
      for (int r = 0; r < 4; ++r) {
        const int prow = mf * 16 + lk * 4 + r;
#pragma unroll
        for (int nf = 0; nf < 4; ++nf) {
          const int pcol = nf * 16 + lr;
          *(__hip_bfloat16*)(pw + ((prow * 128 + pcol * 2) ^ ((prow & 7) << 4))) =
              __float2bfloat16(sc[mf][nf][r]);
        }
      }

    __builtin_amdgcn_s_setprio(1);
#pragma unroll
    for (int kf = 0; kf < 2; ++kf) {
      bf16x8 pa[2], vb[4];
#pragma unroll
      for (int mf = 0; mf < 2; ++mf) {
        const int prow = mf * 16 + lr;
        pa[mf] = *(const bf16x8*)(pw + ((prow * 128 + (kf * 4 + lk) * 16) ^ ((prow & 7) << 4)));
      }
#pragma unroll
      for (int nf = 0; nf < 4; ++nf) {
        const int dh = nf * 16 + lr;
        vb[nf] = *(const bf16x8*)((char*)Vl +
                  (dh * 128 + (((kf * 4 + lk) ^ (dh & 7)) * 16)));
      }
#pragma unroll
      for (int mf = 0; mf < 2; ++mf)
#pragma unroll
        for (int nf = 0; nf < 4; ++nf)
          o[mf][nf] = __builtin_amdgcn_mfma_f32_16x16x32_bf16(pa[mf], vb[nf], o[mf][nf], 0, 0, 0);
    }
    __builtin_amdgcn_s_setprio(0);
  }

  const int part = (b * 8 + h) * S + s;
  float* op = Opart + (size_t)part * 8192;
#pragma unroll
  for (int mf = 0; mf < 2; ++mf)
#pragma unroll
    for (int r = 0; r < 4; ++r) {
      float ls = lsum[mf][r];
      ls += __shfl_xor(ls, 1);
      ls += __shfl_xor(ls, 2);
      ls += __shfl_xor(ls, 4);
      ls += __shfl_xor(ls, 8);
      const int row = w * 32 + mf * 16 + lk * 4 + r;
      if (Od) {
        const float inv = 1.f / ls;
#pragma unroll
        for (int nf = 0; nf < 4; ++nf)
          Od[(size_t)(b * 128 + row) * 512 + h * 64 + nf * 16 + lr] =
              __float2bfloat16(o[mf][nf][r] * inv);
      } else {
#pragma unroll
        for (int nf = 0; nf < 4; ++nf)
          op[(size_t)row * 64 + nf * 16 + lr] = o[mf][nf][r];
        if (lr == 0) Lv[(size_t)part * 128 + row] = ls;
      }
    }
}

__global__ __launch_bounds__(256) void attn_combine_kernel(
    const float* __restrict__ Opart, const float* __restrict__ Lv,
    __hip_bfloat16* __restrict__ O, int S) {
  const int row = blockIdx.x;
  const int b = row >> 7, i = row & 127;
  for (int c = threadIdx.x; c < 512; c += 256) {
    const int h = c >> 6, dh = c & 63;
    const int pbase = (b * 8 + h) * S;
    float L = 0.f, val = 0.f;
    for (int s = 0; s < S; ++s) {
      L += Lv[(size_t)(pbase + s) * 128 + i];
      val += Opart[((size_t)(pbase + s) * 128 + i) * 64 + dh];
    }
    O[(size_t)row * 512 + c] = __float2bfloat16(val / L);
  }
}

// ---------------------------------------------------------------------------
// LayerNorm row helper + merged leading LNs
// ---------------------------------------------------------------------------
DEVI void ln_row(const float* __restrict__ x, const float* __restrict__ w,
                 const float* __restrict__ bb, __hip_bfloat16* __restrict__ y,
                 int row, int t) {
  const float2 v = *(const float2*)&x[(size_t)row * 512 + t * 2];
  float s = v.x + v.y;
  float sq = v.x * v.x + v.y * v.y;
#pragma unroll
  for (int d = 1; d < 64; d <<= 1) {
    s += __shfl_xor(s, d);
    sq += __shfl_xor(sq, d);
  }
  __shared__ float ss[4], ssq[4];
  if ((t & 63) == 0) { ss[t >> 6] = s; ssq[t >> 6] = sq; }
  __syncthreads();
  s = ss[0] + ss[1] + ss[2] + ss[3];
  sq = ssq[0] + ssq[1] + ssq[2] + ssq[3];
  const float mean = s * (1.f / 512.f);
  const float var = sq * (1.f / 512.f) - mean * mean;
  const float rstd = rsqrtf(var + 1e-5f);
  const float2 wv = *(const float2*)&w[t * 2];
  const float2 bv = *(const float2*)&bb[t * 2];
  y[(size_t)row * 512 + t * 2] = __float2bfloat16((v.x - mean) * rstd * wv.x + bv.x);
  y[(size_t)row * 512 + t * 2 + 1] = __float2bfloat16((v.y - mean) * rstd * wv.y + bv.y);
}

__global__ __launch_bounds__(256) void ln2_kernel(
    const float* __restrict__ lat, const float* __restrict__ lw, const float* __restrict__ lb,
    __hip_bfloat16* __restrict__ xout,
    const float* __restrict__ ctx, const float* __restrict__ cw, const float* __restrict__ cb,
    __hip_bfloat16* __restrict__ cout) {
  const int row = blockIdx.x;
  if (row < 1024)
    ln_row(lat, lw, lb, xout, row, threadIdx.x);
  else
    ln_row(ctx, cw, cb, cout, row - 1024, threadIdx.x);
}

// ---------------------------------------------------------------------------
// Fused weight convert+transpose; w1 weights (wi 3/8) column-PERMUTED for GEGLU.
// ---------------------------------------------------------------------------
struct WcvtDesc { const float* src[10]; __hip_bfloat16* dst[10]; };

__global__ __launch_bounds__(256) void wcvt_all_kernel(WcvtDesc d) {
  int tile = blockIdx.x;
  const int set = tile >> 12;
  tile &= 4095;
  int wi, K, N, base;
  if (tile < 256)       { wi = 0; K = 512;  N = 512;  base = 0; }
  else if (tile < 768)  { wi = 1; K = 512;  N = 1024; base = 256; }
  else if (tile < 1024) { wi = 2; K = 512;  N = 512;  base = 768; }
  else if (tile < 3072) { wi = 3; K = 512;  N = 4096; base = 1024; }
  else                  { wi = 4; K = 2048; N = 512;  base = 3072; }
  const bool permute = (wi == 3);
  wi += set * 5;
  const int rel = tile - base;
  const int ntx = N >> 5;
  const int n0 = (rel % ntx) * 32, k0 = (rel / ntx) * 32;
  const int sn0 = permute ? (((n0 >> 6) << 5) + ((n0 & 32) ? 2048 : 0)) : n0;
  const float* W = d.src[wi];
  __hip_bfloat16* Wt = d.dst[wi];
  __shared__ float tl[32][33];
  const int tx = threadIdx.x & 31, ty = threadIdx.x >> 5;
#pragma unroll
  for (int j = 0; j < 4; ++j)
    tl[ty + j * 8][tx] = W[(size_t)(k0 + ty + j * 8) * N + sn0 + tx];
  __syncthreads();
#pragma unroll
  for (int j = 0; j < 4; ++j)
    Wt[(size_t)(n0 + ty + j * 8) * K + k0 + tx] = __float2bfloat16(tl[tx][ty + j * 8]);
}

// ---------------------------------------------------------------------------
extern "C" void kernel_launch(void* const* d_in, const int* in_sizes, int n_in,
                              void* d_out, int out_size, void* d_ws, size_t ws_size,
                              hipStream_t stream) {
  (void)in_sizes; (void)n_in; (void)out_size; (void)ws_size;
  const float* context = (const float*)d_in[0];
  const float* latents = (const float*)d_in[1];
  const float* ca_ln_w = (const float*)d_in[2];
  const float* ca_ln_b = (const float*)d_in[3];
  const float* ca_lnc_w = (const float*)d_in[4];
  const float* ca_lnc_b = (const float*)d_in[5];
  const float* ca_wq = (const float*)d_in[6];
  const float* ca_wkv = (const float*)d_in[7];
  const float* ca_wo = (const float*)d_in[8];
  const float* ca_bo = (const float*)d_in[9];
  const float* cf_ln_w = (const float*)d_in[10];
  const float* cf_ln_b = (const float*)d_in[11];
  const float* cf_w1 = (const float*)d_in[12];
  const float* cf_b1 = (const float*)d_in[13];
  const float* cf_w2 = (const float*)d_in[14];
  const float* cf_b2 = (const float*)d_in[15];
  const float* sa_ln_w = (const float*)d_in[16];
  const float* sa_ln_b = (const float*)d_in[17];
  const float* sa_wq = (const float*)d_in[18];
  const float* sa_wkv = (const float*)d_in[19];
  const float* sa_wo = (const float*)d_in[20];
  const float* sa_bo = (const float*)d_in[21];
  const float* lf_ln_w = (const float*)d_in[22];
  const float* lf_ln_b = (const float*)d_in[23];
  const float* lf_w1 = (const float*)d_in[24];
  const float* lf_b1 = (const float*)d_in[25];
  const float* lf_w2 = (const float*)d_in[26];
  const float* lf_b2 = (const float*)d_in[27];

  typedef __hip_bfloat16 bf;
  char* ws = (char*)d_ws;
  size_t off = 0;
  auto alloc = [&](size_t bytes) -> void* {
    void* p = ws + off;
    off += (bytes + 255) & ~(size_t)255;
    return p;
  };
  bf* wq1t = (bf*)alloc((size_t)512 * 512 * 2);
  bf* wkv1t = (bf*)alloc((size_t)1024 * 512 * 2);
  bf* wo1t = (bf*)alloc((size_t)512 * 512 * 2);
  bf* w1ct = (bf*)alloc((size_t)4096 * 512 * 2);
  bf* w2ct = (bf*)alloc((size_t)512 * 2048 * 2);
  bf* wq2t = (bf*)alloc((size_t)512 * 512 * 2);    // contiguous with wkv2t
  bf* wkv2t = (bf*)alloc((size_t)1024 * 512 * 2);
  bf* wo2t = (bf*)alloc((size_t)512 * 512 * 2);
  bf* w1lt = (bf*)alloc((size_t)4096 * 512 * 2);
  bf* w2lt = (bf*)alloc((size_t)512 * 2048 * 2);
  bf* cn = (bf*)alloc((size_t)32768 * 512 * 2);     // 33.5 MB; multi-reused
  bf* kbuf = (bf*)alloc((size_t)32768 * 512 * 2);   // cross K [row][512]
  bf* vt = (bf*)alloc((size_t)64 * 64 * 4096 * 2);  // cross V^T
  bf* kb2 = (bf*)alloc((size_t)1024 * 512 * 2);     // self K [row][512]
  bf* vt2 = (bf*)alloc((size_t)64 * 64 * 128 * 2);  // self V^T
  float* lv = (float*)alloc((size_t)1024 * 128 * 4);
  float* skq = (float*)alloc((size_t)4 * 1024 * 512 * 4);  // small-GEMM SK partials (8.4 MB)
  bf* xnb = (bf*)alloc((size_t)1024 * 512 * 2);
  bf* qb = (bf*)alloc((size_t)1024 * 512 * 2);
  bf* aob = (bf*)alloc((size_t)1024 * 512 * 2);
  bf* q2b = (bf*)alloc((size_t)1024 * 512 * 2);
  bf* ao2b = (bf*)alloc((size_t)1024 * 512 * 2);
  float* x1 = (float*)alloc((size_t)1024 * 512 * 4);
  float* x2 = (float*)alloc((size_t)1024 * 512 * 4);
  float* x3 = (float*)alloc((size_t)1024 * 512 * 4);
  bf* x2n = (bf*)alloc((size_t)1024 * 512 * 2);
  bf* x3n = (bf*)alloc((size_t)1024 * 512 * 2);
  // cn region time-disjoint reuse:
  float* opart = (float*)cn;                       // attn partials (33.5 MB)
  float* skp = (float*)cn;                         // FFN-down SK=8 partials (16.8 MB)
  bf* agb = (bf*)((char*)cn + 17 * 1024 * 1024);   // GEGLU out (4.2 MB)

  WcvtDesc wd;
  wd.src[0] = ca_wq;  wd.dst[0] = wq1t;
  wd.src[1] = ca_wkv; wd.dst[1] = wkv1t;
  wd.src[2] = ca_wo;  wd.dst[2] = wo1t;
  wd.src[3] = cf_w1;  wd.dst[3] = w1ct;
  wd.src[4] = cf_w2;  wd.dst[4] = w2ct;
  wd.src[5] = sa_wq;  wd.dst[5] = wq2t;
  wd.src[6] = sa_wkv; wd.dst[6] = wkv2t;
  wd.src[7] = sa_wo;  wd.dst[7] = wo2t;
  wd.src[8] = lf_w1;  wd.dst[8] = w1lt;
  wd.src[9] = lf_w2;  wd.dst[9] = w2lt;
  wcvt_all_kernel<<<8192, 256, 0, stream>>>(wd);

  // --- sublayer 1: cross attention ---
  ln2_kernel<<<33792, 256, 0, stream>>>(latents, ca_ln_w, ca_ln_b, xnb,
                                        context, ca_lnc_w, ca_lnc_b, cn);
  gemm_sk<<<dim3(4, 8, 4), 256, 0, stream>>>(xnb, wq1t, skq, 1024, 512, 512);
  reduce_bf16_sk<<<2048, 256, 0, stream>>>(skq, qb, 4);
  proj_kernel<<<dim3(8, 256), 256, 0, stream>>>(cn, wkv1t, nullptr, kbuf, vt, 0, 12);
  attn_split_kernel<<<dim3(8, 8, 16), 256, 0, stream>>>(qb, kbuf, vt, opart, lv, nullptr, 256, 4096, 16);
  attn_combine_kernel<<<1024, 256, 0, stream>>>(opart, lv, aob, 16);
  gemm_sk<<<dim3(4, 8, 4), 256, 0, stream>>>(aob, wo1t, skq, 1024, 512, 512);
  reduce_ln_sk<<<1024, 256, 0, stream>>>(skq, ca_bo, latents, x1, cf_ln_w, cf_ln_b, xnb, 4);

  // --- sublayer 2: cross FFN (GEGLU fused up-proj, SK=8 down-proj) ---
  gemm_geglu<<<dim3(32, 16), 256, 0, stream>>>(xnb, w1ct, agb, cf_b1);
  gemm_sk<<<dim3(4, 8, 8), 256, 0, stream>>>(agb, w2ct, skp, 1024, 512, 2048);
  reduce_ln_sk<<<1024, 256, 0, stream>>>(skp, cf_b2, x1, x2, sa_ln_w, sa_ln_b, x2n, 8);

  // --- sublayer 3: latent self-attention (merged QKV, direct write) ---
  proj_kernel<<<dim3(12, 8), 256, 0, stream>>>(x2n, wq2t, q2b, kb2, vt2, 512, 7);
  attn_split_kernel<<<dim3(8, 8, 1), 256, 0, stream>>>(q2b, kb2, vt2, nullptr, nullptr, ao2b, 128, 128, 1);
  gemm_sk<<<dim3(4, 8, 4), 256, 0, stream>>>(ao2b, wo2t, skq, 1024, 512, 512);
  reduce_ln_sk<<<1024, 256, 0, stream>>>(skq, sa_bo, x2, x3, lf_ln_w, lf_ln_b, x3n, 4);

  // --- sublayer 4: latent FFN (GEGLU fused up-proj, SK=8 down-proj) ---
  gemm_geglu<<<dim3(32, 16), 256, 0, stream>>>(x3n, w1lt, agb, lf_b1);
  gemm_sk<<<dim3(4, 8, 8), 256, 0, stream>>>(agb, w2lt, skp, 1024, 512, 2048);
  reduce_sk<<<2048, 256, 0, stream>>>(skp, lf_b2, x3, (float*)d_out, 8);
}

// Round 12
// 224.093 us; speedup vs baseline: 1.4563x; 1.0493x over previous
//
#include <hip/hip_runtime.h>
#include <hip/hip_bf16.h>
#include <math.h>

// ---------------------------------------------------------------------------
// LBANP encoder layer on MI355X (gfx950).
// Round 12: bf16 attention partials; cross q-proj folded into the KV-proj
// grid (projx_kernel, 2080 blocks); wcvt+LN merged into one prep_kernel.
// ---------------------------------------------------------------------------

typedef __attribute__((ext_vector_type(8))) short bf16x8;   // 8 x bf16 (4 VGPRs)
typedef __attribute__((ext_vector_type(4))) float f32x4;

#define DEVI __device__ __forceinline__

DEVI void load_lds16(const void* g, void* l) {
  __builtin_amdgcn_global_load_lds(
      (const __attribute__((address_space(1))) void*)g,
      (__attribute__((address_space(3))) void*)l, 16, 0, 0);
}

DEVI short bfbits(float x) {
  __hip_bfloat16 h = __float2bfloat16(x);
  return *reinterpret_cast<short*>(&h);
}

// ---------------------------------------------------------------------------
// Split-K GEMM: P[z][M*N] = A[M, kseg] * Bt^T partials (f32).
// 128x128 tile, 2-phase dbuf, slot-XOR swizzle, XCD swizzle.
// ---------------------------------------------------------------------------
__global__ __launch_bounds__(256, 4) void gemm_sk(
    const __hip_bfloat16* __restrict__ A, const __hip_bfloat16* __restrict__ Bt,
    float* __restrict__ P, int M, int N, int K) {
  const int nwg = gridDim.x * gridDim.y;
  const int lid = blockIdx.y * gridDim.x + blockIdx.x;
  const int work = (lid & 7) * (nwg >> 3) + (lid >> 3);
  const int n0 = (work % gridDim.x) * 128;
  const int m0 = (work / gridDim.x) * 128;
  const int KS = K / gridDim.z;
  const int kbeg = blockIdx.z * KS;

  const int t = threadIdx.x;
  const int w = t >> 6, l = t & 63;
  const int lr = l & 15, lk = l >> 4;
  const int wm = (w >> 1) * 64, wn = (w & 1) * 64;
  __shared__ __hip_bfloat16 Al[2][128 * 32];
  __shared__ __hip_bfloat16 Bl[2][128 * 32];

  f32x4 acc[4][4];
  const f32x4 z = {0.f, 0.f, 0.f, 0.f};
#pragma unroll
  for (int i = 0; i < 4; ++i)
#pragma unroll
    for (int j = 0; j < 4; ++j) acc[i][j] = z;

  const int srow = w * 16 + (l >> 2);
  const int scol = ((l & 3) ^ ((l >> 3) & 3)) * 8;
  const __hip_bfloat16* Ag = A + (size_t)(m0 + srow) * K + kbeg + scol;
  const __hip_bfloat16* Bg = Bt + (size_t)(n0 + srow) * K + kbeg + scol;

#define STAGE(buf, k0)                                                   \
  {                                                                      \
    load_lds16(Ag + (k0), (char*)Al[buf] + w * 1024);                    \
    load_lds16(Ag + (size_t)64 * K + (k0), (char*)Al[buf] + 4096 + w * 1024); \
    load_lds16(Bg + (k0), (char*)Bl[buf] + w * 1024);                    \
    load_lds16(Bg + (size_t)64 * K + (k0), (char*)Bl[buf] + 4096 + w * 1024); \
  }

  STAGE(0, 0);
  __syncthreads();
  int cur = 0;
  const int rs = (lk ^ ((lr >> 1) & 3)) * 16;
  for (int k0 = 0; k0 < KS; k0 += 32) {
    if (k0 + 32 < KS) STAGE(cur ^ 1, k0 + 32);
    bf16x8 af[4], bfr[4];
#pragma unroll
    for (int i = 0; i < 4; ++i)
      af[i] = *(const bf16x8*)((const char*)Al[cur] + ((wm + i * 16 + lr) * 64 + rs));
#pragma unroll
    for (int j = 0; j < 4; ++j)
      bfr[j] = *(const bf16x8*)((const char*)Bl[cur] + ((wn + j * 16 + lr) * 64 + rs));
#pragma unroll
    for (int i = 0; i < 4; ++i)
#pragma unroll
      for (int j = 0; j < 4; ++j)
        acc[i][j] = __builtin_amdgcn_mfma_f32_16x16x32_bf16(af[i], bfr[j], acc[i][j], 0, 0, 0);
    __syncthreads();
    cur ^= 1;
  }
#undef STAGE

  float* Pz = P + (size_t)blockIdx.z * M * N;
#pragma unroll
  for (int i = 0; i < 4; ++i) {
    const int row = m0 + wm + i * 16 + lk * 4;
#pragma unroll
    for (int j = 0; j < 4; ++j) {
      const int col = n0 + wn + j * 16 + lr;
#pragma unroll
      for (int r = 0; r < 4; ++r)
        Pz[(size_t)(row + r) * N + col] = acc[i][j][r];
    }
  }
}

// reduce split-K partials: out = sum_sk P + bias + res   (M*N = 524288, N=512)
__global__ __launch_bounds__(256) void reduce_sk(
    const float* __restrict__ P, const float* __restrict__ bias,
    const float* __restrict__ res, float* __restrict__ out, int SK) {
  const int i = blockIdx.x * 256 + threadIdx.x;
  float v = bias[i & 511] + res[i];
  for (int s = 0; s < SK; ++s) v += P[(size_t)s * 524288 + i];
  out[i] = v;
}

// reduce split-K + LayerNorm fused: one block per row; emits f32 x and bf16 LN(x)
__global__ __launch_bounds__(256) void reduce_ln_sk(
    const float* __restrict__ P, const float* __restrict__ bias,
    const float* __restrict__ res, float* __restrict__ xout,
    const float* __restrict__ w, const float* __restrict__ b,
    __hip_bfloat16* __restrict__ y, int SK) {
  const int row = blockIdx.x, t = threadIdx.x;
  const int c = t * 2;
  const size_t base = (size_t)row * 512 + c;
  float2 v = *(const float2*)&res[base];
  v.x += bias[c];
  v.y += bias[c + 1];
  for (int s = 0; s < SK; ++s) {
    const float2 p = *(const float2*)&P[(size_t)s * 524288 + base];
    v.x += p.x;
    v.y += p.y;
  }
  *(float2*)&xout[base] = v;
  float s1 = v.x + v.y, s2 = v.x * v.x + v.y * v.y;
#pragma unroll
  for (int d = 1; d < 64; d <<= 1) {
    s1 += __shfl_xor(s1, d);
    s2 += __shfl_xor(s2, d);
  }
  __shared__ float ss[4], ssq[4];
  if ((t & 63) == 0) { ss[t >> 6] = s1; ssq[t >> 6] = s2; }
  __syncthreads();
  s1 = ss[0] + ss[1] + ss[2] + ss[3];
  s2 = ssq[0] + ssq[1] + ssq[2] + ssq[3];
  const float mean = s1 * (1.f / 512.f);
  const float var = s2 * (1.f / 512.f) - mean * mean;
  const float rstd = rsqrtf(var + 1e-5f);
  y[base] = __float2bfloat16((v.x - mean) * rstd * w[c] + b[c]);
  y[base + 1] = __float2bfloat16((v.y - mean) * rstd * w[c + 1] + b[c + 1]);
}

// ---------------------------------------------------------------------------
// gemm_geglu: 64x128-tile GEMM with fused GEGLU epilogue (permuted w1).
// grid (32, 16) = 512 blocks. 4 waves, 2Mx2N, 32x64/wave, acc[2][4]. LDS 24KB.
// ---------------------------------------------------------------------------
__global__ __launch_bounds__(256, 4) void gemm_geglu(
    const __hip_bfloat16* __restrict__ A, const __hip_bfloat16* __restrict__ Bt,
    __hip_bfloat16* __restrict__ Cb, const float* __restrict__ bias) {
  const int K = 512;
  const int nwg = gridDim.x * gridDim.y;
  const int lid = blockIdx.y * gridDim.x + blockIdx.x;
  const int work = (lid & 7) * (nwg >> 3) + (lid >> 3);
  const int n0 = (work % gridDim.x) * 128;
  const int m0 = (work / gridDim.x) * 64;

  const int t = threadIdx.x;
  const int w = t >> 6, l = t & 63;
  const int lr = l & 15, lk = l >> 4;
  const int wm = (w >> 1) * 32, wn = (w & 1) * 64;
  __shared__ __hip_bfloat16 Al[2][64 * 32];
  __shared__ __hip_bfloat16 Bl[2][128 * 32];

  f32x4 acc[2][4];
  const f32x4 z = {0.f, 0.f, 0.f, 0.f};
#pragma unroll
  for (int i = 0; i < 2; ++i)
#pragma unroll
    for (int j = 0; j < 4; ++j) acc[i][j] = z;

  const int srow = w * 16 + (l >> 2);
  const int scol = ((l & 3) ^ ((l >> 3) & 3)) * 8;
  const __hip_bfloat16* Ag = A + (size_t)(m0 + srow) * K + scol;
  const __hip_bfloat16* Bg = Bt + (size_t)(n0 + srow) * K + scol;

#define STAGE(buf, k0)                                                   \
  {                                                                      \
    load_lds16(Ag + (k0), (char*)Al[buf] + w * 1024);                    \
    load_lds16(Bg + (k0), (char*)Bl[buf] + w * 1024);                    \
    load_lds16(Bg + (size_t)64 * K + (k0), (char*)Bl[buf] + 4096 + w * 1024); \
  }

  STAGE(0, 0);
  __syncthreads();
  int cur = 0;
  const int rs = (lk ^ ((lr >> 1) & 3)) * 16;
  for (int k0 = 0; k0 < K; k0 += 32) {
    if (k0 + 32 < K) STAGE(cur ^ 1, k0 + 32);
    bf16x8 af[2], bfr[4];
#pragma unroll
    for (int i = 0; i < 2; ++i)
      af[i] = *(const bf16x8*)((const char*)Al[cur] + ((wm + i * 16 + lr) * 64 + rs));
#pragma unroll
    for (int j = 0; j < 4; ++j)
      bfr[j] = *(const bf16x8*)((const char*)Bl[cur] + ((wn + j * 16 + lr) * 64 + rs));
#pragma unroll
    for (int i = 0; i < 2; ++i)
#pragma unroll
      for (int j = 0; j < 4; ++j)
        acc[i][j] = __builtin_amdgcn_mfma_f32_16x16x32_bf16(af[i], bfr[j], acc[i][j], 0, 0, 0);
    __syncthreads();
    cur ^= 1;
  }
#undef STAGE

  const int nb = (n0 + wn) >> 1;
  float ba[2], bg[2];
#pragma unroll
  for (int jj = 0; jj < 2; ++jj) {
    ba[jj] = bias[nb + jj * 16 + lr];
    bg[jj] = bias[2048 + nb + jj * 16 + lr];
  }
#pragma unroll
  for (int i = 0; i < 2; ++i) {
    const int row = m0 + wm + i * 16 + lk * 4;
#pragma unroll
    for (int jj = 0; jj < 2; ++jj) {
      const int col = nb + jj * 16 + lr;
#pragma unroll
      for (int r = 0; r < 4; ++r) {
        const float a = acc[i][jj][r] + ba[jj];
        const float g = acc[i][jj + 2][r] + bg[jj];
        const float ge = 0.5f * g * (1.f + erff(g * 0.70710678118f));
        Cb[(size_t)(row + r) * 2048 + col] = __float2bfloat16(a * ge);
      }
    }
  }
}

// ---------------------------------------------------------------------------
// projx: cross-attention projection, 1D grid 2080 = 2048 KV-blocks + 32 Q-blocks.
//   KV blocks: A=ctx (cn), Bt=wkv1t; n0<512 -> Kb, else Vt transposed (rpb 4096).
//   Q blocks:  A=xnb, Bt=wq1t -> Qb plain bf16.
// ---------------------------------------------------------------------------
__global__ __launch_bounds__(256, 4) void projx_kernel(
    const __hip_bfloat16* __restrict__ ctx, const __hip_bfloat16* __restrict__ wkv,
    __hip_bfloat16* __restrict__ Kb, __hip_bfloat16* __restrict__ Vt,
    const __hip_bfloat16* __restrict__ xq, const __hip_bfloat16* __restrict__ wq,
    __hip_bfloat16* __restrict__ Qb) {
  const int nwg = gridDim.x;   // 2080, % 8 == 0
  const int lid = blockIdx.x;
  const int work = (lid & 7) * (nwg >> 3) + (lid >> 3);
  const int K = 512;

  const __hip_bfloat16 *A, *Bt;
  int m0, n0, mode;   // 0 = K half, 1 = V half, 2 = Q
  if (work < 2048) {
    m0 = (work >> 3) * 128;
    n0 = (work & 7) * 128;
    A = ctx; Bt = wkv;
    mode = (n0 < 512) ? 0 : 1;
  } else {
    const int idx = work - 2048;
    m0 = (idx >> 2) * 128;
    n0 = (idx & 3) * 128;
    A = xq; Bt = wq;
    mode = 2;
  }

  const int t = threadIdx.x;
  const int w = t >> 6, l = t & 63;
  const int lr = l & 15, lk = l >> 4;
  const int wm = (w >> 1) * 64, wn = (w & 1) * 64;
  __shared__ __hip_bfloat16 Al[2][128 * 32];
  __shared__ __hip_bfloat16 Bl[2][128 * 32];

  f32x4 acc[4][4];
  const f32x4 z = {0.f, 0.f, 0.f, 0.f};
#pragma unroll
  for (int i = 0; i < 4; ++i)
#pragma unroll
    for (int j = 0; j < 4; ++j) acc[i][j] = z;

  const int srow = w * 16 + (l >> 2);
  const int scol = ((l & 3) ^ ((l >> 3) & 3)) * 8;
  const __hip_bfloat16* Ag = A + (size_t)(m0 + srow) * K + scol;
  const __hip_bfloat16* Bg = Bt + (size_t)(n0 + srow) * K + scol;

#define STAGE(buf, k0)                                                   \
  {                                                                      \
    load_lds16(Ag + (k0), (char*)Al[buf] + w * 1024);                    \
    load_lds16(Ag + (size_t)64 * K + (k0), (char*)Al[buf] + 4096 + w * 1024); \
    load_lds16(Bg + (k0), (char*)Bl[buf] + w * 1024);                    \
    load_lds16(Bg + (size_t)64 * K + (k0), (char*)Bl[buf] + 4096 + w * 1024); \
  }

  STAGE(0, 0);
  __syncthreads();
  int cur = 0;
  const int rs = (lk ^ ((lr >> 1) & 3)) * 16;
  for (int k0 = 0; k0 < K; k0 += 32) {
    if (k0 + 32 < K) STAGE(cur ^ 1, k0 + 32);
    bf16x8 af[4], bfr[4];
#pragma unroll
    for (int i = 0; i < 4; ++i)
      af[i] = *(const bf16x8*)((const char*)Al[cur] + ((wm + i * 16 + lr) * 64 + rs));
#pragma unroll
    for (int j = 0; j < 4; ++j)
      bfr[j] = *(const bf16x8*)((const char*)Bl[cur] + ((wn + j * 16 + lr) * 64 + rs));
#pragma unroll
    for (int i = 0; i < 4; ++i)
#pragma unroll
      for (int j = 0; j < 4; ++j)
        acc[i][j] = __builtin_amdgcn_mfma_f32_16x16x32_bf16(af[i], bfr[j], acc[i][j], 0, 0, 0);
    __syncthreads();
    cur ^= 1;
  }
#undef STAGE

  if (mode == 0) {
#pragma unroll
    for (int i = 0; i < 4; ++i) {
      const int row = m0 + wm + i * 16 + lk * 4;
#pragma unroll
      for (int j = 0; j < 4; ++j) {
        const int col = n0 + wn + j * 16 + lr;
#pragma unroll
        for (int r = 0; r < 4; ++r)
          Kb[(size_t)(row + r) * 512 + col] = __float2bfloat16(acc[i][j][r]);
      }
    }
  } else if (mode == 1) {
#pragma unroll
    for (int i = 0; i < 4; ++i) {
      const int row0 = m0 + wm + i * 16 + lk * 4;
      const int b = row0 >> 12;
      const int key0 = row0 & 4095;
#pragma unroll
      for (int j = 0; j < 4; ++j) {
        const int c = n0 + wn + j * 16 + lr - 512;
        const int hh = c >> 6, dh = c & 63;
        short4 pk;
        pk.x = bfbits(acc[i][j][0]);
        pk.y = bfbits(acc[i][j][1]);
        pk.z = bfbits(acc[i][j][2]);
        pk.w = bfbits(acc[i][j][3]);
        *(short4*)&Vt[((size_t)((b * 8 + hh) * 64 + dh) << 12) + key0] = pk;
      }
    }
  } else {
#pragma unroll
    for (int i = 0; i < 4; ++i) {
      const int row = m0 + wm + i * 16 + lk * 4;
#pragma unroll
      for (int j = 0; j < 4; ++j) {
        const int col = n0 + wn + j * 16 + lr;
#pragma unroll
        for (int r = 0; r < 4; ++r)
          Qb[(size_t)(row + r) * 512 + col] = __float2bfloat16(acc[i][j][r]);
      }
    }
  }
}

// ---------------------------------------------------------------------------
// proj (self-attn): C = A[M,512] * Bt^T, 3-way epilogue by column:
//   col < qcols -> Qb ; col < qcols+512 -> Kb ; else Vt transposed
// ---------------------------------------------------------------------------
__global__ __launch_bounds__(256, 4) void proj_kernel(
    const __hip_bfloat16* __restrict__ A, const __hip_bfloat16* __restrict__ Bt,
    __hip_bfloat16* __restrict__ Qb, __hip_bfloat16* __restrict__ Kb,
    __hip_bfloat16* __restrict__ Vt, int qcols, int rpb_shift) {
  const int nwg = gridDim.x * gridDim.y;
  const int lid = blockIdx.y * gridDim.x + blockIdx.x;
  const int work = (lid & 7) * (nwg >> 3) + (lid >> 3);
  const int n0 = (work % gridDim.x) * 128;
  const int m0 = (work / gridDim.x) * 128;
  const int K = 512;

  const int t = threadIdx.x;
  const int w = t >> 6, l = t & 63;
  const int lr = l & 15, lk = l >> 4;
  const int wm = (w >> 1) * 64, wn = (w & 1) * 64;
  __shared__ __hip_bfloat16 Al[2][128 * 32];
  __shared__ __hip_bfloat16 Bl[2][128 * 32];

  f32x4 acc[4][4];
  const f32x4 z = {0.f, 0.f, 0.f, 0.f};
#pragma unroll
  for (int i = 0; i < 4; ++i)
#pragma unroll
    for (int j = 0; j < 4; ++j) acc[i][j] = z;

  const int srow = w * 16 + (l >> 2);
  const int scol = ((l & 3) ^ ((l >> 3) & 3)) * 8;
  const __hip_bfloat16* Ag = A + (size_t)(m0 + srow) * K + scol;
  const __hip_bfloat16* Bg = Bt + (size_t)(n0 + srow) * K + scol;

#define STAGE(buf, k0)                                                   \
  {                                                                      \
    load_lds16(Ag + (k0), (char*)Al[buf] + w * 1024);                    \
    load_lds16(Ag + (size_t)64 * K + (k0), (char*)Al[buf] + 4096 + w * 1024); \
    load_lds16(Bg + (k0), (char*)Bl[buf] + w * 1024);                    \
    load_lds16(Bg + (size_t)64 * K + (k0), (char*)Bl[buf] + 4096 + w * 1024); \
  }

  STAGE(0, 0);
  __syncthreads();
  int cur = 0;
  const int rs = (lk ^ ((lr >> 1) & 3)) * 16;
  for (int k0 = 0; k0 < K; k0 += 32) {
    if (k0 + 32 < K) STAGE(cur ^ 1, k0 + 32);
    bf16x8 af[4], bfr[4];
#pragma unroll
    for (int i = 0; i < 4; ++i)
      af[i] = *(const bf16x8*)((const char*)Al[cur] + ((wm + i * 16 + lr) * 64 + rs));
#pragma unroll
    for (int j = 0; j < 4; ++j)
      bfr[j] = *(const bf16x8*)((const char*)Bl[cur] + ((wn + j * 16 + lr) * 64 + rs));
#pragma unroll
    for (int i = 0; i < 4; ++i)
#pragma unroll
      for (int j = 0; j < 4; ++j)
        acc[i][j] = __builtin_amdgcn_mfma_f32_16x16x32_bf16(af[i], bfr[j], acc[i][j], 0, 0, 0);
    __syncthreads();
    cur ^= 1;
  }
#undef STAGE

  if (n0 < qcols) {
#pragma unroll
    for (int i = 0; i < 4; ++i) {
      const int row = m0 + wm + i * 16 + lk * 4;
#pragma unroll
      for (int j = 0; j < 4; ++j) {
        const int col = n0 + wn + j * 16 + lr;
#pragma unroll
        for (int r = 0; r < 4; ++r)
          Qb[(size_t)(row + r) * 512 + col] = __float2bfloat16(acc[i][j][r]);
      }
    }
  } else if (n0 < qcols + 512) {
#pragma unroll
    for (int i = 0; i < 4; ++i) {
      const int row = m0 + wm + i * 16 + lk * 4;
#pragma unroll
      for (int j = 0; j < 4; ++j) {
        const int col = n0 + wn + j * 16 + lr - qcols;
#pragma unroll
        for (int r = 0; r < 4; ++r)
          Kb[(size_t)(row + r) * 512 + col] = __float2bfloat16(acc[i][j][r]);
      }
    }
  } else {
    const int rpb = 1 << rpb_shift;
#pragma unroll
    for (int i = 0; i < 4; ++i) {
      const int row0 = m0 + wm + i * 16 + lk * 4;
      const int b = row0 >> rpb_shift;
      const int key0 = row0 & (rpb - 1);
#pragma unroll
      for (int j = 0; j < 4; ++j) {
        const int c = n0 + wn + j * 16 + lr - qcols - 512;
        const int hh = c >> 6, dh = c & 63;
        short4 pk;
        pk.x = bfbits(acc[i][j][0]);
        pk.y = bfbits(acc[i][j][1]);
        pk.z = bfbits(acc[i][j][2]);
        pk.w = bfbits(acc[i][j][3]);
        *(short4*)&Vt[((size_t)((b * 8 + hh) * 64 + dh) << rpb_shift) + key0] = pk;
      }
    }
  }
}

// ---------------------------------------------------------------------------
// Key-split flash attention, static-max softmax (data-safe: |s|<~4 << 88).
// Partials stored as bf16 (rel err ~0.2%); row sums Lv stay f32.
// If Od != nullptr (S==1): write normalized bf16 directly, skip partials.
// ---------------------------------------------------------------------------
__global__ __launch_bounds__(256) void attn_split_kernel(
    const __hip_bfloat16* __restrict__ Q, const __hip_bfloat16* __restrict__ Kb,
    const __hip_bfloat16* __restrict__ Vt,
    __hip_bfloat16* __restrict__ Opart, float* __restrict__ Lv,
    __hip_bfloat16* __restrict__ Od,
    int chunk, int rows_per_b, int S) {
  const float SC2 = 0.18033688f;   // 0.125 * log2(e)
  const int h = blockIdx.x, b = blockIdx.y, s = blockIdx.z;
  const int t = threadIdx.x;
  const int w = t >> 6, l = t & 63;
  const int lr = l & 15, lk = l >> 4;
  __shared__ __hip_bfloat16 Kl[64 * 64];
  __shared__ __hip_bfloat16 Vl[64 * 64];
  __shared__ __hip_bfloat16 Pl[4][32 * 64];

  bf16x8 qf[2][2];
#pragma unroll
  for (int mf = 0; mf < 2; ++mf)
#pragma unroll
    for (int kf = 0; kf < 2; ++kf)
      qf[mf][kf] = *(const bf16x8*)&Q[(size_t)(b * 128 + w * 32 + mf * 16 + lr) * 512 +
                                      h * 64 + kf * 32 + lk * 8];

  f32x4 o[2][4];
  const f32x4 z = {0.f, 0.f, 0.f, 0.f};
#pragma unroll
  for (int mf = 0; mf < 2; ++mf)
#pragma unroll
    for (int nf = 0; nf < 4; ++nf) o[mf][nf] = z;
  float lsum[2][4];
#pragma unroll
  for (int mf = 0; mf < 2; ++mf)
#pragma unroll
    for (int r = 0; r < 4; ++r) lsum[mf][r] = 0.f;

  const __hip_bfloat16* kvb = Kb + (size_t)b * rows_per_b * 512;
  const __hip_bfloat16* vtb = Vt + (size_t)(b * 8 + h) * 64 * rows_per_b;
  char* pw = (char*)Pl[w];
  const int srow = l >> 3;
  const int sslot = (l & 7) ^ srow;
  const int jend = s * chunk + chunk;

  for (int j0 = s * chunk; j0 < jend; j0 += 64) {
    __syncthreads();
#pragma unroll
    for (int p = 0; p < 2; ++p) {
      const int row = p * 32 + w * 8 + srow;
      load_lds16(&kvb[(size_t)(j0 + row) * 512 + h * 64 + sslot * 8],
                 (char*)Kl + p * 4096 + w * 1024);
      load_lds16(&vtb[(size_t)row * rows_per_b + j0 + sslot * 8],
                 (char*)Vl + p * 4096 + w * 1024);
    }
    __syncthreads();

    f32x4 sc[2][4];
#pragma unroll
    for (int mf = 0; mf < 2; ++mf)
#pragma unroll
      for (int nf = 0; nf < 4; ++nf) sc[mf][nf] = z;
    __builtin_amdgcn_s_setprio(1);
#pragma unroll
    for (int kf = 0; kf < 2; ++kf) {
      bf16x8 kb[4];
#pragma unroll
      for (int nf = 0; nf < 4; ++nf) {
        const int key = nf * 16 + lr;
        kb[nf] = *(const bf16x8*)((char*)Kl +
                  (key * 128 + (((kf * 4 + lk) ^ (key & 7)) * 16)));
      }
#pragma unroll
      for (int mf = 0; mf < 2; ++mf)
#pragma unroll
        for (int nf = 0; nf < 4; ++nf)
          sc[mf][nf] = __builtin_amdgcn_mfma_f32_16x16x32_bf16(qf[mf][kf], kb[nf], sc[mf][nf], 0, 0, 0);
    }
    __builtin_amdgcn_s_setprio(0);

#pragma unroll
    for (int mf = 0; mf < 2; ++mf)
#pragma unroll
      for (int nf = 0; nf < 4; ++nf)
#pragma unroll
        for (int r = 0; r < 4; ++r) {
          const float p = exp2f(sc[mf][nf][r] * SC2);
          sc[mf][nf][r] = p;
          lsum[mf][r] += p;
        }

#pragma unroll
    for (int mf = 0; mf < 2; ++mf)
#pragma unroll
      for (int r = 0; r < 4; ++r) {
        const int prow = mf * 16 + lk * 4 + r;
#pragma unroll
        for (int nf = 0; nf < 4; ++nf) {
          const int pcol = nf * 16 + lr;
          *(__hip_bfloat16*)(pw + ((prow * 128 + pcol * 2) ^ ((prow & 7) << 4))) =
              __float2bfloat16(sc[mf][nf][r]);
        }
      }

    __builtin_amdgcn_s_setprio(1);
#pragma unroll
    for (int kf = 0; kf < 2; ++kf) {
      bf16x8 pa[2], vb[4];
#pragma unroll
      for (int mf = 0; mf < 2; ++mf) {
        const int prow = mf * 16 + lr;
        pa[mf] = *(const bf16x8*)(pw + ((prow * 128 + (kf * 4 + lk) * 16) ^ ((prow & 7) << 4)));
      }
#pragma unroll
      for (int nf = 0; nf < 4; ++nf) {
        const int dh = nf * 16 + lr;
        vb[nf] = *(const bf16x8*)((char*)Vl +
                  (dh * 128 + (((kf * 4 + lk) ^ (dh & 7)) * 16)));
      }
#pragma unroll
      for (int mf = 0; mf < 2; ++mf)
#pragma unroll
        for (int nf = 0; nf < 4; ++nf)
          o[mf][nf] = __builtin_amdgcn_mfma_f32_16x16x32_bf16(pa[mf], vb[nf], o[mf][nf], 0, 0, 0);
    }
    __builtin_amdgcn_s_setprio(0);
  }

  const int part = (b * 8 + h) * S + s;
  __hip_bfloat16* op = Opart + (size_t)part * 8192;
#pragma unroll
  for (int mf = 0; mf < 2; ++mf)
#pragma unroll
    for (int r = 0; r < 4; ++r) {
      float ls = lsum[mf][r];
      ls += __shfl_xor(ls, 1);
      ls += __shfl_xor(ls, 2);
      ls += __shfl_xor(ls, 4);
      ls += __shfl_xor(ls, 8);
      const int row = w * 32 + mf * 16 + lk * 4 + r;
      if (Od) {
        const float inv = 1.f / ls;
#pragma unroll
        for (int nf = 0; nf < 4; ++nf)
          Od[(size_t)(b * 128 + row) * 512 + h * 64 + nf * 16 + lr] =
              __float2bfloat16(o[mf][nf][r] * inv);
      } else {
#pragma unroll
        for (int nf = 0; nf < 4; ++nf)
          op[(size_t)row * 64 + nf * 16 + lr] = __float2bfloat16(o[mf][nf][r]);
        if (lr == 0) Lv[(size_t)part * 128 + row] = ls;
      }
    }
}

__global__ __launch_bounds__(256) void attn_combine_kernel(
    const __hip_bfloat16* __restrict__ Opart, const float* __restrict__ Lv,
    __hip_bfloat16* __restrict__ O, int S) {
  const int row = blockIdx.x;
  const int b = row >> 7, i = row & 127;
  for (int c = threadIdx.x; c < 512; c += 256) {
    const int h = c >> 6, dh = c & 63;
    const int pbase = (b * 8 + h) * S;
    float L = 0.f, val = 0.f;
    for (int s = 0; s < S; ++s) {
      L += Lv[(size_t)(pbase + s) * 128 + i];
      val += __bfloat162float(Opart[((size_t)(pbase + s) * 128 + i) * 64 + dh]);
    }
    O[(size_t)row * 512 + c] = __float2bfloat16(val / L);
  }
}

// ---------------------------------------------------------------------------
// LayerNorm row helper
// ---------------------------------------------------------------------------
DEVI void ln_row(const float* __restrict__ x, const float* __restrict__ w,
                 const float* __restrict__ bb, __hip_bfloat16* __restrict__ y,
                 int row, int t) {
  const float2 v = *(const float2*)&x[(size_t)row * 512 + t * 2];
  float s = v.x + v.y;
  float sq = v.x * v.x + v.y * v.y;
#pragma unroll
  for (int d = 1; d < 64; d <<= 1) {
    s += __shfl_xor(s, d);
    sq += __shfl_xor(sq, d);
  }
  __shared__ float ss[4], ssq[4];
  if ((t & 63) == 0) { ss[t >> 6] = s; ssq[t >> 6] = sq; }
  __syncthreads();
  s = ss[0] + ss[1] + ss[2] + ss[3];
  sq = ssq[0] + ssq[1] + ssq[2] + ssq[3];
  const float mean = s * (1.f / 512.f);
  const float var = sq * (1.f / 512.f) - mean * mean;
  const float rstd = rsqrtf(var + 1e-5f);
  const float2 wv = *(const float2*)&w[t * 2];
  const float2 bv = *(const float2*)&bb[t * 2];
  y[(size_t)row * 512 + t * 2] = __float2bfloat16((v.x - mean) * rstd * wv.x + bv.x);
  y[(size_t)row * 512 + t * 2 + 1] = __float2bfloat16((v.y - mean) * rstd * wv.y + bv.y);
}

// ---------------------------------------------------------------------------
// prep: fused weight-convert+transpose (blocks 0..8191, w1 weights PERMUTED
// for GEGLU) + leading LayerNorms (blocks 8192.., latents then context).
// ---------------------------------------------------------------------------
struct WcvtDesc { const float* src[10]; __hip_bfloat16* dst[10]; };

__global__ __launch_bounds__(256) void prep_kernel(
    WcvtDesc d,
    const float* __restrict__ lat, const float* __restrict__ lw,
    const float* __restrict__ lb, __hip_bfloat16* __restrict__ xout,
    const float* __restrict__ ctx, const float* __restrict__ cw,
    const float* __restrict__ cb, __hip_bfloat16* __restrict__ cout) {
  if (blockIdx.x >= 8192) {
    const int row = blockIdx.x - 8192;
    if (row < 1024)
      ln_row(lat, lw, lb, xout, row, threadIdx.x);
    else
      ln_row(ctx, cw, cb, cout, row - 1024, threadIdx.x);
    return;
  }
  int tile = blockIdx.x;
  const int set = tile >> 12;
  tile &= 4095;
  int wi, K, N, base;
  if (tile < 256)       { wi = 0; K = 512;  N = 512;  base = 0; }
  else if (tile < 768)  { wi = 1; K = 512;  N = 1024; base = 256; }
  else if (tile < 1024) { wi = 2; K = 512;  N = 512;  base = 768; }
  else if (tile < 3072) { wi = 3; K = 512;  N = 4096; base = 1024; }
  else                  { wi = 4; K = 2048; N = 512;  base = 3072; }
  const bool permute = (wi == 3);
  wi += set * 5;
  const int rel = tile - base;
  const int ntx = N >> 5;
  const int n0 = (rel % ntx) * 32, k0 = (rel / ntx) * 32;
  const int sn0 = permute ? (((n0 >> 6) << 5) + ((n0 & 32) ? 2048 : 0)) : n0;
  const float* W = d.src[wi];
  __hip_bfloat16* Wt = d.dst[wi];
  __shared__ float tl[32][33];
  const int tx = threadIdx.x & 31, ty = threadIdx.x >> 5;
#pragma unroll
  for (int j = 0; j < 4; ++j)
    tl[ty + j * 8][tx] = W[(size_t)(k0 + ty + j * 8) * N + sn0 + tx];
  __syncthreads();
#pragma unroll
  for (int j = 0; j < 4; ++j)
    Wt[(size_t)(n0 + ty + j * 8) * K + k0 + tx] = __float2bfloat16(tl[tx][ty + j * 8]);
}

// ---------------------------------------------------------------------------
extern "C" void kernel_launch(void* const* d_in, const int* in_sizes, int n_in,
                              void* d_out, int out_size, void* d_ws, size_t ws_size,
                              hipStream_t stream) {
  (void)in_sizes; (void)n_in; (void)out_size; (void)ws_size;
  const float* context = (const float*)d_in[0];
  const float* latents = (const float*)d_in[1];
  const float* ca_ln_w = (const float*)d_in[2];
  const float* ca_ln_b = (const float*)d_in[3];
  const float* ca_lnc_w = (const float*)d_in[4];
  const float* ca_lnc_b = (const float*)d_in[5];
  const float* ca_wq = (const float*)d_in[6];
  const float* ca_wkv = (const float*)d_in[7];
  const float* ca_wo = (const float*)d_in[8];
  const float* ca_bo = (const float*)d_in[9];
  const float* cf_ln_w = (const float*)d_in[10];
  const float* cf_ln_b = (const float*)d_in[11];
  const float* cf_w1 = (const float*)d_in[12];
  const float* cf_b1 = (const float*)d_in[13];
  const float* cf_w2 = (const float*)d_in[14];
  const float* cf_b2 = (const float*)d_in[15];
  const float* sa_ln_w = (const float*)d_in[16];
  const float* sa_ln_b = (const float*)d_in[17];
  const float* sa_wq = (const float*)d_in[18];
  const float* sa_wkv = (const float*)d_in[19];
  const float* sa_wo = (const float*)d_in[20];
  const float* sa_bo = (const float*)d_in[21];
  const float* lf_ln_w = (const float*)d_in[22];
  const float* lf_ln_b = (const float*)d_in[23];
  const float* lf_w1 = (const float*)d_in[24];
  const float* lf_b1 = (const float*)d_in[25];
  const float* lf_w2 = (const float*)d_in[26];
  const float* lf_b2 = (const float*)d_in[27];

  typedef __hip_bfloat16 bf;
  char* ws = (char*)d_ws;
  size_t off = 0;
  auto alloc = [&](size_t bytes) -> void* {
    void* p = ws + off;
    off += (bytes + 255) & ~(size_t)255;
    return p;
  };
  bf* wq1t = (bf*)alloc((size_t)512 * 512 * 2);
  bf* wkv1t = (bf*)alloc((size_t)1024 * 512 * 2);
  bf* wo1t = (bf*)alloc((size_t)512 * 512 * 2);
  bf* w1ct = (bf*)alloc((size_t)4096 * 512 * 2);
  bf* w2ct = (bf*)alloc((size_t)512 * 2048 * 2);
  bf* wq2t = (bf*)alloc((size_t)512 * 512 * 2);    // contiguous with wkv2t
  bf* wkv2t = (bf*)alloc((size_t)1024 * 512 * 2);
  bf* wo2t = (bf*)alloc((size_t)512 * 512 * 2);
  bf* w1lt = (bf*)alloc((size_t)4096 * 512 * 2);
  bf* w2lt = (bf*)alloc((size_t)512 * 2048 * 2);
  bf* cn = (bf*)alloc((size_t)32768 * 512 * 2);     // 33.5 MB; multi-reused
  bf* kbuf = (bf*)alloc((size_t)32768 * 512 * 2);   // cross K [row][512]
  bf* vt = (bf*)alloc((size_t)64 * 64 * 4096 * 2);  // cross V^T
  bf* kb2 = (bf*)alloc((size_t)1024 * 512 * 2);     // self K [row][512]
  bf* vt2 = (bf*)alloc((size_t)64 * 64 * 128 * 2);  // self V^T
  float* lv = (float*)alloc((size_t)1024 * 128 * 4);
  float* skq = (float*)alloc((size_t)4 * 1024 * 512 * 4);  // small-GEMM SK partials
  bf* xnb = (bf*)alloc((size_t)1024 * 512 * 2);
  bf* qb = (bf*)alloc((size_t)1024 * 512 * 2);
  bf* aob = (bf*)alloc((size_t)1024 * 512 * 2);
  bf* q2b = (bf*)alloc((size_t)1024 * 512 * 2);
  bf* ao2b = (bf*)alloc((size_t)1024 * 512 * 2);
  float* x1 = (float*)alloc((size_t)1024 * 512 * 4);
  float* x2 = (float*)alloc((size_t)1024 * 512 * 4);
  float* x3 = (float*)alloc((size_t)1024 * 512 * 4);
  bf* x2n = (bf*)alloc((size_t)1024 * 512 * 2);
  bf* x3n = (bf*)alloc((size_t)1024 * 512 * 2);
  // cn region time-disjoint reuse:
  bf* opart = cn;                                  // attn bf16 partials (16.8 MB)
  float* skp = (float*)cn;                         // FFN-down SK=8 partials (16.8 MB)
  bf* agb = (bf*)((char*)cn + 17 * 1024 * 1024);   // GEGLU out (4.2 MB)

  WcvtDesc wd;
  wd.src[0] = ca_wq;  wd.dst[0] = wq1t;
  wd.src[1] = ca_wkv; wd.dst[1] = wkv1t;
  wd.src[2] = ca_wo;  wd.dst[2] = wo1t;
  wd.src[3] = cf_w1;  wd.dst[3] = w1ct;
  wd.src[4] = cf_w2;  wd.dst[4] = w2ct;
  wd.src[5] = sa_wq;  wd.dst[5] = wq2t;
  wd.src[6] = sa_wkv; wd.dst[6] = wkv2t;
  wd.src[7] = sa_wo;  wd.dst[7] = wo2t;
  wd.src[8] = lf_w1;  wd.dst[8] = w1lt;
  wd.src[9] = lf_w2;  wd.dst[9] = w2lt;

  // --- prep: weight convert + leading LNs in one dispatch ---
  prep_kernel<<<8192 + 33792, 256, 0, stream>>>(
      wd, latents, ca_ln_w, ca_ln_b, xnb, context, ca_lnc_w, ca_lnc_b, cn);

  // --- sublayer 1: cross attention ---
  projx_kernel<<<2080, 256, 0, stream>>>(cn, wkv1t, kbuf, vt, xnb, wq1t, qb);
  attn_split_kernel<<<dim3(8, 8, 16), 256, 0, stream>>>(qb, kbuf, vt, opart, lv, nullptr, 256, 4096, 16);
  attn_combine_kernel<<<1024, 256, 0, stream>>>(opart, lv, aob, 16);
  gemm_sk<<<dim3(4, 8, 4), 256, 0, stream>>>(aob, wo1t, skq, 1024, 512, 512);
  reduce_ln_sk<<<1024, 256, 0, stream>>>(skq, ca_bo, latents, x1, cf_ln_w, cf_ln_b, xnb, 4);

  // --- sublayer 2: cross FFN (GEGLU fused up-proj, SK=8 down-proj) ---
  gemm_geglu<<<dim3(32, 16), 256, 0, stream>>>(xnb, w1ct, agb, cf_b1);
  gemm_sk<<<dim3(4, 8, 8), 256, 0, stream>>>(agb, w2ct, skp, 1024, 512, 2048);
  reduce_ln_sk<<<1024, 256, 0, stream>>>(skp, cf_b2, x1, x2, sa_ln_w, sa_ln_b, x2n, 8);

  // --- sublayer 3: latent self-attention (merged QKV, direct write) ---
  proj_kernel<<<dim3(12, 8), 256, 0, stream>>>(x2n, wq2t, q2b, kb2, vt2, 512, 7);
  attn_split_kernel<<<dim3(8, 8, 1), 256, 0, stream>>>(q2b, kb2, vt2, nullptr, nullptr, ao2b, 128, 128, 1);
  gemm_sk<<<dim3(4, 8, 4), 256, 0, stream>>>(ao2b, wo2t, skq, 1024, 512, 512);
  reduce_ln_sk<<<1024, 256, 0, stream>>>(skq, sa_bo, x2, x3, lf_ln_w, lf_ln_b, x3n, 4);

  // --- sublayer 4: latent FFN (GEGLU fused up-proj, SK=8 down-proj) ---
  gemm_geglu<<<dim3(32, 16), 256, 0, stream>>>(x3n, w1lt, agb, lf_b1);
  gemm_sk<<<dim3(4, 8, 8), 256, 0, stream>>>(agb, w2lt, skp, 1024, 512, 2048);
  reduce_sk<<<2048, 256, 0, stream>>>(skp, lf_b2, x3, (float*)d_out, 8);
}

// Round 13
// 211.797 us; speedup vs baseline: 1.5409x; 1.0581x over previous
//
#include <hip/hip_runtime.h>
#include <hip/hip_bf16.h>
#include <math.h>

// ---------------------------------------------------------------------------
// LBANP encoder layer on MI355X (gfx950).
// Round 13: fp8(e4m3, OCP) operands for the cross projection (projx) —
// BK=64 fp8 tiles have identical byte layout to BK=32 bf16 tiles, so the
// proven staging/swizzle geometry is reused; ds_reads b128->b64, K-steps
// and barriers halve, staged bytes halve, MFMA rate unchanged.
// Weights pre-scaled x16 into e4m3 normal range; 1/16 in the f32 epilogue.
// ---------------------------------------------------------------------------

typedef __attribute__((ext_vector_type(8))) short bf16x8;   // 8 x bf16 (4 VGPRs)
typedef __attribute__((ext_vector_type(4))) float f32x4;
typedef long i64;

#define DEVI __device__ __forceinline__

DEVI void load_lds16(const void* g, void* l) {
  __builtin_amdgcn_global_load_lds(
      (const __attribute__((address_space(1))) void*)g,
      (__attribute__((address_space(3))) void*)l, 16, 0, 0);
}

DEVI short bfbits(float x) {
  __hip_bfloat16 h = __float2bfloat16(x);
  return *reinterpret_cast<short*>(&h);
}

DEVI unsigned short fp8pk2(float a, float b) {
  return (unsigned short)(__builtin_amdgcn_cvt_pk_fp8_f32(a, b, 0, false) & 0xffff);
}

DEVI unsigned char fp8b(float x) {
  return (unsigned char)(__builtin_amdgcn_cvt_pk_fp8_f32(x, x, 0, false) & 0xff);
}

// ---------------------------------------------------------------------------
// Split-K GEMM (bf16): P[z][M*N] = A[M, kseg] * Bt^T partials (f32).
// ---------------------------------------------------------------------------
__global__ __launch_bounds__(256, 4) void gemm_sk(
    const __hip_bfloat16* __restrict__ A, const __hip_bfloat16* __restrict__ Bt,
    float* __restrict__ P, int M, int N, int K) {
  const int nwg = gridDim.x * gridDim.y;
  const int lid = blockIdx.y * gridDim.x + blockIdx.x;
  const int work = (lid & 7) * (nwg >> 3) + (lid >> 3);
  const int n0 = (work % gridDim.x) * 128;
  const int m0 = (work / gridDim.x) * 128;
  const int KS = K / gridDim.z;
  const int kbeg = blockIdx.z * KS;

  const int t = threadIdx.x;
  const int w = t >> 6, l = t & 63;
  const int lr = l & 15, lk = l >> 4;
  const int wm = (w >> 1) * 64, wn = (w & 1) * 64;
  __shared__ __hip_bfloat16 Al[2][128 * 32];
  __shared__ __hip_bfloat16 Bl[2][128 * 32];

  f32x4 acc[4][4];
  const f32x4 z = {0.f, 0.f, 0.f, 0.f};
#pragma unroll
  for (int i = 0; i < 4; ++i)
#pragma unroll
    for (int j = 0; j < 4; ++j) acc[i][j] = z;

  const int srow = w * 16 + (l >> 2);
  const int scol = ((l & 3) ^ ((l >> 3) & 3)) * 8;
  const __hip_bfloat16* Ag = A + (size_t)(m0 + srow) * K + kbeg + scol;
  const __hip_bfloat16* Bg = Bt + (size_t)(n0 + srow) * K + kbeg + scol;

#define STAGE(buf, k0)                                                   \
  {                                                                      \
    load_lds16(Ag + (k0), (char*)Al[buf] + w * 1024);                    \
    load_lds16(Ag + (size_t)64 * K + (k0), (char*)Al[buf] + 4096 + w * 1024); \
    load_lds16(Bg + (k0), (char*)Bl[buf] + w * 1024);                    \
    load_lds16(Bg + (size_t)64 * K + (k0), (char*)Bl[buf] + 4096 + w * 1024); \
  }

  STAGE(0, 0);
  __syncthreads();
  int cur = 0;
  const int rs = (lk ^ ((lr >> 1) & 3)) * 16;
  for (int k0 = 0; k0 < KS; k0 += 32) {
    if (k0 + 32 < KS) STAGE(cur ^ 1, k0 + 32);
    bf16x8 af[4], bfr[4];
#pragma unroll
    for (int i = 0; i < 4; ++i)
      af[i] = *(const bf16x8*)((const char*)Al[cur] + ((wm + i * 16 + lr) * 64 + rs));
#pragma unroll
    for (int j = 0; j < 4; ++j)
      bfr[j] = *(const bf16x8*)((const char*)Bl[cur] + ((wn + j * 16 + lr) * 64 + rs));
#pragma unroll
    for (int i = 0; i < 4; ++i)
#pragma unroll
      for (int j = 0; j < 4; ++j)
        acc[i][j] = __builtin_amdgcn_mfma_f32_16x16x32_bf16(af[i], bfr[j], acc[i][j], 0, 0, 0);
    __syncthreads();
    cur ^= 1;
  }
#undef STAGE

  float* Pz = P + (size_t)blockIdx.z * M * N;
#pragma unroll
  for (int i = 0; i < 4; ++i) {
    const int row = m0 + wm + i * 16 + lk * 4;
#pragma unroll
    for (int j = 0; j < 4; ++j) {
      const int col = n0 + wn + j * 16 + lr;
#pragma unroll
      for (int r = 0; r < 4; ++r)
        Pz[(size_t)(row + r) * N + col] = acc[i][j][r];
    }
  }
}

// reduce split-K partials: out = sum_sk P + bias + res
__global__ __launch_bounds__(256) void reduce_sk(
    const float* __restrict__ P, const float* __restrict__ bias,
    const float* __restrict__ res, float* __restrict__ out, int SK) {
  const int i = blockIdx.x * 256 + threadIdx.x;
  float v = bias[i & 511] + res[i];
  for (int s = 0; s < SK; ++s) v += P[(size_t)s * 524288 + i];
  out[i] = v;
}

// reduce split-K + LayerNorm fused: emits f32 x and bf16 LN(x)
__global__ __launch_bounds__(256) void reduce_ln_sk(
    const float* __restrict__ P, const float* __restrict__ bias,
    const float* __restrict__ res, float* __restrict__ xout,
    const float* __restrict__ w, const float* __restrict__ b,
    __hip_bfloat16* __restrict__ y, int SK) {
  const int row = blockIdx.x, t = threadIdx.x;
  const int c = t * 2;
  const size_t base = (size_t)row * 512 + c;
  float2 v = *(const float2*)&res[base];
  v.x += bias[c];
  v.y += bias[c + 1];
  for (int s = 0; s < SK; ++s) {
    const float2 p = *(const float2*)&P[(size_t)s * 524288 + base];
    v.x += p.x;
    v.y += p.y;
  }
  *(float2*)&xout[base] = v;
  float s1 = v.x + v.y, s2 = v.x * v.x + v.y * v.y;
#pragma unroll
  for (int d = 1; d < 64; d <<= 1) {
    s1 += __shfl_xor(s1, d);
    s2 += __shfl_xor(s2, d);
  }
  __shared__ float ss[4], ssq[4];
  if ((t & 63) == 0) { ss[t >> 6] = s1; ssq[t >> 6] = s2; }
  __syncthreads();
  s1 = ss[0] + ss[1] + ss[2] + ss[3];
  s2 = ssq[0] + ssq[1] + ssq[2] + ssq[3];
  const float mean = s1 * (1.f / 512.f);
  const float var = s2 * (1.f / 512.f) - mean * mean;
  const float rstd = rsqrtf(var + 1e-5f);
  y[base] = __float2bfloat16((v.x - mean) * rstd * w[c] + b[c]);
  y[base + 1] = __float2bfloat16((v.y - mean) * rstd * w[c + 1] + b[c + 1]);
}

// ---------------------------------------------------------------------------
// gemm_geglu: 64x128-tile bf16 GEMM with fused GEGLU epilogue (permuted w1).
// ---------------------------------------------------------------------------
__global__ __launch_bounds__(256, 4) void gemm_geglu(
    const __hip_bfloat16* __restrict__ A, const __hip_bfloat16* __restrict__ Bt,
    __hip_bfloat16* __restrict__ Cb, const float* __restrict__ bias) {
  const int K = 512;
  const int nwg = gridDim.x * gridDim.y;
  const int lid = blockIdx.y * gridDim.x + blockIdx.x;
  const int work = (lid & 7) * (nwg >> 3) + (lid >> 3);
  const int n0 = (work % gridDim.x) * 128;
  const int m0 = (work / gridDim.x) * 64;

  const int t = threadIdx.x;
  const int w = t >> 6, l = t & 63;
  const int lr = l & 15, lk = l >> 4;
  const int wm = (w >> 1) * 32, wn = (w & 1) * 64;
  __shared__ __hip_bfloat16 Al[2][64 * 32];
  __shared__ __hip_bfloat16 Bl[2][128 * 32];

  f32x4 acc[2][4];
  const f32x4 z = {0.f, 0.f, 0.f, 0.f};
#pragma unroll
  for (int i = 0; i < 2; ++i)
#pragma unroll
    for (int j = 0; j < 4; ++j) acc[i][j] = z;

  const int srow = w * 16 + (l >> 2);
  const int scol = ((l & 3) ^ ((l >> 3) & 3)) * 8;
  const __hip_bfloat16* Ag = A + (size_t)(m0 + srow) * K + scol;
  const __hip_bfloat16* Bg = Bt + (size_t)(n0 + srow) * K + scol;

#define STAGE(buf, k0)                                                   \
  {                                                                      \
    load_lds16(Ag + (k0), (char*)Al[buf] + w * 1024);                    \
    load_lds16(Bg + (k0), (char*)Bl[buf] + w * 1024);                    \
    load_lds16(Bg + (size_t)64 * K + (k0), (char*)Bl[buf] + 4096 + w * 1024); \
  }

  STAGE(0, 0);
  __syncthreads();
  int cur = 0;
  const int rs = (lk ^ ((lr >> 1) & 3)) * 16;
  for (int k0 = 0; k0 < K; k0 += 32) {
    if (k0 + 32 < K) STAGE(cur ^ 1, k0 + 32);
    bf16x8 af[2], bfr[4];
#pragma unroll
    for (int i = 0; i < 2; ++i)
      af[i] = *(const bf16x8*)((const char*)Al[cur] + ((wm + i * 16 + lr) * 64 + rs));
#pragma unroll
    for (int j = 0; j < 4; ++j)
      bfr[j] = *(const bf16x8*)((const char*)Bl[cur] + ((wn + j * 16 + lr) * 64 + rs));
#pragma unroll
    for (int i = 0; i < 2; ++i)
#pragma unroll
      for (int j = 0; j < 4; ++j)
        acc[i][j] = __builtin_amdgcn_mfma_f32_16x16x32_bf16(af[i], bfr[j], acc[i][j], 0, 0, 0);
    __syncthreads();
    cur ^= 1;
  }
#undef STAGE

  const int nb = (n0 + wn) >> 1;
  float ba[2], bg[2];
#pragma unroll
  for (int jj = 0; jj < 2; ++jj) {
    ba[jj] = bias[nb + jj * 16 + lr];
    bg[jj] = bias[2048 + nb + jj * 16 + lr];
  }
#pragma unroll
  for (int i = 0; i < 2; ++i) {
    const int row = m0 + wm + i * 16 + lk * 4;
#pragma unroll
    for (int jj = 0; jj < 2; ++jj) {
      const int col = nb + jj * 16 + lr;
#pragma unroll
      for (int r = 0; r < 4; ++r) {
        const float a = acc[i][jj][r] + ba[jj];
        const float g = acc[i][jj + 2][r] + bg[jj];
        const float ge = 0.5f * g * (1.f + erff(g * 0.70710678118f));
        Cb[(size_t)(row + r) * 2048 + col] = __float2bfloat16(a * ge);
      }
    }
  }
}

// ---------------------------------------------------------------------------
// projx (fp8): cross projection, 1D grid 2080 = 2048 KV-blocks + 32 Q-blocks.
// A,Bt fp8 e4m3 (weights pre-scaled x16 -> epilogue x1/16). BK=64 fp8 tiles
// (64 B/row == bf16 BK=32 layout): same staging/swizzle; ds_read_b64 frags.
// ---------------------------------------------------------------------------
__global__ __launch_bounds__(256, 4) void projx_kernel(
    const unsigned char* __restrict__ ctx8, const unsigned char* __restrict__ wkv8,
    __hip_bfloat16* __restrict__ Kb, __hip_bfloat16* __restrict__ Vt,
    const unsigned char* __restrict__ xq8, const unsigned char* __restrict__ wq8,
    __hip_bfloat16* __restrict__ Qb) {
  const int nwg = gridDim.x;   // 2080, % 8 == 0
  const int lid = blockIdx.x;
  const int work = (lid & 7) * (nwg >> 3) + (lid >> 3);

  const unsigned char *A, *Bt;
  int m0, n0, mode;   // 0 = K half, 1 = V half, 2 = Q
  if (work < 2048) {
    m0 = (work >> 3) * 128;
    n0 = (work & 7) * 128;
    A = ctx8; Bt = wkv8;
    mode = (n0 < 512) ? 0 : 1;
  } else {
    const int idx = work - 2048;
    m0 = (idx >> 2) * 128;
    n0 = (idx & 3) * 128;
    A = xq8; Bt = wq8;
    mode = 2;
  }

  const int t = threadIdx.x;
  const int w = t >> 6, l = t & 63;
  const int lr = l & 15, lk = l >> 4;
  const int wm = (w >> 1) * 64, wn = (w & 1) * 64;
  __shared__ unsigned char Al[2][128 * 64];   // 8 KiB per buf
  __shared__ unsigned char Bl[2][128 * 64];

  f32x4 acc[4][4];
  const f32x4 z = {0.f, 0.f, 0.f, 0.f};
#pragma unroll
  for (int i = 0; i < 4; ++i)
#pragma unroll
    for (int j = 0; j < 4; ++j) acc[i][j] = z;

  // staging: lane covers 16B; row = 64 B (64 fp8). Same geometry as bf16 BK=32.
  const int srow = w * 16 + (l >> 2);
  const int sc = ((l & 3) ^ ((l >> 3) & 3)) * 16;   // pre-swizzled byte col
  const unsigned char* Ag = A + (size_t)(m0 + srow) * 512 + sc;
  const unsigned char* Bg = Bt + (size_t)(n0 + srow) * 512 + sc;

#define STAGE(buf, kb)                                                   \
  {                                                                      \
    load_lds16(Ag + (kb), (char*)Al[buf] + w * 1024);                    \
    load_lds16(Ag + (size_t)64 * 512 + (kb), (char*)Al[buf] + 4096 + w * 1024); \
    load_lds16(Bg + (kb), (char*)Bl[buf] + w * 1024);                    \
    load_lds16(Bg + (size_t)64 * 512 + (kb), (char*)Bl[buf] + 4096 + w * 1024); \
  }

  STAGE(0, 0);
  __syncthreads();
  int cur = 0;
  const int p8 = (lk & 1) * 8;         // 8B parity within 16B slot
  const int s16 = lk >> 1;             // base 16B slot contribution from lk
  for (int tt = 0; tt < 8; ++tt) {     // K = 512 = 8 x BK=64
    if (tt < 7) STAGE(cur ^ 1, (tt + 1) * 64);
    i64 af[2][4], bfr[2][4];
#pragma unroll
    for (int ks = 0; ks < 2; ++ks) {
#pragma unroll
      for (int i = 0; i < 4; ++i) {
        const int ar = wm + i * 16 + lr;
        af[ks][i] = *(const i64*)((const char*)Al[cur] + ar * 64 +
                     (((ks * 2 + s16) ^ ((ar >> 1) & 3)) * 16) + p8);
      }
#pragma unroll
      for (int j = 0; j < 4; ++j) {
        const int br = wn + j * 16 + lr;
        bfr[ks][j] = *(const i64*)((const char*)Bl[cur] + br * 64 +
                      (((ks * 2 + s16) ^ ((br >> 1) & 3)) * 16) + p8);
      }
    }
#pragma unroll
    for (int i = 0; i < 4; ++i)
#pragma unroll
      for (int j = 0; j < 4; ++j) {
        acc[i][j] = __builtin_amdgcn_mfma_f32_16x16x32_fp8_fp8(af[0][i], bfr[0][j], acc[i][j], 0, 0, 0);
        acc[i][j] = __builtin_amdgcn_mfma_f32_16x16x32_fp8_fp8(af[1][i], bfr[1][j], acc[i][j], 0, 0, 0);
      }
    __syncthreads();
    cur ^= 1;
  }
#undef STAGE

  const float SCL = 0.0625f;   // undo weight x16
  if (mode == 0) {
#pragma unroll
    for (int i = 0; i < 4; ++i) {
      const int row = m0 + wm + i * 16 + lk * 4;
#pragma unroll
      for (int j = 0; j < 4; ++j) {
        const int col = n0 + wn + j * 16 + lr;
#pragma unroll
        for (int r = 0; r < 4; ++r)
          Kb[(size_t)(row + r) * 512 + col] = __float2bfloat16(acc[i][j][r] * SCL);
      }
    }
  } else if (mode == 1) {
#pragma unroll
    for (int i = 0; i < 4; ++i) {
      const int row0 = m0 + wm + i * 16 + lk * 4;
      const int b = row0 >> 12;
      const int key0 = row0 & 4095;
#pragma unroll
      for (int j = 0; j < 4; ++j) {
        const int c = n0 + wn + j * 16 + lr - 512;
        const int hh = c >> 6, dh = c & 63;
        short4 pk;
        pk.x = bfbits(acc[i][j][0] * SCL);
        pk.y = bfbits(acc[i][j][1] * SCL);
        pk.z = bfbits(acc[i][j][2] * SCL);
        pk.w = bfbits(acc[i][j][3] * SCL);
        *(short4*)&Vt[((size_t)((b * 8 + hh) * 64 + dh) << 12) + key0] = pk;
      }
    }
  } else {
#pragma unroll
    for (int i = 0; i < 4; ++i) {
      const int row = m0 + wm + i * 16 + lk * 4;
#pragma unroll
      for (int j = 0; j < 4; ++j) {
        const int col = n0 + wn + j * 16 + lr;
#pragma unroll
        for (int r = 0; r < 4; ++r)
          Qb[(size_t)(row + r) * 512 + col] = __float2bfloat16(acc[i][j][r] * SCL);
      }
    }
  }
}

// ---------------------------------------------------------------------------
// proj (self-attn, bf16): 3-way epilogue by column.
// ---------------------------------------------------------------------------
__global__ __launch_bounds__(256, 4) void proj_kernel(
    const __hip_bfloat16* __restrict__ A, const __hip_bfloat16* __restrict__ Bt,
    __hip_bfloat16* __restrict__ Qb, __hip_bfloat16* __restrict__ Kb,
    __hip_bfloat16* __restrict__ Vt, int qcols, int rpb_shift) {
  const int nwg = gridDim.x * gridDim.y;
  const int lid = blockIdx.y * gridDim.x + blockIdx.x;
  const int work = (lid & 7) * (nwg >> 3) + (lid >> 3);
  const int n0 = (work % gridDim.x) * 128;
  const int m0 = (work / gridDim.x) * 128;
  const int K = 512;

  const int t = threadIdx.x;
  const int w = t >> 6, l = t & 63;
  const int lr = l & 15, lk = l >> 4;
  const int wm = (w >> 1) * 64, wn = (w & 1) * 64;
  __shared__ __hip_bfloat16 Al[2][128 * 32];
  __shared__ __hip_bfloat16 Bl[2][128 * 32];

  f32x4 acc[4][4];
  const f32x4 z = {0.f, 0.f, 0.f, 0.f};
#pragma unroll
  for (int i = 0; i < 4; ++i)
#pragma unroll
    for (int j = 0; j < 4; ++j) acc[i][j] = z;

  const int srow = w * 16 + (l >> 2);
  const int scol = ((l & 3) ^ ((l >> 3) & 3)) * 8;
  const __hip_bfloat16* Ag = A + (size_t)(m0 + srow) * K + scol;
  const __hip_bfloat16* Bg = Bt + (size_t)(n0 + srow) * K + scol;

#define STAGE(buf, k0)                                                   \
  {                                                                      \
    load_lds16(Ag + (k0), (char*)Al[buf] + w * 1024);                    \
    load_lds16(Ag + (size_t)64 * K + (k0), (char*)Al[buf] + 4096 + w * 1024); \
    load_lds16(Bg + (k0), (char*)Bl[buf] + w * 1024);                    \
    load_lds16(Bg + (size_t)64 * K + (k0), (char*)Bl[buf] + 4096 + w * 1024); \
  }

  STAGE(0, 0);
  __syncthreads();
  int cur = 0;
  const int rs = (lk ^ ((lr >> 1) & 3)) * 16;
  for (int k0 = 0; k0 < K; k0 += 32) {
    if (k0 + 32 < K) STAGE(cur ^ 1, k0 + 32);
    bf16x8 af[4], bfr[4];
#pragma unroll
    for (int i = 0; i < 4; ++i)
      af[i] = *(const bf16x8*)((const char*)Al[cur] + ((wm + i * 16 + lr) * 64 + rs));
#pragma unroll
    for (int j = 0; j < 4; ++j)
      bfr[j] = *(const bf16x8*)((const char*)Bl[cur] + ((wn + j * 16 + lr) * 64 + rs));
#pragma unroll
    for (int i = 0; i < 4; ++i)
#pragma unroll
      for (int j = 0; j < 4; ++j)
        acc[i][j] = __builtin_amdgcn_mfma_f32_16x16x32_bf16(af[i], bfr[j], acc[i][j], 0, 0, 0);
    __syncthreads();
    cur ^= 1;
  }
#undef STAGE

  if (n0 < qcols) {
#pragma unroll
    for (int i = 0; i < 4; ++i) {
      const int row = m0 + wm + i * 16 + lk * 4;
#pragma unroll
      for (int j = 0; j < 4; ++j) {
        const int col = n0 + wn + j * 16 + lr;
#pragma unroll
        for (int r = 0; r < 4; ++r)
          Qb[(size_t)(row + r) * 512 + col] = __float2bfloat16(acc[i][j][r]);
      }
    }
  } else if (n0 < qcols + 512) {
#pragma unroll
    for (int i = 0; i < 4; ++i) {
      const int row = m0 + wm + i * 16 + lk * 4;
#pragma unroll
      for (int j = 0; j < 4; ++j) {
        const int col = n0 + wn + j * 16 + lr - qcols;
#pragma unroll
        for (int r = 0; r < 4; ++r)
          Kb[(size_t)(row + r) * 512 + col] = __float2bfloat16(acc[i][j][r]);
      }
    }
  } else {
    const int rpb = 1 << rpb_shift;
#pragma unroll
    for (int i = 0; i < 4; ++i) {
      const int row0 = m0 + wm + i * 16 + lk * 4;
      const int b = row0 >> rpb_shift;
      const int key0 = row0 & (rpb - 1);
#pragma unroll
      for (int j = 0; j < 4; ++j) {
        const int c = n0 + wn + j * 16 + lr - qcols - 512;
        const int hh = c >> 6, dh = c & 63;
        short4 pk;
        pk.x = bfbits(acc[i][j][0]);
        pk.y = bfbits(acc[i][j][1]);
        pk.z = bfbits(acc[i][j][2]);
        pk.w = bfbits(acc[i][j][3]);
        *(short4*)&Vt[((size_t)((b * 8 + hh) * 64 + dh) << rpb_shift) + key0] = pk;
      }
    }
  }
}

// ---------------------------------------------------------------------------
// Key-split flash attention, static-max softmax; bf16 partials, f32 row sums.
// ---------------------------------------------------------------------------
__global__ __launch_bounds__(256) void attn_split_kernel(
    const __hip_bfloat16* __restrict__ Q, const __hip_bfloat16* __restrict__ Kb,
    const __hip_bfloat16* __restrict__ Vt,
    __hip_bfloat16* __restrict__ Opart, float* __restrict__ Lv,
    __hip_bfloat16* __restrict__ Od,
    int chunk, int rows_per_b, int S) {
  const float SC2 = 0.18033688f;   // 0.125 * log2(e)
  const int h = blockIdx.x, b = blockIdx.y, s = blockIdx.z;
  const int t = threadIdx.x;
  const int w = t >> 6, l = t & 63;
  const int lr = l & 15, lk = l >> 4;
  __shared__ __hip_bfloat16 Kl[64 * 64];
  __shared__ __hip_bfloat16 Vl[64 * 64];
  __shared__ __hip_bfloat16 Pl[4][32 * 64];

  bf16x8 qf[2][2];
#pragma unroll
  for (int mf = 0; mf < 2; ++mf)
#pragma unroll
    for (int kf = 0; kf < 2; ++kf)
      qf[mf][kf] = *(const bf16x8*)&Q[(size_t)(b * 128 + w * 32 + mf * 16 + lr) * 512 +
                                      h * 64 + kf * 32 + lk * 8];

  f32x4 o[2][4];
  const f32x4 z = {0.f, 0.f, 0.f, 0.f};
#pragma unroll
  for (int mf = 0; mf < 2; ++mf)
#pragma unroll
    for (int nf = 0; nf < 4; ++nf) o[mf][nf] = z;
  float lsum[2][4];
#pragma unroll
  for (int mf = 0; mf < 2; ++mf)
#pragma unroll
    for (int r = 0; r < 4; ++r) lsum[mf][r] = 0.f;

  const __hip_bfloat16* kvb = Kb + (size_t)b * rows_per_b * 512;
  const __hip_bfloat16* vtb = Vt + (size_t)(b * 8 + h) * 64 * rows_per_b;
  char* pw = (char*)Pl[w];
  const int srow = l >> 3;
  const int sslot = (l & 7) ^ srow;
  const int jend = s * chunk + chunk;

  for (int j0 = s * chunk; j0 < jend; j0 += 64) {
    __syncthreads();
#pragma unroll
    for (int p = 0; p < 2; ++p) {
      const int row = p * 32 + w * 8 + srow;
      load_lds16(&kvb[(size_t)(j0 + row) * 512 + h * 64 + sslot * 8],
                 (char*)Kl + p * 4096 + w * 1024);
      load_lds16(&vtb[(size_t)row * rows_per_b + j0 + sslot * 8],
                 (char*)Vl + p * 4096 + w * 1024);
    }
    __syncthreads();

    f32x4 sc[2][4];
#pragma unroll
    for (int mf = 0; mf < 2; ++mf)
#pragma unroll
      for (int nf = 0; nf < 4; ++nf) sc[mf][nf] = z;
    __builtin_amdgcn_s_setprio(1);
#pragma unroll
    for (int kf = 0; kf < 2; ++kf) {
      bf16x8 kb[4];
#pragma unroll
      for (int nf = 0; nf < 4; ++nf) {
        const int key = nf * 16 + lr;
        kb[nf] = *(const bf16x8*)((char*)Kl +
                  (key * 128 + (((kf * 4 + lk) ^ (key & 7)) * 16)));
      }
#pragma unroll
      for (int mf = 0; mf < 2; ++mf)
#pragma unroll
        for (int nf = 0; nf < 4; ++nf)
          sc[mf][nf] = __builtin_amdgcn_mfma_f32_16x16x32_bf16(qf[mf][kf], kb[nf], sc[mf][nf], 0, 0, 0);
    }
    __builtin_amdgcn_s_setprio(0);

#pragma unroll
    for (int mf = 0; mf < 2; ++mf)
#pragma unroll
      for (int nf = 0; nf < 4; ++nf)
#pragma unroll
        for (int r = 0; r < 4; ++r) {
          const float p = exp2f(sc[mf][nf][r] * SC2);
          sc[mf][nf][r] = p;
          lsum[mf][r] += p;
        }

#pragma unroll
    for (int mf = 0; mf < 2; ++mf)
#pragma unroll
      for (int r = 0; r < 4; ++r) {
        const int prow = mf * 16 + lk * 4 + r;
#pragma unroll
        for (int nf = 0; nf < 4; ++nf) {
          const int pcol = nf * 16 + lr;
          *(__hip_bfloat16*)(pw + ((prow * 128 + pcol * 2) ^ ((prow & 7) << 4))) =
              __float2bfloat16(sc[mf][nf][r]);
        }
      }

    __builtin_amdgcn_s_setprio(1);
#pragma unroll
    for (int kf = 0; kf < 2; ++kf) {
      bf16x8 pa[2], vb[4];
#pragma unroll
      for (int mf = 0; mf < 2; ++mf) {
        const int prow = mf * 16 + lr;
        pa[mf] = *(const bf16x8*)(pw + ((prow * 128 + (kf * 4 + lk) * 16) ^ ((prow & 7) << 4)));
      }
#pragma unroll
      for (int nf = 0; nf < 4; ++nf) {
        const int dh = nf * 16 + lr;
        vb[nf] = *(const bf16x8*)((char*)Vl +
                  (dh * 128 + (((kf * 4 + lk) ^ (dh & 7)) * 16)));
      }
#pragma unroll
      for (int mf = 0; mf < 2; ++mf)
#pragma unroll
        for (int nf = 0; nf < 4; ++nf)
          o[mf][nf] = __builtin_amdgcn_mfma_f32_16x16x32_bf16(pa[mf], vb[nf], o[mf][nf], 0, 0, 0);
    }
    __builtin_amdgcn_s_setprio(0);
  }

  const int part = (b * 8 + h) * S + s;
  __hip_bfloat16* op = Opart + (size_t)part * 8192;
#pragma unroll
  for (int mf = 0; mf < 2; ++mf)
#pragma unroll
    for (int r = 0; r < 4; ++r) {
      float ls = lsum[mf][r];
      ls += __shfl_xor(ls, 1);
      ls += __shfl_xor(ls, 2);
      ls += __shfl_xor(ls, 4);
      ls += __shfl_xor(ls, 8);
      const int row = w * 32 + mf * 16 + lk * 4 + r;
      if (Od) {
        const float inv = 1.f / ls;
#pragma unroll
        for (int nf = 0; nf < 4; ++nf)
          Od[(size_t)(b * 128 + row) * 512 + h * 64 + nf * 16 + lr] =
              __float2bfloat16(o[mf][nf][r] * inv);
      } else {
#pragma unroll
        for (int nf = 0; nf < 4; ++nf)
          op[(size_t)row * 64 + nf * 16 + lr] = __float2bfloat16(o[mf][nf][r]);
        if (lr == 0) Lv[(size_t)part * 128 + row] = ls;
      }
    }
}

__global__ __launch_bounds__(256) void attn_combine_kernel(
    const __hip_bfloat16* __restrict__ Opart, const float* __restrict__ Lv,
    __hip_bfloat16* __restrict__ O, int S) {
  const int row = blockIdx.x;
  const int b = row >> 7, i = row & 127;
  for (int c = threadIdx.x; c < 512; c += 256) {
    const int h = c >> 6, dh = c & 63;
    const int pbase = (b * 8 + h) * S;
    float L = 0.f, val = 0.f;
    for (int s = 0; s < S; ++s) {
      L += Lv[(size_t)(pbase + s) * 128 + i];
      val += __bfloat162float(Opart[((size_t)(pbase + s) * 128 + i) * 64 + dh]);
    }
    O[(size_t)row * 512 + c] = __float2bfloat16(val / L);
  }
}

// ---------------------------------------------------------------------------
// LayerNorm row helpers (bf16 out / fp8 out)
// ---------------------------------------------------------------------------
DEVI void ln_stats(float vx, float vy, int t, float* mean, float* rstd) {
  float s = vx + vy, sq = vx * vx + vy * vy;
#pragma unroll
  for (int d = 1; d < 64; d <<= 1) {
    s += __shfl_xor(s, d);
    sq += __shfl_xor(sq, d);
  }
  __shared__ float ss[4], ssq[4];
  if ((t & 63) == 0) { ss[t >> 6] = s; ssq[t >> 6] = sq; }
  __syncthreads();
  s = ss[0] + ss[1] + ss[2] + ss[3];
  sq = ssq[0] + ssq[1] + ssq[2] + ssq[3];
  *mean = s * (1.f / 512.f);
  const float var = sq * (1.f / 512.f) - (*mean) * (*mean);
  *rstd = rsqrtf(var + 1e-5f);
}

DEVI void ln_row_q(const float* __restrict__ x, const float* __restrict__ w,
                   const float* __restrict__ bb, unsigned char* __restrict__ y,
                   int row, int t) {
  const float2 v = *(const float2*)&x[(size_t)row * 512 + t * 2];
  float mean, rstd;
  ln_stats(v.x, v.y, t, &mean, &rstd);
  const float2 wv = *(const float2*)&w[t * 2];
  const float2 bv = *(const float2*)&bb[t * 2];
  const float y0 = (v.x - mean) * rstd * wv.x + bv.x;
  const float y1 = (v.y - mean) * rstd * wv.y + bv.y;
  *(unsigned short*)&y[(size_t)row * 512 + t * 2] = fp8pk2(y0, y1);
}

// ---------------------------------------------------------------------------
// prep: fused weight-convert+transpose (blocks 0..8191; w1 weights PERMUTED
// for GEGLU; set-0 wq/wkv -> fp8 x16) + leading LayerNorms -> fp8 (blocks 8192+).
// ---------------------------------------------------------------------------
struct WcvtDesc { const float* src[10]; __hip_bfloat16* dst[10]; };

__global__ __launch_bounds__(256) void prep_kernel(
    WcvtDesc d, unsigned char* __restrict__ wq8, unsigned char* __restrict__ wkv8,
    const float* __restrict__ lat, const float* __restrict__ lw,
    const float* __restrict__ lb, unsigned char* __restrict__ xq8,
    const float* __restrict__ ctx, const float* __restrict__ cw,
    const float* __restrict__ cb, unsigned char* __restrict__ cn8) {
  if (blockIdx.x >= 8192) {
    const int row = blockIdx.x - 8192;
    if (row < 1024)
      ln_row_q(lat, lw, lb, xq8, row, threadIdx.x);
    else
      ln_row_q(ctx, cw, cb, cn8, row - 1024, threadIdx.x);
    return;
  }
  int tile = blockIdx.x;
  const int set = tile >> 12;
  tile &= 4095;
  int wi0, K, N, base;
  if (tile < 256)       { wi0 = 0; K = 512;  N = 512;  base = 0; }
  else if (tile < 768)  { wi0 = 1; K = 512;  N = 1024; base = 256; }
  else if (tile < 1024) { wi0 = 2; K = 512;  N = 512;  base = 768; }
  else if (tile < 3072) { wi0 = 3; K = 512;  N = 4096; base = 1024; }
  else                  { wi0 = 4; K = 2048; N = 512;  base = 3072; }
  const bool permute = (wi0 == 3);
  const bool tofp8 = (set == 0 && wi0 < 2);
  const int wi = wi0 + set * 5;
  const int rel = tile - base;
  const int ntx = N >> 5;
  const int n0 = (rel % ntx) * 32, k0 = (rel / ntx) * 32;
  const int sn0 = permute ? (((n0 >> 6) << 5) + ((n0 & 32) ? 2048 : 0)) : n0;
  const float* W = d.src[wi];
  __shared__ float tl[32][33];
  const int tx = threadIdx.x & 31, ty = threadIdx.x >> 5;
#pragma unroll
  for (int j = 0; j < 4; ++j)
    tl[ty + j * 8][tx] = W[(size_t)(k0 + ty + j * 8) * N + sn0 + tx];
  __syncthreads();
  if (tofp8) {
    unsigned char* Wq = (wi0 == 0) ? wq8 : wkv8;
#pragma unroll
    for (int j = 0; j < 4; ++j)
      Wq[(size_t)(n0 + ty + j * 8) * 512 + k0 + tx] = fp8b(tl[tx][ty + j * 8] * 16.f);
  } else {
    __hip_bfloat16* Wt = d.dst[wi];
#pragma unroll
    for (int j = 0; j < 4; ++j)
      Wt[(size_t)(n0 + ty + j * 8) * K + k0 + tx] = __float2bfloat16(tl[tx][ty + j * 8]);
  }
}

// ---------------------------------------------------------------------------
extern "C" void kernel_launch(void* const* d_in, const int* in_sizes, int n_in,
                              void* d_out, int out_size, void* d_ws, size_t ws_size,
                              hipStream_t stream) {
  (void)in_sizes; (void)n_in; (void)out_size; (void)ws_size;
  const float* context = (const float*)d_in[0];
  const float* latents = (const float*)d_in[1];
  const float* ca_ln_w = (const float*)d_in[2];
  const float* ca_ln_b = (const float*)d_in[3];
  const float* ca_lnc_w = (const float*)d_in[4];
  const float* ca_lnc_b = (const float*)d_in[5];
  const float* ca_wq = (const float*)d_in[6];
  const float* ca_wkv = (const float*)d_in[7];
  const float* ca_wo = (const float*)d_in[8];
  const float* ca_bo = (const float*)d_in[9];
  const float* cf_ln_w = (const float*)d_in[10];
  const float* cf_ln_b = (const float*)d_in[11];
  const float* cf_w1 = (const float*)d_in[12];
  const float* cf_b1 = (const float*)d_in[13];
  const float* cf_w2 = (const float*)d_in[14];
  const float* cf_b2 = (const float*)d_in[15];
  const float* sa_ln_w = (const float*)d_in[16];
  const float* sa_ln_b = (const float*)d_in[17];
  const float* sa_wq = (const float*)d_in[18];
  const float* sa_wkv = (const float*)d_in[19];
  const float* sa_wo = (const float*)d_in[20];
  const float* sa_bo = (const float*)d_in[21];
  const float* lf_ln_w = (const float*)d_in[22];
  const float* lf_ln_b = (const float*)d_in[23];
  const float* lf_w1 = (const float*)d_in[24];
  const float* lf_b1 = (const float*)d_in[25];
  const float* lf_w2 = (const float*)d_in[26];
  const float* lf_b2 = (const float*)d_in[27];

  typedef __hip_bfloat16 bf;
  char* ws = (char*)d_ws;
  size_t off = 0;
  auto alloc = [&](size_t bytes) -> void* {
    void* p = ws + off;
    off += (bytes + 255) & ~(size_t)255;
    return p;
  };
  bf* wq1t = (bf*)alloc((size_t)512 * 512 * 2);     // unused (fp8 path)
  bf* wkv1t = (bf*)alloc((size_t)1024 * 512 * 2);   // unused (fp8 path)
  bf* wo1t = (bf*)alloc((size_t)512 * 512 * 2);
  bf* w1ct = (bf*)alloc((size_t)4096 * 512 * 2);
  bf* w2ct = (bf*)alloc((size_t)512 * 2048 * 2);
  bf* wq2t = (bf*)alloc((size_t)512 * 512 * 2);
  bf* wkv2t = (bf*)alloc((size_t)1024 * 512 * 2);
  bf* wo2t = (bf*)alloc((size_t)512 * 512 * 2);
  bf* w1lt = (bf*)alloc((size_t)4096 * 512 * 2);
  bf* w2lt = (bf*)alloc((size_t)512 * 2048 * 2);
  unsigned char* wq8 = (unsigned char*)alloc((size_t)512 * 512);
  unsigned char* wkv8 = (unsigned char*)alloc((size_t)1024 * 512);
  unsigned char* cn8 = (unsigned char*)alloc((size_t)32768 * 512);   // 16.8 MB
  unsigned char* xq8 = (unsigned char*)alloc((size_t)1024 * 512);
  bf* cn = (bf*)alloc((size_t)32768 * 512 * 2);     // reuse region (33.5 MB)
  bf* kbuf = (bf*)alloc((size_t)32768 * 512 * 2);   // cross K [row][512]
  bf* vt = (bf*)alloc((size_t)64 * 64 * 4096 * 2);  // cross V^T
  bf* kb2 = (bf*)alloc((size_t)1024 * 512 * 2);     // self K
  bf* vt2 = (bf*)alloc((size_t)64 * 64 * 128 * 2);  // self V^T
  float* lv = (float*)alloc((size_t)1024 * 128 * 4);
  float* skq = (float*)alloc((size_t)4 * 1024 * 512 * 4);
  bf* xnb = (bf*)alloc((size_t)1024 * 512 * 2);
  bf* qb = (bf*)alloc((size_t)1024 * 512 * 2);
  bf* aob = (bf*)alloc((size_t)1024 * 512 * 2);
  bf* q2b = (bf*)alloc((size_t)1024 * 512 * 2);
  bf* ao2b = (bf*)alloc((size_t)1024 * 512 * 2);
  float* x1 = (float*)alloc((size_t)1024 * 512 * 4);
  float* x2 = (float*)alloc((size_t)1024 * 512 * 4);
  float* x3 = (float*)alloc((size_t)1024 * 512 * 4);
  bf* x2n = (bf*)alloc((size_t)1024 * 512 * 2);
  bf* x3n = (bf*)alloc((size_t)1024 * 512 * 2);
  // cn region time-disjoint reuse:
  bf* opart = cn;                                  // attn bf16 partials (16.8 MB)
  float* skp = (float*)cn;                         // FFN-down SK=8 partials (16.8 MB)
  bf* agb = (bf*)((char*)cn + 17 * 1024 * 1024);   // GEGLU out (4.2 MB)

  WcvtDesc wd;
  wd.src[0] = ca_wq;  wd.dst[0] = wq1t;
  wd.src[1] = ca_wkv; wd.dst[1] = wkv1t;
  wd.src[2] = ca_wo;  wd.dst[2] = wo1t;
  wd.src[3] = cf_w1;  wd.dst[3] = w1ct;
  wd.src[4] = cf_w2;  wd.dst[4] = w2ct;
  wd.src[5] = sa_wq;  wd.dst[5] = wq2t;
  wd.src[6] = sa_wkv; wd.dst[6] = wkv2t;
  wd.src[7] = sa_wo;  wd.dst[7] = wo2t;
  wd.src[8] = lf_w1;  wd.dst[8] = w1lt;
  wd.src[9] = lf_w2;  wd.dst[9] = w2lt;

  // --- prep: weight convert (+fp8 for cross wq/wkv) + leading LNs -> fp8 ---
  prep_kernel<<<8192 + 33792, 256, 0, stream>>>(
      wd, wq8, wkv8, latents, ca_ln_w, ca_ln_b, xq8,
      context, ca_lnc_w, ca_lnc_b, cn8);

  // --- sublayer 1: cross attention (fp8 projection) ---
  projx_kernel<<<2080, 256, 0, stream>>>(cn8, wkv8, kbuf, vt, xq8, wq8, qb);
  attn_split_kernel<<<dim3(8, 8, 16), 256, 0, stream>>>(qb, kbuf, vt, opart, lv, nullptr, 256, 4096, 16);
  attn_combine_kernel<<<1024, 256, 0, stream>>>(opart, lv, aob, 16);
  gemm_sk<<<dim3(4, 8, 4), 256, 0, stream>>>(aob, wo1t, skq, 1024, 512, 512);
  reduce_ln_sk<<<1024, 256, 0, stream>>>(skq, ca_bo, latents, x1, cf_ln_w, cf_ln_b, xnb, 4);

  // --- sublayer 2: cross FFN (GEGLU fused up-proj, SK=8 down-proj) ---
  gemm_geglu<<<dim3(32, 16), 256, 0, stream>>>(xnb, w1ct, agb, cf_b1);
  gemm_sk<<<dim3(4, 8, 8), 256, 0, stream>>>(agb, w2ct, skp, 1024, 512, 2048);
  reduce_ln_sk<<<1024, 256, 0, stream>>>(skp, cf_b2, x1, x2, sa_ln_w, sa_ln_b, x2n, 8);

  // --- sublayer 3: latent self-attention (merged QKV, direct write) ---
  proj_kernel<<<dim3(12, 8), 256, 0, stream>>>(x2n, wq2t, q2b, kb2, vt2, 512, 7);
  attn_split_kernel<<<dim3(8, 8, 1), 256, 0, stream>>>(q2b, kb2, vt2, nullptr, nullptr, ao2b, 128, 128, 1);
  gemm_sk<<<dim3(4, 8, 4), 256, 0, stream>>>(ao2b, wo2t, skq, 1024, 512, 512);
  reduce_ln_sk<<<1024, 256, 0, stream>>>(skq, sa_bo, x2, x3, lf_ln_w, lf_ln_b, x3n, 4);

  // --- sublayer 4: latent FFN (GEGLU fused up-proj, SK=8 down-proj) ---
  gemm_geglu<<<dim3(32, 16), 256, 0, stream>>>(x3n, w1lt, agb, lf_b1);
  gemm_sk<<<dim3(4, 8, 8), 256, 0, stream>>>(agb, w2lt, skp, 1024, 512, 2048);
  reduce_sk<<<2048, 256, 0, stream>>>(skp, lf_b2, x3, (float*)d_out, 8);
}

// Round 14
// 192.526 us; speedup vs baseline: 1.6951x; 1.1001x over previous
//
#include <hip/hip_runtime.h>
#include <hip/hip_bf16.h>
#include <math.h>

// ---------------------------------------------------------------------------
// LBANP encoder layer on MI355X (gfx950).
// Round 14: wave-per-row LayerNorms (no LDS/barrier, float4 loads, packed
// stores) in prep + reduce_ln_sk; vectorized reduce_sk / attn_combine.
// ---------------------------------------------------------------------------

typedef __attribute__((ext_vector_type(8))) short bf16x8;   // 8 x bf16 (4 VGPRs)
typedef __attribute__((ext_vector_type(4))) float f32x4;
typedef long i64;

#define DEVI __device__ __forceinline__

DEVI void load_lds16(const void* g, void* l) {
  __builtin_amdgcn_global_load_lds(
      (const __attribute__((address_space(1))) void*)g,
      (__attribute__((address_space(3))) void*)l, 16, 0, 0);
}

DEVI short bfbits(float x) {
  __hip_bfloat16 h = __float2bfloat16(x);
  return *reinterpret_cast<short*>(&h);
}

DEVI unsigned int fp8pk2(float a, float b) {
  return __builtin_amdgcn_cvt_pk_fp8_f32(a, b, 0, false) & 0xffff;
}

DEVI unsigned char fp8b(float x) {
  return (unsigned char)(__builtin_amdgcn_cvt_pk_fp8_f32(x, x, 0, false) & 0xff);
}

// ---------------------------------------------------------------------------
// Split-K GEMM (bf16): P[z][M*N] = A[M, kseg] * Bt^T partials (f32).
// ---------------------------------------------------------------------------
__global__ __launch_bounds__(256, 4) void gemm_sk(
    const __hip_bfloat16* __restrict__ A, const __hip_bfloat16* __restrict__ Bt,
    float* __restrict__ P, int M, int N, int K) {
  const int nwg = gridDim.x * gridDim.y;
  const int lid = blockIdx.y * gridDim.x + blockIdx.x;
  const int work = (lid & 7) * (nwg >> 3) + (lid >> 3);
  const int n0 = (work % gridDim.x) * 128;
  const int m0 = (work / gridDim.x) * 128;
  const int KS = K / gridDim.z;
  const int kbeg = blockIdx.z * KS;

  const int t = threadIdx.x;
  const int w = t >> 6, l = t & 63;
  const int lr = l & 15, lk = l >> 4;
  const int wm = (w >> 1) * 64, wn = (w & 1) * 64;
  __shared__ __hip_bfloat16 Al[2][128 * 32];
  __shared__ __hip_bfloat16 Bl[2][128 * 32];

  f32x4 acc[4][4];
  const f32x4 z = {0.f, 0.f, 0.f, 0.f};
#pragma unroll
  for (int i = 0; i < 4; ++i)
#pragma unroll
    for (int j = 0; j < 4; ++j) acc[i][j] = z;

  const int srow = w * 16 + (l >> 2);
  const int scol = ((l & 3) ^ ((l >> 3) & 3)) * 8;
  const __hip_bfloat16* Ag = A + (size_t)(m0 + srow) * K + kbeg + scol;
  const __hip_bfloat16* Bg = Bt + (size_t)(n0 + srow) * K + kbeg + scol;

#define STAGE(buf, k0)                                                   \
  {                                                                      \
    load_lds16(Ag + (k0), (char*)Al[buf] + w * 1024);                    \
    load_lds16(Ag + (size_t)64 * K + (k0), (char*)Al[buf] + 4096 + w * 1024); \
    load_lds16(Bg + (k0), (char*)Bl[buf] + w * 1024);                    \
    load_lds16(Bg + (size_t)64 * K + (k0), (char*)Bl[buf] + 4096 + w * 1024); \
  }

  STAGE(0, 0);
  __syncthreads();
  int cur = 0;
  const int rs = (lk ^ ((lr >> 1) & 3)) * 16;
  for (int k0 = 0; k0 < KS; k0 += 32) {
    if (k0 + 32 < KS) STAGE(cur ^ 1, k0 + 32);
    bf16x8 af[4], bfr[4];
#pragma unroll
    for (int i = 0; i < 4; ++i)
      af[i] = *(const bf16x8*)((const char*)Al[cur] + ((wm + i * 16 + lr) * 64 + rs));
#pragma unroll
    for (int j = 0; j < 4; ++j)
      bfr[j] = *(const bf16x8*)((const char*)Bl[cur] + ((wn + j * 16 + lr) * 64 + rs));
#pragma unroll
    for (int i = 0; i < 4; ++i)
#pragma unroll
      for (int j = 0; j < 4; ++j)
        acc[i][j] = __builtin_amdgcn_mfma_f32_16x16x32_bf16(af[i], bfr[j], acc[i][j], 0, 0, 0);
    __syncthreads();
    cur ^= 1;
  }
#undef STAGE

  float* Pz = P + (size_t)blockIdx.z * M * N;
#pragma unroll
  for (int i = 0; i < 4; ++i) {
    const int row = m0 + wm + i * 16 + lk * 4;
#pragma unroll
    for (int j = 0; j < 4; ++j) {
      const int col = n0 + wn + j * 16 + lr;
#pragma unroll
      for (int r = 0; r < 4; ++r)
        Pz[(size_t)(row + r) * N + col] = acc[i][j][r];
    }
  }
}

// reduce split-K partials (float4): out = sum_sk P + bias + res  (grid 512x256)
__global__ __launch_bounds__(256) void reduce_sk(
    const float* __restrict__ P, const float* __restrict__ bias,
    const float* __restrict__ res, float* __restrict__ out, int SK) {
  const int i = (blockIdx.x * 256 + threadIdx.x) * 4;
  f32x4 v = *(const f32x4*)&bias[i & 511];
  const f32x4 rr = *(const f32x4*)&res[i];
  v += rr;
  for (int s = 0; s < SK; ++s) v += *(const f32x4*)&P[(size_t)s * 524288 + i];
  *(f32x4*)&out[i] = v;
}

// ---------------------------------------------------------------------------
// reduce split-K + LayerNorm, wave-per-row: lane l covers cols 8l..8l+7.
// 4 rows/block; grid 256 x 256thr. Emits f32 x and bf16 LN(x).
// ---------------------------------------------------------------------------
__global__ __launch_bounds__(256) void reduce_ln_sk(
    const float* __restrict__ P, const float* __restrict__ bias,
    const float* __restrict__ res, float* __restrict__ xout,
    const float* __restrict__ w, const float* __restrict__ b,
    __hip_bfloat16* __restrict__ y, int SK) {
  const int row = blockIdx.x * 4 + (threadIdx.x >> 6);
  const int l = threadIdx.x & 63;
  const size_t base = (size_t)row * 512 + l * 8;
  f32x4 v0 = *(const f32x4*)&res[base];
  f32x4 v1 = *(const f32x4*)&res[base + 4];
  v0 += *(const f32x4*)&bias[l * 8];
  v1 += *(const f32x4*)&bias[l * 8 + 4];
  for (int s = 0; s < SK; ++s) {
    v0 += *(const f32x4*)&P[(size_t)s * 524288 + base];
    v1 += *(const f32x4*)&P[(size_t)s * 524288 + base + 4];
  }
  *(f32x4*)&xout[base] = v0;
  *(f32x4*)&xout[base + 4] = v1;
  float s1 = 0.f, s2 = 0.f;
#pragma unroll
  for (int e = 0; e < 4; ++e) {
    s1 += v0[e] + v1[e];
    s2 += v0[e] * v0[e] + v1[e] * v1[e];
  }
#pragma unroll
  for (int d = 1; d < 64; d <<= 1) {
    s1 += __shfl_xor(s1, d);
    s2 += __shfl_xor(s2, d);
  }
  const float mean = s1 * (1.f / 512.f);
  const float var = s2 * (1.f / 512.f) - mean * mean;
  const float rstd = rsqrtf(var + 1e-5f);
  const f32x4 w0 = *(const f32x4*)&w[l * 8], w1 = *(const f32x4*)&w[l * 8 + 4];
  const f32x4 b0 = *(const f32x4*)&b[l * 8], b1 = *(const f32x4*)&b[l * 8 + 4];
  bf16x8 o;
#pragma unroll
  for (int e = 0; e < 4; ++e) {
    o[e] = bfbits((v0[e] - mean) * rstd * w0[e] + b0[e]);
    o[e + 4] = bfbits((v1[e] - mean) * rstd * w1[e] + b1[e]);
  }
  *(bf16x8*)&y[base] = o;
}

// ---------------------------------------------------------------------------
// gemm_geglu: 64x128-tile bf16 GEMM with fused GEGLU epilogue (permuted w1).
// ---------------------------------------------------------------------------
__global__ __launch_bounds__(256, 4) void gemm_geglu(
    const __hip_bfloat16* __restrict__ A, const __hip_bfloat16* __restrict__ Bt,
    __hip_bfloat16* __restrict__ Cb, const float* __restrict__ bias) {
  const int K = 512;
  const int nwg = gridDim.x * gridDim.y;
  const int lid = blockIdx.y * gridDim.x + blockIdx.x;
  const int work = (lid & 7) * (nwg >> 3) + (lid >> 3);
  const int n0 = (work % gridDim.x) * 128;
  const int m0 = (work / gridDim.x) * 64;

  const int t = threadIdx.x;
  const int w = t >> 6, l = t & 63;
  const int lr = l & 15, lk = l >> 4;
  const int wm = (w >> 1) * 32, wn = (w & 1) * 64;
  __shared__ __hip_bfloat16 Al[2][64 * 32];
  __shared__ __hip_bfloat16 Bl[2][128 * 32];

  f32x4 acc[2][4];
  const f32x4 z = {0.f, 0.f, 0.f, 0.f};
#pragma unroll
  for (int i = 0; i < 2; ++i)
#pragma unroll
    for (int j = 0; j < 4; ++j) acc[i][j] = z;

  const int srow = w * 16 + (l >> 2);
  const int scol = ((l & 3) ^ ((l >> 3) & 3)) * 8;
  const __hip_bfloat16* Ag = A + (size_t)(m0 + srow) * K + scol;
  const __hip_bfloat16* Bg = Bt + (size_t)(n0 + srow) * K + scol;

#define STAGE(buf, k0)                                                   \
  {                                                                      \
    load_lds16(Ag + (k0), (char*)Al[buf] + w * 1024);                    \
    load_lds16(Bg + (k0), (char*)Bl[buf] + w * 1024);                    \
    load_lds16(Bg + (size_t)64 * K + (k0), (char*)Bl[buf] + 4096 + w * 1024); \
  }

  STAGE(0, 0);
  __syncthreads();
  int cur = 0;
  const int rs = (lk ^ ((lr >> 1) & 3)) * 16;
  for (int k0 = 0; k0 < K; k0 += 32) {
    if (k0 + 32 < K) STAGE(cur ^ 1, k0 + 32);
    bf16x8 af[2], bfr[4];
#pragma unroll
    for (int i = 0; i < 2; ++i)
      af[i] = *(const bf16x8*)((const char*)Al[cur] + ((wm + i * 16 + lr) * 64 + rs));
#pragma unroll
    for (int j = 0; j < 4; ++j)
      bfr[j] = *(const bf16x8*)((const char*)Bl[cur] + ((wn + j * 16 + lr) * 64 + rs));
#pragma unroll
    for (int i = 0; i < 2; ++i)
#pragma unroll
      for (int j = 0; j < 4; ++j)
        acc[i][j] = __builtin_amdgcn_mfma_f32_16x16x32_bf16(af[i], bfr[j], acc[i][j], 0, 0, 0);
    __syncthreads();
    cur ^= 1;
  }
#undef STAGE

  const int nb = (n0 + wn) >> 1;
  float ba[2], bg[2];
#pragma unroll
  for (int jj = 0; jj < 2; ++jj) {
    ba[jj] = bias[nb + jj * 16 + lr];
    bg[jj] = bias[2048 + nb + jj * 16 + lr];
  }
#pragma unroll
  for (int i = 0; i < 2; ++i) {
    const int row = m0 + wm + i * 16 + lk * 4;
#pragma unroll
    for (int jj = 0; jj < 2; ++jj) {
      const int col = nb + jj * 16 + lr;
#pragma unroll
      for (int r = 0; r < 4; ++r) {
        const float a = acc[i][jj][r] + ba[jj];
        const float g = acc[i][jj + 2][r] + bg[jj];
        const float ge = 0.5f * g * (1.f + erff(g * 0.70710678118f));
        Cb[(size_t)(row + r) * 2048 + col] = __float2bfloat16(a * ge);
      }
    }
  }
}

// ---------------------------------------------------------------------------
// projx (fp8): cross projection, 1D grid 2080 = 2048 KV-blocks + 32 Q-blocks.
// ---------------------------------------------------------------------------
__global__ __launch_bounds__(256, 4) void projx_kernel(
    const unsigned char* __restrict__ ctx8, const unsigned char* __restrict__ wkv8,
    __hip_bfloat16* __restrict__ Kb, __hip_bfloat16* __restrict__ Vt,
    const unsigned char* __restrict__ xq8, const unsigned char* __restrict__ wq8,
    __hip_bfloat16* __restrict__ Qb) {
  const int nwg = gridDim.x;   // 2080, % 8 == 0
  const int lid = blockIdx.x;
  const int work = (lid & 7) * (nwg >> 3) + (lid >> 3);

  const unsigned char *A, *Bt;
  int m0, n0, mode;   // 0 = K half, 1 = V half, 2 = Q
  if (work < 2048) {
    m0 = (work >> 3) * 128;
    n0 = (work & 7) * 128;
    A = ctx8; Bt = wkv8;
    mode = (n0 < 512) ? 0 : 1;
  } else {
    const int idx = work - 2048;
    m0 = (idx >> 2) * 128;
    n0 = (idx & 3) * 128;
    A = xq8; Bt = wq8;
    mode = 2;
  }

  const int t = threadIdx.x;
  const int w = t >> 6, l = t & 63;
  const int lr = l & 15, lk = l >> 4;
  const int wm = (w >> 1) * 64, wn = (w & 1) * 64;
  __shared__ unsigned char Al[2][128 * 64];
  __shared__ unsigned char Bl[2][128 * 64];

  f32x4 acc[4][4];
  const f32x4 z = {0.f, 0.f, 0.f, 0.f};
#pragma unroll
  for (int i = 0; i < 4; ++i)
#pragma unroll
    for (int j = 0; j < 4; ++j) acc[i][j] = z;

  const int srow = w * 16 + (l >> 2);
  const int sc = ((l & 3) ^ ((l >> 3) & 3)) * 16;
  const unsigned char* Ag = A + (size_t)(m0 + srow) * 512 + sc;
  const unsigned char* Bg = Bt + (size_t)(n0 + srow) * 512 + sc;

#define STAGE(buf, kb)                                                   \
  {                                                                      \
    load_lds16(Ag + (kb), (char*)Al[buf] + w * 1024);                    \
    load_lds16(Ag + (size_t)64 * 512 + (kb), (char*)Al[buf] + 4096 + w * 1024); \
    load_lds16(Bg + (kb), (char*)Bl[buf] + w * 1024);                    \
    load_lds16(Bg + (size_t)64 * 512 + (kb), (char*)Bl[buf] + 4096 + w * 1024); \
  }

  STAGE(0, 0);
  __syncthreads();
  int cur = 0;
  const int p8 = (lk & 1) * 8;
  const int s16 = lk >> 1;
  for (int tt = 0; tt < 8; ++tt) {
    if (tt < 7) STAGE(cur ^ 1, (tt + 1) * 64);
    i64 af[2][4], bfr[2][4];
#pragma unroll
    for (int ks = 0; ks < 2; ++ks) {
#pragma unroll
      for (int i = 0; i < 4; ++i) {
        const int ar = wm + i * 16 + lr;
        af[ks][i] = *(const i64*)((const char*)Al[cur] + ar * 64 +
                     (((ks * 2 + s16) ^ ((ar >> 1) & 3)) * 16) + p8);
      }
#pragma unroll
      for (int j = 0; j < 4; ++j) {
        const int br = wn + j * 16 + lr;
        bfr[ks][j] = *(const i64*)((const char*)Bl[cur] + br * 64 +
                      (((ks * 2 + s16) ^ ((br >> 1) & 3)) * 16) + p8);
      }
    }
#pragma unroll
    for (int i = 0; i < 4; ++i)
#pragma unroll
      for (int j = 0; j < 4; ++j) {
        acc[i][j] = __builtin_amdgcn_mfma_f32_16x16x32_fp8_fp8(af[0][i], bfr[0][j], acc[i][j], 0, 0, 0);
        acc[i][j] = __builtin_amdgcn_mfma_f32_16x16x32_fp8_fp8(af[1][i], bfr[1][j], acc[i][j], 0, 0, 0);
      }
    __syncthreads();
    cur ^= 1;
  }
#undef STAGE

  const float SCL = 0.0625f;
  if (mode == 0) {
#pragma unroll
    for (int i = 0; i < 4; ++i) {
      const int row = m0 + wm + i * 16 + lk * 4;
#pragma unroll
      for (int j = 0; j < 4; ++j) {
        const int col = n0 + wn + j * 16 + lr;
#pragma unroll
        for (int r = 0; r < 4; ++r)
          Kb[(size_t)(row + r) * 512 + col] = __float2bfloat16(acc[i][j][r] * SCL);
      }
    }
  } else if (mode == 1) {
#pragma unroll
    for (int i = 0; i < 4; ++i) {
      const int row0 = m0 + wm + i * 16 + lk * 4;
      const int b = row0 >> 12;
      const int key0 = row0 & 4095;
#pragma unroll
      for (int j = 0; j < 4; ++j) {
        const int c = n0 + wn + j * 16 + lr - 512;
        const int hh = c >> 6, dh = c & 63;
        short4 pk;
        pk.x = bfbits(acc[i][j][0] * SCL);
        pk.y = bfbits(acc[i][j][1] * SCL);
        pk.z = bfbits(acc[i][j][2] * SCL);
        pk.w = bfbits(acc[i][j][3] * SCL);
        *(short4*)&Vt[((size_t)((b * 8 + hh) * 64 + dh) << 12) + key0] = pk;
      }
    }
  } else {
#pragma unroll
    for (int i = 0; i < 4; ++i) {
      const int row = m0 + wm + i * 16 + lk * 4;
#pragma unroll
      for (int j = 0; j < 4; ++j) {
        const int col = n0 + wn + j * 16 + lr;
#pragma unroll
        for (int r = 0; r < 4; ++r)
          Qb[(size_t)(row + r) * 512 + col] = __float2bfloat16(acc[i][j][r] * SCL);
      }
    }
  }
}

// ---------------------------------------------------------------------------
// proj (self-attn, bf16): 3-way epilogue by column.
// ---------------------------------------------------------------------------
__global__ __launch_bounds__(256, 4) void proj_kernel(
    const __hip_bfloat16* __restrict__ A, const __hip_bfloat16* __restrict__ Bt,
    __hip_bfloat16* __restrict__ Qb, __hip_bfloat16* __restrict__ Kb,
    __hip_bfloat16* __restrict__ Vt, int qcols, int rpb_shift) {
  const int nwg = gridDim.x * gridDim.y;
  const int lid = blockIdx.y * gridDim.x + blockIdx.x;
  const int work = (lid & 7) * (nwg >> 3) + (lid >> 3);
  const int n0 = (work % gridDim.x) * 128;
  const int m0 = (work / gridDim.x) * 128;
  const int K = 512;

  const int t = threadIdx.x;
  const int w = t >> 6, l = t & 63;
  const int lr = l & 15, lk = l >> 4;
  const int wm = (w >> 1) * 64, wn = (w & 1) * 64;
  __shared__ __hip_bfloat16 Al[2][128 * 32];
  __shared__ __hip_bfloat16 Bl[2][128 * 32];

  f32x4 acc[4][4];
  const f32x4 z = {0.f, 0.f, 0.f, 0.f};
#pragma unroll
  for (int i = 0; i < 4; ++i)
#pragma unroll
    for (int j = 0; j < 4; ++j) acc[i][j] = z;

  const int srow = w * 16 + (l >> 2);
  const int scol = ((l & 3) ^ ((l >> 3) & 3)) * 8;
  const __hip_bfloat16* Ag = A + (size_t)(m0 + srow) * K + scol;
  const __hip_bfloat16* Bg = Bt + (size_t)(n0 + srow) * K + scol;

#define STAGE(buf, k0)                                                   \
  {                                                                      \
    load_lds16(Ag + (k0), (char*)Al[buf] + w * 1024);                    \
    load_lds16(Ag + (size_t)64 * K + (k0), (char*)Al[buf] + 4096 + w * 1024); \
    load_lds16(Bg + (k0), (char*)Bl[buf] + w * 1024);                    \
    load_lds16(Bg + (size_t)64 * K + (k0), (char*)Bl[buf] + 4096 + w * 1024); \
  }

  STAGE(0, 0);
  __syncthreads();
  int cur = 0;
  const int rs = (lk ^ ((lr >> 1) & 3)) * 16;
  for (int k0 = 0; k0 < K; k0 += 32) {
    if (k0 + 32 < K) STAGE(cur ^ 1, k0 + 32);
    bf16x8 af[4], bfr[4];
#pragma unroll
    for (int i = 0; i < 4; ++i)
      af[i] = *(const bf16x8*)((const char*)Al[cur] + ((wm + i * 16 + lr) * 64 + rs));
#pragma unroll
    for (int j = 0; j < 4; ++j)
      bfr[j] = *(const bf16x8*)((const char*)Bl[cur] + ((wn + j * 16 + lr) * 64 + rs));
#pragma unroll
    for (int i = 0; i < 4; ++i)
#pragma unroll
      for (int j = 0; j < 4; ++j)
        acc[i][j] = __builtin_amdgcn_mfma_f32_16x16x32_bf16(af[i], bfr[j], acc[i][j], 0, 0, 0);
    __syncthreads();
    cur ^= 1;
  }
#undef STAGE

  if (n0 < qcols) {
#pragma unroll
    for (int i = 0; i < 4; ++i) {
      const int row = m0 + wm + i * 16 + lk * 4;
#pragma unroll
      for (int j = 0; j < 4; ++j) {
        const int col = n0 + wn + j * 16 + lr;
#pragma unroll
        for (int r = 0; r < 4; ++r)
          Qb[(size_t)(row + r) * 512 + col] = __float2bfloat16(acc[i][j][r]);
      }
    }
  } else if (n0 < qcols + 512) {
#pragma unroll
    for (int i = 0; i < 4; ++i) {
      const int row = m0 + wm + i * 16 + lk * 4;
#pragma unroll
      for (int j = 0; j < 4; ++j) {
        const int col = n0 + wn + j * 16 + lr - qcols;
#pragma unroll
        for (int r = 0; r < 4; ++r)
          Kb[(size_t)(row + r) * 512 + col] = __float2bfloat16(acc[i][j][r]);
      }
    }
  } else {
    const int rpb = 1 << rpb_shift;
#pragma unroll
    for (int i = 0; i < 4; ++i) {
      const int row0 = m0 + wm + i * 16 + lk * 4;
      const int b = row0 >> rpb_shift;
      const int key0 = row0 & (rpb - 1);
#pragma unroll
      for (int j = 0; j < 4; ++j) {
        const int c = n0 + wn + j * 16 + lr - qcols - 512;
        const int hh = c >> 6, dh = c & 63;
        short4 pk;
        pk.x = bfbits(acc[i][j][0]);
        pk.y = bfbits(acc[i][j][1]);
        pk.z = bfbits(acc[i][j][2]);
        pk.w = bfbits(acc[i][j][3]);
        *(short4*)&Vt[((size_t)((b * 8 + hh) * 64 + dh) << rpb_shift) + key0] = pk;
      }
    }
  }
}

// ---------------------------------------------------------------------------
// Key-split flash attention, static-max softmax; bf16 partials, f32 row sums.
// ---------------------------------------------------------------------------
__global__ __launch_bounds__(256) void attn_split_kernel(
    const __hip_bfloat16* __restrict__ Q, const __hip_bfloat16* __restrict__ Kb,
    const __hip_bfloat16* __restrict__ Vt,
    __hip_bfloat16* __restrict__ Opart, float* __restrict__ Lv,
    __hip_bfloat16* __restrict__ Od,
    int chunk, int rows_per_b, int S) {
  const float SC2 = 0.18033688f;   // 0.125 * log2(e)
  const int h = blockIdx.x, b = blockIdx.y, s = blockIdx.z;
  const int t = threadIdx.x;
  const int w = t >> 6, l = t & 63;
  const int lr = l & 15, lk = l >> 4;
  __shared__ __hip_bfloat16 Kl[64 * 64];
  __shared__ __hip_bfloat16 Vl[64 * 64];
  __shared__ __hip_bfloat16 Pl[4][32 * 64];

  bf16x8 qf[2][2];
#pragma unroll
  for (int mf = 0; mf < 2; ++mf)
#pragma unroll
    for (int kf = 0; kf < 2; ++kf)
      qf[mf][kf] = *(const bf16x8*)&Q[(size_t)(b * 128 + w * 32 + mf * 16 + lr) * 512 +
                                      h * 64 + kf * 32 + lk * 8];

  f32x4 o[2][4];
  const f32x4 z = {0.f, 0.f, 0.f, 0.f};
#pragma unroll
  for (int mf = 0; mf < 2; ++mf)
#pragma unroll
    for (int nf = 0; nf < 4; ++nf) o[mf][nf] = z;
  float lsum[2][4];
#pragma unroll
  for (int mf = 0; mf < 2; ++mf)
#pragma unroll
    for (int r = 0; r < 4; ++r) lsum[mf][r] = 0.f;

  const __hip_bfloat16* kvb = Kb + (size_t)b * rows_per_b * 512;
  const __hip_bfloat16* vtb = Vt + (size_t)(b * 8 + h) * 64 * rows_per_b;
  char* pw = (char*)Pl[w];
  const int srow = l >> 3;
  const int sslot = (l & 7) ^ srow;
  const int jend = s * chunk + chunk;

  for (int j0 = s * chunk; j0 < jend; j0 += 64) {
    __syncthreads();
#pragma unroll
    for (int p = 0; p < 2; ++p) {
      const int row = p * 32 + w * 8 + srow;
      load_lds16(&kvb[(size_t)(j0 + row) * 512 + h * 64 + sslot * 8],
                 (char*)Kl + p * 4096 + w * 1024);
      load_lds16(&vtb[(size_t)row * rows_per_b + j0 + sslot * 8],
                 (char*)Vl + p * 4096 + w * 1024);
    }
    __syncthreads();

    f32x4 sc[2][4];
#pragma unroll
    for (int mf = 0; mf < 2; ++mf)
#pragma unroll
      for (int nf = 0; nf < 4; ++nf) sc[mf][nf] = z;
    __builtin_amdgcn_s_setprio(1);
#pragma unroll
    for (int kf = 0; kf < 2; ++kf) {
      bf16x8 kb[4];
#pragma unroll
      for (int nf = 0; nf < 4; ++nf) {
        const int key = nf * 16 + lr;
        kb[nf] = *(const bf16x8*)((char*)Kl +
                  (key * 128 + (((kf * 4 + lk) ^ (key & 7)) * 16)));
      }
#pragma unroll
      for (int mf = 0; mf < 2; ++mf)
#pragma unroll
        for (int nf = 0; nf < 4; ++nf)
          sc[mf][nf] = __builtin_amdgcn_mfma_f32_16x16x32_bf16(qf[mf][kf], kb[nf], sc[mf][nf], 0, 0, 0);
    }
    __builtin_amdgcn_s_setprio(0);

#pragma unroll
    for (int mf = 0; mf < 2; ++mf)
#pragma unroll
      for (int nf = 0; nf < 4; ++nf)
#pragma unroll
        for (int r = 0; r < 4; ++r) {
          const float p = exp2f(sc[mf][nf][r] * SC2);
          sc[mf][nf][r] = p;
          lsum[mf][r] += p;
        }

#pragma unroll
    for (int mf = 0; mf < 2; ++mf)
#pragma unroll
      for (int r = 0; r < 4; ++r) {
        const int prow = mf * 16 + lk * 4 + r;
#pragma unroll
        for (int nf = 0; nf < 4; ++nf) {
          const int pcol = nf * 16 + lr;
          *(__hip_bfloat16*)(pw + ((prow * 128 + pcol * 2) ^ ((prow & 7) << 4))) =
              __float2bfloat16(sc[mf][nf][r]);
        }
      }

    __builtin_amdgcn_s_setprio(1);
#pragma unroll
    for (int kf = 0; kf < 2; ++kf) {
      bf16x8 pa[2], vb[4];
#pragma unroll
      for (int mf = 0; mf < 2; ++mf) {
        const int prow = mf * 16 + lr;
        pa[mf] = *(const bf16x8*)(pw + ((prow * 128 + (kf * 4 + lk) * 16) ^ ((prow & 7) << 4)));
      }
#pragma unroll
      for (int nf = 0; nf < 4; ++nf) {
        const int dh = nf * 16 + lr;
        vb[nf] = *(const bf16x8*)((char*)Vl +
                  (dh * 128 + (((kf * 4 + lk) ^ (dh & 7)) * 16)));
      }
#pragma unroll
      for (int mf = 0; mf < 2; ++mf)
#pragma unroll
        for (int nf = 0; nf < 4; ++nf)
          o[mf][nf] = __builtin_amdgcn_mfma_f32_16x16x32_bf16(pa[mf], vb[nf], o[mf][nf], 0, 0, 0);
    }
    __builtin_amdgcn_s_setprio(0);
  }

  const int part = (b * 8 + h) * S + s;
  __hip_bfloat16* op = Opart + (size_t)part * 8192;
#pragma unroll
  for (int mf = 0; mf < 2; ++mf)
#pragma unroll
    for (int r = 0; r < 4; ++r) {
      float ls = lsum[mf][r];
      ls += __shfl_xor(ls, 1);
      ls += __shfl_xor(ls, 2);
      ls += __shfl_xor(ls, 4);
      ls += __shfl_xor(ls, 8);
      const int row = w * 32 + mf * 16 + lk * 4 + r;
      if (Od) {
        const float inv = 1.f / ls;
#pragma unroll
        for (int nf = 0; nf < 4; ++nf)
          Od[(size_t)(b * 128 + row) * 512 + h * 64 + nf * 16 + lr] =
              __float2bfloat16(o[mf][nf][r] * inv);
      } else {
#pragma unroll
        for (int nf = 0; nf < 4; ++nf)
          op[(size_t)row * 64 + nf * 16 + lr] = __float2bfloat16(o[mf][nf][r]);
        if (lr == 0) Lv[(size_t)part * 128 + row] = ls;
      }
    }
}

// combine (vectorized): thread t handles cols 2t, 2t+1 of its row.
__global__ __launch_bounds__(256) void attn_combine_kernel(
    const __hip_bfloat16* __restrict__ Opart, const float* __restrict__ Lv,
    __hip_bfloat16* __restrict__ O, int S) {
  const int row = blockIdx.x;
  const int b = row >> 7, i = row & 127;
  const int t = threadIdx.x;
  const int h = t >> 5, dh0 = (t * 2) & 63;
  const int pbase = (b * 8 + h) * S;
  float L = 0.f, v0 = 0.f, v1 = 0.f;
  for (int s = 0; s < S; ++s) {
    L += Lv[(size_t)(pbase + s) * 128 + i];
    const __hip_bfloat16* p = &Opart[((size_t)(pbase + s) * 128 + i) * 64 + dh0];
    const ushort2 u = *(const ushort2*)p;
    const unsigned int b0 = (unsigned int)u.x << 16, b1 = (unsigned int)u.y << 16;
    v0 += *(const float*)&b0;
    v1 += *(const float*)&b1;
  }
  const float inv = 1.f / L;
  ushort2 out;
  out.x = (unsigned short)bfbits(v0 * inv);
  out.y = (unsigned short)bfbits(v1 * inv);
  *(ushort2*)&O[(size_t)row * 512 + t * 2] = out;
}

// ---------------------------------------------------------------------------
// wave-per-row LayerNorm -> fp8 (lane l covers cols 8l..8l+7; no LDS/barrier)
// ---------------------------------------------------------------------------
DEVI void ln_wave_q(const float* __restrict__ x, const float* __restrict__ w,
                    const float* __restrict__ bb, unsigned char* __restrict__ y,
                    int row) {
  const int l = threadIdx.x & 63;
  const size_t base = (size_t)row * 512 + l * 8;
  const f32x4 v0 = *(const f32x4*)&x[base];
  const f32x4 v1 = *(const f32x4*)&x[base + 4];
  float s = 0.f, sq = 0.f;
#pragma unroll
  for (int e = 0; e < 4; ++e) {
    s += v0[e] + v1[e];
    sq += v0[e] * v0[e] + v1[e] * v1[e];
  }
#pragma unroll
  for (int d = 1; d < 64; d <<= 1) {
    s += __shfl_xor(s, d);
    sq += __shfl_xor(sq, d);
  }
  const float mean = s * (1.f / 512.f);
  const float var = sq * (1.f / 512.f) - mean * mean;
  const float rstd = rsqrtf(var + 1e-5f);
  const f32x4 w0 = *(const f32x4*)&w[l * 8], w1 = *(const f32x4*)&w[l * 8 + 4];
  const f32x4 b0 = *(const f32x4*)&bb[l * 8], b1 = *(const f32x4*)&bb[l * 8 + 4];
  float yv[8];
#pragma unroll
  for (int e = 0; e < 4; ++e) {
    yv[e] = (v0[e] - mean) * rstd * w0[e] + b0[e];
    yv[e + 4] = (v1[e] - mean) * rstd * w1[e] + b1[e];
  }
  uint2 pk;
  pk.x = fp8pk2(yv[0], yv[1]) | (fp8pk2(yv[2], yv[3]) << 16);
  pk.y = fp8pk2(yv[4], yv[5]) | (fp8pk2(yv[6], yv[7]) << 16);
  *(uint2*)&y[base] = pk;
}

// ---------------------------------------------------------------------------
// prep: weight-convert (blocks 0..8191; w1 PERMUTED; set-0 wq/wkv -> fp8 x16)
// + wave-per-row leading LayerNorms -> fp8 (blocks 8192.., 4 rows/block).
// ---------------------------------------------------------------------------
struct WcvtDesc { const float* src[10]; __hip_bfloat16* dst[10]; };

__global__ __launch_bounds__(256) void prep_kernel(
    WcvtDesc d, unsigned char* __restrict__ wq8, unsigned char* __restrict__ wkv8,
    const float* __restrict__ lat, const float* __restrict__ lw,
    const float* __restrict__ lb, unsigned char* __restrict__ xq8,
    const float* __restrict__ ctx, const float* __restrict__ cw,
    const float* __restrict__ cb, unsigned char* __restrict__ cn8) {
  if (blockIdx.x >= 8192) {
    const int row = (blockIdx.x - 8192) * 4 + (threadIdx.x >> 6);
    if (row < 1024)
      ln_wave_q(lat, lw, lb, xq8, row);
    else
      ln_wave_q(ctx, cw, cb, cn8, row - 1024);
    return;
  }
  int tile = blockIdx.x;
  const int set = tile >> 12;
  tile &= 4095;
  int wi0, K, N, base;
  if (tile < 256)       { wi0 = 0; K = 512;  N = 512;  base = 0; }
  else if (tile < 768)  { wi0 = 1; K = 512;  N = 1024; base = 256; }
  else if (tile < 1024) { wi0 = 2; K = 512;  N = 512;  base = 768; }
  else if (tile < 3072) { wi0 = 3; K = 512;  N = 4096; base = 1024; }
  else                  { wi0 = 4; K = 2048; N = 512;  base = 3072; }
  const bool permute = (wi0 == 3);
  const bool tofp8 = (set == 0 && wi0 < 2);
  const int wi = wi0 + set * 5;
  const int rel = tile - base;
  const int ntx = N >> 5;
  const int n0 = (rel % ntx) * 32, k0 = (rel / ntx) * 32;
  const int sn0 = permute ? (((n0 >> 6) << 5) + ((n0 & 32) ? 2048 : 0)) : n0;
  const float* W = d.src[wi];
  __shared__ float tl[32][33];
  const int tx = threadIdx.x & 31, ty = threadIdx.x >> 5;
#pragma unroll
  for (int j = 0; j < 4; ++j)
    tl[ty + j * 8][tx] = W[(size_t)(k0 + ty + j * 8) * N + sn0 + tx];
  __syncthreads();
  if (tofp8) {
    unsigned char* Wq = (wi0 == 0) ? wq8 : wkv8;
#pragma unroll
    for (int j = 0; j < 4; ++j)
      Wq[(size_t)(n0 + ty + j * 8) * 512 + k0 + tx] = fp8b(tl[tx][ty + j * 8] * 16.f);
  } else {
    __hip_bfloat16* Wt = d.dst[wi];
#pragma unroll
    for (int j = 0; j < 4; ++j)
      Wt[(size_t)(n0 + ty + j * 8) * K + k0 + tx] = __float2bfloat16(tl[tx][ty + j * 8]);
  }
}

// ---------------------------------------------------------------------------
extern "C" void kernel_launch(void* const* d_in, const int* in_sizes, int n_in,
                              void* d_out, int out_size, void* d_ws, size_t ws_size,
                              hipStream_t stream) {
  (void)in_sizes; (void)n_in; (void)out_size; (void)ws_size;
  const float* context = (const float*)d_in[0];
  const float* latents = (const float*)d_in[1];
  const float* ca_ln_w = (const float*)d_in[2];
  const float* ca_ln_b = (const float*)d_in[3];
  const float* ca_lnc_w = (const float*)d_in[4];
  const float* ca_lnc_b = (const float*)d_in[5];
  const float* ca_wq = (const float*)d_in[6];
  const float* ca_wkv = (const float*)d_in[7];
  const float* ca_wo = (const float*)d_in[8];
  const float* ca_bo = (const float*)d_in[9];
  const float* cf_ln_w = (const float*)d_in[10];
  const float* cf_ln_b = (const float*)d_in[11];
  const float* cf_w1 = (const float*)d_in[12];
  const float* cf_b1 = (const float*)d_in[13];
  const float* cf_w2 = (const float*)d_in[14];
  const float* cf_b2 = (const float*)d_in[15];
  const float* sa_ln_w = (const float*)d_in[16];
  const float* sa_ln_b = (const float*)d_in[17];
  const float* sa_wq = (const float*)d_in[18];
  const float* sa_wkv = (const float*)d_in[19];
  const float* sa_wo = (const float*)d_in[20];
  const float* sa_bo = (const float*)d_in[21];
  const float* lf_ln_w = (const float*)d_in[22];
  const float* lf_ln_b = (const float*)d_in[23];
  const float* lf_w1 = (const float*)d_in[24];
  const float* lf_b1 = (const float*)d_in[25];
  const float* lf_w2 = (const float*)d_in[26];
  const float* lf_b2 = (const float*)d_in[27];

  typedef __hip_bfloat16 bf;
  char* ws = (char*)d_ws;
  size_t off = 0;
  auto alloc = [&](size_t bytes) -> void* {
    void* p = ws + off;
    off += (bytes + 255) & ~(size_t)255;
    return p;
  };
  bf* wq1t = (bf*)alloc((size_t)512 * 512 * 2);     // unused (fp8 path)
  bf* wkv1t = (bf*)alloc((size_t)1024 * 512 * 2);   // unused (fp8 path)
  bf* wo1t = (bf*)alloc((size_t)512 * 512 * 2);
  bf* w1ct = (bf*)alloc((size_t)4096 * 512 * 2);
  bf* w2ct = (bf*)alloc((size_t)512 * 2048 * 2);
  bf* wq2t = (bf*)alloc((size_t)512 * 512 * 2);
  bf* wkv2t = (bf*)alloc((size_t)1024 * 512 * 2);
  bf* wo2t = (bf*)alloc((size_t)512 * 512 * 2);
  bf* w1lt = (bf*)alloc((size_t)4096 * 512 * 2);
  bf* w2lt = (bf*)alloc((size_t)512 * 2048 * 2);
  unsigned char* wq8 = (unsigned char*)alloc((size_t)512 * 512);
  unsigned char* wkv8 = (unsigned char*)alloc((size_t)1024 * 512);
  unsigned char* cn8 = (unsigned char*)alloc((size_t)32768 * 512);   // 16.8 MB
  unsigned char* xq8 = (unsigned char*)alloc((size_t)1024 * 512);
  bf* cn = (bf*)alloc((size_t)32768 * 512 * 2);     // reuse region (33.5 MB)
  bf* kbuf = (bf*)alloc((size_t)32768 * 512 * 2);   // cross K [row][512]
  bf* vt = (bf*)alloc((size_t)64 * 64 * 4096 * 2);  // cross V^T
  bf* kb2 = (bf*)alloc((size_t)1024 * 512 * 2);     // self K
  bf* vt2 = (bf*)alloc((size_t)64 * 64 * 128 * 2);  // self V^T
  float* lv = (float*)alloc((size_t)1024 * 128 * 4);
  float* skq = (float*)alloc((size_t)4 * 1024 * 512 * 4);
  bf* xnb = (bf*)alloc((size_t)1024 * 512 * 2);
  bf* qb = (bf*)alloc((size_t)1024 * 512 * 2);
  bf* aob = (bf*)alloc((size_t)1024 * 512 * 2);
  bf* q2b = (bf*)alloc((size_t)1024 * 512 * 2);
  bf* ao2b = (bf*)alloc((size_t)1024 * 512 * 2);
  float* x1 = (float*)alloc((size_t)1024 * 512 * 4);
  float* x2 = (float*)alloc((size_t)1024 * 512 * 4);
  float* x3 = (float*)alloc((size_t)1024 * 512 * 4);
  bf* x2n = (bf*)alloc((size_t)1024 * 512 * 2);
  bf* x3n = (bf*)alloc((size_t)1024 * 512 * 2);
  // cn region time-disjoint reuse:
  bf* opart = cn;                                  // attn bf16 partials (16.8 MB)
  float* skp = (float*)cn;                         // FFN-down SK=8 partials (16.8 MB)
  bf* agb = (bf*)((char*)cn + 17 * 1024 * 1024);   // GEGLU out (4.2 MB)

  WcvtDesc wd;
  wd.src[0] = ca_wq;  wd.dst[0] = wq1t;
  wd.src[1] = ca_wkv; wd.dst[1] = wkv1t;
  wd.src[2] = ca_wo;  wd.dst[2] = wo1t;
  wd.src[3] = cf_w1;  wd.dst[3] = w1ct;
  wd.src[4] = cf_w2;  wd.dst[4] = w2ct;
  wd.src[5] = sa_wq;  wd.dst[5] = wq2t;
  wd.src[6] = sa_wkv; wd.dst[6] = wkv2t;
  wd.src[7] = sa_wo;  wd.dst[7] = wo2t;
  wd.src[8] = lf_w1;  wd.dst[8] = w1lt;
  wd.src[9] = lf_w2;  wd.dst[9] = w2lt;

  // --- prep: weight convert (+fp8 cross wq/wkv) + wave-per-row LNs -> fp8 ---
  prep_kernel<<<8192 + 8448, 256, 0, stream>>>(
      wd, wq8, wkv8, latents, ca_ln_w, ca_ln_b, xq8,
      context, ca_lnc_w, ca_lnc_b, cn8);

  // --- sublayer 1: cross attention (fp8 projection) ---
  projx_kernel<<<2080, 256, 0, stream>>>(cn8, wkv8, kbuf, vt, xq8, wq8, qb);
  attn_split_kernel<<<dim3(8, 8, 16), 256, 0, stream>>>(qb, kbuf, vt, opart, lv, nullptr, 256, 4096, 16);
  attn_combine_kernel<<<1024, 256, 0, stream>>>(opart, lv, aob, 16);
  gemm_sk<<<dim3(4, 8, 4), 256, 0, stream>>>(aob, wo1t, skq, 1024, 512, 512);
  reduce_ln_sk<<<256, 256, 0, stream>>>(skq, ca_bo, latents, x1, cf_ln_w, cf_ln_b, xnb, 4);

  // --- sublayer 2: cross FFN (GEGLU fused up-proj, SK=8 down-proj) ---
  gemm_geglu<<<dim3(32, 16), 256, 0, stream>>>(xnb, w1ct, agb, cf_b1);
  gemm_sk<<<dim3(4, 8, 8), 256, 0, stream>>>(agb, w2ct, skp, 1024, 512, 2048);
  reduce_ln_sk<<<256, 256, 0, stream>>>(skp, cf_b2, x1, x2, sa_ln_w, sa_ln_b, x2n, 8);

  // --- sublayer 3: latent self-attention (merged QKV, direct write) ---
  proj_kernel<<<dim3(12, 8), 256, 0, stream>>>(x2n, wq2t, q2b, kb2, vt2, 512, 7);
  attn_split_kernel<<<dim3(8, 8, 1), 256, 0, stream>>>(q2b, kb2, vt2, nullptr, nullptr, ao2b, 128, 128, 1);
  gemm_sk<<<dim3(4, 8, 4), 256, 0, stream>>>(ao2b, wo2t, skq, 1024, 512, 512);
  reduce_ln_sk<<<256, 256, 0, stream>>>(skq, sa_bo, x2, x3, lf_ln_w, lf_ln_b, x3n, 4);

  // --- sublayer 4: latent FFN (GEGLU fused up-proj, SK=8 down-proj) ---
  gemm_geglu<<<dim3(32, 16), 256, 0, stream>>>(x3n, w1lt, agb, lf_b1);
  gemm_sk<<<dim3(4, 8, 8), 256, 0, stream>>>(agb, w2lt, skp, 1024, 512, 2048);
  reduce_sk<<<512, 256, 0, stream>>>(skp, lf_b2, x3, (float*)d_out, 8);
}

// Round 15
// 191.357 us; speedup vs baseline: 1.7054x; 1.0061x over previous
//
#include <hip/hip_runtime.h>
#include <hip/hip_bf16.h>
#include <math.h>

// ---------------------------------------------------------------------------
// LBANP encoder layer on MI355X (gfx950).
// Round 15: k-granule-interleaved fp8 storage ([0,4,1,5,2,6,3,7] per 64B
// K-group) so projx reads conflict-free ds_read_b128 (bf16-proven pattern)
// instead of 4-way-conflicted b64 pairs.
// ---------------------------------------------------------------------------

typedef __attribute__((ext_vector_type(8))) short bf16x8;   // 8 x bf16 (4 VGPRs)
typedef __attribute__((ext_vector_type(4))) float f32x4;
typedef long i64;
typedef __attribute__((ext_vector_type(2))) long i64x2;

#define DEVI __device__ __forceinline__

DEVI void load_lds16(const void* g, void* l) {
  __builtin_amdgcn_global_load_lds(
      (const __attribute__((address_space(1))) void*)g,
      (__attribute__((address_space(3))) void*)l, 16, 0, 0);
}

DEVI short bfbits(float x) {
  __hip_bfloat16 h = __float2bfloat16(x);
  return *reinterpret_cast<short*>(&h);
}

DEVI unsigned int fp8pk2(float a, float b) {
  return __builtin_amdgcn_cvt_pk_fp8_f32(a, b, 0, false) & 0xffff;
}

DEVI unsigned char fp8b(float x) {
  return (unsigned char)(__builtin_amdgcn_cvt_pk_fp8_f32(x, x, 0, false) & 0xff);
}

// ---------------------------------------------------------------------------
// Split-K GEMM (bf16): P[z][M*N] = A[M, kseg] * Bt^T partials (f32).
// ---------------------------------------------------------------------------
__global__ __launch_bounds__(256, 4) void gemm_sk(
    const __hip_bfloat16* __restrict__ A, const __hip_bfloat16* __restrict__ Bt,
    float* __restrict__ P, int M, int N, int K) {
  const int nwg = gridDim.x * gridDim.y;
  const int lid = blockIdx.y * gridDim.x + blockIdx.x;
  const int work = (lid & 7) * (nwg >> 3) + (lid >> 3);
  const int n0 = (work % gridDim.x) * 128;
  const int m0 = (work / gridDim.x) * 128;
  const int KS = K / gridDim.z;
  const int kbeg = blockIdx.z * KS;

  const int t = threadIdx.x;
  const int w = t >> 6, l = t & 63;
  const int lr = l & 15, lk = l >> 4;
  const int wm = (w >> 1) * 64, wn = (w & 1) * 64;
  __shared__ __hip_bfloat16 Al[2][128 * 32];
  __shared__ __hip_bfloat16 Bl[2][128 * 32];

  f32x4 acc[4][4];
  const f32x4 z = {0.f, 0.f, 0.f, 0.f};
#pragma unroll
  for (int i = 0; i < 4; ++i)
#pragma unroll
    for (int j = 0; j < 4; ++j) acc[i][j] = z;

  const int srow = w * 16 + (l >> 2);
  const int scol = ((l & 3) ^ ((l >> 3) & 3)) * 8;
  const __hip_bfloat16* Ag = A + (size_t)(m0 + srow) * K + kbeg + scol;
  const __hip_bfloat16* Bg = Bt + (size_t)(n0 + srow) * K + kbeg + scol;

#define STAGE(buf, k0)                                                   \
  {                                                                      \
    load_lds16(Ag + (k0), (char*)Al[buf] + w * 1024);                    \
    load_lds16(Ag + (size_t)64 * K + (k0), (char*)Al[buf] + 4096 + w * 1024); \
    load_lds16(Bg + (k0), (char*)Bl[buf] + w * 1024);                    \
    load_lds16(Bg + (size_t)64 * K + (k0), (char*)Bl[buf] + 4096 + w * 1024); \
  }

  STAGE(0, 0);
  __syncthreads();
  int cur = 0;
  const int rs = (lk ^ ((lr >> 1) & 3)) * 16;
  for (int k0 = 0; k0 < KS; k0 += 32) {
    if (k0 + 32 < KS) STAGE(cur ^ 1, k0 + 32);
    bf16x8 af[4], bfr[4];
#pragma unroll
    for (int i = 0; i < 4; ++i)
      af[i] = *(const bf16x8*)((const char*)Al[cur] + ((wm + i * 16 + lr) * 64 + rs));
#pragma unroll
    for (int j = 0; j < 4; ++j)
      bfr[j] = *(const bf16x8*)((const char*)Bl[cur] + ((wn + j * 16 + lr) * 64 + rs));
#pragma unroll
    for (int i = 0; i < 4; ++i)
#pragma unroll
      for (int j = 0; j < 4; ++j)
        acc[i][j] = __builtin_amdgcn_mfma_f32_16x16x32_bf16(af[i], bfr[j], acc[i][j], 0, 0, 0);
    __syncthreads();
    cur ^= 1;
  }
#undef STAGE

  float* Pz = P + (size_t)blockIdx.z * M * N;
#pragma unroll
  for (int i = 0; i < 4; ++i) {
    const int row = m0 + wm + i * 16 + lk * 4;
#pragma unroll
    for (int j = 0; j < 4; ++j) {
      const int col = n0 + wn + j * 16 + lr;
#pragma unroll
      for (int r = 0; r < 4; ++r)
        Pz[(size_t)(row + r) * N + col] = acc[i][j][r];
    }
  }
}

// reduce split-K partials (float4): out = sum_sk P + bias + res  (grid 512x256)
__global__ __launch_bounds__(256) void reduce_sk(
    const float* __restrict__ P, const float* __restrict__ bias,
    const float* __restrict__ res, float* __restrict__ out, int SK) {
  const int i = (blockIdx.x * 256 + threadIdx.x) * 4;
  f32x4 v = *(const f32x4*)&bias[i & 511];
  const f32x4 rr = *(const f32x4*)&res[i];
  v += rr;
  for (int s = 0; s < SK; ++s) v += *(const f32x4*)&P[(size_t)s * 524288 + i];
  *(f32x4*)&out[i] = v;
}

// ---------------------------------------------------------------------------
// reduce split-K + LayerNorm, wave-per-row. Emits f32 x and bf16 LN(x).
// ---------------------------------------------------------------------------
__global__ __launch_bounds__(256) void reduce_ln_sk(
    const float* __restrict__ P, const float* __restrict__ bias,
    const float* __restrict__ res, float* __restrict__ xout,
    const float* __restrict__ w, const float* __restrict__ b,
    __hip_bfloat16* __restrict__ y, int SK) {
  const int row = blockIdx.x * 4 + (threadIdx.x >> 6);
  const int l = threadIdx.x & 63;
  const size_t base = (size_t)row * 512 + l * 8;
  f32x4 v0 = *(const f32x4*)&res[base];
  f32x4 v1 = *(const f32x4*)&res[base + 4];
  v0 += *(const f32x4*)&bias[l * 8];
  v1 += *(const f32x4*)&bias[l * 8 + 4];
  for (int s = 0; s < SK; ++s) {
    v0 += *(const f32x4*)&P[(size_t)s * 524288 + base];
    v1 += *(const f32x4*)&P[(size_t)s * 524288 + base + 4];
  }
  *(f32x4*)&xout[base] = v0;
  *(f32x4*)&xout[base + 4] = v1;
  float s1 = 0.f, s2 = 0.f;
#pragma unroll
  for (int e = 0; e < 4; ++e) {
    s1 += v0[e] + v1[e];
    s2 += v0[e] * v0[e] + v1[e] * v1[e];
  }
#pragma unroll
  for (int d = 1; d < 64; d <<= 1) {
    s1 += __shfl_xor(s1, d);
    s2 += __shfl_xor(s2, d);
  }
  const float mean = s1 * (1.f / 512.f);
  const float var = s2 * (1.f / 512.f) - mean * mean;
  const float rstd = rsqrtf(var + 1e-5f);
  const f32x4 w0 = *(const f32x4*)&w[l * 8], w1 = *(const f32x4*)&w[l * 8 + 4];
  const f32x4 b0 = *(const f32x4*)&b[l * 8], b1 = *(const f32x4*)&b[l * 8 + 4];
  bf16x8 o;
#pragma unroll
  for (int e = 0; e < 4; ++e) {
    o[e] = bfbits((v0[e] - mean) * rstd * w0[e] + b0[e]);
    o[e + 4] = bfbits((v1[e] - mean) * rstd * w1[e] + b1[e]);
  }
  *(bf16x8*)&y[base] = o;
}

// ---------------------------------------------------------------------------
// gemm_geglu: 64x128-tile bf16 GEMM with fused GEGLU epilogue (permuted w1).
// ---------------------------------------------------------------------------
__global__ __launch_bounds__(256, 4) void gemm_geglu(
    const __hip_bfloat16* __restrict__ A, const __hip_bfloat16* __restrict__ Bt,
    __hip_bfloat16* __restrict__ Cb, const float* __restrict__ bias) {
  const int K = 512;
  const int nwg = gridDim.x * gridDim.y;
  const int lid = blockIdx.y * gridDim.x + blockIdx.x;
  const int work = (lid & 7) * (nwg >> 3) + (lid >> 3);
  const int n0 = (work % gridDim.x) * 128;
  const int m0 = (work / gridDim.x) * 64;

  const int t = threadIdx.x;
  const int w = t >> 6, l = t & 63;
  const int lr = l & 15, lk = l >> 4;
  const int wm = (w >> 1) * 32, wn = (w & 1) * 64;
  __shared__ __hip_bfloat16 Al[2][64 * 32];
  __shared__ __hip_bfloat16 Bl[2][128 * 32];

  f32x4 acc[2][4];
  const f32x4 z = {0.f, 0.f, 0.f, 0.f};
#pragma unroll
  for (int i = 0; i < 2; ++i)
#pragma unroll
    for (int j = 0; j < 4; ++j) acc[i][j] = z;

  const int srow = w * 16 + (l >> 2);
  const int scol = ((l & 3) ^ ((l >> 3) & 3)) * 8;
  const __hip_bfloat16* Ag = A + (size_t)(m0 + srow) * K + scol;
  const __hip_bfloat16* Bg = Bt + (size_t)(n0 + srow) * K + scol;

#define STAGE(buf, k0)                                                   \
  {                                                                      \
    load_lds16(Ag + (k0), (char*)Al[buf] + w * 1024);                    \
    load_lds16(Bg + (k0), (char*)Bl[buf] + w * 1024);                    \
    load_lds16(Bg + (size_t)64 * K + (k0), (char*)Bl[buf] + 4096 + w * 1024); \
  }

  STAGE(0, 0);
  __syncthreads();
  int cur = 0;
  const int rs = (lk ^ ((lr >> 1) & 3)) * 16;
  for (int k0 = 0; k0 < K; k0 += 32) {
    if (k0 + 32 < K) STAGE(cur ^ 1, k0 + 32);
    bf16x8 af[2], bfr[4];
#pragma unroll
    for (int i = 0; i < 2; ++i)
      af[i] = *(const bf16x8*)((const char*)Al[cur] + ((wm + i * 16 + lr) * 64 + rs));
#pragma unroll
    for (int j = 0; j < 4; ++j)
      bfr[j] = *(const bf16x8*)((const char*)Bl[cur] + ((wn + j * 16 + lr) * 64 + rs));
#pragma unroll
    for (int i = 0; i < 2; ++i)
#pragma unroll
      for (int j = 0; j < 4; ++j)
        acc[i][j] = __builtin_amdgcn_mfma_f32_16x16x32_bf16(af[i], bfr[j], acc[i][j], 0, 0, 0);
    __syncthreads();
    cur ^= 1;
  }
#undef STAGE

  const int nb = (n0 + wn) >> 1;
  float ba[2], bg[2];
#pragma unroll
  for (int jj = 0; jj < 2; ++jj) {
    ba[jj] = bias[nb + jj * 16 + lr];
    bg[jj] = bias[2048 + nb + jj * 16 + lr];
  }
#pragma unroll
  for (int i = 0; i < 2; ++i) {
    const int row = m0 + wm + i * 16 + lk * 4;
#pragma unroll
    for (int jj = 0; jj < 2; ++jj) {
      const int col = nb + jj * 16 + lr;
#pragma unroll
      for (int r = 0; r < 4; ++r) {
        const float a = acc[i][jj][r] + ba[jj];
        const float g = acc[i][jj + 2][r] + bg[jj];
        const float ge = 0.5f * g * (1.f + erff(g * 0.70710678118f));
        Cb[(size_t)(row + r) * 2048 + col] = __float2bfloat16(a * ge);
      }
    }
  }
}

// ---------------------------------------------------------------------------
// projx (fp8, granule-interleaved): 1D grid 2080 = 2048 KV + 32 Q blocks.
// fp8 buffers store each 64B K-group as granules [0,4,1,5,2,6,3,7], so a
// single b128 read at slot (lk ^ (lr>>1)&3) yields both k-slices per lane.
// ---------------------------------------------------------------------------
__global__ __launch_bounds__(256, 4) void projx_kernel(
    const unsigned char* __restrict__ ctx8, const unsigned char* __restrict__ wkv8,
    __hip_bfloat16* __restrict__ Kb, __hip_bfloat16* __restrict__ Vt,
    const unsigned char* __restrict__ xq8, const unsigned char* __restrict__ wq8,
    __hip_bfloat16* __restrict__ Qb) {
  const int nwg = gridDim.x;   // 2080, % 8 == 0
  const int lid = blockIdx.x;
  const int work = (lid & 7) * (nwg >> 3) + (lid >> 3);

  const unsigned char *A, *Bt;
  int m0, n0, mode;   // 0 = K half, 1 = V half, 2 = Q
  if (work < 2048) {
    m0 = (work >> 3) * 128;
    n0 = (work & 7) * 128;
    A = ctx8; Bt = wkv8;
    mode = (n0 < 512) ? 0 : 1;
  } else {
    const int idx = work - 2048;
    m0 = (idx >> 2) * 128;
    n0 = (idx & 3) * 128;
    A = xq8; Bt = wq8;
    mode = 2;
  }

  const int t = threadIdx.x;
  const int w = t >> 6, l = t & 63;
  const int lr = l & 15, lk = l >> 4;
  const int wm = (w >> 1) * 64, wn = (w & 1) * 64;
  __shared__ unsigned char Al[2][128 * 64];
  __shared__ unsigned char Bl[2][128 * 64];

  f32x4 acc[4][4];
  const f32x4 z = {0.f, 0.f, 0.f, 0.f};
#pragma unroll
  for (int i = 0; i < 4; ++i)
#pragma unroll
    for (int j = 0; j < 4; ++j) acc[i][j] = z;

  const int srow = w * 16 + (l >> 2);
  const int sc = ((l & 3) ^ ((l >> 3) & 3)) * 16;
  const unsigned char* Ag = A + (size_t)(m0 + srow) * 512 + sc;
  const unsigned char* Bg = Bt + (size_t)(n0 + srow) * 512 + sc;

#define STAGE(buf, kb)                                                   \
  {                                                                      \
    load_lds16(Ag + (kb), (char*)Al[buf] + w * 1024);                    \
    load_lds16(Ag + (size_t)64 * 512 + (kb), (char*)Al[buf] + 4096 + w * 1024); \
    load_lds16(Bg + (kb), (char*)Bl[buf] + w * 1024);                    \
    load_lds16(Bg + (size_t)64 * 512 + (kb), (char*)Bl[buf] + 4096 + w * 1024); \
  }

  STAGE(0, 0);
  __syncthreads();
  int cur = 0;
  const int rs = (lk ^ ((lr >> 1) & 3)) * 16;
  for (int tt = 0; tt < 8; ++tt) {
    if (tt < 7) STAGE(cur ^ 1, (tt + 1) * 64);
    i64 af[2][4], bfr[2][4];
#pragma unroll
    for (int i = 0; i < 4; ++i) {
      const int ar = wm + i * 16 + lr;
      const i64x2 v = *(const i64x2*)((const char*)Al[cur] + ar * 64 + rs);
      af[0][i] = v[0];
      af[1][i] = v[1];
    }
#pragma unroll
    for (int j = 0; j < 4; ++j) {
      const int br = wn + j * 16 + lr;
      const i64x2 v = *(const i64x2*)((const char*)Bl[cur] + br * 64 + rs);
      bfr[0][j] = v[0];
      bfr[1][j] = v[1];
    }
#pragma unroll
    for (int i = 0; i < 4; ++i)
#pragma unroll
      for (int j = 0; j < 4; ++j) {
        acc[i][j] = __builtin_amdgcn_mfma_f32_16x16x32_fp8_fp8(af[0][i], bfr[0][j], acc[i][j], 0, 0, 0);
        acc[i][j] = __builtin_amdgcn_mfma_f32_16x16x32_fp8_fp8(af[1][i], bfr[1][j], acc[i][j], 0, 0, 0);
      }
    __syncthreads();
    cur ^= 1;
  }
#undef STAGE

  const float SCL = 0.0625f;
  if (mode == 0) {
#pragma unroll
    for (int i = 0; i < 4; ++i) {
      const int row = m0 + wm + i * 16 + lk * 4;
#pragma unroll
      for (int j = 0; j < 4; ++j) {
        const int col = n0 + wn + j * 16 + lr;
#pragma unroll
        for (int r = 0; r < 4; ++r)
          Kb[(size_t)(row + r) * 512 + col] = __float2bfloat16(acc[i][j][r] * SCL);
      }
    }
  } else if (mode == 1) {
#pragma unroll
    for (int i = 0; i < 4; ++i) {
      const int row0 = m0 + wm + i * 16 + lk * 4;
      const int b = row0 >> 12;
      const int key0 = row0 & 4095;
#pragma unroll
      for (int j = 0; j < 4; ++j) {
        const int c = n0 + wn + j * 16 + lr - 512;
        const int hh = c >> 6, dh = c & 63;
        short4 pk;
        pk.x = bfbits(acc[i][j][0] * SCL);
        pk.y = bfbits(acc[i][j][1] * SCL);
        pk.z = bfbits(acc[i][j][2] * SCL);
        pk.w = bfbits(acc[i][j][3] * SCL);
        *(short4*)&Vt[((size_t)((b * 8 + hh) * 64 + dh) << 12) + key0] = pk;
      }
    }
  } else {
#pragma unroll
    for (int i = 0; i < 4; ++i) {
      const int row = m0 + wm + i * 16 + lk * 4;
#pragma unroll
      for (int j = 0; j < 4; ++j) {
        const int col = n0 + wn + j * 16 + lr;
#pragma unroll
        for (int r = 0; r < 4; ++r)
          Qb[(size_t)(row + r) * 512 + col] = __float2bfloat16(acc[i][j][r] * SCL);
      }
    }
  }
}

// ---------------------------------------------------------------------------
// proj (self-attn, bf16): 3-way epilogue by column.
// ---------------------------------------------------------------------------
__global__ __launch_bounds__(256, 4) void proj_kernel(
    const __hip_bfloat16* __restrict__ A, const __hip_bfloat16* __restrict__ Bt,
    __hip_bfloat16* __restrict__ Qb, __hip_bfloat16* __restrict__ Kb,
    __hip_bfloat16* __restrict__ Vt, int qcols, int rpb_shift) {
  const int nwg = gridDim.x * gridDim.y;
  const int lid = blockIdx.y * gridDim.x + blockIdx.x;
  const int work = (lid & 7) * (nwg >> 3) + (lid >> 3);
  const int n0 = (work % gridDim.x) * 128;
  const int m0 = (work / gridDim.x) * 128;
  const int K = 512;

  const int t = threadIdx.x;
  const int w = t >> 6, l = t & 63;
  const int lr = l & 15, lk = l >> 4;
  const int wm = (w >> 1) * 64, wn = (w & 1) * 64;
  __shared__ __hip_bfloat16 Al[2][128 * 32];
  __shared__ __hip_bfloat16 Bl[2][128 * 32];

  f32x4 acc[4][4];
  const f32x4 z = {0.f, 0.f, 0.f, 0.f};
#pragma unroll
  for (int i = 0; i < 4; ++i)
#pragma unroll
    for (int j = 0; j < 4; ++j) acc[i][j] = z;

  const int srow = w * 16 + (l >> 2);
  const int scol = ((l & 3) ^ ((l >> 3) & 3)) * 8;
  const __hip_bfloat16* Ag = A + (size_t)(m0 + srow) * K + scol;
  const __hip_bfloat16* Bg = Bt + (size_t)(n0 + srow) * K + scol;

#define STAGE(buf, k0)                                                   \
  {                                                                      \
    load_lds16(Ag + (k0), (char*)Al[buf] + w * 1024);                    \
    load_lds16(Ag + (size_t)64 * K + (k0), (char*)Al[buf] + 4096 + w * 1024); \
    load_lds16(Bg + (k0), (char*)Bl[buf] + w * 1024);                    \
    load_lds16(Bg + (size_t)64 * K + (k0), (char*)Bl[buf] + 4096 + w * 1024); \
  }

  STAGE(0, 0);
  __syncthreads();
  int cur = 0;
  const int rs = (lk ^ ((lr >> 1) & 3)) * 16;
  for (int k0 = 0; k0 < K; k0 += 32) {
    if (k0 + 32 < K) STAGE(cur ^ 1, k0 + 32);
    bf16x8 af[4], bfr[4];
#pragma unroll
    for (int i = 0; i < 4; ++i)
      af[i] = *(const bf16x8*)((const char*)Al[cur] + ((wm + i * 16 + lr) * 64 + rs));
#pragma unroll
    for (int j = 0; j < 4; ++j)
      bfr[j] = *(const bf16x8*)((const char*)Bl[cur] + ((wn + j * 16 + lr) * 64 + rs));
#pragma unroll
    for (int i = 0; i < 4; ++i)
#pragma unroll
      for (int j = 0; j < 4; ++j)
        acc[i][j] = __builtin_amdgcn_mfma_f32_16x16x32_bf16(af[i], bfr[j], acc[i][j], 0, 0, 0);
    __syncthreads();
    cur ^= 1;
  }
#undef STAGE

  if (n0 < qcols) {
#pragma unroll
    for (int i = 0; i < 4; ++i) {
      const int row = m0 + wm + i * 16 + lk * 4;
#pragma unroll
      for (int j = 0; j < 4; ++j) {
        const int col = n0 + wn + j * 16 + lr;
#pragma unroll
        for (int r = 0; r < 4; ++r)
          Qb[(size_t)(row + r) * 512 + col] = __float2bfloat16(acc[i][j][r]);
      }
    }
  } else if (n0 < qcols + 512) {
#pragma unroll
    for (int i = 0; i < 4; ++i) {
      const int row = m0 + wm + i * 16 + lk * 4;
#pragma unroll
      for (int j = 0; j < 4; ++j) {
        const int col = n0 + wn + j * 16 + lr - qcols;
#pragma unroll
        for (int r = 0; r < 4; ++r)
          Kb[(size_t)(row + r) * 512 + col] = __float2bfloat16(acc[i][j][r]);
      }
    }
  } else {
    const int rpb = 1 << rpb_shift;
#pragma unroll
    for (int i = 0; i < 4; ++i) {
      const int row0 = m0 + wm + i * 16 + lk * 4;
      const int b = row0 >> rpb_shift;
      const int key0 = row0 & (rpb - 1);
#pragma unroll
      for (int j = 0; j < 4; ++j) {
        const int c = n0 + wn + j * 16 + lr - qcols - 512;
        const int hh = c >> 6, dh = c & 63;
        short4 pk;
        pk.x = bfbits(acc[i][j][0]);
        pk.y = bfbits(acc[i][j][1]);
        pk.z = bfbits(acc[i][j][2]);
        pk.w = bfbits(acc[i][j][3]);
        *(short4*)&Vt[((size_t)((b * 8 + hh) * 64 + dh) << rpb_shift) + key0] = pk;
      }
    }
  }
}

// ---------------------------------------------------------------------------
// Key-split flash attention, static-max softmax; bf16 partials, f32 row sums.
// ---------------------------------------------------------------------------
__global__ __launch_bounds__(256) void attn_split_kernel(
    const __hip_bfloat16* __restrict__ Q, const __hip_bfloat16* __restrict__ Kb,
    const __hip_bfloat16* __restrict__ Vt,
    __hip_bfloat16* __restrict__ Opart, float* __restrict__ Lv,
    __hip_bfloat16* __restrict__ Od,
    int chunk, int rows_per_b, int S) {
  const float SC2 = 0.18033688f;   // 0.125 * log2(e)
  const int h = blockIdx.x, b = blockIdx.y, s = blockIdx.z;
  const int t = threadIdx.x;
  const int w = t >> 6, l = t & 63;
  const int lr = l & 15, lk = l >> 4;
  __shared__ __hip_bfloat16 Kl[64 * 64];
  __shared__ __hip_bfloat16 Vl[64 * 64];
  __shared__ __hip_bfloat16 Pl[4][32 * 64];

  bf16x8 qf[2][2];
#pragma unroll
  for (int mf = 0; mf < 2; ++mf)
#pragma unroll
    for (int kf = 0; kf < 2; ++kf)
      qf[mf][kf] = *(const bf16x8*)&Q[(size_t)(b * 128 + w * 32 + mf * 16 + lr) * 512 +
                                      h * 64 + kf * 32 + lk * 8];

  f32x4 o[2][4];
  const f32x4 z = {0.f, 0.f, 0.f, 0.f};
#pragma unroll
  for (int mf = 0; mf < 2; ++mf)
#pragma unroll
    for (int nf = 0; nf < 4; ++nf) o[mf][nf] = z;
  float lsum[2][4];
#pragma unroll
  for (int mf = 0; mf < 2; ++mf)
#pragma unroll
    for (int r = 0; r < 4; ++r) lsum[mf][r] = 0.f;

  const __hip_bfloat16* kvb = Kb + (size_t)b * rows_per_b * 512;
  const __hip_bfloat16* vtb = Vt + (size_t)(b * 8 + h) * 64 * rows_per_b;
  char* pw = (char*)Pl[w];
  const int srow = l >> 3;
  const int sslot = (l & 7) ^ srow;
  const int jend = s * chunk + chunk;

  for (int j0 = s * chunk; j0 < jend; j0 += 64) {
    __syncthreads();
#pragma unroll
    for (int p = 0; p < 2; ++p) {
      const int row = p * 32 + w * 8 + srow;
      load_lds16(&kvb[(size_t)(j0 + row) * 512 + h * 64 + sslot * 8],
                 (char*)Kl + p * 4096 + w * 1024);
      load_lds16(&vtb[(size_t)row * rows_per_b + j0 + sslot * 8],
                 (char*)Vl + p * 4096 + w * 1024);
    }
    __syncthreads();

    f32x4 sc[2][4];
#pragma unroll
    for (int mf = 0; mf < 2; ++mf)
#pragma unroll
      for (int nf = 0; nf < 4; ++nf) sc[mf][nf] = z;
    __builtin_amdgcn_s_setprio(1);
#pragma unroll
    for (int kf = 0; kf < 2; ++kf) {
      bf16x8 kb[4];
#pragma unroll
      for (int nf = 0; nf < 4; ++nf) {
        const int key = nf * 16 + lr;
        kb[nf] = *(const bf16x8*)((char*)Kl +
                  (key * 128 + (((kf * 4 + lk) ^ (key & 7)) * 16)));
      }
#pragma unroll
      for (int mf = 0; mf < 2; ++mf)
#pragma unroll
        for (int nf = 0; nf < 4; ++nf)
          sc[mf][nf] = __builtin_amdgcn_mfma_f32_16x16x32_bf16(qf[mf][kf], kb[nf], sc[mf][nf], 0, 0, 0);
    }
    __builtin_amdgcn_s_setprio(0);

#pragma unroll
    for (int mf = 0; mf < 2; ++mf)
#pragma unroll
      for (int nf = 0; nf < 4; ++nf)
#pragma unroll
        for (int r = 0; r < 4; ++r) {
          const float p = exp2f(sc[mf][nf][r] * SC2);
          sc[mf][nf][r] = p;
          lsum[mf][r] += p;
        }

#pragma unroll
    for (int mf = 0; mf < 2; ++mf)
#pragma unroll
      for (int r = 0; r < 4; ++r) {
        const int prow = mf * 16 + lk * 4 + r;
#pragma unroll
        for (int nf = 0; nf < 4; ++nf) {
          const int pcol = nf * 16 + lr;
          *(__hip_bfloat16*)(pw + ((prow * 128 + pcol * 2) ^ ((prow & 7) << 4))) =
              __float2bfloat16(sc[mf][nf][r]);
        }
      }

    __builtin_amdgcn_s_setprio(1);
#pragma unroll
    for (int kf = 0; kf < 2; ++kf) {
      bf16x8 pa[2], vb[4];
#pragma unroll
      for (int mf = 0; mf < 2; ++mf) {
        const int prow = mf * 16 + lr;
        pa[mf] = *(const bf16x8*)(pw + ((prow * 128 + (kf * 4 + lk) * 16) ^ ((prow & 7) << 4)));
      }
#pragma unroll
      for (int nf = 0; nf < 4; ++nf) {
        const int dh = nf * 16 + lr;
        vb[nf] = *(const bf16x8*)((char*)Vl +
                  (dh * 128 + (((kf * 4 + lk) ^ (dh & 7)) * 16)));
      }
#pragma unroll
      for (int mf = 0; mf < 2; ++mf)
#pragma unroll
        for (int nf = 0; nf < 4; ++nf)
          o[mf][nf] = __builtin_amdgcn_mfma_f32_16x16x32_bf16(pa[mf], vb[nf], o[mf][nf], 0, 0, 0);
    }
    __builtin_amdgcn_s_setprio(0);
  }

  const int part = (b * 8 + h) * S + s;
  __hip_bfloat16* op = Opart + (size_t)part * 8192;
#pragma unroll
  for (int mf = 0; mf < 2; ++mf)
#pragma unroll
    for (int r = 0; r < 4; ++r) {
      float ls = lsum[mf][r];
      ls += __shfl_xor(ls, 1);
      ls += __shfl_xor(ls, 2);
      ls += __shfl_xor(ls, 4);
      ls += __shfl_xor(ls, 8);
      const int row = w * 32 + mf * 16 + lk * 4 + r;
      if (Od) {
        const float inv = 1.f / ls;
#pragma unroll
        for (int nf = 0; nf < 4; ++nf)
          Od[(size_t)(b * 128 + row) * 512 + h * 64 + nf * 16 + lr] =
              __float2bfloat16(o[mf][nf][r] * inv);
      } else {
#pragma unroll
        for (int nf = 0; nf < 4; ++nf)
          op[(size_t)row * 64 + nf * 16 + lr] = __float2bfloat16(o[mf][nf][r]);
        if (lr == 0) Lv[(size_t)part * 128 + row] = ls;
      }
    }
}

// combine (vectorized): thread t handles cols 2t, 2t+1 of its row.
__global__ __launch_bounds__(256) void attn_combine_kernel(
    const __hip_bfloat16* __restrict__ Opart, const float* __restrict__ Lv,
    __hip_bfloat16* __restrict__ O, int S) {
  const int row = blockIdx.x;
  const int b = row >> 7, i = row & 127;
  const int t = threadIdx.x;
  const int h = t >> 5, dh0 = (t * 2) & 63;
  const int pbase = (b * 8 + h) * S;
  float L = 0.f, v0 = 0.f, v1 = 0.f;
  for (int s = 0; s < S; ++s) {
    L += Lv[(size_t)(pbase + s) * 128 + i];
    const __hip_bfloat16* p = &Opart[((size_t)(pbase + s) * 128 + i) * 64 + dh0];
    const ushort2 u = *(const ushort2*)p;
    const unsigned int b0 = (unsigned int)u.x << 16, b1 = (unsigned int)u.y << 16;
    v0 += *(const float*)&b0;
    v1 += *(const float*)&b1;
  }
  const float inv = 1.f / L;
  ushort2 out;
  out.x = (unsigned short)bfbits(v0 * inv);
  out.y = (unsigned short)bfbits(v1 * inv);
  *(ushort2*)&O[(size_t)row * 512 + t * 2] = out;
}

// ---------------------------------------------------------------------------
// wave-per-row LayerNorm -> fp8, granule-interleaved store:
// lane l's 8 bytes (granule l) land at group (l>>3), position (gg&3)*2+(gg>>2).
// ---------------------------------------------------------------------------
DEVI void ln_wave_q(const float* __restrict__ x, const float* __restrict__ w,
                    const float* __restrict__ bb, unsigned char* __restrict__ y,
                    int row) {
  const int l = threadIdx.x & 63;
  const size_t base = (size_t)row * 512 + l * 8;
  const f32x4 v0 = *(const f32x4*)&x[base];
  const f32x4 v1 = *(const f32x4*)&x[base + 4];
  float s = 0.f, sq = 0.f;
#pragma unroll
  for (int e = 0; e < 4; ++e) {
    s += v0[e] + v1[e];
    sq += v0[e] * v0[e] + v1[e] * v1[e];
  }
#pragma unroll
  for (int d = 1; d < 64; d <<= 1) {
    s += __shfl_xor(s, d);
    sq += __shfl_xor(sq, d);
  }
  const float mean = s * (1.f / 512.f);
  const float var = sq * (1.f / 512.f) - mean * mean;
  const float rstd = rsqrtf(var + 1e-5f);
  const f32x4 w0 = *(const f32x4*)&w[l * 8], w1 = *(const f32x4*)&w[l * 8 + 4];
  const f32x4 b0 = *(const f32x4*)&bb[l * 8], b1 = *(const f32x4*)&bb[l * 8 + 4];
  float yv[8];
#pragma unroll
  for (int e = 0; e < 4; ++e) {
    yv[e] = (v0[e] - mean) * rstd * w0[e] + b0[e];
    yv[e + 4] = (v1[e] - mean) * rstd * w1[e] + b1[e];
  }
  uint2 pk;
  pk.x = fp8pk2(yv[0], yv[1]) | (fp8pk2(yv[2], yv[3]) << 16);
  pk.y = fp8pk2(yv[4], yv[5]) | (fp8pk2(yv[6], yv[7]) << 16);
  const int gg = l & 7;
  const size_t wb = (size_t)row * 512 + (l >> 3) * 64 +
                    ((gg & 3) * 2 + (gg >> 2)) * 8;
  *(uint2*)&y[wb] = pk;
}

// ---------------------------------------------------------------------------
// prep: weight-convert (blocks 0..8191; w1 PERMUTED; set-0 wq/wkv -> fp8 x16,
// k-granule-interleaved) + wave-per-row LNs -> fp8 (blocks 8192+).
// ---------------------------------------------------------------------------
struct WcvtDesc { const float* src[10]; __hip_bfloat16* dst[10]; };

__global__ __launch_bounds__(256) void prep_kernel(
    WcvtDesc d, unsigned char* __restrict__ wq8, unsigned char* __restrict__ wkv8,
    const float* __restrict__ lat, const float* __restrict__ lw,
    const float* __restrict__ lb, unsigned char* __restrict__ xq8,
    const float* __restrict__ ctx, const float* __restrict__ cw,
    const float* __restrict__ cb, unsigned char* __restrict__ cn8) {
  if (blockIdx.x >= 8192) {
    const int row = (blockIdx.x - 8192) * 4 + (threadIdx.x >> 6);
    if (row < 1024)
      ln_wave_q(lat, lw, lb, xq8, row);
    else
      ln_wave_q(ctx, cw, cb, cn8, row - 1024);
    return;
  }
  int tile = blockIdx.x;
  const int set = tile >> 12;
  tile &= 4095;
  int wi0, K, N, base;
  if (tile < 256)       { wi0 = 0; K = 512;  N = 512;  base = 0; }
  else if (tile < 768)  { wi0 = 1; K = 512;  N = 1024; base = 256; }
  else if (tile < 1024) { wi0 = 2; K = 512;  N = 512;  base = 768; }
  else if (tile < 3072) { wi0 = 3; K = 512;  N = 4096; base = 1024; }
  else                  { wi0 = 4; K = 2048; N = 512;  base = 3072; }
  const bool permute = (wi0 == 3);
  const bool tofp8 = (set == 0 && wi0 < 2);
  const int wi = wi0 + set * 5;
  const int rel = tile - base;
  const int ntx = N >> 5;
  const int n0 = (rel % ntx) * 32, k0 = (rel / ntx) * 32;
  const int sn0 = permute ? (((n0 >> 6) << 5) + ((n0 & 32) ? 2048 : 0)) : n0;
  const float* W = d.src[wi];
  __shared__ float tl[32][33];
  const int tx = threadIdx.x & 31, ty = threadIdx.x >> 5;
#pragma unroll
  for (int j = 0; j < 4; ++j)
    tl[ty + j * 8][tx] = W[(size_t)(k0 + ty + j * 8) * N + sn0 + tx];
  __syncthreads();
  if (tofp8) {
    unsigned char* Wq = (wi0 == 0) ? wq8 : wkv8;
    const int k = k0 + tx;
    const int gg = (k >> 3) & 7;
    const int kp = (k & ~63) + ((gg & 3) * 2 + (gg >> 2)) * 8 + (k & 7);
#pragma unroll
    for (int j = 0; j < 4; ++j)
      Wq[(size_t)(n0 + ty + j * 8) * 512 + kp] = fp8b(tl[tx][ty + j * 8] * 16.f);
  } else {
    __hip_bfloat16* Wt = d.dst[wi];
#pragma unroll
    for (int j = 0; j < 4; ++j)
      Wt[(size_t)(n0 + ty + j * 8) * K + k0 + tx] = __float2bfloat16(tl[tx][ty + j * 8]);
  }
}

// ---------------------------------------------------------------------------
extern "C" void kernel_launch(void* const* d_in, const int* in_sizes, int n_in,
                              void* d_out, int out_size, void* d_ws, size_t ws_size,
                              hipStream_t stream) {
  (void)in_sizes; (void)n_in; (void)out_size; (void)ws_size;
  const float* context = (const float*)d_in[0];
  const float* latents = (const float*)d_in[1];
  const float* ca_ln_w = (const float*)d_in[2];
  const float* ca_ln_b = (const float*)d_in[3];
  const float* ca_lnc_w = (const float*)d_in[4];
  const float* ca_lnc_b = (const float*)d_in[5];
  const float* ca_wq = (const float*)d_in[6];
  const float* ca_wkv = (const float*)d_in[7];
  const float* ca_wo = (const float*)d_in[8];
  const float* ca_bo = (const float*)d_in[9];
  const float* cf_ln_w = (const float*)d_in[10];
  const float* cf_ln_b = (const float*)d_in[11];
  const float* cf_w1 = (const float*)d_in[12];
  const float* cf_b1 = (const float*)d_in[13];
  const float* cf_w2 = (const float*)d_in[14];
  const float* cf_b2 = (const float*)d_in[15];
  const float* sa_ln_w = (const float*)d_in[16];
  const float* sa_ln_b = (const float*)d_in[17];
  const float* sa_wq = (const float*)d_in[18];
  const float* sa_wkv = (const float*)d_in[19];
  const float* sa_wo = (const float*)d_in[20];
  const float* sa_bo = (const float*)d_in[21];
  const float* lf_ln_w = (const float*)d_in[22];
  const float* lf_ln_b = (const float*)d_in[23];
  const float* lf_w1 = (const float*)d_in[24];
  const float* lf_b1 = (const float*)d_in[25];
  const float* lf_w2 = (const float*)d_in[26];
  const float* lf_b2 = (const float*)d_in[27];

  typedef __hip_bfloat16 bf;
  char* ws = (char*)d_ws;
  size_t off = 0;
  auto alloc = [&](size_t bytes) -> void* {
    void* p = ws + off;
    off += (bytes + 255) & ~(size_t)255;
    return p;
  };
  bf* wq1t = (bf*)alloc((size_t)512 * 512 * 2);     // unused (fp8 path)
  bf* wkv1t = (bf*)alloc((size_t)1024 * 512 * 2);   // unused (fp8 path)
  bf* wo1t = (bf*)alloc((size_t)512 * 512 * 2);
  bf* w1ct = (bf*)alloc((size_t)4096 * 512 * 2);
  bf* w2ct = (bf*)alloc((size_t)512 * 2048 * 2);
  bf* wq2t = (bf*)alloc((size_t)512 * 512 * 2);
  bf* wkv2t = (bf*)alloc((size_t)1024 * 512 * 2);
  bf* wo2t = (bf*)alloc((size_t)512 * 512 * 2);
  bf* w1lt = (bf*)alloc((size_t)4096 * 512 * 2);
  bf* w2lt = (bf*)alloc((size_t)512 * 2048 * 2);
  unsigned char* wq8 = (unsigned char*)alloc((size_t)512 * 512);
  unsigned char* wkv8 = (unsigned char*)alloc((size_t)1024 * 512);
  unsigned char* cn8 = (unsigned char*)alloc((size_t)32768 * 512);   // 16.8 MB
  unsigned char* xq8 = (unsigned char*)alloc((size_t)1024 * 512);
  bf* cn = (bf*)alloc((size_t)32768 * 512 * 2);     // reuse region (33.5 MB)
  bf* kbuf = (bf*)alloc((size_t)32768 * 512 * 2);   // cross K [row][512]
  bf* vt = (bf*)alloc((size_t)64 * 64 * 4096 * 2);  // cross V^T
  bf* kb2 = (bf*)alloc((size_t)1024 * 512 * 2);     // self K
  bf* vt2 = (bf*)alloc((size_t)64 * 64 * 128 * 2);  // self V^T
  float* lv = (float*)alloc((size_t)1024 * 128 * 4);
  float* skq = (float*)alloc((size_t)4 * 1024 * 512 * 4);
  bf* xnb = (bf*)alloc((size_t)1024 * 512 * 2);
  bf* qb = (bf*)alloc((size_t)1024 * 512 * 2);
  bf* aob = (bf*)alloc((size_t)1024 * 512 * 2);
  bf* q2b = (bf*)alloc((size_t)1024 * 512 * 2);
  bf* ao2b = (bf*)alloc((size_t)1024 * 512 * 2);
  float* x1 = (float*)alloc((size_t)1024 * 512 * 4);
  float* x2 = (float*)alloc((size_t)1024 * 512 * 4);
  float* x3 = (float*)alloc((size_t)1024 * 512 * 4);
  bf* x2n = (bf*)alloc((size_t)1024 * 512 * 2);
  bf* x3n = (bf*)alloc((size_t)1024 * 512 * 2);
  // cn region time-disjoint reuse:
  bf* opart = cn;                                  // attn bf16 partials (16.8 MB)
  float* skp = (float*)cn;                         // FFN-down SK=8 partials (16.8 MB)
  bf* agb = (bf*)((char*)cn + 17 * 1024 * 1024);   // GEGLU out (4.2 MB)

  WcvtDesc wd;
  wd.src[0] = ca_wq;  wd.dst[0] = wq1t;
  wd.src[1] = ca_wkv; wd.dst[1] = wkv1t;
  wd.src[2] = ca_wo;  wd.dst[2] = wo1t;
  wd.src[3] = cf_w1;  wd.dst[3] = w1ct;
  wd.src[4] = cf_w2;  wd.dst[4] = w2ct;
  wd.src[5] = sa_wq;  wd.dst[5] = wq2t;
  wd.src[6] = sa_wkv; wd.dst[6] = wkv2t;
  wd.src[7] = sa_wo;  wd.dst[7] = wo2t;
  wd.src[8] = lf_w1;  wd.dst[8] = w1lt;
  wd.src[9] = lf_w2;  wd.dst[9] = w2lt;

  // --- prep: weight convert (+fp8 cross wq/wkv) + wave-per-row LNs -> fp8 ---
  prep_kernel<<<8192 + 8448, 256, 0, stream>>>(
      wd, wq8, wkv8, latents, ca_ln_w, ca_ln_b, xq8,
      context, ca_lnc_w, ca_lnc_b, cn8);

  // --- sublayer 1: cross attention (fp8 projection) ---
  projx_kernel<<<2080, 256, 0, stream>>>(cn8, wkv8, kbuf, vt, xq8, wq8, qb);
  attn_split_kernel<<<dim3(8, 8, 16), 256, 0, stream>>>(qb, kbuf, vt, opart, lv, nullptr, 256, 4096, 16);
  attn_combine_kernel<<<1024, 256, 0, stream>>>(opart, lv, aob, 16);
  gemm_sk<<<dim3(4, 8, 4), 256, 0, stream>>>(aob, wo1t, skq, 1024, 512, 512);
  reduce_ln_sk<<<256, 256, 0, stream>>>(skq, ca_bo, latents, x1, cf_ln_w, cf_ln_b, xnb, 4);

  // --- sublayer 2: cross FFN (GEGLU fused up-proj, SK=8 down-proj) ---
  gemm_geglu<<<dim3(32, 16), 256, 0, stream>>>(xnb, w1ct, agb, cf_b1);
  gemm_sk<<<dim3(4, 8, 8), 256, 0, stream>>>(agb, w2ct, skp, 1024, 512, 2048);
  reduce_ln_sk<<<256, 256, 0, stream>>>(skp, cf_b2, x1, x2, sa_ln_w, sa_ln_b, x2n, 8);

  // --- sublayer 3: latent self-attention (merged QKV, direct write) ---
  proj_kernel<<<dim3(12, 8), 256, 0, stream>>>(x2n, wq2t, q2b, kb2, vt2, 512, 7);
  attn_split_kernel<<<dim3(8, 8, 1), 256, 0, stream>>>(q2b, kb2, vt2, nullptr, nullptr, ao2b, 128, 128, 1);
  gemm_sk<<<dim3(4, 8, 4), 256, 0, stream>>>(ao2b, wo2t, skq, 1024, 512, 512);
  reduce_ln_sk<<<256, 256, 0, stream>>>(skq, sa_bo, x2, x3, lf_ln_w, lf_ln_b, x3n, 4);

  // --- sublayer 4: latent FFN (GEGLU fused up-proj, SK=8 down-proj) ---
  gemm_geglu<<<dim3(32, 16), 256, 0, stream>>>(x3n, w1lt, agb, lf_b1);
  gemm_sk<<<dim3(4, 8, 8), 256, 0, stream>>>(agb, w2lt, skp, 1024, 512, 2048);
  reduce_sk<<<512, 256, 0, stream>>>(skp, lf_b2, x3, (float*)d_out, 8);
}

// Round 16
// 187.929 us; speedup vs baseline: 1.7365x; 1.0182x over previous
//
#include <hip/hip_runtime.h>
#include <hip/hip_bf16.h>
#include <math.h>

// ---------------------------------------------------------------------------
// LBANP encoder layer on MI355X (gfx950).
// Round 16: fp8 Q/K end-to-end for cross attention — projx writes K half and
// Q as fp8 e4m3 (x4 prescale, granule-interleaved per 64B head slice);
// attn_split<1> stages K fp8 (1 load/thread) and runs QK^T on
// mfma_f32_16x16x32_fp8_fp8 with the softmax scale folding the 1/16.
// Self-attention keeps the bf16 path (attn_split<0>).
// ---------------------------------------------------------------------------

typedef __attribute__((ext_vector_type(8))) short bf16x8;   // 8 x bf16 (4 VGPRs)
typedef __attribute__((ext_vector_type(4))) float f32x4;
typedef long i64;
typedef __attribute__((ext_vector_type(2))) long i64x2;

#define DEVI __device__ __forceinline__

DEVI void load_lds16(const void* g, void* l) {
  __builtin_amdgcn_global_load_lds(
      (const __attribute__((address_space(1))) void*)g,
      (__attribute__((address_space(3))) void*)l, 16, 0, 0);
}

DEVI short bfbits(float x) {
  __hip_bfloat16 h = __float2bfloat16(x);
  return *reinterpret_cast<short*>(&h);
}

DEVI unsigned int fp8pk2(float a, float b) {
  return __builtin_amdgcn_cvt_pk_fp8_f32(a, b, 0, false) & 0xffff;
}

DEVI unsigned char fp8b(float x) {
  return (unsigned char)(__builtin_amdgcn_cvt_pk_fp8_f32(x, x, 0, false) & 0xff);
}

// byte position of logical col within a granule-interleaved 64B group
DEVI int gpos(int col) {
  const int g = (col >> 3) & 7;
  return (col & ~63) + (g & 3) * 16 + (g >> 2) * 8 + (col & 7);
}

// ---------------------------------------------------------------------------
// Split-K GEMM (bf16): P[z][M*N] = A[M, kseg] * Bt^T partials (f32).
// ---------------------------------------------------------------------------
__global__ __launch_bounds__(256, 4) void gemm_sk(
    const __hip_bfloat16* __restrict__ A, const __hip_bfloat16* __restrict__ Bt,
    float* __restrict__ P, int M, int N, int K) {
  const int nwg = gridDim.x * gridDim.y;
  const int lid = blockIdx.y * gridDim.x + blockIdx.x;
  const int work = (lid & 7) * (nwg >> 3) + (lid >> 3);
  const int n0 = (work % gridDim.x) * 128;
  const int m0 = (work / gridDim.x) * 128;
  const int KS = K / gridDim.z;
  const int kbeg = blockIdx.z * KS;

  const int t = threadIdx.x;
  const int w = t >> 6, l = t & 63;
  const int lr = l & 15, lk = l >> 4;
  const int wm = (w >> 1) * 64, wn = (w & 1) * 64;
  __shared__ __hip_bfloat16 Al[2][128 * 32];
  __shared__ __hip_bfloat16 Bl[2][128 * 32];

  f32x4 acc[4][4];
  const f32x4 z = {0.f, 0.f, 0.f, 0.f};
#pragma unroll
  for (int i = 0; i < 4; ++i)
#pragma unroll
    for (int j = 0; j < 4; ++j) acc[i][j] = z;

  const int srow = w * 16 + (l >> 2);
  const int scol = ((l & 3) ^ ((l >> 3) & 3)) * 8;
  const __hip_bfloat16* Ag = A + (size_t)(m0 + srow) * K + kbeg + scol;
  const __hip_bfloat16* Bg = Bt + (size_t)(n0 + srow) * K + kbeg + scol;

#define STAGE(buf, k0)                                                   \
  {                                                                      \
    load_lds16(Ag + (k0), (char*)Al[buf] + w * 1024);                    \
    load_lds16(Ag + (size_t)64 * K + (k0), (char*)Al[buf] + 4096 + w * 1024); \
    load_lds16(Bg + (k0), (char*)Bl[buf] + w * 1024);                    \
    load_lds16(Bg + (size_t)64 * K + (k0), (char*)Bl[buf] + 4096 + w * 1024); \
  }

  STAGE(0, 0);
  __syncthreads();
  int cur = 0;
  const int rs = (lk ^ ((lr >> 1) & 3)) * 16;
  for (int k0 = 0; k0 < KS; k0 += 32) {
    if (k0 + 32 < KS) STAGE(cur ^ 1, k0 + 32);
    bf16x8 af[4], bfr[4];
#pragma unroll
    for (int i = 0; i < 4; ++i)
      af[i] = *(const bf16x8*)((const char*)Al[cur] + ((wm + i * 16 + lr) * 64 + rs));
#pragma unroll
    for (int j = 0; j < 4; ++j)
      bfr[j] = *(const bf16x8*)((const char*)Bl[cur] + ((wn + j * 16 + lr) * 64 + rs));
#pragma unroll
    for (int i = 0; i < 4; ++i)
#pragma unroll
      for (int j = 0; j < 4; ++j)
        acc[i][j] = __builtin_amdgcn_mfma_f32_16x16x32_bf16(af[i], bfr[j], acc[i][j], 0, 0, 0);
    __syncthreads();
    cur ^= 1;
  }
#undef STAGE

  float* Pz = P + (size_t)blockIdx.z * M * N;
#pragma unroll
  for (int i = 0; i < 4; ++i) {
    const int row = m0 + wm + i * 16 + lk * 4;
#pragma unroll
    for (int j = 0; j < 4; ++j) {
      const int col = n0 + wn + j * 16 + lr;
#pragma unroll
      for (int r = 0; r < 4; ++r)
        Pz[(size_t)(row + r) * N + col] = acc[i][j][r];
    }
  }
}

// reduce split-K partials (float4): out = sum_sk P + bias + res  (grid 512x256)
__global__ __launch_bounds__(256) void reduce_sk(
    const float* __restrict__ P, const float* __restrict__ bias,
    const float* __restrict__ res, float* __restrict__ out, int SK) {
  const int i = (blockIdx.x * 256 + threadIdx.x) * 4;
  f32x4 v = *(const f32x4*)&bias[i & 511];
  const f32x4 rr = *(const f32x4*)&res[i];
  v += rr;
  for (int s = 0; s < SK; ++s) v += *(const f32x4*)&P[(size_t)s * 524288 + i];
  *(f32x4*)&out[i] = v;
}

// ---------------------------------------------------------------------------
// reduce split-K + LayerNorm, wave-per-row. Emits f32 x and bf16 LN(x).
// ---------------------------------------------------------------------------
__global__ __launch_bounds__(256) void reduce_ln_sk(
    const float* __restrict__ P, const float* __restrict__ bias,
    const float* __restrict__ res, float* __restrict__ xout,
    const float* __restrict__ w, const float* __restrict__ b,
    __hip_bfloat16* __restrict__ y, int SK) {
  const int row = blockIdx.x * 4 + (threadIdx.x >> 6);
  const int l = threadIdx.x & 63;
  const size_t base = (size_t)row * 512 + l * 8;
  f32x4 v0 = *(const f32x4*)&res[base];
  f32x4 v1 = *(const f32x4*)&res[base + 4];
  v0 += *(const f32x4*)&bias[l * 8];
  v1 += *(const f32x4*)&bias[l * 8 + 4];
  for (int s = 0; s < SK; ++s) {
    v0 += *(const f32x4*)&P[(size_t)s * 524288 + base];
    v1 += *(const f32x4*)&P[(size_t)s * 524288 + base + 4];
  }
  *(f32x4*)&xout[base] = v0;
  *(f32x4*)&xout[base + 4] = v1;
  float s1 = 0.f, s2 = 0.f;
#pragma unroll
  for (int e = 0; e < 4; ++e) {
    s1 += v0[e] + v1[e];
    s2 += v0[e] * v0[e] + v1[e] * v1[e];
  }
#pragma unroll
  for (int d = 1; d < 64; d <<= 1) {
    s1 += __shfl_xor(s1, d);
    s2 += __shfl_xor(s2, d);
  }
  const float mean = s1 * (1.f / 512.f);
  const float var = s2 * (1.f / 512.f) - mean * mean;
  const float rstd = rsqrtf(var + 1e-5f);
  const f32x4 w0 = *(const f32x4*)&w[l * 8], w1 = *(const f32x4*)&w[l * 8 + 4];
  const f32x4 b0 = *(const f32x4*)&b[l * 8], b1 = *(const f32x4*)&b[l * 8 + 4];
  bf16x8 o;
#pragma unroll
  for (int e = 0; e < 4; ++e) {
    o[e] = bfbits((v0[e] - mean) * rstd * w0[e] + b0[e]);
    o[e + 4] = bfbits((v1[e] - mean) * rstd * w1[e] + b1[e]);
  }
  *(bf16x8*)&y[base] = o;
}

// ---------------------------------------------------------------------------
// gemm_geglu: 64x128-tile bf16 GEMM with fused GEGLU epilogue (permuted w1).
// ---------------------------------------------------------------------------
__global__ __launch_bounds__(256, 4) void gemm_geglu(
    const __hip_bfloat16* __restrict__ A, const __hip_bfloat16* __restrict__ Bt,
    __hip_bfloat16* __restrict__ Cb, const float* __restrict__ bias) {
  const int K = 512;
  const int nwg = gridDim.x * gridDim.y;
  const int lid = blockIdx.y * gridDim.x + blockIdx.x;
  const int work = (lid & 7) * (nwg >> 3) + (lid >> 3);
  const int n0 = (work % gridDim.x) * 128;
  const int m0 = (work / gridDim.x) * 64;

  const int t = threadIdx.x;
  const int w = t >> 6, l = t & 63;
  const int lr = l & 15, lk = l >> 4;
  const int wm = (w >> 1) * 32, wn = (w & 1) * 64;
  __shared__ __hip_bfloat16 Al[2][64 * 32];
  __shared__ __hip_bfloat16 Bl[2][128 * 32];

  f32x4 acc[2][4];
  const f32x4 z = {0.f, 0.f, 0.f, 0.f};
#pragma unroll
  for (int i = 0; i < 2; ++i)
#pragma unroll
    for (int j = 0; j < 4; ++j) acc[i][j] = z;

  const int srow = w * 16 + (l >> 2);
  const int scol = ((l & 3) ^ ((l >> 3) & 3)) * 8;
  const __hip_bfloat16* Ag = A + (size_t)(m0 + srow) * K + scol;
  const __hip_bfloat16* Bg = Bt + (size_t)(n0 + srow) * K + scol;

#define STAGE(buf, k0)                                                   \
  {                                                                      \
    load_lds16(Ag + (k0), (char*)Al[buf] + w * 1024);                    \
    load_lds16(Bg + (k0), (char*)Bl[buf] + w * 1024);                    \
    load_lds16(Bg + (size_t)64 * K + (k0), (char*)Bl[buf] + 4096 + w * 1024); \
  }

  STAGE(0, 0);
  __syncthreads();
  int cur = 0;
  const int rs = (lk ^ ((lr >> 1) & 3)) * 16;
  for (int k0 = 0; k0 < K; k0 += 32) {
    if (k0 + 32 < K) STAGE(cur ^ 1, k0 + 32);
    bf16x8 af[2], bfr[4];
#pragma unroll
    for (int i = 0; i < 2; ++i)
      af[i] = *(const bf16x8*)((const char*)Al[cur] + ((wm + i * 16 + lr) * 64 + rs));
#pragma unroll
    for (int j = 0; j < 4; ++j)
      bfr[j] = *(const bf16x8*)((const char*)Bl[cur] + ((wn + j * 16 + lr) * 64 + rs));
#pragma unroll
    for (int i = 0; i < 2; ++i)
#pragma unroll
      for (int j = 0; j < 4; ++j)
        acc[i][j] = __builtin_amdgcn_mfma_f32_16x16x32_bf16(af[i], bfr[j], acc[i][j], 0, 0, 0);
    __syncthreads();
    cur ^= 1;
  }
#undef STAGE

  const int nb = (n0 + wn) >> 1;
  float ba[2], bg[2];
#pragma unroll
  for (int jj = 0; jj < 2; ++jj) {
    ba[jj] = bias[nb + jj * 16 + lr];
    bg[jj] = bias[2048 + nb + jj * 16 + lr];
  }
#pragma unroll
  for (int i = 0; i < 2; ++i) {
    const int row = m0 + wm + i * 16 + lk * 4;
#pragma unroll
    for (int jj = 0; jj < 2; ++jj) {
      const int col = nb + jj * 16 + lr;
#pragma unroll
      for (int r = 0; r < 4; ++r) {
        const float a = acc[i][jj][r] + ba[jj];
        const float g = acc[i][jj + 2][r] + bg[jj];
        const float ge = 0.5f * g * (1.f + erff(g * 0.70710678118f));
        Cb[(size_t)(row + r) * 2048 + col] = __float2bfloat16(a * ge);
      }
    }
  }
}

// ---------------------------------------------------------------------------
// projx (fp8 in AND out for Q/K): 1D grid 2080 = 2048 KV + 32 Q blocks.
// Inputs granule-interleaved fp8. Outputs: K half / Q -> fp8 x4 prescale,
// granule-interleaved per 64B head slice; V half -> bf16 transposed.
// ---------------------------------------------------------------------------
__global__ __launch_bounds__(256, 4) void projx_kernel(
    const unsigned char* __restrict__ ctx8, const unsigned char* __restrict__ wkv8,
    unsigned char* __restrict__ K8, __hip_bfloat16* __restrict__ Vt,
    const unsigned char* __restrict__ xq8, const unsigned char* __restrict__ wq8,
    unsigned char* __restrict__ Q8) {
  const int nwg = gridDim.x;   // 2080, % 8 == 0
  const int lid = blockIdx.x;
  const int work = (lid & 7) * (nwg >> 3) + (lid >> 3);

  const unsigned char *A, *Bt;
  int m0, n0, mode;   // 0 = K half, 1 = V half, 2 = Q
  if (work < 2048) {
    m0 = (work >> 3) * 128;
    n0 = (work & 7) * 128;
    A = ctx8; Bt = wkv8;
    mode = (n0 < 512) ? 0 : 1;
  } else {
    const int idx = work - 2048;
    m0 = (idx >> 2) * 128;
    n0 = (idx & 3) * 128;
    A = xq8; Bt = wq8;
    mode = 2;
  }

  const int t = threadIdx.x;
  const int w = t >> 6, l = t & 63;
  const int lr = l & 15, lk = l >> 4;
  const int wm = (w >> 1) * 64, wn = (w & 1) * 64;
  __shared__ unsigned char Al[2][128 * 64];
  __shared__ unsigned char Bl[2][128 * 64];

  f32x4 acc[4][4];
  const f32x4 z = {0.f, 0.f, 0.f, 0.f};
#pragma unroll
  for (int i = 0; i < 4; ++i)
#pragma unroll
    for (int j = 0; j < 4; ++j) acc[i][j] = z;

  const int srow = w * 16 + (l >> 2);
  const int sc = ((l & 3) ^ ((l >> 3) & 3)) * 16;
  const unsigned char* Ag = A + (size_t)(m0 + srow) * 512 + sc;
  const unsigned char* Bg = Bt + (size_t)(n0 + srow) * 512 + sc;

#define STAGE(buf, kb)                                                   \
  {                                                                      \
    load_lds16(Ag + (kb), (char*)Al[buf] + w * 1024);                    \
    load_lds16(Ag + (size_t)64 * 512 + (kb), (char*)Al[buf] + 4096 + w * 1024); \
    load_lds16(Bg + (kb), (char*)Bl[buf] + w * 1024);                    \
    load_lds16(Bg + (size_t)64 * 512 + (kb), (char*)Bl[buf] + 4096 + w * 1024); \
  }

  STAGE(0, 0);
  __syncthreads();
  int cur = 0;
  const int rs = (lk ^ ((lr >> 1) & 3)) * 16;
  for (int tt = 0; tt < 8; ++tt) {
    if (tt < 7) STAGE(cur ^ 1, (tt + 1) * 64);
    i64 af[2][4], bfr[2][4];
#pragma unroll
    for (int i = 0; i < 4; ++i) {
      const int ar = wm + i * 16 + lr;
      const i64x2 v = *(const i64x2*)((const char*)Al[cur] + ar * 64 + rs);
      af[0][i] = v[0];
      af[1][i] = v[1];
    }
#pragma unroll
    for (int j = 0; j < 4; ++j) {
      const int br = wn + j * 16 + lr;
      const i64x2 v = *(const i64x2*)((const char*)Bl[cur] + br * 64 + rs);
      bfr[0][j] = v[0];
      bfr[1][j] = v[1];
    }
#pragma unroll
    for (int i = 0; i < 4; ++i)
#pragma unroll
      for (int j = 0; j < 4; ++j) {
        acc[i][j] = __builtin_amdgcn_mfma_f32_16x16x32_fp8_fp8(af[0][i], bfr[0][j], acc[i][j], 0, 0, 0);
        acc[i][j] = __builtin_amdgcn_mfma_f32_16x16x32_fp8_fp8(af[1][i], bfr[1][j], acc[i][j], 0, 0, 0);
      }
    __syncthreads();
    cur ^= 1;
  }
#undef STAGE

  const float SCL = 0.0625f;          // undo weight x16
  const float SQK = SCL * 4.f;        // fp8 Q/K prescale x4
  if (mode == 0) {
#pragma unroll
    for (int i = 0; i < 4; ++i) {
      const int row = m0 + wm + i * 16 + lk * 4;
#pragma unroll
      for (int j = 0; j < 4; ++j) {
        const int bp = gpos(n0 + wn + j * 16 + lr);
#pragma unroll
        for (int r = 0; r < 4; ++r)
          K8[(size_t)(row + r) * 512 + bp] = fp8b(acc[i][j][r] * SQK);
      }
    }
  } else if (mode == 1) {
#pragma unroll
    for (int i = 0; i < 4; ++i) {
      const int row0 = m0 + wm + i * 16 + lk * 4;
      const int b = row0 >> 12;
      const int key0 = row0 & 4095;
#pragma unroll
      for (int j = 0; j < 4; ++j) {
        const int c = n0 + wn + j * 16 + lr - 512;
        const int hh = c >> 6, dh = c & 63;
        short4 pk;
        pk.x = bfbits(acc[i][j][0] * SCL);
        pk.y = bfbits(acc[i][j][1] * SCL);
        pk.z = bfbits(acc[i][j][2] * SCL);
        pk.w = bfbits(acc[i][j][3] * SCL);
        *(short4*)&Vt[((size_t)((b * 8 + hh) * 64 + dh) << 12) + key0] = pk;
      }
    }
  } else {
#pragma unroll
    for (int i = 0; i < 4; ++i) {
      const int row = m0 + wm + i * 16 + lk * 4;
#pragma unroll
      for (int j = 0; j < 4; ++j) {
        const int bp = gpos(n0 + wn + j * 16 + lr);
#pragma unroll
        for (int r = 0; r < 4; ++r)
          Q8[(size_t)(row + r) * 512 + bp] = fp8b(acc[i][j][r] * SQK);
      }
    }
  }
}

// ---------------------------------------------------------------------------
// proj (self-attn, bf16): 3-way epilogue by column.
// ---------------------------------------------------------------------------
__global__ __launch_bounds__(256, 4) void proj_kernel(
    const __hip_bfloat16* __restrict__ A, const __hip_bfloat16* __restrict__ Bt,
    __hip_bfloat16* __restrict__ Qb, __hip_bfloat16* __restrict__ Kb,
    __hip_bfloat16* __restrict__ Vt, int qcols, int rpb_shift) {
  const int nwg = gridDim.x * gridDim.y;
  const int lid = blockIdx.y * gridDim.x + blockIdx.x;
  const int work = (lid & 7) * (nwg >> 3) + (lid >> 3);
  const int n0 = (work % gridDim.x) * 128;
  const int m0 = (work / gridDim.x) * 128;
  const int K = 512;

  const int t = threadIdx.x;
  const int w = t >> 6, l = t & 63;
  const int lr = l & 15, lk = l >> 4;
  const int wm = (w >> 1) * 64, wn = (w & 1) * 64;
  __shared__ __hip_bfloat16 Al[2][128 * 32];
  __shared__ __hip_bfloat16 Bl[2][128 * 32];

  f32x4 acc[4][4];
  const f32x4 z = {0.f, 0.f, 0.f, 0.f};
#pragma unroll
  for (int i = 0; i < 4; ++i)
#pragma unroll
    for (int j = 0; j < 4; ++j) acc[i][j] = z;

  const int srow = w * 16 + (l >> 2);
  const int scol = ((l & 3) ^ ((l >> 3) & 3)) * 8;
  const __hip_bfloat16* Ag = A + (size_t)(m0 + srow) * K + scol;
  const __hip_bfloat16* Bg = Bt + (size_t)(n0 + srow) * K + scol;

#define STAGE(buf, k0)                                                   \
  {                                                                      \
    load_lds16(Ag + (k0), (char*)Al[buf] + w * 1024);                    \
    load_lds16(Ag + (size_t)64 * K + (k0), (char*)Al[buf] + 4096 + w * 1024); \
    load_lds16(Bg + (k0), (char*)Bl[buf] + w * 1024);                    \
    load_lds16(Bg + (size_t)64 * K + (k0), (char*)Bl[buf] + 4096 + w * 1024); \
  }

  STAGE(0, 0);
  __syncthreads();
  int cur = 0;
  const int rs = (lk ^ ((lr >> 1) & 3)) * 16;
  for (int k0 = 0; k0 < K; k0 += 32) {
    if (k0 + 32 < K) STAGE(cur ^ 1, k0 + 32);
    bf16x8 af[4], bfr[4];
#pragma unroll
    for (int i = 0; i < 4; ++i)
      af[i] = *(const bf16x8*)((const char*)Al[cur] + ((wm + i * 16 + lr) * 64 + rs));
#pragma unroll
    for (int j = 0; j < 4; ++j)
      bfr[j] = *(const bf16x8*)((const char*)Bl[cur] + ((wn + j * 16 + lr) * 64 + rs));
#pragma unroll
    for (int i = 0; i < 4; ++i)
#pragma unroll
      for (int j = 0; j < 4; ++j)
        acc[i][j] = __builtin_amdgcn_mfma_f32_16x16x32_bf16(af[i], bfr[j], acc[i][j], 0, 0, 0);
    __syncthreads();
    cur ^= 1;
  }
#undef STAGE

  if (n0 < qcols) {
#pragma unroll
    for (int i = 0; i < 4; ++i) {
      const int row = m0 + wm + i * 16 + lk * 4;
#pragma unroll
      for (int j = 0; j < 4; ++j) {
        const int col = n0 + wn + j * 16 + lr;
#pragma unroll
        for (int r = 0; r < 4; ++r)
          Qb[(size_t)(row + r) * 512 + col] = __float2bfloat16(acc[i][j][r]);
      }
    }
  } else if (n0 < qcols + 512) {
#pragma unroll
    for (int i = 0; i < 4; ++i) {
      const int row = m0 + wm + i * 16 + lk * 4;
#pragma unroll
      for (int j = 0; j < 4; ++j) {
        const int col = n0 + wn + j * 16 + lr - qcols;
#pragma unroll
        for (int r = 0; r < 4; ++r)
          Kb[(size_t)(row + r) * 512 + col] = __float2bfloat16(acc[i][j][r]);
      }
    }
  } else {
    const int rpb = 1 << rpb_shift;
#pragma unroll
    for (int i = 0; i < 4; ++i) {
      const int row0 = m0 + wm + i * 16 + lk * 4;
      const int b = row0 >> rpb_shift;
      const int key0 = row0 & (rpb - 1);
#pragma unroll
      for (int j = 0; j < 4; ++j) {
        const int c = n0 + wn + j * 16 + lr - qcols - 512;
        const int hh = c >> 6, dh = c & 63;
        short4 pk;
        pk.x = bfbits(acc[i][j][0]);
        pk.y = bfbits(acc[i][j][1]);
        pk.z = bfbits(acc[i][j][2]);
        pk.w = bfbits(acc[i][j][3]);
        *(short4*)&Vt[((size_t)((b * 8 + hh) * 64 + dh) << rpb_shift) + key0] = pk;
      }
    }
  }
}

// ---------------------------------------------------------------------------
// Key-split flash attention, static-max softmax; bf16 partials, f32 row sums.
// QK8=1: Q/K fp8 (granule-interleaved, x4 prescaled), QK^T on fp8 MFMA.
// QK8=0: bf16 path (self-attention). If Od != nullptr (S==1): direct write.
// ---------------------------------------------------------------------------
template <int QK8>
__global__ __launch_bounds__(256) void attn_split_kernel(
    const void* __restrict__ Qp, const void* __restrict__ Kp,
    const __hip_bfloat16* __restrict__ Vt,
    __hip_bfloat16* __restrict__ Opart, float* __restrict__ Lv,
    __hip_bfloat16* __restrict__ Od,
    int chunk, int rows_per_b, int S) {
  const float SC2 = QK8 ? (0.18033688f / 16.f) : 0.18033688f;
  const int h = blockIdx.x, b = blockIdx.y, s = blockIdx.z;
  const int t = threadIdx.x;
  const int w = t >> 6, l = t & 63;
  const int lr = l & 15, lk = l >> 4;
  __shared__ unsigned char Kraw[QK8 ? 4096 : 8192];
  __shared__ __hip_bfloat16 Vl[64 * 64];
  __shared__ __hip_bfloat16 Pl[4][32 * 64];

  // Q fragments
  bf16x8 qf[2][2];
  i64 qf8[2][2];
  if constexpr (QK8) {
    const unsigned char* q8 = (const unsigned char*)Qp;
#pragma unroll
    for (int mf = 0; mf < 2; ++mf) {
      const i64x2 qv = *(const i64x2*)&q8[(size_t)(b * 128 + w * 32 + mf * 16 + lr) * 512 +
                                          h * 64 + lk * 16];
      qf8[mf][0] = qv[0];
      qf8[mf][1] = qv[1];
    }
  } else {
    const __hip_bfloat16* Q = (const __hip_bfloat16*)Qp;
#pragma unroll
    for (int mf = 0; mf < 2; ++mf)
#pragma unroll
      for (int kf = 0; kf < 2; ++kf)
        qf[mf][kf] = *(const bf16x8*)&Q[(size_t)(b * 128 + w * 32 + mf * 16 + lr) * 512 +
                                        h * 64 + kf * 32 + lk * 8];
  }

  f32x4 o[2][4];
  const f32x4 z = {0.f, 0.f, 0.f, 0.f};
#pragma unroll
  for (int mf = 0; mf < 2; ++mf)
#pragma unroll
    for (int nf = 0; nf < 4; ++nf) o[mf][nf] = z;
  float lsum[2][4];
#pragma unroll
  for (int mf = 0; mf < 2; ++mf)
#pragma unroll
    for (int r = 0; r < 4; ++r) lsum[mf][r] = 0.f;

  const __hip_bfloat16* vtb = Vt + (size_t)(b * 8 + h) * 64 * rows_per_b;
  char* pw = (char*)Pl[w];
  const int srow = l >> 3;
  const int sslot = (l & 7) ^ srow;
  const int jend = s * chunk + chunk;

  for (int j0 = s * chunk; j0 < jend; j0 += 64) {
    __syncthreads();
    if constexpr (QK8) {
      // K fp8 tile: 64 rows x 64B; thread t covers row t>>2, lds slot t&3.
      const unsigned char* k8b = (const unsigned char*)Kp + (size_t)b * rows_per_b * 512;
      const int kr = t >> 2, kslot = t & 3;
      const int src = kslot ^ ((kr >> 1) & 3);
      load_lds16(&k8b[(size_t)(j0 + kr) * 512 + h * 64 + src * 16], (char*)Kraw + t * 16);
#pragma unroll
      for (int p = 0; p < 2; ++p) {
        const int row = p * 32 + w * 8 + srow;
        load_lds16(&vtb[(size_t)row * rows_per_b + j0 + sslot * 8],
                   (char*)Vl + p * 4096 + w * 1024);
      }
    } else {
      const __hip_bfloat16* kvb = (const __hip_bfloat16*)Kp + (size_t)b * rows_per_b * 512;
#pragma unroll
      for (int p = 0; p < 2; ++p) {
        const int row = p * 32 + w * 8 + srow;
        load_lds16(&kvb[(size_t)(j0 + row) * 512 + h * 64 + sslot * 8],
                   (char*)Kraw + p * 4096 + w * 1024);
        load_lds16(&vtb[(size_t)row * rows_per_b + j0 + sslot * 8],
                   (char*)Vl + p * 4096 + w * 1024);
      }
    }
    __syncthreads();

    f32x4 sc[2][4];
#pragma unroll
    for (int mf = 0; mf < 2; ++mf)
#pragma unroll
      for (int nf = 0; nf < 4; ++nf) sc[mf][nf] = z;
    __builtin_amdgcn_s_setprio(1);
    if constexpr (QK8) {
      const int rs8 = (lk ^ ((lr >> 1) & 3)) * 16;
#pragma unroll
      for (int nf = 0; nf < 4; ++nf) {
        const int key = nf * 16 + lr;
        const i64x2 kv = *(const i64x2*)((const char*)Kraw + key * 64 + rs8);
#pragma unroll
        for (int mf = 0; mf < 2; ++mf) {
          sc[mf][nf] = __builtin_amdgcn_mfma_f32_16x16x32_fp8_fp8(qf8[mf][0], kv[0], sc[mf][nf], 0, 0, 0);
          sc[mf][nf] = __builtin_amdgcn_mfma_f32_16x16x32_fp8_fp8(qf8[mf][1], kv[1], sc[mf][nf], 0, 0, 0);
        }
      }
    } else {
#pragma unroll
      for (int kf = 0; kf < 2; ++kf) {
        bf16x8 kb[4];
#pragma unroll
        for (int nf = 0; nf < 4; ++nf) {
          const int key = nf * 16 + lr;
          kb[nf] = *(const bf16x8*)((const char*)Kraw +
                    (key * 128 + (((kf * 4 + lk) ^ (key & 7)) * 16)));
        }
#pragma unroll
        for (int mf = 0; mf < 2; ++mf)
#pragma unroll
          for (int nf = 0; nf < 4; ++nf)
            sc[mf][nf] = __builtin_amdgcn_mfma_f32_16x16x32_bf16(qf[mf][kf], kb[nf], sc[mf][nf], 0, 0, 0);
      }
    }
    __builtin_amdgcn_s_setprio(0);

#pragma unroll
    for (int mf = 0; mf < 2; ++mf)
#pragma unroll
      for (int nf = 0; nf < 4; ++nf)
#pragma unroll
        for (int r = 0; r < 4; ++r) {
          const float p = exp2f(sc[mf][nf][r] * SC2);
          sc[mf][nf][r] = p;
          lsum[mf][r] += p;
        }

#pragma unroll
    for (int mf = 0; mf < 2; ++mf)
#pragma unroll
      for (int r = 0; r < 4; ++r) {
        const int prow = mf * 16 + lk * 4 + r;
#pragma unroll
        for (int nf = 0; nf < 4; ++nf) {
          const int pcol = nf * 16 + lr;
          *(__hip_bfloat16*)(pw + ((prow * 128 + pcol * 2) ^ ((prow & 7) << 4))) =
              __float2bfloat16(sc[mf][nf][r]);
        }
      }

    __builtin_amdgcn_s_setprio(1);
#pragma unroll
    for (int kf = 0; kf < 2; ++kf) {
      bf16x8 pa[2], vb[4];
#pragma unroll
      for (int mf = 0; mf < 2; ++mf) {
        const int prow = mf * 16 + lr;
        pa[mf] = *(const bf16x8*)(pw + ((prow * 128 + (kf * 4 + lk) * 16) ^ ((prow & 7) << 4)));
      }
#pragma unroll
      for (int nf = 0; nf < 4; ++nf) {
        const int dh = nf * 16 + lr;
        vb[nf] = *(const bf16x8*)((char*)Vl +
                  (dh * 128 + (((kf * 4 + lk) ^ (dh & 7)) * 16)));
      }
#pragma unroll
      for (int mf = 0; mf < 2; ++mf)
#pragma unroll
        for (int nf = 0; nf < 4; ++nf)
          o[mf][nf] = __builtin_amdgcn_mfma_f32_16x16x32_bf16(pa[mf], vb[nf], o[mf][nf], 0, 0, 0);
    }
    __builtin_amdgcn_s_setprio(0);
  }

  const int part = (b * 8 + h) * S + s;
  __hip_bfloat16* op = Opart + (size_t)part * 8192;
#pragma unroll
  for (int mf = 0; mf < 2; ++mf)
#pragma unroll
    for (int r = 0; r < 4; ++r) {
      float ls = lsum[mf][r];
      ls += __shfl_xor(ls, 1);
      ls += __shfl_xor(ls, 2);
      ls += __shfl_xor(ls, 4);
      ls += __shfl_xor(ls, 8);
      const int row = w * 32 + mf * 16 + lk * 4 + r;
      if (Od) {
        const float inv = 1.f / ls;
#pragma unroll
        for (int nf = 0; nf < 4; ++nf)
          Od[(size_t)(b * 128 + row) * 512 + h * 64 + nf * 16 + lr] =
              __float2bfloat16(o[mf][nf][r] * inv);
      } else {
#pragma unroll
        for (int nf = 0; nf < 4; ++nf)
          op[(size_t)row * 64 + nf * 16 + lr] = __float2bfloat16(o[mf][nf][r]);
        if (lr == 0) Lv[(size_t)part * 128 + row] = ls;
      }
    }
}

// combine (vectorized): thread t handles cols 2t, 2t+1 of its row.
__global__ __launch_bounds__(256) void attn_combine_kernel(
    const __hip_bfloat16* __restrict__ Opart, const float* __restrict__ Lv,
    __hip_bfloat16* __restrict__ O, int S) {
  const int row = blockIdx.x;
  const int b = row >> 7, i = row & 127;
  const int t = threadIdx.x;
  const int h = t >> 5, dh0 = (t * 2) & 63;
  const int pbase = (b * 8 + h) * S;
  float L = 0.f, v0 = 0.f, v1 = 0.f;
  for (int s = 0; s < S; ++s) {
    L += Lv[(size_t)(pbase + s) * 128 + i];
    const __hip_bfloat16* p = &Opart[((size_t)(pbase + s) * 128 + i) * 64 + dh0];
    const ushort2 u = *(const ushort2*)p;
    const unsigned int b0 = (unsigned int)u.x << 16, b1 = (unsigned int)u.y << 16;
    v0 += *(const float*)&b0;
    v1 += *(const float*)&b1;
  }
  const float inv = 1.f / L;
  ushort2 out;
  out.x = (unsigned short)bfbits(v0 * inv);
  out.y = (unsigned short)bfbits(v1 * inv);
  *(ushort2*)&O[(size_t)row * 512 + t * 2] = out;
}

// ---------------------------------------------------------------------------
// wave-per-row LayerNorm -> fp8, granule-interleaved store.
// ---------------------------------------------------------------------------
DEVI void ln_wave_q(const float* __restrict__ x, const float* __restrict__ w,
                    const float* __restrict__ bb, unsigned char* __restrict__ y,
                    int row) {
  const int l = threadIdx.x & 63;
  const size_t base = (size_t)row * 512 + l * 8;
  const f32x4 v0 = *(const f32x4*)&x[base];
  const f32x4 v1 = *(const f32x4*)&x[base + 4];
  float s = 0.f, sq = 0.f;
#pragma unroll
  for (int e = 0; e < 4; ++e) {
    s += v0[e] + v1[e];
    sq += v0[e] * v0[e] + v1[e] * v1[e];
  }
#pragma unroll
  for (int d = 1; d < 64; d <<= 1) {
    s += __shfl_xor(s, d);
    sq += __shfl_xor(sq, d);
  }
  const float mean = s * (1.f / 512.f);
  const float var = sq * (1.f / 512.f) - mean * mean;
  const float rstd = rsqrtf(var + 1e-5f);
  const f32x4 w0 = *(const f32x4*)&w[l * 8], w1 = *(const f32x4*)&w[l * 8 + 4];
  const f32x4 b0 = *(const f32x4*)&bb[l * 8], b1 = *(const f32x4*)&bb[l * 8 + 4];
  float yv[8];
#pragma unroll
  for (int e = 0; e < 4; ++e) {
    yv[e] = (v0[e] - mean) * rstd * w0[e] + b0[e];
    yv[e + 4] = (v1[e] - mean) * rstd * w1[e] + b1[e];
  }
  uint2 pk;
  pk.x = fp8pk2(yv[0], yv[1]) | (fp8pk2(yv[2], yv[3]) << 16);
  pk.y = fp8pk2(yv[4], yv[5]) | (fp8pk2(yv[6], yv[7]) << 16);
  const int gg = l & 7;
  const size_t wb = (size_t)row * 512 + (l >> 3) * 64 +
                    ((gg & 3) * 2 + (gg >> 2)) * 8;
  *(uint2*)&y[wb] = pk;
}

// ---------------------------------------------------------------------------
// prep: weight-convert (blocks 0..8191; w1 PERMUTED; set-0 wq/wkv -> fp8 x16,
// k-granule-interleaved) + wave-per-row LNs -> fp8 (blocks 8192+).
// ---------------------------------------------------------------------------
struct WcvtDesc { const float* src[10]; __hip_bfloat16* dst[10]; };

__global__ __launch_bounds__(256) void prep_kernel(
    WcvtDesc d, unsigned char* __restrict__ wq8, unsigned char* __restrict__ wkv8,
    const float* __restrict__ lat, const float* __restrict__ lw,
    const float* __restrict__ lb, unsigned char* __restrict__ xq8,
    const float* __restrict__ ctx, const float* __restrict__ cw,
    const float* __restrict__ cb, unsigned char* __restrict__ cn8) {
  if (blockIdx.x >= 8192) {
    const int row = (blockIdx.x - 8192) * 4 + (threadIdx.x >> 6);
    if (row < 1024)
      ln_wave_q(lat, lw, lb, xq8, row);
    else
      ln_wave_q(ctx, cw, cb, cn8, row - 1024);
    return;
  }
  int tile = blockIdx.x;
  const int set = tile >> 12;
  tile &= 4095;
  int wi0, K, N, base;
  if (tile < 256)       { wi0 = 0; K = 512;  N = 512;  base = 0; }
  else if (tile < 768)  { wi0 = 1; K = 512;  N = 1024; base = 256; }
  else if (tile < 1024) { wi0 = 2; K = 512;  N = 512;  base = 768; }
  else if (tile < 3072) { wi0 = 3; K = 512;  N = 4096; base = 1024; }
  else                  { wi0 = 4; K = 2048; N = 512;  base = 3072; }
  const bool permute = (wi0 == 3);
  const bool tofp8 = (set == 0 && wi0 < 2);
  const int wi = wi0 + set * 5;
  const int rel = tile - base;
  const int ntx = N >> 5;
  const int n0 = (rel % ntx) * 32, k0 = (rel / ntx) * 32;
  const int sn0 = permute ? (((n0 >> 6) << 5) + ((n0 & 32) ? 2048 : 0)) : n0;
  const float* W = d.src[wi];
  __shared__ float tl[32][33];
  const int tx = threadIdx.x & 31, ty = threadIdx.x >> 5;
#pragma unroll
  for (int j = 0; j < 4; ++j)
    tl[ty + j * 8][tx] = W[(size_t)(k0 + ty + j * 8) * N + sn0 + tx];
  __syncthreads();
  if (tofp8) {
    unsigned char* Wq = (wi0 == 0) ? wq8 : wkv8;
    const int k = k0 + tx;
    const int gg = (k >> 3) & 7;
    const int kp = (k & ~63) + ((gg & 3) * 2 + (gg >> 2)) * 8 + (k & 7);
#pragma unroll
    for (int j = 0; j < 4; ++j)
      Wq[(size_t)(n0 + ty + j * 8) * 512 + kp] = fp8b(tl[tx][ty + j * 8] * 16.f);
  } else {
    __hip_bfloat16* Wt = d.dst[wi];
#pragma unroll
    for (int j = 0; j < 4; ++j)
      Wt[(size_t)(n0 + ty + j * 8) * K + k0 + tx] = __float2bfloat16(tl[tx][ty + j * 8]);
  }
}

// ---------------------------------------------------------------------------
extern "C" void kernel_launch(void* const* d_in, const int* in_sizes, int n_in,
                              void* d_out, int out_size, void* d_ws, size_t ws_size,
                              hipStream_t stream) {
  (void)in_sizes; (void)n_in; (void)out_size; (void)ws_size;
  const float* context = (const float*)d_in[0];
  const float* latents = (const float*)d_in[1];
  const float* ca_ln_w = (const float*)d_in[2];
  const float* ca_ln_b = (const float*)d_in[3];
  const float* ca_lnc_w = (const float*)d_in[4];
  const float* ca_lnc_b = (const float*)d_in[5];
  const float* ca_wq = (const float*)d_in[6];
  const float* ca_wkv = (const float*)d_in[7];
  const float* ca_wo = (const float*)d_in[8];
  const float* ca_bo = (const float*)d_in[9];
  const float* cf_ln_w = (const float*)d_in[10];
  const float* cf_ln_b = (const float*)d_in[11];
  const float* cf_w1 = (const float*)d_in[12];
  const float* cf_b1 = (const float*)d_in[13];
  const float* cf_w2 = (const float*)d_in[14];
  const float* cf_b2 = (const float*)d_in[15];
  const float* sa_ln_w = (const float*)d_in[16];
  const float* sa_ln_b = (const float*)d_in[17];
  const float* sa_wq = (const float*)d_in[18];
  const float* sa_wkv = (const float*)d_in[19];
  const float* sa_wo = (const float*)d_in[20];
  const float* sa_bo = (const float*)d_in[21];
  const float* lf_ln_w = (const float*)d_in[22];
  const float* lf_ln_b = (const float*)d_in[23];
  const float* lf_w1 = (const float*)d_in[24];
  const float* lf_b1 = (const float*)d_in[25];
  const float* lf_w2 = (const float*)d_in[26];
  const float* lf_b2 = (const float*)d_in[27];

  typedef __hip_bfloat16 bf;
  char* ws = (char*)d_ws;
  size_t off = 0;
  auto alloc = [&](size_t bytes) -> void* {
    void* p = ws + off;
    off += (bytes + 255) & ~(size_t)255;
    return p;
  };
  bf* wq1t = (bf*)alloc((size_t)512 * 512 * 2);     // unused (fp8 path)
  bf* wkv1t = (bf*)alloc((size_t)1024 * 512 * 2);   // unused (fp8 path)
  bf* wo1t = (bf*)alloc((size_t)512 * 512 * 2);
  bf* w1ct = (bf*)alloc((size_t)4096 * 512 * 2);
  bf* w2ct = (bf*)alloc((size_t)512 * 2048 * 2);
  bf* wq2t = (bf*)alloc((size_t)512 * 512 * 2);
  bf* wkv2t = (bf*)alloc((size_t)1024 * 512 * 2);
  bf* wo2t = (bf*)alloc((size_t)512 * 512 * 2);
  bf* w1lt = (bf*)alloc((size_t)4096 * 512 * 2);
  bf* w2lt = (bf*)alloc((size_t)512 * 2048 * 2);
  unsigned char* wq8 = (unsigned char*)alloc((size_t)512 * 512);
  unsigned char* wkv8 = (unsigned char*)alloc((size_t)1024 * 512);
  unsigned char* cn8 = (unsigned char*)alloc((size_t)32768 * 512);   // 16.8 MB
  unsigned char* xq8 = (unsigned char*)alloc((size_t)1024 * 512);
  unsigned char* k8 = (unsigned char*)alloc((size_t)32768 * 512);    // cross K fp8
  unsigned char* q8 = (unsigned char*)alloc((size_t)1024 * 512);     // cross Q fp8
  bf* cn = (bf*)alloc((size_t)32768 * 512 * 2);     // reuse region (33.5 MB)
  bf* vt = (bf*)alloc((size_t)64 * 64 * 4096 * 2);  // cross V^T
  bf* kb2 = (bf*)alloc((size_t)1024 * 512 * 2);     // self K
  bf* vt2 = (bf*)alloc((size_t)64 * 64 * 128 * 2);  // self V^T
  float* lv = (float*)alloc((size_t)1024 * 128 * 4);
  float* skq = (float*)alloc((size_t)4 * 1024 * 512 * 4);
  bf* xnb = (bf*)alloc((size_t)1024 * 512 * 2);
  bf* aob = (bf*)alloc((size_t)1024 * 512 * 2);
  bf* q2b = (bf*)alloc((size_t)1024 * 512 * 2);
  bf* ao2b = (bf*)alloc((size_t)1024 * 512 * 2);
  float* x1 = (float*)alloc((size_t)1024 * 512 * 4);
  float* x2 = (float*)alloc((size_t)1024 * 512 * 4);
  float* x3 = (float*)alloc((size_t)1024 * 512 * 4);
  bf* x2n = (bf*)alloc((size_t)1024 * 512 * 2);
  bf* x3n = (bf*)alloc((size_t)1024 * 512 * 2);
  // cn region time-disjoint reuse:
  bf* opart = cn;                                  // attn bf16 partials (16.8 MB)
  float* skp = (float*)cn;                         // FFN-down SK=8 partials (16.8 MB)
  bf* agb = (bf*)((char*)cn + 17 * 1024 * 1024);   // GEGLU out (4.2 MB)

  WcvtDesc wd;
  wd.src[0] = ca_wq;  wd.dst[0] = wq1t;
  wd.src[1] = ca_wkv; wd.dst[1] = wkv1t;
  wd.src[2] = ca_wo;  wd.dst[2] = wo1t;
  wd.src[3] = cf_w1;  wd.dst[3] = w1ct;
  wd.src[4] = cf_w2;  wd.dst[4] = w2ct;
  wd.src[5] = sa_wq;  wd.dst[5] = wq2t;
  wd.src[6] = sa_wkv; wd.dst[6] = wkv2t;
  wd.src[7] = sa_wo;  wd.dst[7] = wo2t;
  wd.src[8] = lf_w1;  wd.dst[8] = w1lt;
  wd.src[9] = lf_w2;  wd.dst[9] = w2lt;

  // --- prep: weight convert (+fp8 cross wq/wkv) + wave-per-row LNs -> fp8 ---
  prep_kernel<<<8192 + 8448, 256, 0, stream>>>(
      wd, wq8, wkv8, latents, ca_ln_w, ca_ln_b, xq8,
      context, ca_lnc_w, ca_lnc_b, cn8);

  // --- sublayer 1: cross attention (fp8 Q/K end-to-end) ---
  projx_kernel<<<2080, 256, 0, stream>>>(cn8, wkv8, k8, vt, xq8, wq8, q8);
  attn_split_kernel<1><<<dim3(8, 8, 16), 256, 0, stream>>>(q8, k8, vt, opart, lv, nullptr, 256, 4096, 16);
  attn_combine_kernel<<<1024, 256, 0, stream>>>(opart, lv, aob, 16);
  gemm_sk<<<dim3(4, 8, 4), 256, 0, stream>>>(aob, wo1t, skq, 1024, 512, 512);
  reduce_ln_sk<<<256, 256, 0, stream>>>(skq, ca_bo, latents, x1, cf_ln_w, cf_ln_b, xnb, 4);

  // --- sublayer 2: cross FFN (GEGLU fused up-proj, SK=8 down-proj) ---
  gemm_geglu<<<dim3(32, 16), 256, 0, stream>>>(xnb, w1ct, agb, cf_b1);
  gemm_sk<<<dim3(4, 8, 8), 256, 0, stream>>>(agb, w2ct, skp, 1024, 512, 2048);
  reduce_ln_sk<<<256, 256, 0, stream>>>(skp, cf_b2, x1, x2, sa_ln_w, sa_ln_b, x2n, 8);

  // --- sublayer 3: latent self-attention (bf16, merged QKV, direct write) ---
  proj_kernel<<<dim3(12, 8), 256, 0, stream>>>(x2n, wq2t, q2b, kb2, vt2, 512, 7);
  attn_split_kernel<0><<<dim3(8, 8, 1), 256, 0, stream>>>(q2b, kb2, vt2, nullptr, nullptr, ao2b, 128, 128, 1);
  gemm_sk<<<dim3(4, 8, 4), 256, 0, stream>>>(ao2b, wo2t, skq, 1024, 512, 512);
  reduce_ln_sk<<<256, 256, 0, stream>>>(skq, sa_bo, x2, x3, lf_ln_w, lf_ln_b, x3n, 4);

  // --- sublayer 4: latent FFN (GEGLU fused up-proj, SK=8 down-proj) ---
  gemm_geglu<<<dim3(32, 16), 256, 0, stream>>>(x3n, w1lt, agb, lf_b1);
  gemm_sk<<<dim3(4, 8, 8), 256, 0, stream>>>(agb, w2lt, skp, 1024, 512, 2048);
  reduce_sk<<<512, 256, 0, stream>>>(skp, lf_b2, x3, (float*)d_out, 8);
}